// Round 4
// baseline (1431.522 us; speedup 1.0000x reference)
//
#include <hip/hip_runtime.h>
#include <hip/hip_bf16.h>
#include <cstdint>

typedef __hip_bfloat16 bf16;
typedef unsigned short u16;
typedef unsigned int u32;
typedef __attribute__((ext_vector_type(8))) short short8;
typedef __attribute__((ext_vector_type(4))) float f32x4;

__device__ __forceinline__ float tofloat(float x){ return x; }
__device__ __forceinline__ float tofloat(bf16 x){ return __bfloat162float(x); }
__device__ __forceinline__ float b2f(u16 a){ return __uint_as_float(((unsigned)a) << 16); }
__device__ __forceinline__ u16 f2b(float f){           // round-to-nearest-even
    unsigned u = __float_as_uint(f);
    return (u16)((u + 0x7FFFu + ((u >> 16) & 1u)) >> 16);
}
__device__ __forceinline__ void storec(float* p, float v){ *p = v; }
__device__ __forceinline__ void storec(u16* p, float v){ *p = f2b(v); }

static inline int divup(long a, long b){ return (int)((a + b - 1) / b); }

#define NBLK_STATS 256

// ---------------- input dtype detection -------------------------------------
__global__ void zero_int(int* p){ *p = 0; }

__global__ void detect_f32(const u16* __restrict__ h, long n, int* flag)
{
    long i = (long)blockIdx.x * blockDim.x + threadIdx.x;
    long st = (long)gridDim.x * blockDim.x;
    int c = 0;
    for (; i < n; i += st)
        if (((h[i] >> 7) & 0xFF) == 0xFF) c++;
    if (c) atomicAdd(flag, c);
}

// convert all weights: fp32 pool + bf16 pool in one launch
struct ConvTab { const void* src[14]; float* dst[14]; u16* dstB[14]; int n[14]; };

__global__ void conv_all(ConvTab t, const int* __restrict__ flagp)
{
    bool f32 = (*flagp != 0);
    int seg = blockIdx.y;
    const void* s = t.src[seg];
    float* d = t.dst[seg];
    u16*   dB = t.dstB[seg];
    int n = t.n[seg];
    long i = (long)blockIdx.x * blockDim.x + threadIdx.x;
    long st = (long)gridDim.x * blockDim.x;
    for (; i < n; i += st) {
        float v = f32 ? ((const float*)s)[i] : tofloat(((const bf16*)s)[i]);
        d[i] = v; dB[i] = f2b(v);
    }
}

__global__ void conv_in(const void* __restrict__ src, float* __restrict__ dst,
                        long n, const int* __restrict__ flagp)
{
    bool f32 = (*flagp != 0);
    long i = (long)blockIdx.x * blockDim.x + threadIdx.x;
    long st = (long)gridDim.x * blockDim.x;
    for (; i < n; i += st)
        dst[i] = f32 ? ((const float*)src)[i] : tofloat(((const bf16*)src)[i]);
}

__global__ void conv_dual_b16(const void* __restrict__ src, u16* __restrict__ dst,
                              long n, const int* __restrict__ flagp)
{
    bool f32 = (*flagp != 0);
    long i = (long)blockIdx.x * blockDim.x + threadIdx.x;
    long st = (long)gridDim.x * blockDim.x;
    for (; i < n; i += st)
        dst[i] = f32 ? f2b(((const float*)src)[i]) : ((const u16*)src)[i];
}

__global__ void conv_f32_b16(const float* __restrict__ src, u16* __restrict__ dst, long n)
{
    long i = (long)blockIdx.x * blockDim.x + threadIdx.x;
    long st = (long)gridDim.x * blockDim.x;
    for (; i < n; i += st) dst[i] = f2b(src[i]);
}

// convert mol_x fp32 -> bf16 copy (only when input is fp32); vectorized x4
__global__ void conv_molx(const float* __restrict__ src, u16* __restrict__ dst,
                          long n4, const int* __restrict__ flagp)
{
    if (*flagp == 0) return;   // input already bf16; agg reads original
    long i = (long)blockIdx.x * blockDim.x + threadIdx.x;
    long st = (long)gridDim.x * blockDim.x;
    for (; i < n4; i += st) {
        float4 v = ((const float4*)src)[i];
        ushort4 o;
        o.x = f2b(v.x); o.y = f2b(v.y); o.z = f2b(v.z); o.w = f2b(v.w);
        ((ushort4*)dst)[i] = o;
    }
}

// ---------------- CSR edge flattening ---------------------------------------
// ebM[j] = {src, bits(en)}
__global__ void flatten_mol(const int* __restrict__ bins, const int* __restrict__ src,
                            const float* __restrict__ en, long E, int2* __restrict__ out)
{
    long i = (long)blockIdx.x * blockDim.x + threadIdx.x;
    long st = (long)gridDim.x * blockDim.x;
    for (; i < E; i += st) {
        int e = bins[i];
        out[i] = make_int2(src[e], __float_as_int(en[e]));
    }
}

// ebK[j] = {(r<<16)|src, bits(en)}  (src < 65536, r < 8)
__global__ void flatten_kg(const int* __restrict__ bins, const int* __restrict__ src,
                           const int* __restrict__ et, const float* __restrict__ en,
                           long E, int2* __restrict__ out)
{
    long i = (long)blockIdx.x * blockDim.x + threadIdx.x;
    long st = (long)gridDim.x * blockDim.x;
    for (; i < E; i += st) {
        int e = bins[i];
        out[i] = make_int2((et[e] << 16) | src[e], __float_as_int(en[e]));
    }
}

// ---------------- MFMA GEMM: C[M,N] = A[M,K] @ B[K,N], bf16 in, fp32 acc ----
template<typename TC>
__global__ __launch_bounds__(256)
void gemm_mfma(const u16* __restrict__ A, int lda,
               const u16* __restrict__ B, int ldb,
               TC* __restrict__ C, int ldc,
               int M, int N, int K, long sB, long sC)
{
    __shared__ __align__(16) u16 As[64][40];   // [m][k], stride 80 B
    __shared__ __align__(16) u16 Bs[64][40];   // [n][k] (transposed)
    const u16* Bp = B + (long)blockIdx.z * sB;
    TC*        Cp = C + (long)blockIdx.z * sC;
    const int tid = threadIdx.x;
    const int lane = tid & 63, wave = tid >> 6;
    const int l15 = lane & 15, quad = lane >> 4;
    const int wm = (wave & 1) * 32, wn = (wave >> 1) * 32;
    const int row0 = blockIdx.x * 64, col0 = blockIdx.y * 64;
    const int arow = tid >> 2, ak = (tid & 3) * 8;
    const int bk = tid >> 3,  bn = (tid & 7) * 8;

    f32x4 acc[2][2];
#pragma unroll
    for (int i = 0; i < 2; i++)
#pragma unroll
        for (int j = 0; j < 2; j++)
#pragma unroll
            for (int r = 0; r < 4; r++) acc[i][j][r] = 0.f;

    for (int k0 = 0; k0 < K; k0 += 32) {
        {   // stage A: 64 rows x 32 k
            int r = row0 + arow;
            ushort4 v0 = {0,0,0,0}, v1 = {0,0,0,0};
            if (r < M) {
                const u16* p = A + (long)r * lda + k0 + ak;
                v0 = *(const ushort4*)p;
                v1 = *(const ushort4*)(p + 4);
            }
            *(ushort4*)&As[arow][ak]     = v0;
            *(ushort4*)&As[arow][ak + 4] = v1;
        }
        {   // stage B transposed: Bs[n][k]
            const u16* p = Bp + (long)(k0 + bk) * ldb + col0 + bn;
            ushort4 v0 = *(const ushort4*)p;
            ushort4 v1 = *(const ushort4*)(p + 4);
            Bs[bn + 0][bk] = v0.x; Bs[bn + 1][bk] = v0.y;
            Bs[bn + 2][bk] = v0.z; Bs[bn + 3][bk] = v0.w;
            Bs[bn + 4][bk] = v1.x; Bs[bn + 5][bk] = v1.y;
            Bs[bn + 6][bk] = v1.z; Bs[bn + 7][bk] = v1.w;
        }
        __syncthreads();
        short8 a0 = *(const short8*)&As[wm + l15][quad * 8];
        short8 a1 = *(const short8*)&As[wm + 16 + l15][quad * 8];
        short8 b0 = *(const short8*)&Bs[wn + l15][quad * 8];
        short8 b1 = *(const short8*)&Bs[wn + 16 + l15][quad * 8];
        acc[0][0] = __builtin_amdgcn_mfma_f32_16x16x32_bf16(a0, b0, acc[0][0], 0, 0, 0);
        acc[0][1] = __builtin_amdgcn_mfma_f32_16x16x32_bf16(a0, b1, acc[0][1], 0, 0, 0);
        acc[1][0] = __builtin_amdgcn_mfma_f32_16x16x32_bf16(a1, b0, acc[1][0], 0, 0, 0);
        acc[1][1] = __builtin_amdgcn_mfma_f32_16x16x32_bf16(a1, b1, acc[1][1], 0, 0, 0);
        __syncthreads();
    }
#pragma unroll
    for (int i = 0; i < 2; i++)
#pragma unroll
        for (int j = 0; j < 2; j++)
#pragma unroll
            for (int r = 0; r < 4; r++) {
                int row = row0 + wm + i * 16 + quad * 4 + r;
                int col = col0 + wn + j * 16 + l15;
                if (row < M) storec(&Cp[(long)row * ldc + col], acc[i][j][r]);
            }
}

// ---------------- vector GEMM (fp32, small) ---------------------------------
__global__ __launch_bounds__(256)
void gemm64(const float* __restrict__ A, int lda,
            const float* __restrict__ B, int ldb,
            float* __restrict__ C, int ldc,
            int M, int N, int K)
{
    __shared__ float As[16][68];
    __shared__ float Bs[16][68];
    const int tid = threadIdx.x;
    const int row0 = blockIdx.x * 64, col0 = blockIdx.y * 64;
    float acc[4][4];
#pragma unroll
    for (int i = 0; i < 4; i++)
#pragma unroll
        for (int j = 0; j < 4; j++) acc[i][j] = 0.f;
    const int ar = tid >> 2, ak = (tid & 3) * 4;
    const int bk = tid >> 4, bc = (tid & 15) * 4;
    const int ty4 = (tid >> 4) * 4, tx4 = (tid & 15) * 4;
    for (int k0 = 0; k0 < K; k0 += 16) {
        {
            int row = row0 + ar;
            float4 v = make_float4(0.f, 0.f, 0.f, 0.f);
            if (row < M) v = *(const float4*)(A + (long)row * lda + k0 + ak);
            As[ak + 0][ar] = v.x; As[ak + 1][ar] = v.y;
            As[ak + 2][ar] = v.z; As[ak + 3][ar] = v.w;
        }
        {
            int c = col0 + bc;
            float4 v = make_float4(0.f, 0.f, 0.f, 0.f);
            if (c < N) v = *(const float4*)(B + (long)(k0 + bk) * ldb + c);
            *(float4*)&Bs[bk][bc] = v;
        }
        __syncthreads();
#pragma unroll
        for (int k = 0; k < 16; k++) {
            float4 a = *(const float4*)&As[k][ty4];
            float4 b = *(const float4*)&Bs[k][tx4];
            acc[0][0] += a.x * b.x; acc[0][1] += a.x * b.y; acc[0][2] += a.x * b.z; acc[0][3] += a.x * b.w;
            acc[1][0] += a.y * b.x; acc[1][1] += a.y * b.y; acc[1][2] += a.y * b.z; acc[1][3] += a.y * b.w;
            acc[2][0] += a.z * b.x; acc[2][1] += a.z * b.y; acc[2][2] += a.z * b.z; acc[2][3] += a.z * b.w;
            acc[3][0] += a.w * b.x; acc[3][1] += a.w * b.y; acc[3][2] += a.w * b.z; acc[3][3] += a.w * b.w;
        }
        __syncthreads();
    }
    int c = col0 + tx4;
#pragma unroll
    for (int i = 0; i < 4; i++) {
        int r = row0 + ty4 + i;
        if (r < M && c < N)
            *(float4*)&C[(long)r * ldc + c] =
                make_float4(acc[i][0], acc[i][1], acc[i][2], acc[i][3]);
    }
}

// ---------------- utility / CSR build ---------------------------------------
__global__ void filli(int* p, long n, int v)
{
    long i = (long)blockIdx.x * blockDim.x + threadIdx.x;
    long st = (long)gridDim.x * blockDim.x;
    for (; i < n; i += st) p[i] = v;
}

__global__ void hist_int(const int* __restrict__ key, long n, int* __restrict__ h)
{
    long i = (long)blockIdx.x * blockDim.x + threadIdx.x;
    long st = (long)gridDim.x * blockDim.x;
    for (; i < n; i += st) atomicAdd(&h[key[i]], 1);
}

__global__ __launch_bounds__(1024)
void scan_bsum(const int* __restrict__ in, int n, int* __restrict__ btot)
{
    __shared__ int sh[1024];
    int tid = threadIdx.x;
    int i0 = blockIdx.x * 4096 + tid * 4;
    int s = 0;
#pragma unroll
    for (int t = 0; t < 4; t++) { int idx = i0 + t; s += (idx < n) ? in[idx] : 0; }
    sh[tid] = s;
    __syncthreads();
    for (int off = 512; off > 0; off >>= 1) {
        if (tid < off) sh[tid] += sh[tid + off];
        __syncthreads();
    }
    if (tid == 0) btot[blockIdx.x] = sh[0];
}

__global__ void scan_tiny(const int* __restrict__ btot, int nb, int* __restrict__ boff)
{
    if (threadIdx.x == 0) {
        int c = 0;
        for (int b = 0; b < nb; b++) { boff[b] = c; c += btot[b]; }
        boff[nb] = c;
    }
}

__global__ __launch_bounds__(1024)
void scan_final(const int* __restrict__ in, int n, const int* __restrict__ boff,
                int nb, int* __restrict__ out)
{
    __shared__ int buf[1024];
    int tid = threadIdx.x;
    int i0 = blockIdx.x * 4096 + tid * 4;
    int v[4]; int s = 0;
#pragma unroll
    for (int t = 0; t < 4; t++) {
        int idx = i0 + t;
        v[t] = (idx < n) ? in[idx] : 0;
        s += v[t];
    }
    buf[tid] = s;
    __syncthreads();
    for (int off = 1; off < 1024; off <<= 1) {
        int t = (tid >= off) ? buf[tid - off] : 0;
        __syncthreads();
        buf[tid] += t;
        __syncthreads();
    }
    int excl = buf[tid] - s + boff[blockIdx.x];
#pragma unroll
    for (int t = 0; t < 4; t++) {
        int idx = i0 + t;
        if (idx < n) out[idx] = excl;
        excl += v[t];
    }
    if (blockIdx.x == 0 && tid == 0) out[n] = boff[nb];
}

__global__ void bin_by(const int* __restrict__ key, long n,
                       const int* __restrict__ off, int* __restrict__ cursor,
                       int* __restrict__ bins)
{
    long i = (long)blockIdx.x * blockDim.x + threadIdx.x;
    long st = (long)gridDim.x * blockDim.x;
    for (; i < n; i += st) {
        int k = key[i];
        int pos = off[k] + atomicAdd(&cursor[k], 1);
        bins[pos] = (int)i;
    }
}

__global__ void dinv_from_deg(const int* __restrict__ deg, float* __restrict__ dinv, long n)
{
    long i = (long)blockIdx.x * blockDim.x + threadIdx.x;
    long st = (long)gridDim.x * blockDim.x;
    for (; i < n; i += st) dinv[i] = rsqrtf((float)(deg[i] + 1));
}

__global__ void kg_cnt(const int* __restrict__ dst, const int* __restrict__ et,
                       long E, int NKG, float* cnt)
{
    long i = (long)blockIdx.x * blockDim.x + threadIdx.x;
    long st = (long)gridDim.x * blockDim.x;
    for (; i < E; i += st) atomicAdd(&cnt[(long)et[i] * NKG + dst[i]], 1.0f);
}

__global__ void kg_enorm(const int* __restrict__ dst, const int* __restrict__ et,
                         const float* __restrict__ cnt, long E, int NKG,
                         float* __restrict__ en)
{
    long i = (long)blockIdx.x * blockDim.x + threadIdx.x;
    long st = (long)gridDim.x * blockDim.x;
    for (; i < E; i += st)
        en[i] = 1.0f / fmaxf(cnt[(long)et[i] * NKG + dst[i]], 1.0f);
}

__global__ void mol_enorm(const int* __restrict__ src, const int* __restrict__ dst,
                          const float* __restrict__ dinv, long E, float* __restrict__ en)
{
    long i = (long)blockIdx.x * blockDim.x + threadIdx.x;
    long st = (long)gridDim.x * blockDim.x;
    for (; i < E; i += st) en[i] = dinv[src[i]] * dinv[dst[i]];
}

// ---------------- batch-norm stats (v2: vectorized, NBLK_STATS blocks) ------
__global__ __launch_bounds__(256)
void colstats_b16_v2(const u16* __restrict__ X, int M, int ld, int c0, int NC,
                     float* __restrict__ p1, float* __restrict__ p2)
{
    __shared__ float sh1[1024], sh2[1024];
    int tid = threadIdx.x;
    int ncg = NC >> 2;                 // col groups of 4
    int cg  = tid & (ncg - 1);
    int rg  = tid / ncg;
    int nrg = 256 / ncg;
    float s0=0,s1=0,s2=0,s3=0, q0=0,q1=0,q2=0,q3=0;
    const u16* base = X + c0 + 4 * cg;
    for (long row = (long)blockIdx.x * nrg + rg; row < M; row += (long)gridDim.x * nrg) {
        ushort4 v = *(const ushort4*)(base + row * (long)ld);
        float f0 = b2f(v.x), f1 = b2f(v.y), f2 = b2f(v.z), f3 = b2f(v.w);
        s0 += f0; q0 += f0 * f0; s1 += f1; q1 += f1 * f1;
        s2 += f2; q2 += f2 * f2; s3 += f3; q3 += f3 * f3;
    }
    float4* S1 = (float4*)sh1; float4* S2 = (float4*)sh2;
    S1[tid] = make_float4(s0, s1, s2, s3);
    S2[tid] = make_float4(q0, q1, q2, q3);
    __syncthreads();
    for (int off = nrg >> 1; off > 0; off >>= 1) {
        if (rg < off) {
            float4 a = S1[tid], b = S1[tid + off * ncg];
            S1[tid] = make_float4(a.x + b.x, a.y + b.y, a.z + b.z, a.w + b.w);
            float4 c = S2[tid], d = S2[tid + off * ncg];
            S2[tid] = make_float4(c.x + d.x, c.y + d.y, c.z + d.z, c.w + d.w);
        }
        __syncthreads();
    }
    if (rg == 0) {
        *(float4*)&p1[(long)blockIdx.x * NC + 4 * cg] = S1[tid];
        *(float4*)&p2[(long)blockIdx.x * NC + 4 * cg] = S2[tid];
    }
}

__global__ __launch_bounds__(256)
void colstats_f32_v2(const float* __restrict__ X, int M, int N,
                     float* __restrict__ p1, float* __restrict__ p2)
{
    __shared__ float sh1[1024], sh2[1024];
    int tid = threadIdx.x;
    int ncg = N >> 2;
    int cg  = tid & (ncg - 1);
    int rg  = tid / ncg;
    int nrg = 256 / ncg;
    float s0=0,s1=0,s2=0,s3=0, q0=0,q1=0,q2=0,q3=0;
    const float* base = X + 4 * cg;
    for (long row = (long)blockIdx.x * nrg + rg; row < M; row += (long)gridDim.x * nrg) {
        float4 v = *(const float4*)(base + row * (long)N);
        s0 += v.x; q0 += v.x * v.x; s1 += v.y; q1 += v.y * v.y;
        s2 += v.z; q2 += v.z * v.z; s3 += v.w; q3 += v.w * v.w;
    }
    float4* S1 = (float4*)sh1; float4* S2 = (float4*)sh2;
    S1[tid] = make_float4(s0, s1, s2, s3);
    S2[tid] = make_float4(q0, q1, q2, q3);
    __syncthreads();
    for (int off = nrg >> 1; off > 0; off >>= 1) {
        if (rg < off) {
            float4 a = S1[tid], b = S1[tid + off * ncg];
            S1[tid] = make_float4(a.x + b.x, a.y + b.y, a.z + b.z, a.w + b.w);
            float4 c = S2[tid], d = S2[tid + off * ncg];
            S2[tid] = make_float4(c.x + d.x, c.y + d.y, c.z + d.z, c.w + d.w);
        }
        __syncthreads();
    }
    if (rg == 0) {
        *(float4*)&p1[(long)blockIdx.x * N + 4 * cg] = S1[tid];
        *(float4*)&p2[(long)blockIdx.x * N + 4 * cg] = S2[tid];
    }
}

__global__ void colstats_reduce_v2(const float* __restrict__ p1, const float* __restrict__ p2,
                                   int nblk, int N, float invM,
                                   float* __restrict__ s1o, float* __restrict__ s2o)
{
    __shared__ float sh1[256], sh2[256];
    int tid = threadIdx.x;
    int col = blockIdx.x * 64 + (tid & 63);
    int seg = tid >> 6;
    float a = 0.f, c = 0.f;
    for (int b = seg; b < nblk; b += 4) {
        a += p1[(long)b * N + col];
        c += p2[(long)b * N + col];
    }
    sh1[tid] = a; sh2[tid] = c;
    __syncthreads();
    if (seg == 0) {
        a = sh1[tid] + sh1[tid + 64] + sh1[tid + 128] + sh1[tid + 192];
        c = sh2[tid] + sh2[tid + 64] + sh2[tid + 128] + sh2[tid + 192];
        float mean = a * invM;
        float var  = fmaxf(c * invM - mean * mean, 0.f);
        s1o[col] = mean;
        s2o[col] = rsqrtf(var + 1e-5f);
    }
}

__global__ void bn_apply(float* X, long total, int mask,
                         const float* __restrict__ s1, const float* __restrict__ s2)
{
    long i = (long)blockIdx.x * blockDim.x + threadIdx.x;
    long st = (long)gridDim.x * blockDim.x;
    for (; i < total; i += st) {
        int j = (int)(i & mask);
        X[i] = fmaxf((X[i] - s1[j]) * s2[j], 0.f);
    }
}

// BN+ReLU, fp32 in place AND bf16 copy
__global__ void bn_apply_dual(float* __restrict__ X, u16* __restrict__ Xb, long total,
                              int mask, const float* __restrict__ s1,
                              const float* __restrict__ s2)
{
    long i = (long)blockIdx.x * blockDim.x + threadIdx.x;
    long st = (long)gridDim.x * blockDim.x;
    for (; i < total; i += st) {
        int j = (int)(i & mask);
        float y = fmaxf((X[i] - s1[j]) * s2[j], 0.f);
        X[i] = y;
        Xb[i] = f2b(y);
    }
}

// BN+ReLU in place on bf16 contiguous [M, NC]; u32 words (2 cols each)
__global__ void bn_apply_b16_v2(u32* __restrict__ X, long n2, int maskHalf,
                                const float* __restrict__ s1, const float* __restrict__ s2)
{
    long i = (long)blockIdx.x * blockDim.x + threadIdx.x;
    long st = (long)gridDim.x * blockDim.x;
    for (; i < n2; i += st) {
        u32 v = X[i];
        int f = (int)(i & maskHalf) * 2;
        float y0 = fmaxf((b2f((u16)(v & 0xFFFF)) - s1[f])     * s2[f],     0.f);
        float y1 = fmaxf((b2f((u16)(v >> 16))    - s1[f + 1]) * s2[f + 1], 0.f);
        X[i] = (u32)f2b(y0) | ((u32)f2b(y1) << 16);
    }
}

// ---------------- CSR aggregation (no atomics) ------------------------------
__global__ __launch_bounds__(256)
void mol_agg_in(const void* __restrict__ Xraw, const u16* __restrict__ Xcvt,
                const int* __restrict__ flagp, const float* __restrict__ dinv,
                const int* __restrict__ off, const int2* __restrict__ eb,
                int NM, u16* __restrict__ out)
{
    const u16* X = (*flagp != 0) ? Xcvt : (const u16*)Xraw;
    int wid  = (int)(((long)blockIdx.x * 256 + threadIdx.x) >> 6);
    int lane = threadIdx.x & 63;
    if (wid >= NM) return;
    float dv = dinv[wid];
    float acc = b2f(X[(long)wid * 64 + lane]) * dv * dv;
    int j = off[wid], j1 = off[wid + 1];
    for (; j + 3 < j1; j += 4) {
        int2 e0 = eb[j], e1 = eb[j + 1], e2 = eb[j + 2], e3 = eb[j + 3];
        float v0 = b2f(X[(long)e0.x * 64 + lane]);
        float v1 = b2f(X[(long)e1.x * 64 + lane]);
        float v2 = b2f(X[(long)e2.x * 64 + lane]);
        float v3 = b2f(X[(long)e3.x * 64 + lane]);
        acc += v0 * __int_as_float(e0.y) + v1 * __int_as_float(e1.y)
             + v2 * __int_as_float(e2.y) + v3 * __int_as_float(e3.y);
    }
    for (; j < j1; j++) {
        int2 e = eb[j];
        acc += b2f(X[(long)e.x * 64 + lane]) * __int_as_float(e.y);
    }
    out[(long)wid * 64 + lane] = f2b(acc);
}

__global__ __launch_bounds__(256)
void mol_agg128(const u16* __restrict__ G, const float* __restrict__ dinv,
                const int* __restrict__ off, const int2* __restrict__ eb,
                int NM, u16* __restrict__ out)
{
    int wid  = (int)(((long)blockIdx.x * 256 + threadIdx.x) >> 6);
    int lane = threadIdx.x & 63;
    if (wid >= NM) return;
    float dv = dinv[wid], dv2 = dv * dv;
    u32 u = *(const u32*)(G + (long)wid * 128 + 2 * lane);
    float a0 = b2f((u16)(u & 0xFFFF)) * dv2;
    float a1 = b2f((u16)(u >> 16)) * dv2;
    int j = off[wid], j1 = off[wid + 1];
    for (; j + 3 < j1; j += 4) {
        int2 e0 = eb[j], e1 = eb[j + 1], e2 = eb[j + 2], e3 = eb[j + 3];
        u32 v0 = *(const u32*)(G + (long)e0.x * 128 + 2 * lane);
        u32 v1 = *(const u32*)(G + (long)e1.x * 128 + 2 * lane);
        u32 v2 = *(const u32*)(G + (long)e2.x * 128 + 2 * lane);
        u32 v3 = *(const u32*)(G + (long)e3.x * 128 + 2 * lane);
        float n0 = __int_as_float(e0.y), n1 = __int_as_float(e1.y);
        float n2 = __int_as_float(e2.y), n3 = __int_as_float(e3.y);
        a0 += b2f((u16)(v0 & 0xFFFF)) * n0 + b2f((u16)(v1 & 0xFFFF)) * n1
            + b2f((u16)(v2 & 0xFFFF)) * n2 + b2f((u16)(v3 & 0xFFFF)) * n3;
        a1 += b2f((u16)(v0 >> 16)) * n0 + b2f((u16)(v1 >> 16)) * n1
            + b2f((u16)(v2 >> 16)) * n2 + b2f((u16)(v3 >> 16)) * n3;
    }
    for (; j < j1; j++) {
        int2 e = eb[j];
        u32 v = *(const u32*)(G + (long)e.x * 128 + 2 * lane);
        float n = __int_as_float(e.y);
        a0 += b2f((u16)(v & 0xFFFF)) * n;
        a1 += b2f((u16)(v >> 16)) * n;
    }
    u32 o = (u32)f2b(a0) | ((u32)f2b(a1) << 16);
    *(u32*)(out + (long)wid * 128 + 2 * lane) = o;
}

// RGCN pre-aggregation in input space: per node, per-relation mean of x_src.
// xin bf16 [NKG,256] (L2-resident); eb[j] = {(r<<16)|src, bits(en)}.
// Output aggx bf16 [NKG, 2304]: cols 0:256 = x row, cols 256+r*256+c = agg_r[c].
__global__ __launch_bounds__(256)
void kg_preagg(const u16* __restrict__ xin, const int* __restrict__ off,
               const int2* __restrict__ eb, int NKG, u16* __restrict__ aggx)
{
    __shared__ float lds[4][8 * 256];     // 32 KB, one 8x256 scratch per wave
    int wav  = threadIdx.x >> 6;
    int lane = threadIdx.x & 63;
    int wid  = blockIdx.x * 4 + wav;
    float* L = lds[wav];
    const int c4 = 4 * lane;
    const float4 z4 = make_float4(0.f, 0.f, 0.f, 0.f);
#pragma unroll
    for (int c = 0; c < 2048; c += 256) *(float4*)&L[c + c4] = z4;
    if (wid >= NKG) return;               // wave-private LDS; no barrier needed
    {
        int j = off[wid], j1 = off[wid + 1];
        for (; j + 1 < j1; j += 2) {
            int2 e0 = eb[j], e1 = eb[j + 1];
            ushort4 v0 = *(const ushort4*)(xin + (long)(e0.x & 0xFFFF) * 256 + c4);
            ushort4 v1 = *(const ushort4*)(xin + (long)(e1.x & 0xFFFF) * 256 + c4);
            float n0 = __int_as_float(e0.y), n1 = __int_as_float(e1.y);
            float* p0 = L + ((e0.x >> 16) << 8) + c4;
            p0[0] += b2f(v0.x) * n0; p0[1] += b2f(v0.y) * n0;
            p0[2] += b2f(v0.z) * n0; p0[3] += b2f(v0.w) * n0;
            float* p1 = L + ((e1.x >> 16) << 8) + c4;
            p1[0] += b2f(v1.x) * n1; p1[1] += b2f(v1.y) * n1;
            p1[2] += b2f(v1.z) * n1; p1[3] += b2f(v1.w) * n1;
        }
        if (j < j1) {
            int2 e = eb[j];
            ushort4 v = *(const ushort4*)(xin + (long)(e.x & 0xFFFF) * 256 + c4);
            float n = __int_as_float(e.y);
            float* p = L + ((e.x >> 16) << 8) + c4;
            p[0] += b2f(v.x) * n; p[1] += b2f(v.y) * n;
            p[2] += b2f(v.z) * n; p[3] += b2f(v.w) * n;
        }
    }
    u16* orow = aggx + (long)wid * 2304;
    *(ushort4*)(orow + c4) = *(const ushort4*)(xin + (long)wid * 256 + c4);
#pragma unroll
    for (int r = 0; r < 8; r++) {
        float* p = L + r * 256 + c4;
        ushort4 o;
        o.x = f2b(p[0]); o.y = f2b(p[1]); o.z = f2b(p[2]); o.w = f2b(p[3]);
        *(ushort4*)(orow + 256 + r * 256 + c4) = o;
    }
}

// mean-pool bf16 chunk [NM,64] with fused BN+ReLU
__global__ __launch_bounds__(256)
void pool_b16(const u16* __restrict__ g, const int* __restrict__ off,
              const int* __restrict__ bins, int ND,
              const float* __restrict__ s1, const float* __restrict__ s2,
              float* __restrict__ gout, int c0)
{
    int wid  = (int)(((long)blockIdx.x * 256 + threadIdx.x) >> 6);
    int lane = threadIdx.x & 63;
    if (wid >= ND) return;
    float m = s1[lane], r = s2[lane];
    int j0 = off[wid], j1 = off[wid + 1];
    float acc = 0.f;
    for (int j = j0; j < j1; j++)
        acc += fmaxf((b2f(g[(long)bins[j] * 64 + lane]) - m) * r, 0.f);
    gout[(long)wid * 256 + c0 + lane] = acc / fmaxf((float)(j1 - j0), 1.0f);
}

// ---------------- attention fusion ------------------------------------------
__global__ void attention_fuse(const float* __restrict__ go, const float* __restrict__ fpv,
                               const float* __restrict__ W1, const float* __restrict__ B1,
                               const float* __restrict__ W2,
                               float* __restrict__ emb, float* __restrict__ beta_out)
{
    int d = blockIdx.x;
    int t = threadIdx.x;
    __shared__ float z[2][256];
    __shared__ float red[128];
    for (int c = t; c < 256; c += 128) {
        z[0][c] = go[(long)d * 256 + c];
        z[1][c] = fpv[(long)d * 256 + c];
    }
    __syncthreads();
    float s[2];
    for (int v = 0; v < 2; v++) {
        float acc = B1[t];
        for (int k = 0; k < 256; k++) acc += z[v][k] * W1[k * 128 + t];
        red[t] = tanhf(acc) * W2[t];
        __syncthreads();
        for (int off = 64; off > 0; off >>= 1) {
            if (t < off) red[t] += red[t + off];
            __syncthreads();
        }
        s[v] = red[0];
        __syncthreads();
    }
    float m = fmaxf(s[0], s[1]);
    float e0 = expf(s[0] - m), e1 = expf(s[1] - m);
    float inv = 1.0f / (e0 + e1);
    float b0 = e0 * inv, b1 = e1 * inv;
    for (int c = t; c < 256; c += 128)
        emb[(long)d * 256 + c] = b0 * z[0][c] + b1 * z[1][c];
    if (t == 0) {
        beta_out[d * 2 + 0] = b0;
        beta_out[d * 2 + 1] = b1;
    }
}

// ---------------- final linear + log_softmax, fused BN on x4 ----------------
__global__ void logits_out_bn(const float* __restrict__ x4,
                              const float* __restrict__ s1, const float* __restrict__ s2,
                              const float* __restrict__ w, const float* __restrict__ b,
                              float* __restrict__ out, int NKG)
{
    int i = blockIdx.x * blockDim.x + threadIdx.x;
    if (i >= NKG) return;
    float a0 = b[0], a1 = b[1];
    for (int k = 0; k < 64; k++) {
        float v = fmaxf((x4[(long)i * 64 + k] - s1[k]) * s2[k], 0.f);
        a0 += v * w[k * 2 + 0];
        a1 += v * w[k * 2 + 1];
    }
    float m = fmaxf(a0, a1);
    float lse = m + logf(expf(a0 - m) + expf(a1 - m));
    out[i * 2 + 0] = a0 - lse;
    out[i * 2 + 1] = a1 - lse;
}

// ============================================================================
extern "C" void kernel_launch(void* const* d_in, const int* in_sizes, int n_in,
                              void* d_out, int out_size, void* d_ws, size_t ws_size,
                              hipStream_t stream)
{
    (void)in_sizes; (void)n_in; (void)out_size; (void)ws_size;
    const int ND = 4096, NM = 131072, NKG = 9510, NGENE = 5414;
    const long EM = 524288, EK = 524288;

    const void* fp_data = d_in[0];
    const void* mol_x   = d_in[1];
    const int*  mol_batch = (const int*)d_in[2];
    const int*  mol_ei  = (const int*)d_in[3];
    const int*  kg_ei   = (const int*)d_in[4];
    const int*  kg_et   = (const int*)d_in[5];

    const int* mol_src = mol_ei;
    const int* mol_dst = mol_ei + EM;
    const int* kg_src  = kg_ei;
    const int* kg_dst  = kg_ei + EK;

    float* out_ls   = (float*)d_out;          // [9510,2] fp32
    float* out_beta = (float*)d_out + 19020;  // [4096,2,1] fp32

    // ---- workspace carve ----
    char* wp = (char*)d_ws;
    auto carve = [&](size_t bytes) { char* p = wp; wp += (bytes + 255) & ~(size_t)255; return p; };
    float* stats = (float*)carve(4096);
    int*   flag  = (int*)carve(256);
    float* dinv  = (float*)carve((size_t)NM * 4);
    float* enM   = (float*)carve((size_t)EM * 4);
    float* enK   = (float*)carve((size_t)EK * 4);
    float* part1 = (float*)carve((size_t)NBLK_STATS * 512 * 4);
    float* part2 = (float*)carve((size_t)NBLK_STATS * 512 * 4);
    int*   sbt   = (int*)carve(256);
    int*   sbo   = (int*)carve(256);
    float* Wpool = (float*)carve((size_t)1630000 * 4);     // fp32 weights
    u16*   WpoolB= (u16*)carve((size_t)1630000 * 2);       // bf16 weights
    float* fpb   = (float*)carve((size_t)ND * 256 * 4);
    float* gout  = (float*)carve((size_t)ND * 256 * 4);
    // zero-span
    char*  z0    = wp;
    float* cntK  = (float*)carve((size_t)8 * NKG * 4);
    int* mdeg = (int*)carve((size_t)NM * 4);
    int* mcur = (int*)carve((size_t)NM * 4);
    int* kdeg = (int*)carve((size_t)NKG * 4);
    int* kcur = (int*)carve((size_t)NKG * 4);
    int* pdeg = (int*)carve((size_t)ND * 4);
    int* pcur = (int*)carve((size_t)ND * 4);
    char*  z1    = wp;
    int* moff = (int*)carve((size_t)(NM + 1) * 4);
    int* mbins= (int*)carve((size_t)EM * 4);
    int* koff = (int*)carve((size_t)(NKG + 1) * 4);
    int* kbins= (int*)carve((size_t)EK * 4);
    int* poff = (int*)carve((size_t)(ND + 1) * 4);
    int* pbins= (int*)carve((size_t)NM * 4);
    char*  REG1  = carve((size_t)NM * 128 * 2);            // 33.6 MB
    char*  REG2  = carve((size_t)NM * 128 * 2);            // 33.6 MB  (contiguous with HB)
    u16*   HB    = (u16*)carve((size_t)NM * 64 * 2);       // 16.8 MB

    // phase views
    float* fp1 = (float*)REG1;                 // fp: [4096,512] f32
    u16*   XB  = (u16*)REG1;                   // mol pre: [NM,64] bf16 converted input
    u16*   G1  = (u16*)REG1;                   // mol: [NM,128] bf16
    // rgcn chain in REG1:
    float* xkg = (float*)REG1;                 // [NKG,256] f32 (emb+gene)
    float* x2  = xkg + (size_t)NKG * 256;      // [NKG,256] f32
    float* x3  = x2  + (size_t)NKG * 256;      // [NKG,128] f32
    float* x4  = x3  + (size_t)NKG * 128;      // [NKG,64]  f32
    u16*   xb  = (u16*)(x4 + (size_t)NKG * 64);// [NKG,256] bf16 (after x4, fits REG1)
    u16*   x2b = (u16*)REG1;                   // [NKG,256] bf16 (overlaps xkg: dead then)
    u16*   Xfb = (u16*)REG2;                   // fp: [4096,1024] bf16
    u16*   G1A = (u16*)REG2;                   // mol: [NM,128] bf16 aggregated
    u16*   AGGX= (u16*)REG2;                   // rgcn: [NKG,2304] bf16 (43.8 MB, REG2+HB)
    u16*   fp1b = HB;                          // fp: [4096,512] bf16
    u16*   Xagg = HB;                          // mol L1: [NM,64] bf16
    // flattened CSR edge tables (aliased; lifetimes verified)
    int2* ebM = (int2*)gout;                   // mol edges; gout written only after dead
    int2* ebK = (int2*)fpb;                    // kg edges; fpb dead after attention_fuse

    // ---- dtype detect + weight conversion (fp32 + bf16 pools) ----
    zero_int<<<1, 1, 0, stream>>>(flag);
    detect_f32<<<1024, 256, 0, stream>>>((const u16*)fp_data, (long)ND * 1024, flag);
    ConvTab tab;
    // NOTE: rg_root before rg_w so [root; W_0..W_7] is contiguous = [2304, N] GEMM B
    const int widx[14] = {6, 8, 10, 12, 14, 15, 16, 19, 18, 22, 21, 24, 26, 27};
    const int wn[14]   = {1024*512, 512*256, 64*128, 128*256, 256*128, 128, 128,
                          256*256, 8*256*256, 256*128, 8*256*128, 128*64, 64*2, 2};
    float* wf[14]; u16* wb[14];
    {
        size_t o = 0;
        for (int i = 0; i < 14; i++) {
            tab.src[i]  = d_in[widx[i]];
            tab.dst[i]  = Wpool + o;
            tab.dstB[i] = WpoolB + o;
            tab.n[i]    = wn[i];
            wf[i] = Wpool + o; wb[i] = WpoolB + o;
            o += (size_t)wn[i];
        }
    }
    conv_all<<<dim3(32, 14), 256, 0, stream>>>(tab, flag);
    u16 *fp_w1b = wb[0], *fp_w2b = wb[1], *gcn_w1b = wb[2], *gcn_w2b = wb[3];
    float *att_w1c = wf[4], *att_b1c = wf[5], *att_w2c = wf[6];
    u16 *Wcat1 = wb[7];   // [2304,256]: rg_root1 rows then rg_w1 (8*256 rows)
    u16 *Wcat2 = wb[9];   // [2304,128]: rg_root2 rows then rg_w2
    float *lin1_wc = wf[11], *lin2_wc = wf[12], *lin2_bc = wf[13];

    // ---- CSR builds ----
    filli<<<512, 256, 0, stream>>>((int*)z0, (long)(z1 - z0) / 4, 0);
    auto scan = [&](const int* deg, int* off, int n) {
        int nb = divup(n, 4096);
        scan_bsum<<<nb, 1024, 0, stream>>>(deg, n, sbt);
        scan_tiny<<<1, 64, 0, stream>>>(sbt, nb, sbo);
        scan_final<<<nb, 1024, 0, stream>>>(deg, n, sbo, nb, off);
    };
    hist_int<<<2048, 256, 0, stream>>>(mol_dst, EM, mdeg);
    scan(mdeg, moff, NM);
    bin_by<<<2048, 256, 0, stream>>>(mol_dst, EM, moff, mcur, mbins);
    dinv_from_deg<<<512, 256, 0, stream>>>(mdeg, dinv, NM);
    mol_enorm<<<1024, 256, 0, stream>>>(mol_src, mol_dst, dinv, EM, enM);
    flatten_mol<<<2048, 256, 0, stream>>>(mbins, mol_src, enM, EM, ebM);

    hist_int<<<2048, 256, 0, stream>>>(kg_dst, EK, kdeg);
    scan(kdeg, koff, NKG);
    bin_by<<<2048, 256, 0, stream>>>(kg_dst, EK, koff, kcur, kbins);
    kg_cnt<<<2048, 256, 0, stream>>>(kg_dst, kg_et, EK, NKG, cntK);
    kg_enorm<<<1024, 256, 0, stream>>>(kg_dst, kg_et, cntK, EK, NKG, enK);

    hist_int<<<512, 256, 0, stream>>>(mol_batch, NM, pdeg);
    scan(pdeg, poff, ND);
    bin_by<<<512, 256, 0, stream>>>(mol_batch, NM, poff, pcur, pbins);

    // ---- BN helpers (v2) ----
    auto bn_stats = [&](const float* X, int M, int N) {
        colstats_f32_v2<<<NBLK_STATS, 256, 0, stream>>>(X, M, N, part1, part2);
        colstats_reduce_v2<<<N / 64, 256, 0, stream>>>(part1, part2, NBLK_STATS, N,
                                                       1.0f / M, stats, stats + 512);
    };
    auto bn_stats_b16 = [&](const u16* X, int M, int ld, int c0, int NC) {
        colstats_b16_v2<<<NBLK_STATS, 256, 0, stream>>>(X, M, ld, c0, NC, part1, part2);
        colstats_reduce_v2<<<NC / 64, 256, 0, stream>>>(part1, part2, NBLK_STATS, NC,
                                                        1.0f / M, stats, stats + 512);
    };

    // ---------- fingerprint MLP branch (MFMA) ----------
    conv_dual_b16<<<2048, 256, 0, stream>>>(fp_data, Xfb, (long)ND * 1024, flag);
    gemm_mfma<float><<<dim3(64, 8, 1), 256, 0, stream>>>(
        Xfb, 1024, fp_w1b, 512, fp1, 512, ND, 512, 1024, 0, 0);
    bn_stats(fp1, ND, 512);
    bn_apply_dual<<<2048, 256, 0, stream>>>(fp1, fp1b, (long)ND * 512, 511,
                                            stats, stats + 512);
    gemm_mfma<float><<<dim3(64, 4, 1), 256, 0, stream>>>(
        fp1b, 512, fp_w2b, 256, fpb, 256, ND, 256, 512, 0, 0);
    bn_stats(fpb, ND, 256);
    bn_apply<<<2048, 256, 0, stream>>>(fpb, (long)ND * 256, 255, stats, stats + 512);

    // ---------- mol GCN layer 1: bf16-convert, aggregate-then-GEMM ----------
    conv_molx<<<2048, 256, 0, stream>>>((const float*)mol_x, XB, (long)NM * 16, flag);
    mol_agg_in<<<32768, 256, 0, stream>>>(mol_x, XB, flag, dinv, moff, ebM, NM, Xagg);
    gemm_mfma<u16><<<dim3(2048, 2, 1), 256, 0, stream>>>(
        Xagg, 64, gcn_w1b, 128, G1, 128, NM, 128, 64, 0, 0);   // G1 overwrites XB (dead)
    bn_stats_b16(G1, NM, 128, 0, 128);
    bn_apply_b16_v2<<<8192, 256, 0, stream>>>((u32*)G1, (long)NM * 64, 63,
                                              stats, stats + 512);

    // ---------- mol GCN layer 2: aggregate-then-GEMM + BN + pool ------------
    mol_agg128<<<32768, 256, 0, stream>>>(G1, dinv, moff, ebM, NM, G1A);
    // ebM (gout) is dead past this point; pool_b16 below may overwrite gout
    for (int c0 = 0; c0 < 256; c0 += 64) {
        gemm_mfma<u16><<<dim3(2048, 1, 1), 256, 0, stream>>>(
            G1A, 128, gcn_w2b + c0, 256, HB, 64, NM, 64, 128, 0, 0);
        bn_stats_b16(HB, NM, 64, 0, 64);
        pool_b16<<<1024, 256, 0, stream>>>(HB, poff, pbins, ND,
                                           stats, stats + 512, gout, c0);
    }

    // ---------- attention fusion ----------
    attention_fuse<<<ND, 128, 0, stream>>>(gout, fpb, att_w1c, att_b1c, att_w2c,
                                           xkg, out_beta);
    // fpb dead now; build flattened KG edge table in its place
    flatten_kg<<<2048, 256, 0, stream>>>(kbins, kg_src, kg_et, enK, EK, ebK);
    conv_in<<<512, 256, 0, stream>>>(d_in[17], xkg + (long)ND * 256,
                                     (long)NGENE * 256, flag);
    conv_f32_b16<<<1024, 256, 0, stream>>>(xkg, xb, (long)NKG * 256);

    // ---------- RGCN layer 1 (256 -> 256): preagg + single K=2304 GEMM ------
    kg_preagg<<<divup(NKG, 4), 256, 0, stream>>>(xb, koff, ebK, NKG, AGGX);
    gemm_mfma<float><<<dim3(divup(NKG, 64), 4, 1), 256, 0, stream>>>(
        AGGX, 2304, Wcat1, 256, x2, 256, NKG, 256, 2304, 0, 0);
    bn_stats(x2, NKG, 256);
    bn_apply_dual<<<2048, 256, 0, stream>>>(x2, x2b, (long)NKG * 256, 255,
                                            stats, stats + 512);

    // ---------- RGCN layer 2 (256 -> 128): preagg + single K=2304 GEMM ------
    kg_preagg<<<divup(NKG, 4), 256, 0, stream>>>(x2b, koff, ebK, NKG, AGGX);
    gemm_mfma<float><<<dim3(divup(NKG, 64), 2, 1), 256, 0, stream>>>(
        AGGX, 2304, Wcat2, 128, x3, 128, NKG, 128, 2304, 0, 0);
    bn_stats(x3, NKG, 128);
    bn_apply<<<2048, 256, 0, stream>>>(x3, (long)NKG * 128, 127, stats, stats + 512);

    // ---------- classifier head ----------
    gemm64<<<dim3(divup(NKG, 64), 1, 1), 256, 0, stream>>>(
        x3, 128, lin1_wc, 64, x4, 64, NKG, 64, 128);
    bn_stats(x4, NKG, 64);
    logits_out_bn<<<divup(NKG, 256), 256, 0, stream>>>(x4, stats, stats + 512,
                                                       lin2_wc, lin2_bc, out_ls, NKG);
}

// Round 5
// 1379.298 us; speedup vs baseline: 1.0379x; 1.0379x over previous
//
#include <hip/hip_runtime.h>
#include <hip/hip_bf16.h>
#include <cstdint>

typedef __hip_bfloat16 bf16;
typedef unsigned short u16;
typedef unsigned int u32;
typedef __attribute__((ext_vector_type(8))) short short8;
typedef __attribute__((ext_vector_type(4))) float f32x4;

__device__ __forceinline__ float tofloat(float x){ return x; }
__device__ __forceinline__ float tofloat(bf16 x){ return __bfloat162float(x); }
__device__ __forceinline__ float b2f(u16 a){ return __uint_as_float(((unsigned)a) << 16); }
__device__ __forceinline__ u16 f2b(float f){           // round-to-nearest-even
    unsigned u = __float_as_uint(f);
    return (u16)((u + 0x7FFFu + ((u >> 16) & 1u)) >> 16);
}
__device__ __forceinline__ void storec(float* p, float v){ *p = v; }
__device__ __forceinline__ void storec(u16* p, float v){ *p = f2b(v); }

static inline int divup(long a, long b){ return (int)((a + b - 1) / b); }

#define NBLK_STATS 256

// ---------------- input dtype detection -------------------------------------
__global__ void zero_int(int* p){ *p = 0; }

__global__ void detect_f32(const u16* __restrict__ h, long n, int* flag)
{
    long i = (long)blockIdx.x * blockDim.x + threadIdx.x;
    long st = (long)gridDim.x * blockDim.x;
    int c = 0;
    for (; i < n; i += st)
        if (((h[i] >> 7) & 0xFF) == 0xFF) c++;
    if (c) atomicAdd(flag, c);
}

// convert all weights: fp32 pool + bf16 pool in one launch
struct ConvTab { const void* src[14]; float* dst[14]; u16* dstB[14]; int n[14]; };

__global__ void conv_all(ConvTab t, const int* __restrict__ flagp)
{
    bool f32 = (*flagp != 0);
    int seg = blockIdx.y;
    const void* s = t.src[seg];
    float* d = t.dst[seg];
    u16*   dB = t.dstB[seg];
    int n = t.n[seg];
    long i = (long)blockIdx.x * blockDim.x + threadIdx.x;
    long st = (long)gridDim.x * blockDim.x;
    for (; i < n; i += st) {
        float v = f32 ? ((const float*)s)[i] : tofloat(((const bf16*)s)[i]);
        d[i] = v; dB[i] = f2b(v);
    }
}

__global__ void conv_in(const void* __restrict__ src, float* __restrict__ dst,
                        long n, const int* __restrict__ flagp)
{
    bool f32 = (*flagp != 0);
    long i = (long)blockIdx.x * blockDim.x + threadIdx.x;
    long st = (long)gridDim.x * blockDim.x;
    for (; i < n; i += st)
        dst[i] = f32 ? ((const float*)src)[i] : tofloat(((const bf16*)src)[i]);
}

__global__ void conv_dual_b16(const void* __restrict__ src, u16* __restrict__ dst,
                              long n, const int* __restrict__ flagp)
{
    bool f32 = (*flagp != 0);
    long i = (long)blockIdx.x * blockDim.x + threadIdx.x;
    long st = (long)gridDim.x * blockDim.x;
    for (; i < n; i += st)
        dst[i] = f32 ? f2b(((const float*)src)[i]) : ((const u16*)src)[i];
}

__global__ void conv_f32_b16(const float* __restrict__ src, u16* __restrict__ dst, long n)
{
    long i = (long)blockIdx.x * blockDim.x + threadIdx.x;
    long st = (long)gridDim.x * blockDim.x;
    for (; i < n; i += st) dst[i] = f2b(src[i]);
}

// convert mol_x fp32 -> bf16 copy (only when input is fp32); vectorized x4
__global__ void conv_molx(const float* __restrict__ src, u16* __restrict__ dst,
                          long n4, const int* __restrict__ flagp)
{
    if (*flagp == 0) return;   // input already bf16; agg reads original
    long i = (long)blockIdx.x * blockDim.x + threadIdx.x;
    long st = (long)gridDim.x * blockDim.x;
    for (; i < n4; i += st) {
        float4 v = ((const float4*)src)[i];
        ushort4 o;
        o.x = f2b(v.x); o.y = f2b(v.y); o.z = f2b(v.z); o.w = f2b(v.w);
        ((ushort4*)dst)[i] = o;
    }
}

// bf16 transpose: dst[n*K + k] = src[k*N + n]
__global__ __launch_bounds__(256)
void transpose_b16(const u16* __restrict__ src, u16* __restrict__ dst, int K, int N)
{
    __shared__ u16 t[32][33];
    int k0 = blockIdx.x * 32, n0 = blockIdx.y * 32;
    int x = threadIdx.x & 31, y = threadIdx.x >> 5;   // y in 0..7
    for (int yy = y; yy < 32; yy += 8) {
        int k = k0 + yy, n = n0 + x;
        t[yy][x] = (k < K && n < N) ? src[(long)k * N + n] : (u16)0;
    }
    __syncthreads();
    for (int yy = y; yy < 32; yy += 8) {
        int n = n0 + yy, k = k0 + x;
        if (n < N && k < K) dst[(long)n * K + k] = t[x][yy];
    }
}

// ---------------- CSR edge flattening ---------------------------------------
// ebM[j] = {src, bits(en)}
__global__ void flatten_mol(const int* __restrict__ bins, const int* __restrict__ src,
                            const float* __restrict__ en, long E, int2* __restrict__ out)
{
    long i = (long)blockIdx.x * blockDim.x + threadIdx.x;
    long st = (long)gridDim.x * blockDim.x;
    for (; i < E; i += st) {
        int e = bins[i];
        out[i] = make_int2(src[e], __float_as_int(en[e]));
    }
}

// ebK[j] = {(r<<16)|src, bits(en)}  (src < 65536, r < 8)
__global__ void flatten_kg(const int* __restrict__ bins, const int* __restrict__ src,
                           const int* __restrict__ et, const float* __restrict__ en,
                           long E, int2* __restrict__ out)
{
    long i = (long)blockIdx.x * blockDim.x + threadIdx.x;
    long st = (long)gridDim.x * blockDim.x;
    for (; i < E; i += st) {
        int e = bins[i];
        out[i] = make_int2((et[e] << 16) | src[e], __float_as_int(en[e]));
    }
}

// ---------------- MFMA GEMM (B pre-transposed): C = A @ B, bf16, fp32 acc ---
// A [M,K] lda; BT [N,K] ldbt (row n = column n of B). Tile 64 x (NBLK*64).
// Both A and B staged as row-copies (ushort4) -> no transpose-scatter conflicts.
// N must be a multiple of NBLK*64; K multiple of 32.
template<typename TC, int NBLK>
__global__ __launch_bounds__(256)
void gemm_bt(const u16* __restrict__ A, int lda,
             const u16* __restrict__ BT, int ldbt,
             TC* __restrict__ C, int ldc,
             int M, int N, int K)
{
    __shared__ __align__(16) u16 As[64][40];          // [m][k]
    __shared__ __align__(16) u16 Bs[NBLK * 64][40];   // [n][k]
    const int tid = threadIdx.x;
    const int lane = tid & 63, wave = tid >> 6;
    const int l15 = lane & 15, quad = lane >> 4;
    const int wm = (wave & 1) * 32, wn = (wave >> 1) * 32;
    const int row0 = blockIdx.x * 64, col0 = blockIdx.y * (NBLK * 64);
    const int arow = tid >> 2, ak = (tid & 3) * 8;

    f32x4 acc[NBLK][2][2];
#pragma unroll
    for (int t = 0; t < NBLK; t++)
#pragma unroll
        for (int i = 0; i < 2; i++)
#pragma unroll
            for (int j = 0; j < 2; j++)
#pragma unroll
                for (int r = 0; r < 4; r++) acc[t][i][j][r] = 0.f;

    for (int k0 = 0; k0 < K; k0 += 32) {
        {   // stage A: 64 rows x 32 k
            int r = row0 + arow;
            ushort4 v0 = {0,0,0,0}, v1 = {0,0,0,0};
            if (r < M) {
                const u16* p = A + (long)r * lda + k0 + ak;
                v0 = *(const ushort4*)p;
                v1 = *(const ushort4*)(p + 4);
            }
            *(ushort4*)&As[arow][ak]     = v0;
            *(ushort4*)&As[arow][ak + 4] = v1;
        }
#pragma unroll
        for (int t = 0; t < NBLK; t++) {   // stage B rows (already transposed)
            const u16* p = BT + (long)(col0 + t * 64 + arow) * ldbt + k0 + ak;
            ushort4 v0 = *(const ushort4*)p;
            ushort4 v1 = *(const ushort4*)(p + 4);
            *(ushort4*)&Bs[t * 64 + arow][ak]     = v0;
            *(ushort4*)&Bs[t * 64 + arow][ak + 4] = v1;
        }
        __syncthreads();
        short8 a0 = *(const short8*)&As[wm + l15][quad * 8];
        short8 a1 = *(const short8*)&As[wm + 16 + l15][quad * 8];
#pragma unroll
        for (int t = 0; t < NBLK; t++) {
            short8 b0 = *(const short8*)&Bs[t * 64 + wn + l15][quad * 8];
            short8 b1 = *(const short8*)&Bs[t * 64 + wn + 16 + l15][quad * 8];
            acc[t][0][0] = __builtin_amdgcn_mfma_f32_16x16x32_bf16(a0, b0, acc[t][0][0], 0, 0, 0);
            acc[t][0][1] = __builtin_amdgcn_mfma_f32_16x16x32_bf16(a0, b1, acc[t][0][1], 0, 0, 0);
            acc[t][1][0] = __builtin_amdgcn_mfma_f32_16x16x32_bf16(a1, b0, acc[t][1][0], 0, 0, 0);
            acc[t][1][1] = __builtin_amdgcn_mfma_f32_16x16x32_bf16(a1, b1, acc[t][1][1], 0, 0, 0);
        }
        __syncthreads();
    }
#pragma unroll
    for (int t = 0; t < NBLK; t++)
#pragma unroll
        for (int i = 0; i < 2; i++)
#pragma unroll
            for (int j = 0; j < 2; j++)
#pragma unroll
                for (int r = 0; r < 4; r++) {
                    int row = row0 + wm + i * 16 + quad * 4 + r;
                    int col = col0 + t * 64 + wn + j * 16 + l15;
                    if (row < M) storec(&C[(long)row * ldc + col], acc[t][i][j][r]);
                }
}

// ---------------- vector GEMM (fp32, small) ---------------------------------
__global__ __launch_bounds__(256)
void gemm64(const float* __restrict__ A, int lda,
            const float* __restrict__ B, int ldb,
            float* __restrict__ C, int ldc,
            int M, int N, int K)
{
    __shared__ float As[16][68];
    __shared__ float Bs[16][68];
    const int tid = threadIdx.x;
    const int row0 = blockIdx.x * 64, col0 = blockIdx.y * 64;
    float acc[4][4];
#pragma unroll
    for (int i = 0; i < 4; i++)
#pragma unroll
        for (int j = 0; j < 4; j++) acc[i][j] = 0.f;
    const int ar = tid >> 2, ak = (tid & 3) * 4;
    const int bk = tid >> 4, bc = (tid & 15) * 4;
    const int ty4 = (tid >> 4) * 4, tx4 = (tid & 15) * 4;
    for (int k0 = 0; k0 < K; k0 += 16) {
        {
            int row = row0 + ar;
            float4 v = make_float4(0.f, 0.f, 0.f, 0.f);
            if (row < M) v = *(const float4*)(A + (long)row * lda + k0 + ak);
            As[ak + 0][ar] = v.x; As[ak + 1][ar] = v.y;
            As[ak + 2][ar] = v.z; As[ak + 3][ar] = v.w;
        }
        {
            int c = col0 + bc;
            float4 v = make_float4(0.f, 0.f, 0.f, 0.f);
            if (c < N) v = *(const float4*)(B + (long)(k0 + bk) * ldb + c);
            *(float4*)&Bs[bk][bc] = v;
        }
        __syncthreads();
#pragma unroll
        for (int k = 0; k < 16; k++) {
            float4 a = *(const float4*)&As[k][ty4];
            float4 b = *(const float4*)&Bs[k][tx4];
            acc[0][0] += a.x * b.x; acc[0][1] += a.x * b.y; acc[0][2] += a.x * b.z; acc[0][3] += a.x * b.w;
            acc[1][0] += a.y * b.x; acc[1][1] += a.y * b.y; acc[1][2] += a.y * b.z; acc[1][3] += a.y * b.w;
            acc[2][0] += a.z * b.x; acc[2][1] += a.z * b.y; acc[2][2] += a.z * b.z; acc[2][3] += a.z * b.w;
            acc[3][0] += a.w * b.x; acc[3][1] += a.w * b.y; acc[3][2] += a.w * b.z; acc[3][3] += a.w * b.w;
        }
        __syncthreads();
    }
    int c = col0 + tx4;
#pragma unroll
    for (int i = 0; i < 4; i++) {
        int r = row0 + ty4 + i;
        if (r < M && c < N)
            *(float4*)&C[(long)r * ldc + c] =
                make_float4(acc[i][0], acc[i][1], acc[i][2], acc[i][3]);
    }
}

// ---------------- utility / CSR build ---------------------------------------
__global__ void filli(int* p, long n, int v)
{
    long i = (long)blockIdx.x * blockDim.x + threadIdx.x;
    long st = (long)gridDim.x * blockDim.x;
    for (; i < n; i += st) p[i] = v;
}

__global__ void hist_int(const int* __restrict__ key, long n, int* __restrict__ h)
{
    long i = (long)blockIdx.x * blockDim.x + threadIdx.x;
    long st = (long)gridDim.x * blockDim.x;
    for (; i < n; i += st) atomicAdd(&h[key[i]], 1);
}

__global__ __launch_bounds__(1024)
void scan_bsum(const int* __restrict__ in, int n, int* __restrict__ btot)
{
    __shared__ int sh[1024];
    int tid = threadIdx.x;
    int i0 = blockIdx.x * 4096 + tid * 4;
    int s = 0;
#pragma unroll
    for (int t = 0; t < 4; t++) { int idx = i0 + t; s += (idx < n) ? in[idx] : 0; }
    sh[tid] = s;
    __syncthreads();
    for (int off = 512; off > 0; off >>= 1) {
        if (tid < off) sh[tid] += sh[tid + off];
        __syncthreads();
    }
    if (tid == 0) btot[blockIdx.x] = sh[0];
}

__global__ void scan_tiny(const int* __restrict__ btot, int nb, int* __restrict__ boff)
{
    if (threadIdx.x == 0) {
        int c = 0;
        for (int b = 0; b < nb; b++) { boff[b] = c; c += btot[b]; }
        boff[nb] = c;
    }
}

__global__ __launch_bounds__(1024)
void scan_final(const int* __restrict__ in, int n, const int* __restrict__ boff,
                int nb, int* __restrict__ out)
{
    __shared__ int buf[1024];
    int tid = threadIdx.x;
    int i0 = blockIdx.x * 4096 + tid * 4;
    int v[4]; int s = 0;
#pragma unroll
    for (int t = 0; t < 4; t++) {
        int idx = i0 + t;
        v[t] = (idx < n) ? in[idx] : 0;
        s += v[t];
    }
    buf[tid] = s;
    __syncthreads();
    for (int off = 1; off < 1024; off <<= 1) {
        int t = (tid >= off) ? buf[tid - off] : 0;
        __syncthreads();
        buf[tid] += t;
        __syncthreads();
    }
    int excl = buf[tid] - s + boff[blockIdx.x];
#pragma unroll
    for (int t = 0; t < 4; t++) {
        int idx = i0 + t;
        if (idx < n) out[idx] = excl;
        excl += v[t];
    }
    if (blockIdx.x == 0 && tid == 0) out[n] = boff[nb];
}

__global__ void bin_by(const int* __restrict__ key, long n,
                       const int* __restrict__ off, int* __restrict__ cursor,
                       int* __restrict__ bins)
{
    long i = (long)blockIdx.x * blockDim.x + threadIdx.x;
    long st = (long)gridDim.x * blockDim.x;
    for (; i < n; i += st) {
        int k = key[i];
        int pos = off[k] + atomicAdd(&cursor[k], 1);
        bins[pos] = (int)i;
    }
}

__global__ void dinv_from_deg(const int* __restrict__ deg, float* __restrict__ dinv, long n)
{
    long i = (long)blockIdx.x * blockDim.x + threadIdx.x;
    long st = (long)gridDim.x * blockDim.x;
    for (; i < n; i += st) dinv[i] = rsqrtf((float)(deg[i] + 1));
}

__global__ void kg_cnt(const int* __restrict__ dst, const int* __restrict__ et,
                       long E, int NKG, float* cnt)
{
    long i = (long)blockIdx.x * blockDim.x + threadIdx.x;
    long st = (long)gridDim.x * blockDim.x;
    for (; i < E; i += st) atomicAdd(&cnt[(long)et[i] * NKG + dst[i]], 1.0f);
}

__global__ void kg_enorm(const int* __restrict__ dst, const int* __restrict__ et,
                         const float* __restrict__ cnt, long E, int NKG,
                         float* __restrict__ en)
{
    long i = (long)blockIdx.x * blockDim.x + threadIdx.x;
    long st = (long)gridDim.x * blockDim.x;
    for (; i < E; i += st)
        en[i] = 1.0f / fmaxf(cnt[(long)et[i] * NKG + dst[i]], 1.0f);
}

__global__ void mol_enorm(const int* __restrict__ src, const int* __restrict__ dst,
                          const float* __restrict__ dinv, long E, float* __restrict__ en)
{
    long i = (long)blockIdx.x * blockDim.x + threadIdx.x;
    long st = (long)gridDim.x * blockDim.x;
    for (; i < E; i += st) en[i] = dinv[src[i]] * dinv[dst[i]];
}

// ---------------- batch-norm stats (v2: vectorized, NBLK_STATS blocks) ------
__global__ __launch_bounds__(256)
void colstats_b16_v2(const u16* __restrict__ X, int M, int ld, int c0, int NC,
                     float* __restrict__ p1, float* __restrict__ p2)
{
    __shared__ float sh1[1024], sh2[1024];
    int tid = threadIdx.x;
    int ncg = NC >> 2;                 // col groups of 4
    int cg  = tid & (ncg - 1);
    int rg  = tid / ncg;
    int nrg = 256 / ncg;
    float s0=0,s1=0,s2=0,s3=0, q0=0,q1=0,q2=0,q3=0;
    const u16* base = X + c0 + 4 * cg;
    for (long row = (long)blockIdx.x * nrg + rg; row < M; row += (long)gridDim.x * nrg) {
        ushort4 v = *(const ushort4*)(base + row * (long)ld);
        float f0 = b2f(v.x), f1 = b2f(v.y), f2 = b2f(v.z), f3 = b2f(v.w);
        s0 += f0; q0 += f0 * f0; s1 += f1; q1 += f1 * f1;
        s2 += f2; q2 += f2 * f2; s3 += f3; q3 += f3 * f3;
    }
    float4* S1 = (float4*)sh1; float4* S2 = (float4*)sh2;
    S1[tid] = make_float4(s0, s1, s2, s3);
    S2[tid] = make_float4(q0, q1, q2, q3);
    __syncthreads();
    for (int off = nrg >> 1; off > 0; off >>= 1) {
        if (rg < off) {
            float4 a = S1[tid], b = S1[tid + off * ncg];
            S1[tid] = make_float4(a.x + b.x, a.y + b.y, a.z + b.z, a.w + b.w);
            float4 c = S2[tid], d = S2[tid + off * ncg];
            S2[tid] = make_float4(c.x + d.x, c.y + d.y, c.z + d.z, c.w + d.w);
        }
        __syncthreads();
    }
    if (rg == 0) {
        *(float4*)&p1[(long)blockIdx.x * NC + 4 * cg] = S1[tid];
        *(float4*)&p2[(long)blockIdx.x * NC + 4 * cg] = S2[tid];
    }
}

__global__ __launch_bounds__(256)
void colstats_f32_v2(const float* __restrict__ X, int M, int N,
                     float* __restrict__ p1, float* __restrict__ p2)
{
    __shared__ float sh1[1024], sh2[1024];
    int tid = threadIdx.x;
    int ncg = N >> 2;
    int cg  = tid & (ncg - 1);
    int rg  = tid / ncg;
    int nrg = 256 / ncg;
    float s0=0,s1=0,s2=0,s3=0, q0=0,q1=0,q2=0,q3=0;
    const float* base = X + 4 * cg;
    for (long row = (long)blockIdx.x * nrg + rg; row < M; row += (long)gridDim.x * nrg) {
        float4 v = *(const float4*)(base + row * (long)N);
        s0 += v.x; q0 += v.x * v.x; s1 += v.y; q1 += v.y * v.y;
        s2 += v.z; q2 += v.z * v.z; s3 += v.w; q3 += v.w * v.w;
    }
    float4* S1 = (float4*)sh1; float4* S2 = (float4*)sh2;
    S1[tid] = make_float4(s0, s1, s2, s3);
    S2[tid] = make_float4(q0, q1, q2, q3);
    __syncthreads();
    for (int off = nrg >> 1; off > 0; off >>= 1) {
        if (rg < off) {
            float4 a = S1[tid], b = S1[tid + off * ncg];
            S1[tid] = make_float4(a.x + b.x, a.y + b.y, a.z + b.z, a.w + b.w);
            float4 c = S2[tid], d = S2[tid + off * ncg];
            S2[tid] = make_float4(c.x + d.x, c.y + d.y, c.z + d.z, c.w + d.w);
        }
        __syncthreads();
    }
    if (rg == 0) {
        *(float4*)&p1[(long)blockIdx.x * N + 4 * cg] = S1[tid];
        *(float4*)&p2[(long)blockIdx.x * N + 4 * cg] = S2[tid];
    }
}

__global__ void colstats_reduce_v2(const float* __restrict__ p1, const float* __restrict__ p2,
                                   int nblk, int N, float invM,
                                   float* __restrict__ s1o, float* __restrict__ s2o)
{
    __shared__ float sh1[256], sh2[256];
    int tid = threadIdx.x;
    int col = blockIdx.x * 64 + (tid & 63);
    int seg = tid >> 6;
    float a = 0.f, c = 0.f;
    for (int b = seg; b < nblk; b += 4) {
        a += p1[(long)b * N + col];
        c += p2[(long)b * N + col];
    }
    sh1[tid] = a; sh2[tid] = c;
    __syncthreads();
    if (seg == 0) {
        a = sh1[tid] + sh1[tid + 64] + sh1[tid + 128] + sh1[tid + 192];
        c = sh2[tid] + sh2[tid + 64] + sh2[tid + 128] + sh2[tid + 192];
        float mean = a * invM;
        float var  = fmaxf(c * invM - mean * mean, 0.f);
        s1o[col] = mean;
        s2o[col] = rsqrtf(var + 1e-5f);
    }
}

__global__ void bn_apply(float* X, long total, int mask,
                         const float* __restrict__ s1, const float* __restrict__ s2)
{
    long i = (long)blockIdx.x * blockDim.x + threadIdx.x;
    long st = (long)gridDim.x * blockDim.x;
    for (; i < total; i += st) {
        int j = (int)(i & mask);
        X[i] = fmaxf((X[i] - s1[j]) * s2[j], 0.f);
    }
}

// BN+ReLU, fp32 in place AND bf16 copy
__global__ void bn_apply_dual(float* __restrict__ X, u16* __restrict__ Xb, long total,
                              int mask, const float* __restrict__ s1,
                              const float* __restrict__ s2)
{
    long i = (long)blockIdx.x * blockDim.x + threadIdx.x;
    long st = (long)gridDim.x * blockDim.x;
    for (; i < total; i += st) {
        int j = (int)(i & mask);
        float y = fmaxf((X[i] - s1[j]) * s2[j], 0.f);
        X[i] = y;
        Xb[i] = f2b(y);
    }
}

// BN+ReLU in place on bf16 contiguous [M, NC]; u32 words (2 cols each)
__global__ void bn_apply_b16_v2(u32* __restrict__ X, long n2, int maskHalf,
                                const float* __restrict__ s1, const float* __restrict__ s2)
{
    long i = (long)blockIdx.x * blockDim.x + threadIdx.x;
    long st = (long)gridDim.x * blockDim.x;
    for (; i < n2; i += st) {
        u32 v = X[i];
        int f = (int)(i & maskHalf) * 2;
        float y0 = fmaxf((b2f((u16)(v & 0xFFFF)) - s1[f])     * s2[f],     0.f);
        float y1 = fmaxf((b2f((u16)(v >> 16))    - s1[f + 1]) * s2[f + 1], 0.f);
        X[i] = (u32)f2b(y0) | ((u32)f2b(y1) << 16);
    }
}

// ---------------- CSR aggregation (no atomics) ------------------------------
__global__ __launch_bounds__(256)
void mol_agg_in(const void* __restrict__ Xraw, const u16* __restrict__ Xcvt,
                const int* __restrict__ flagp, const float* __restrict__ dinv,
                const int* __restrict__ off, const int2* __restrict__ eb,
                int NM, u16* __restrict__ out)
{
    const u16* X = (*flagp != 0) ? Xcvt : (const u16*)Xraw;
    int wid  = (int)(((long)blockIdx.x * 256 + threadIdx.x) >> 6);
    int lane = threadIdx.x & 63;
    if (wid >= NM) return;
    float dv = dinv[wid];
    float acc = b2f(X[(long)wid * 64 + lane]) * dv * dv;
    int j = off[wid], j1 = off[wid + 1];
    for (; j + 3 < j1; j += 4) {
        int2 e0 = eb[j], e1 = eb[j + 1], e2 = eb[j + 2], e3 = eb[j + 3];
        float v0 = b2f(X[(long)e0.x * 64 + lane]);
        float v1 = b2f(X[(long)e1.x * 64 + lane]);
        float v2 = b2f(X[(long)e2.x * 64 + lane]);
        float v3 = b2f(X[(long)e3.x * 64 + lane]);
        acc += v0 * __int_as_float(e0.y) + v1 * __int_as_float(e1.y)
             + v2 * __int_as_float(e2.y) + v3 * __int_as_float(e3.y);
    }
    for (; j < j1; j++) {
        int2 e = eb[j];
        acc += b2f(X[(long)e.x * 64 + lane]) * __int_as_float(e.y);
    }
    out[(long)wid * 64 + lane] = f2b(acc);
}

__global__ __launch_bounds__(256)
void mol_agg128(const u16* __restrict__ G, const float* __restrict__ dinv,
                const int* __restrict__ off, const int2* __restrict__ eb,
                int NM, u16* __restrict__ out)
{
    int wid  = (int)(((long)blockIdx.x * 256 + threadIdx.x) >> 6);
    int lane = threadIdx.x & 63;
    if (wid >= NM) return;
    float dv = dinv[wid], dv2 = dv * dv;
    u32 u = *(const u32*)(G + (long)wid * 128 + 2 * lane);
    float a0 = b2f((u16)(u & 0xFFFF)) * dv2;
    float a1 = b2f((u16)(u >> 16)) * dv2;
    int j = off[wid], j1 = off[wid + 1];
    for (; j + 3 < j1; j += 4) {
        int2 e0 = eb[j], e1 = eb[j + 1], e2 = eb[j + 2], e3 = eb[j + 3];
        u32 v0 = *(const u32*)(G + (long)e0.x * 128 + 2 * lane);
        u32 v1 = *(const u32*)(G + (long)e1.x * 128 + 2 * lane);
        u32 v2 = *(const u32*)(G + (long)e2.x * 128 + 2 * lane);
        u32 v3 = *(const u32*)(G + (long)e3.x * 128 + 2 * lane);
        float n0 = __int_as_float(e0.y), n1 = __int_as_float(e1.y);
        float n2 = __int_as_float(e2.y), n3 = __int_as_float(e3.y);
        a0 += b2f((u16)(v0 & 0xFFFF)) * n0 + b2f((u16)(v1 & 0xFFFF)) * n1
            + b2f((u16)(v2 & 0xFFFF)) * n2 + b2f((u16)(v3 & 0xFFFF)) * n3;
        a1 += b2f((u16)(v0 >> 16)) * n0 + b2f((u16)(v1 >> 16)) * n1
            + b2f((u16)(v2 >> 16)) * n2 + b2f((u16)(v3 >> 16)) * n3;
    }
    for (; j < j1; j++) {
        int2 e = eb[j];
        u32 v = *(const u32*)(G + (long)e.x * 128 + 2 * lane);
        float n = __int_as_float(e.y);
        a0 += b2f((u16)(v & 0xFFFF)) * n;
        a1 += b2f((u16)(v >> 16)) * n;
    }
    u32 o = (u32)f2b(a0) | ((u32)f2b(a1) << 16);
    *(u32*)(out + (long)wid * 128 + 2 * lane) = o;
}

// RGCN pre-aggregation in input space: per node, per-relation mean of x_src.
// xin bf16 [NKG,256] (L2-resident); eb[j] = {(r<<16)|src, bits(en)}.
// Output aggx bf16 [NKG, 2304]: cols 0:256 = x row, cols 256+r*256+c = agg_r[c].
__global__ __launch_bounds__(256)
void kg_preagg(const u16* __restrict__ xin, const int* __restrict__ off,
               const int2* __restrict__ eb, int NKG, u16* __restrict__ aggx)
{
    __shared__ float lds[4][8 * 256];     // 32 KB, one 8x256 scratch per wave
    int wav  = threadIdx.x >> 6;
    int lane = threadIdx.x & 63;
    int wid  = blockIdx.x * 4 + wav;
    float* L = lds[wav];
    const int c4 = 4 * lane;
    const float4 z4 = make_float4(0.f, 0.f, 0.f, 0.f);
#pragma unroll
    for (int c = 0; c < 2048; c += 256) *(float4*)&L[c + c4] = z4;
    if (wid >= NKG) return;               // wave-private LDS; no barrier needed
    {
        int j = off[wid], j1 = off[wid + 1];
        for (; j + 1 < j1; j += 2) {
            int2 e0 = eb[j], e1 = eb[j + 1];
            ushort4 v0 = *(const ushort4*)(xin + (long)(e0.x & 0xFFFF) * 256 + c4);
            ushort4 v1 = *(const ushort4*)(xin + (long)(e1.x & 0xFFFF) * 256 + c4);
            float n0 = __int_as_float(e0.y), n1 = __int_as_float(e1.y);
            float* p0 = L + ((e0.x >> 16) << 8) + c4;
            p0[0] += b2f(v0.x) * n0; p0[1] += b2f(v0.y) * n0;
            p0[2] += b2f(v0.z) * n0; p0[3] += b2f(v0.w) * n0;
            float* p1 = L + ((e1.x >> 16) << 8) + c4;
            p1[0] += b2f(v1.x) * n1; p1[1] += b2f(v1.y) * n1;
            p1[2] += b2f(v1.z) * n1; p1[3] += b2f(v1.w) * n1;
        }
        if (j < j1) {
            int2 e = eb[j];
            ushort4 v = *(const ushort4*)(xin + (long)(e.x & 0xFFFF) * 256 + c4);
            float n = __int_as_float(e.y);
            float* p = L + ((e.x >> 16) << 8) + c4;
            p[0] += b2f(v.x) * n; p[1] += b2f(v.y) * n;
            p[2] += b2f(v.z) * n; p[3] += b2f(v.w) * n;
        }
    }
    u16* orow = aggx + (long)wid * 2304;
    *(ushort4*)(orow + c4) = *(const ushort4*)(xin + (long)wid * 256 + c4);
#pragma unroll
    for (int r = 0; r < 8; r++) {
        float* p = L + r * 256 + c4;
        ushort4 o;
        o.x = f2b(p[0]); o.y = f2b(p[1]); o.z = f2b(p[2]); o.w = f2b(p[3]);
        *(ushort4*)(orow + 256 + r * 256 + c4) = o;
    }
}

// mean-pool bf16 chunk [NM,64] with fused BN+ReLU
__global__ __launch_bounds__(256)
void pool_b16(const u16* __restrict__ g, const int* __restrict__ off,
              const int* __restrict__ bins, int ND,
              const float* __restrict__ s1, const float* __restrict__ s2,
              float* __restrict__ gout, int c0)
{
    int wid  = (int)(((long)blockIdx.x * 256 + threadIdx.x) >> 6);
    int lane = threadIdx.x & 63;
    if (wid >= ND) return;
    float m = s1[lane], r = s2[lane];
    int j0 = off[wid], j1 = off[wid + 1];
    float acc = 0.f;
    for (int j = j0; j < j1; j++)
        acc += fmaxf((b2f(g[(long)bins[j] * 64 + lane]) - m) * r, 0.f);
    gout[(long)wid * 256 + c0 + lane] = acc / fmaxf((float)(j1 - j0), 1.0f);
}

// ---------------- attention fusion ------------------------------------------
__global__ void attention_fuse(const float* __restrict__ go, const float* __restrict__ fpv,
                               const float* __restrict__ W1, const float* __restrict__ B1,
                               const float* __restrict__ W2,
                               float* __restrict__ emb, float* __restrict__ beta_out)
{
    int d = blockIdx.x;
    int t = threadIdx.x;
    __shared__ float z[2][256];
    __shared__ float red[128];
    for (int c = t; c < 256; c += 128) {
        z[0][c] = go[(long)d * 256 + c];
        z[1][c] = fpv[(long)d * 256 + c];
    }
    __syncthreads();
    float s[2];
    for (int v = 0; v < 2; v++) {
        float acc = B1[t];
        for (int k = 0; k < 256; k++) acc += z[v][k] * W1[k * 128 + t];
        red[t] = tanhf(acc) * W2[t];
        __syncthreads();
        for (int off = 64; off > 0; off >>= 1) {
            if (t < off) red[t] += red[t + off];
            __syncthreads();
        }
        s[v] = red[0];
        __syncthreads();
    }
    float m = fmaxf(s[0], s[1]);
    float e0 = expf(s[0] - m), e1 = expf(s[1] - m);
    float inv = 1.0f / (e0 + e1);
    float b0 = e0 * inv, b1 = e1 * inv;
    for (int c = t; c < 256; c += 128)
        emb[(long)d * 256 + c] = b0 * z[0][c] + b1 * z[1][c];
    if (t == 0) {
        beta_out[d * 2 + 0] = b0;
        beta_out[d * 2 + 1] = b1;
    }
}

// ---------------- final linear + log_softmax, fused BN on x4 ----------------
__global__ void logits_out_bn(const float* __restrict__ x4,
                              const float* __restrict__ s1, const float* __restrict__ s2,
                              const float* __restrict__ w, const float* __restrict__ b,
                              float* __restrict__ out, int NKG)
{
    int i = blockIdx.x * blockDim.x + threadIdx.x;
    if (i >= NKG) return;
    float a0 = b[0], a1 = b[1];
    for (int k = 0; k < 64; k++) {
        float v = fmaxf((x4[(long)i * 64 + k] - s1[k]) * s2[k], 0.f);
        a0 += v * w[k * 2 + 0];
        a1 += v * w[k * 2 + 1];
    }
    float m = fmaxf(a0, a1);
    float lse = m + logf(expf(a0 - m) + expf(a1 - m));
    out[i * 2 + 0] = a0 - lse;
    out[i * 2 + 1] = a1 - lse;
}

// ============================================================================
extern "C" void kernel_launch(void* const* d_in, const int* in_sizes, int n_in,
                              void* d_out, int out_size, void* d_ws, size_t ws_size,
                              hipStream_t stream)
{
    (void)in_sizes; (void)n_in; (void)out_size; (void)ws_size;
    const int ND = 4096, NM = 131072, NKG = 9510, NGENE = 5414;
    const long EM = 524288, EK = 524288;

    const void* fp_data = d_in[0];
    const void* mol_x   = d_in[1];
    const int*  mol_batch = (const int*)d_in[2];
    const int*  mol_ei  = (const int*)d_in[3];
    const int*  kg_ei   = (const int*)d_in[4];
    const int*  kg_et   = (const int*)d_in[5];

    const int* mol_src = mol_ei;
    const int* mol_dst = mol_ei + EM;
    const int* kg_src  = kg_ei;
    const int* kg_dst  = kg_ei + EK;

    float* out_ls   = (float*)d_out;          // [9510,2] fp32
    float* out_beta = (float*)d_out + 19020;  // [4096,2,1] fp32

    // ---- workspace carve ----
    char* wp = (char*)d_ws;
    auto carve = [&](size_t bytes) { char* p = wp; wp += (bytes + 255) & ~(size_t)255; return p; };
    float* stats = (float*)carve(4096);
    int*   flag  = (int*)carve(256);
    float* dinv  = (float*)carve((size_t)NM * 4);
    float* enM   = (float*)carve((size_t)EM * 4);
    float* enK   = (float*)carve((size_t)EK * 4);
    float* part1 = (float*)carve((size_t)NBLK_STATS * 512 * 4);
    float* part2 = (float*)carve((size_t)NBLK_STATS * 512 * 4);
    int*   sbt   = (int*)carve(256);
    int*   sbo   = (int*)carve(256);
    float* Wpool = (float*)carve((size_t)1630000 * 4);     // fp32 weights
    u16*   WpoolB= (u16*)carve((size_t)1630000 * 2);       // bf16 weights
    u16*   WpoolT= (u16*)carve((size_t)1600000 * 2);       // bf16 transposed gemm weights
    float* fpb   = (float*)carve((size_t)ND * 256 * 4);
    float* gout  = (float*)carve((size_t)ND * 256 * 4);
    // zero-span
    char*  z0    = wp;
    float* cntK  = (float*)carve((size_t)8 * NKG * 4);
    int* mdeg = (int*)carve((size_t)NM * 4);
    int* mcur = (int*)carve((size_t)NM * 4);
    int* kdeg = (int*)carve((size_t)NKG * 4);
    int* kcur = (int*)carve((size_t)NKG * 4);
    int* pdeg = (int*)carve((size_t)ND * 4);
    int* pcur = (int*)carve((size_t)ND * 4);
    char*  z1    = wp;
    int* moff = (int*)carve((size_t)(NM + 1) * 4);
    int* mbins= (int*)carve((size_t)EM * 4);
    int* koff = (int*)carve((size_t)(NKG + 1) * 4);
    int* kbins= (int*)carve((size_t)EK * 4);
    int* poff = (int*)carve((size_t)(ND + 1) * 4);
    int* pbins= (int*)carve((size_t)NM * 4);
    char*  REG1  = carve((size_t)NM * 128 * 2);            // 33.6 MB
    char*  REG2  = carve((size_t)NM * 128 * 2);            // 33.6 MB  (contiguous with HB)
    u16*   HB    = (u16*)carve((size_t)NM * 64 * 2);       // 16.8 MB

    // phase views
    float* fp1 = (float*)REG1;                 // fp: [4096,512] f32
    u16*   XB  = (u16*)REG1;                   // mol pre: [NM,64] bf16 converted input
    u16*   G1  = (u16*)REG1;                   // mol: [NM,128] bf16
    // rgcn chain in REG1:
    float* xkg = (float*)REG1;                 // [NKG,256] f32 (emb+gene)
    float* x2  = xkg + (size_t)NKG * 256;      // [NKG,256] f32
    float* x3  = x2  + (size_t)NKG * 256;      // [NKG,128] f32
    float* x4  = x3  + (size_t)NKG * 128;      // [NKG,64]  f32
    u16*   xb  = (u16*)(x4 + (size_t)NKG * 64);// [NKG,256] bf16 (after x4, fits REG1)
    u16*   x2b = (u16*)REG1;                   // [NKG,256] bf16 (overlaps xkg: dead then)
    u16*   Xfb = (u16*)REG2;                   // fp: [4096,1024] bf16
    u16*   G1A = (u16*)REG2;                   // mol: [NM,128] bf16 aggregated
    u16*   AGGX= (u16*)REG2;                   // rgcn: [NKG,2304] bf16 (43.8 MB, REG2+HB)
    u16*   fp1b = HB;                          // fp: [4096,512] bf16
    u16*   Xagg = HB;                          // mol L1: [NM,64] bf16
    // flattened CSR edge tables (aliased; lifetimes verified)
    int2* ebM = (int2*)gout;                   // mol edges; gout written only after dead
    int2* ebK = (int2*)fpb;                    // kg edges; fpb dead after attention_fuse

    // ---- dtype detect + weight conversion (fp32 + bf16 pools) ----
    zero_int<<<1, 1, 0, stream>>>(flag);
    detect_f32<<<1024, 256, 0, stream>>>((const u16*)fp_data, (long)ND * 1024, flag);
    ConvTab tab;
    // NOTE: rg_root before rg_w so [root; W_0..W_7] is contiguous = [2304, N] GEMM B
    const int widx[14] = {6, 8, 10, 12, 14, 15, 16, 19, 18, 22, 21, 24, 26, 27};
    const int wn[14]   = {1024*512, 512*256, 64*128, 128*256, 256*128, 128, 128,
                          256*256, 8*256*256, 256*128, 8*256*128, 128*64, 64*2, 2};
    float* wf[14]; u16* wb[14];
    {
        size_t o = 0;
        for (int i = 0; i < 14; i++) {
            tab.src[i]  = d_in[widx[i]];
            tab.dst[i]  = Wpool + o;
            tab.dstB[i] = WpoolB + o;
            tab.n[i]    = wn[i];
            wf[i] = Wpool + o; wb[i] = WpoolB + o;
            o += (size_t)wn[i];
        }
    }
    conv_all<<<dim3(32, 14), 256, 0, stream>>>(tab, flag);
    float *att_w1c = wf[4], *att_b1c = wf[5], *att_w2c = wf[6];
    float *lin1_wc = wf[11], *lin2_wc = wf[12], *lin2_bc = wf[13];

    // ---- transposed bf16 weights for gemm_bt (BT[n*K+k] = B[k*N+n]) ----
    u16* T_fpw1  = WpoolT;                        // [512,1024]
    u16* T_fpw2  = T_fpw1 + (size_t)512 * 1024;   // [256,512]
    u16* T_gcnw1 = T_fpw2 + (size_t)256 * 512;    // [128,64]
    u16* T_gcnw2 = T_gcnw1 + (size_t)128 * 64;    // [256,128]
    u16* T_w1    = T_gcnw2 + (size_t)256 * 128;   // [256,2304]
    u16* T_w2    = T_w1 + (size_t)256 * 2304;     // [128,2304]
    transpose_b16<<<dim3(32, 16), 256, 0, stream>>>(wb[0], T_fpw1, 1024, 512);
    transpose_b16<<<dim3(16, 8),  256, 0, stream>>>(wb[1], T_fpw2, 512, 256);
    transpose_b16<<<dim3(2, 4),   256, 0, stream>>>(wb[2], T_gcnw1, 64, 128);
    transpose_b16<<<dim3(4, 8),   256, 0, stream>>>(wb[3], T_gcnw2, 128, 256);
    transpose_b16<<<dim3(72, 8),  256, 0, stream>>>(wb[7], T_w1, 2304, 256);
    transpose_b16<<<dim3(72, 4),  256, 0, stream>>>(wb[9], T_w2, 2304, 128);

    // ---- CSR builds ----
    filli<<<512, 256, 0, stream>>>((int*)z0, (long)(z1 - z0) / 4, 0);
    auto scan = [&](const int* deg, int* off, int n) {
        int nb = divup(n, 4096);
        scan_bsum<<<nb, 1024, 0, stream>>>(deg, n, sbt);
        scan_tiny<<<1, 64, 0, stream>>>(sbt, nb, sbo);
        scan_final<<<nb, 1024, 0, stream>>>(deg, n, sbo, nb, off);
    };
    hist_int<<<2048, 256, 0, stream>>>(mol_dst, EM, mdeg);
    scan(mdeg, moff, NM);
    bin_by<<<2048, 256, 0, stream>>>(mol_dst, EM, moff, mcur, mbins);
    dinv_from_deg<<<512, 256, 0, stream>>>(mdeg, dinv, NM);
    mol_enorm<<<1024, 256, 0, stream>>>(mol_src, mol_dst, dinv, EM, enM);
    flatten_mol<<<2048, 256, 0, stream>>>(mbins, mol_src, enM, EM, ebM);

    hist_int<<<2048, 256, 0, stream>>>(kg_dst, EK, kdeg);
    scan(kdeg, koff, NKG);
    bin_by<<<2048, 256, 0, stream>>>(kg_dst, EK, koff, kcur, kbins);
    kg_cnt<<<2048, 256, 0, stream>>>(kg_dst, kg_et, EK, NKG, cntK);
    kg_enorm<<<1024, 256, 0, stream>>>(kg_dst, kg_et, cntK, EK, NKG, enK);

    hist_int<<<512, 256, 0, stream>>>(mol_batch, NM, pdeg);
    scan(pdeg, poff, ND);
    bin_by<<<512, 256, 0, stream>>>(mol_batch, NM, poff, pcur, pbins);

    // ---- BN helpers (v2) ----
    auto bn_stats = [&](const float* X, int M, int N) {
        colstats_f32_v2<<<NBLK_STATS, 256, 0, stream>>>(X, M, N, part1, part2);
        colstats_reduce_v2<<<N / 64, 256, 0, stream>>>(part1, part2, NBLK_STATS, N,
                                                       1.0f / M, stats, stats + 512);
    };
    auto bn_stats_b16 = [&](const u16* X, int M, int ld, int c0, int NC) {
        colstats_b16_v2<<<NBLK_STATS, 256, 0, stream>>>(X, M, ld, c0, NC, part1, part2);
        colstats_reduce_v2<<<NC / 64, 256, 0, stream>>>(part1, part2, NBLK_STATS, NC,
                                                        1.0f / M, stats, stats + 512);
    };

    // ---------- fingerprint MLP branch (MFMA) ----------
    conv_dual_b16<<<2048, 256, 0, stream>>>(fp_data, Xfb, (long)ND * 1024, flag);
    gemm_bt<float, 2><<<dim3(64, 4), 256, 0, stream>>>(
        Xfb, 1024, T_fpw1, 1024, fp1, 512, ND, 512, 1024);
    bn_stats(fp1, ND, 512);
    bn_apply_dual<<<2048, 256, 0, stream>>>(fp1, fp1b, (long)ND * 512, 511,
                                            stats, stats + 512);
    gemm_bt<float, 1><<<dim3(64, 4), 256, 0, stream>>>(
        fp1b, 512, T_fpw2, 512, fpb, 256, ND, 256, 512);
    bn_stats(fpb, ND, 256);
    bn_apply<<<2048, 256, 0, stream>>>(fpb, (long)ND * 256, 255, stats, stats + 512);

    // ---------- mol GCN layer 1: bf16-convert, aggregate-then-GEMM ----------
    conv_molx<<<2048, 256, 0, stream>>>((const float*)mol_x, XB, (long)NM * 16, flag);
    mol_agg_in<<<32768, 256, 0, stream>>>(mol_x, XB, flag, dinv, moff, ebM, NM, Xagg);
    gemm_bt<u16, 2><<<dim3(2048, 1), 256, 0, stream>>>(
        Xagg, 64, T_gcnw1, 64, G1, 128, NM, 128, 64);   // G1 overwrites XB (dead)
    bn_stats_b16(G1, NM, 128, 0, 128);
    bn_apply_b16_v2<<<8192, 256, 0, stream>>>((u32*)G1, (long)NM * 64, 63,
                                              stats, stats + 512);

    // ---------- mol GCN layer 2: aggregate-then-GEMM + BN + pool ------------
    mol_agg128<<<32768, 256, 0, stream>>>(G1, dinv, moff, ebM, NM, G1A);
    // ebM (gout) is dead past this point; pool_b16 below may overwrite gout
    for (int c0 = 0; c0 < 256; c0 += 64) {
        gemm_bt<u16, 1><<<dim3(2048, 1), 256, 0, stream>>>(
            G1A, 128, T_gcnw2 + (size_t)c0 * 128, 128, HB, 64, NM, 64, 128);
        bn_stats_b16(HB, NM, 64, 0, 64);
        pool_b16<<<1024, 256, 0, stream>>>(HB, poff, pbins, ND,
                                           stats, stats + 512, gout, c0);
    }

    // ---------- attention fusion ----------
    attention_fuse<<<ND, 128, 0, stream>>>(gout, fpb, att_w1c, att_b1c, att_w2c,
                                           xkg, out_beta);
    // fpb dead now; build flattened KG edge table in its place
    flatten_kg<<<2048, 256, 0, stream>>>(kbins, kg_src, kg_et, enK, EK, ebK);
    conv_in<<<512, 256, 0, stream>>>(d_in[17], xkg + (long)ND * 256,
                                     (long)NGENE * 256, flag);
    conv_f32_b16<<<1024, 256, 0, stream>>>(xkg, xb, (long)NKG * 256);

    // ---------- RGCN layer 1 (256 -> 256): preagg + single K=2304 GEMM ------
    kg_preagg<<<divup(NKG, 4), 256, 0, stream>>>(xb, koff, ebK, NKG, AGGX);
    gemm_bt<float, 4><<<dim3(divup(NKG, 64), 1), 256, 0, stream>>>(
        AGGX, 2304, T_w1, 2304, x2, 256, NKG, 256, 2304);
    bn_stats(x2, NKG, 256);
    bn_apply_dual<<<2048, 256, 0, stream>>>(x2, x2b, (long)NKG * 256, 255,
                                            stats, stats + 512);

    // ---------- RGCN layer 2 (256 -> 128): preagg + single K=2304 GEMM ------
    kg_preagg<<<divup(NKG, 4), 256, 0, stream>>>(x2b, koff, ebK, NKG, AGGX);
    gemm_bt<float, 2><<<dim3(divup(NKG, 64), 1), 256, 0, stream>>>(
        AGGX, 2304, T_w2, 2304, x3, 128, NKG, 128, 2304);
    bn_stats(x3, NKG, 128);
    bn_apply<<<2048, 256, 0, stream>>>(x3, (long)NKG * 128, 127, stats, stats + 512);

    // ---------- classifier head ----------
    gemm64<<<dim3(divup(NKG, 64), 1, 1), 256, 0, stream>>>(
        x3, 128, lin1_wc, 64, x4, 64, NKG, 64, 128);
    bn_stats(x4, NKG, 64);
    logits_out_bn<<<divup(NKG, 256), 256, 0, stream>>>(x4, stats, stats + 512,
                                                       lin2_wc, lin2_bc, out_ls, NKG);
}

// Round 6
// 1250.168 us; speedup vs baseline: 1.1451x; 1.1033x over previous
//
#include <hip/hip_runtime.h>
#include <hip/hip_bf16.h>
#include <cstdint>

typedef __hip_bfloat16 bf16;
typedef unsigned short u16;
typedef unsigned int u32;
typedef __attribute__((ext_vector_type(8))) short short8;
typedef __attribute__((ext_vector_type(4))) float f32x4;

__device__ __forceinline__ float tofloat(float x){ return x; }
__device__ __forceinline__ float tofloat(bf16 x){ return __bfloat162float(x); }
__device__ __forceinline__ float b2f(u16 a){ return __uint_as_float(((unsigned)a) << 16); }
__device__ __forceinline__ u16 f2b(float f){           // round-to-nearest-even
    unsigned u = __float_as_uint(f);
    return (u16)((u + 0x7FFFu + ((u >> 16) & 1u)) >> 16);
}
__device__ __forceinline__ void storec(float* p, float v){ *p = v; }
__device__ __forceinline__ void storec(u16* p, float v){ *p = f2b(v); }

static inline int divup(long a, long b){ return (int)((a + b - 1) / b); }

#define NBLK_STATS 256

// ---------------- input dtype detection -------------------------------------
__global__ void zero_int(int* p){ *p = 0; }

__global__ void detect_f32(const u16* __restrict__ h, long n, int* flag)
{
    long i = (long)blockIdx.x * blockDim.x + threadIdx.x;
    long st = (long)gridDim.x * blockDim.x;
    int c = 0;
    for (; i < n; i += st)
        if (((h[i] >> 7) & 0xFF) == 0xFF) c++;
    if (c) atomicAdd(flag, c);
}

// convert all weights: fp32 pool + bf16 pool in one launch
struct ConvTab { const void* src[14]; float* dst[14]; u16* dstB[14]; int n[14]; };

__global__ void conv_all(ConvTab t, const int* __restrict__ flagp)
{
    bool f32 = (*flagp != 0);
    int seg = blockIdx.y;
    const void* s = t.src[seg];
    float* d = t.dst[seg];
    u16*   dB = t.dstB[seg];
    int n = t.n[seg];
    long i = (long)blockIdx.x * blockDim.x + threadIdx.x;
    long st = (long)gridDim.x * blockDim.x;
    for (; i < n; i += st) {
        float v = f32 ? ((const float*)s)[i] : tofloat(((const bf16*)s)[i]);
        d[i] = v; dB[i] = f2b(v);
    }
}

__global__ void conv_in(const void* __restrict__ src, float* __restrict__ dst,
                        long n, const int* __restrict__ flagp)
{
    bool f32 = (*flagp != 0);
    long i = (long)blockIdx.x * blockDim.x + threadIdx.x;
    long st = (long)gridDim.x * blockDim.x;
    for (; i < n; i += st)
        dst[i] = f32 ? ((const float*)src)[i] : tofloat(((const bf16*)src)[i]);
}

__global__ void conv_dual_b16(const void* __restrict__ src, u16* __restrict__ dst,
                              long n, const int* __restrict__ flagp)
{
    bool f32 = (*flagp != 0);
    long i = (long)blockIdx.x * blockDim.x + threadIdx.x;
    long st = (long)gridDim.x * blockDim.x;
    for (; i < n; i += st)
        dst[i] = f32 ? f2b(((const float*)src)[i]) : ((const u16*)src)[i];
}

__global__ void conv_f32_b16(const float* __restrict__ src, u16* __restrict__ dst, long n)
{
    long i = (long)blockIdx.x * blockDim.x + threadIdx.x;
    long st = (long)gridDim.x * blockDim.x;
    for (; i < n; i += st) dst[i] = f2b(src[i]);
}

// convert mol_x fp32 -> bf16 copy (only when input is fp32); vectorized x4
__global__ void conv_molx(const float* __restrict__ src, u16* __restrict__ dst,
                          long n4, const int* __restrict__ flagp)
{
    if (*flagp == 0) return;   // input already bf16; agg reads original
    long i = (long)blockIdx.x * blockDim.x + threadIdx.x;
    long st = (long)gridDim.x * blockDim.x;
    for (; i < n4; i += st) {
        float4 v = ((const float4*)src)[i];
        ushort4 o;
        o.x = f2b(v.x); o.y = f2b(v.y); o.z = f2b(v.z); o.w = f2b(v.w);
        ((ushort4*)dst)[i] = o;
    }
}

// bf16 transpose: dst[n*K + k] = src[k*N + n]
__global__ __launch_bounds__(256)
void transpose_b16(const u16* __restrict__ src, u16* __restrict__ dst, int K, int N)
{
    __shared__ u16 t[32][33];
    int k0 = blockIdx.x * 32, n0 = blockIdx.y * 32;
    int x = threadIdx.x & 31, y = threadIdx.x >> 5;   // y in 0..7
    for (int yy = y; yy < 32; yy += 8) {
        int k = k0 + yy, n = n0 + x;
        t[yy][x] = (k < K && n < N) ? src[(long)k * N + n] : (u16)0;
    }
    __syncthreads();
    for (int yy = y; yy < 32; yy += 8) {
        int n = n0 + yy, k = k0 + x;
        if (n < N && k < K) dst[(long)n * K + k] = t[x][yy];
    }
}

// ---------------- CSR edge flattening ---------------------------------------
// ebM[j] = {src, bits(en)}
__global__ void flatten_mol(const int* __restrict__ bins, const int* __restrict__ src,
                            const float* __restrict__ en, long E, int2* __restrict__ out)
{
    long i = (long)blockIdx.x * blockDim.x + threadIdx.x;
    long st = (long)gridDim.x * blockDim.x;
    for (; i < E; i += st) {
        int e = bins[i];
        out[i] = make_int2(src[e], __float_as_int(en[e]));
    }
}

// KG segment key: dst*8 + et  (segments = (node, relation) pairs)
__global__ void kg_key2(const int* __restrict__ dst, const int* __restrict__ et,
                        long E, int* __restrict__ key)
{
    long i = (long)blockIdx.x * blockDim.x + threadIdx.x;
    long st = (long)gridDim.x * blockDim.x;
    for (; i < E; i += st) key[i] = dst[i] * 8 + et[i];
}

// flatten KG edges to src index only (mean norm comes from segment length)
__global__ void flatten_kg_src(const int* __restrict__ bins, const int* __restrict__ src,
                               long E, int* __restrict__ out)
{
    long i = (long)blockIdx.x * blockDim.x + threadIdx.x;
    long st = (long)gridDim.x * blockDim.x;
    for (; i < E; i += st) out[i] = src[bins[i]];
}

// ---------------- MFMA GEMM (B pre-transposed): C = A @ B, bf16, fp32 acc ---
// A [M,K] lda; BT [N,K] ldbt (row n = column n of B). Tile 64 x (NBLK*64).
// Both A and B staged as row-copies (ushort4) -> no transpose-scatter conflicts.
// N must be a multiple of NBLK*64; K multiple of 32.
template<typename TC, int NBLK>
__global__ __launch_bounds__(256)
void gemm_bt(const u16* __restrict__ A, int lda,
             const u16* __restrict__ BT, int ldbt,
             TC* __restrict__ C, int ldc,
             int M, int N, int K)
{
    __shared__ __align__(16) u16 As[64][40];          // [m][k]
    __shared__ __align__(16) u16 Bs[NBLK * 64][40];   // [n][k]
    const int tid = threadIdx.x;
    const int lane = tid & 63, wave = tid >> 6;
    const int l15 = lane & 15, quad = lane >> 4;
    const int wm = (wave & 1) * 32, wn = (wave >> 1) * 32;
    const int row0 = blockIdx.x * 64, col0 = blockIdx.y * (NBLK * 64);
    const int arow = tid >> 2, ak = (tid & 3) * 8;

    f32x4 acc[NBLK][2][2];
#pragma unroll
    for (int t = 0; t < NBLK; t++)
#pragma unroll
        for (int i = 0; i < 2; i++)
#pragma unroll
            for (int j = 0; j < 2; j++)
#pragma unroll
                for (int r = 0; r < 4; r++) acc[t][i][j][r] = 0.f;

    for (int k0 = 0; k0 < K; k0 += 32) {
        {   // stage A: 64 rows x 32 k
            int r = row0 + arow;
            ushort4 v0 = {0,0,0,0}, v1 = {0,0,0,0};
            if (r < M) {
                const u16* p = A + (long)r * lda + k0 + ak;
                v0 = *(const ushort4*)p;
                v1 = *(const ushort4*)(p + 4);
            }
            *(ushort4*)&As[arow][ak]     = v0;
            *(ushort4*)&As[arow][ak + 4] = v1;
        }
#pragma unroll
        for (int t = 0; t < NBLK; t++) {   // stage B rows (already transposed)
            const u16* p = BT + (long)(col0 + t * 64 + arow) * ldbt + k0 + ak;
            ushort4 v0 = *(const ushort4*)p;
            ushort4 v1 = *(const ushort4*)(p + 4);
            *(ushort4*)&Bs[t * 64 + arow][ak]     = v0;
            *(ushort4*)&Bs[t * 64 + arow][ak + 4] = v1;
        }
        __syncthreads();
        short8 a0 = *(const short8*)&As[wm + l15][quad * 8];
        short8 a1 = *(const short8*)&As[wm + 16 + l15][quad * 8];
#pragma unroll
        for (int t = 0; t < NBLK; t++) {
            short8 b0 = *(const short8*)&Bs[t * 64 + wn + l15][quad * 8];
            short8 b1 = *(const short8*)&Bs[t * 64 + wn + 16 + l15][quad * 8];
            acc[t][0][0] = __builtin_amdgcn_mfma_f32_16x16x32_bf16(a0, b0, acc[t][0][0], 0, 0, 0);
            acc[t][0][1] = __builtin_amdgcn_mfma_f32_16x16x32_bf16(a0, b1, acc[t][0][1], 0, 0, 0);
            acc[t][1][0] = __builtin_amdgcn_mfma_f32_16x16x32_bf16(a1, b0, acc[t][1][0], 0, 0, 0);
            acc[t][1][1] = __builtin_amdgcn_mfma_f32_16x16x32_bf16(a1, b1, acc[t][1][1], 0, 0, 0);
        }
        __syncthreads();
    }
#pragma unroll
    for (int t = 0; t < NBLK; t++)
#pragma unroll
        for (int i = 0; i < 2; i++)
#pragma unroll
            for (int j = 0; j < 2; j++)
#pragma unroll
                for (int r = 0; r < 4; r++) {
                    int row = row0 + wm + i * 16 + quad * 4 + r;
                    int col = col0 + t * 64 + wn + j * 16 + l15;
                    if (row < M) storec(&C[(long)row * ldc + col], acc[t][i][j][r]);
                }
}

// ---------------- vector GEMM (fp32, small) ---------------------------------
__global__ __launch_bounds__(256)
void gemm64(const float* __restrict__ A, int lda,
            const float* __restrict__ B, int ldb,
            float* __restrict__ C, int ldc,
            int M, int N, int K)
{
    __shared__ float As[16][68];
    __shared__ float Bs[16][68];
    const int tid = threadIdx.x;
    const int row0 = blockIdx.x * 64, col0 = blockIdx.y * 64;
    float acc[4][4];
#pragma unroll
    for (int i = 0; i < 4; i++)
#pragma unroll
        for (int j = 0; j < 4; j++) acc[i][j] = 0.f;
    const int ar = tid >> 2, ak = (tid & 3) * 4;
    const int bk = tid >> 4, bc = (tid & 15) * 4;
    const int ty4 = (tid >> 4) * 4, tx4 = (tid & 15) * 4;
    for (int k0 = 0; k0 < K; k0 += 16) {
        {
            int row = row0 + ar;
            float4 v = make_float4(0.f, 0.f, 0.f, 0.f);
            if (row < M) v = *(const float4*)(A + (long)row * lda + k0 + ak);
            As[ak + 0][ar] = v.x; As[ak + 1][ar] = v.y;
            As[ak + 2][ar] = v.z; As[ak + 3][ar] = v.w;
        }
        {
            int c = col0 + bc;
            float4 v = make_float4(0.f, 0.f, 0.f, 0.f);
            if (c < N) v = *(const float4*)(B + (long)(k0 + bk) * ldb + c);
            *(float4*)&Bs[bk][bc] = v;
        }
        __syncthreads();
#pragma unroll
        for (int k = 0; k < 16; k++) {
            float4 a = *(const float4*)&As[k][ty4];
            float4 b = *(const float4*)&Bs[k][tx4];
            acc[0][0] += a.x * b.x; acc[0][1] += a.x * b.y; acc[0][2] += a.x * b.z; acc[0][3] += a.x * b.w;
            acc[1][0] += a.y * b.x; acc[1][1] += a.y * b.y; acc[1][2] += a.y * b.z; acc[1][3] += a.y * b.w;
            acc[2][0] += a.z * b.x; acc[2][1] += a.z * b.y; acc[2][2] += a.z * b.z; acc[2][3] += a.z * b.w;
            acc[3][0] += a.w * b.x; acc[3][1] += a.w * b.y; acc[3][2] += a.w * b.z; acc[3][3] += a.w * b.w;
        }
        __syncthreads();
    }
    int c = col0 + tx4;
#pragma unroll
    for (int i = 0; i < 4; i++) {
        int r = row0 + ty4 + i;
        if (r < M && c < N)
            *(float4*)&C[(long)r * ldc + c] =
                make_float4(acc[i][0], acc[i][1], acc[i][2], acc[i][3]);
    }
}

// ---------------- utility / CSR build ---------------------------------------
__global__ void filli(int* p, long n, int v)
{
    long i = (long)blockIdx.x * blockDim.x + threadIdx.x;
    long st = (long)gridDim.x * blockDim.x;
    for (; i < n; i += st) p[i] = v;
}

__global__ void hist_int(const int* __restrict__ key, long n, int* __restrict__ h)
{
    long i = (long)blockIdx.x * blockDim.x + threadIdx.x;
    long st = (long)gridDim.x * blockDim.x;
    for (; i < n; i += st) atomicAdd(&h[key[i]], 1);
}

__global__ __launch_bounds__(1024)
void scan_bsum(const int* __restrict__ in, int n, int* __restrict__ btot)
{
    __shared__ int sh[1024];
    int tid = threadIdx.x;
    int i0 = blockIdx.x * 4096 + tid * 4;
    int s = 0;
#pragma unroll
    for (int t = 0; t < 4; t++) { int idx = i0 + t; s += (idx < n) ? in[idx] : 0; }
    sh[tid] = s;
    __syncthreads();
    for (int off = 512; off > 0; off >>= 1) {
        if (tid < off) sh[tid] += sh[tid + off];
        __syncthreads();
    }
    if (tid == 0) btot[blockIdx.x] = sh[0];
}

__global__ void scan_tiny(const int* __restrict__ btot, int nb, int* __restrict__ boff)
{
    if (threadIdx.x == 0) {
        int c = 0;
        for (int b = 0; b < nb; b++) { boff[b] = c; c += btot[b]; }
        boff[nb] = c;
    }
}

__global__ __launch_bounds__(1024)
void scan_final(const int* __restrict__ in, int n, const int* __restrict__ boff,
                int nb, int* __restrict__ out)
{
    __shared__ int buf[1024];
    int tid = threadIdx.x;
    int i0 = blockIdx.x * 4096 + tid * 4;
    int v[4]; int s = 0;
#pragma unroll
    for (int t = 0; t < 4; t++) {
        int idx = i0 + t;
        v[t] = (idx < n) ? in[idx] : 0;
        s += v[t];
    }
    buf[tid] = s;
    __syncthreads();
    for (int off = 1; off < 1024; off <<= 1) {
        int t = (tid >= off) ? buf[tid - off] : 0;
        __syncthreads();
        buf[tid] += t;
        __syncthreads();
    }
    int excl = buf[tid] - s + boff[blockIdx.x];
#pragma unroll
    for (int t = 0; t < 4; t++) {
        int idx = i0 + t;
        if (idx < n) out[idx] = excl;
        excl += v[t];
    }
    if (blockIdx.x == 0 && tid == 0) out[n] = boff[nb];
}

__global__ void bin_by(const int* __restrict__ key, long n,
                       const int* __restrict__ off, int* __restrict__ cursor,
                       int* __restrict__ bins)
{
    long i = (long)blockIdx.x * blockDim.x + threadIdx.x;
    long st = (long)gridDim.x * blockDim.x;
    for (; i < n; i += st) {
        int k = key[i];
        int pos = off[k] + atomicAdd(&cursor[k], 1);
        bins[pos] = (int)i;
    }
}

__global__ void dinv_from_deg(const int* __restrict__ deg, float* __restrict__ dinv, long n)
{
    long i = (long)blockIdx.x * blockDim.x + threadIdx.x;
    long st = (long)gridDim.x * blockDim.x;
    for (; i < n; i += st) dinv[i] = rsqrtf((float)(deg[i] + 1));
}

__global__ void mol_enorm(const int* __restrict__ src, const int* __restrict__ dst,
                          const float* __restrict__ dinv, long E, float* __restrict__ en)
{
    long i = (long)blockIdx.x * blockDim.x + threadIdx.x;
    long st = (long)gridDim.x * blockDim.x;
    for (; i < E; i += st) en[i] = dinv[src[i]] * dinv[dst[i]];
}

// ---------------- batch-norm stats (v2: vectorized, NBLK_STATS blocks) ------
__global__ __launch_bounds__(256)
void colstats_b16_v2(const u16* __restrict__ X, int M, int ld, int c0, int NC,
                     float* __restrict__ p1, float* __restrict__ p2)
{
    __shared__ float sh1[1024], sh2[1024];
    int tid = threadIdx.x;
    int ncg = NC >> 2;                 // col groups of 4
    int cg  = tid & (ncg - 1);
    int rg  = tid / ncg;
    int nrg = 256 / ncg;
    float s0=0,s1=0,s2=0,s3=0, q0=0,q1=0,q2=0,q3=0;
    const u16* base = X + c0 + 4 * cg;
    for (long row = (long)blockIdx.x * nrg + rg; row < M; row += (long)gridDim.x * nrg) {
        ushort4 v = *(const ushort4*)(base + row * (long)ld);
        float f0 = b2f(v.x), f1 = b2f(v.y), f2 = b2f(v.z), f3 = b2f(v.w);
        s0 += f0; q0 += f0 * f0; s1 += f1; q1 += f1 * f1;
        s2 += f2; q2 += f2 * f2; s3 += f3; q3 += f3 * f3;
    }
    float4* S1 = (float4*)sh1; float4* S2 = (float4*)sh2;
    S1[tid] = make_float4(s0, s1, s2, s3);
    S2[tid] = make_float4(q0, q1, q2, q3);
    __syncthreads();
    for (int off = nrg >> 1; off > 0; off >>= 1) {
        if (rg < off) {
            float4 a = S1[tid], b = S1[tid + off * ncg];
            S1[tid] = make_float4(a.x + b.x, a.y + b.y, a.z + b.z, a.w + b.w);
            float4 c = S2[tid], d = S2[tid + off * ncg];
            S2[tid] = make_float4(c.x + d.x, c.y + d.y, c.z + d.z, c.w + d.w);
        }
        __syncthreads();
    }
    if (rg == 0) {
        *(float4*)&p1[(long)blockIdx.x * NC + 4 * cg] = S1[tid];
        *(float4*)&p2[(long)blockIdx.x * NC + 4 * cg] = S2[tid];
    }
}

__global__ __launch_bounds__(256)
void colstats_f32_v2(const float* __restrict__ X, int M, int N,
                     float* __restrict__ p1, float* __restrict__ p2)
{
    __shared__ float sh1[1024], sh2[1024];
    int tid = threadIdx.x;
    int ncg = N >> 2;
    int cg  = tid & (ncg - 1);
    int rg  = tid / ncg;
    int nrg = 256 / ncg;
    float s0=0,s1=0,s2=0,s3=0, q0=0,q1=0,q2=0,q3=0;
    const float* base = X + 4 * cg;
    for (long row = (long)blockIdx.x * nrg + rg; row < M; row += (long)gridDim.x * nrg) {
        float4 v = *(const float4*)(base + row * (long)N);
        s0 += v.x; q0 += v.x * v.x; s1 += v.y; q1 += v.y * v.y;
        s2 += v.z; q2 += v.z * v.z; s3 += v.w; q3 += v.w * v.w;
    }
    float4* S1 = (float4*)sh1; float4* S2 = (float4*)sh2;
    S1[tid] = make_float4(s0, s1, s2, s3);
    S2[tid] = make_float4(q0, q1, q2, q3);
    __syncthreads();
    for (int off = nrg >> 1; off > 0; off >>= 1) {
        if (rg < off) {
            float4 a = S1[tid], b = S1[tid + off * ncg];
            S1[tid] = make_float4(a.x + b.x, a.y + b.y, a.z + b.z, a.w + b.w);
            float4 c = S2[tid], d = S2[tid + off * ncg];
            S2[tid] = make_float4(c.x + d.x, c.y + d.y, c.z + d.z, c.w + d.w);
        }
        __syncthreads();
    }
    if (rg == 0) {
        *(float4*)&p1[(long)blockIdx.x * N + 4 * cg] = S1[tid];
        *(float4*)&p2[(long)blockIdx.x * N + 4 * cg] = S2[tid];
    }
}

__global__ void colstats_reduce_v2(const float* __restrict__ p1, const float* __restrict__ p2,
                                   int nblk, int N, float invM,
                                   float* __restrict__ s1o, float* __restrict__ s2o)
{
    __shared__ float sh1[256], sh2[256];
    int tid = threadIdx.x;
    int col = blockIdx.x * 64 + (tid & 63);
    int seg = tid >> 6;
    float a = 0.f, c = 0.f;
    for (int b = seg; b < nblk; b += 4) {
        a += p1[(long)b * N + col];
        c += p2[(long)b * N + col];
    }
    sh1[tid] = a; sh2[tid] = c;
    __syncthreads();
    if (seg == 0) {
        a = sh1[tid] + sh1[tid + 64] + sh1[tid + 128] + sh1[tid + 192];
        c = sh2[tid] + sh2[tid + 64] + sh2[tid + 128] + sh2[tid + 192];
        float mean = a * invM;
        float var  = fmaxf(c * invM - mean * mean, 0.f);
        s1o[col] = mean;
        s2o[col] = rsqrtf(var + 1e-5f);
    }
}

__global__ void bn_apply(float* X, long total, int mask,
                         const float* __restrict__ s1, const float* __restrict__ s2)
{
    long i = (long)blockIdx.x * blockDim.x + threadIdx.x;
    long st = (long)gridDim.x * blockDim.x;
    for (; i < total; i += st) {
        int j = (int)(i & mask);
        X[i] = fmaxf((X[i] - s1[j]) * s2[j], 0.f);
    }
}

// BN+ReLU, fp32 in place AND bf16 copy
__global__ void bn_apply_dual(float* __restrict__ X, u16* __restrict__ Xb, long total,
                              int mask, const float* __restrict__ s1,
                              const float* __restrict__ s2)
{
    long i = (long)blockIdx.x * blockDim.x + threadIdx.x;
    long st = (long)gridDim.x * blockDim.x;
    for (; i < total; i += st) {
        int j = (int)(i & mask);
        float y = fmaxf((X[i] - s1[j]) * s2[j], 0.f);
        X[i] = y;
        Xb[i] = f2b(y);
    }
}

// BN+ReLU in place on bf16 contiguous [M, NC]; u32 words (2 cols each)
__global__ void bn_apply_b16_v2(u32* __restrict__ X, long n2, int maskHalf,
                                const float* __restrict__ s1, const float* __restrict__ s2)
{
    long i = (long)blockIdx.x * blockDim.x + threadIdx.x;
    long st = (long)gridDim.x * blockDim.x;
    for (; i < n2; i += st) {
        u32 v = X[i];
        int f = (int)(i & maskHalf) * 2;
        float y0 = fmaxf((b2f((u16)(v & 0xFFFF)) - s1[f])     * s2[f],     0.f);
        float y1 = fmaxf((b2f((u16)(v >> 16))    - s1[f + 1]) * s2[f + 1], 0.f);
        X[i] = (u32)f2b(y0) | ((u32)f2b(y1) << 16);
    }
}

// ---------------- CSR aggregation (no atomics) ------------------------------
__global__ __launch_bounds__(256)
void mol_agg_in(const void* __restrict__ Xraw, const u16* __restrict__ Xcvt,
                const int* __restrict__ flagp, const float* __restrict__ dinv,
                const int* __restrict__ off, const int2* __restrict__ eb,
                int NM, u16* __restrict__ out)
{
    const u16* X = (*flagp != 0) ? Xcvt : (const u16*)Xraw;
    int wid  = (int)(((long)blockIdx.x * 256 + threadIdx.x) >> 6);
    int lane = threadIdx.x & 63;
    if (wid >= NM) return;
    float dv = dinv[wid];
    float acc = b2f(X[(long)wid * 64 + lane]) * dv * dv;
    int j = off[wid], j1 = off[wid + 1];
    for (; j + 3 < j1; j += 4) {
        int2 e0 = eb[j], e1 = eb[j + 1], e2 = eb[j + 2], e3 = eb[j + 3];
        float v0 = b2f(X[(long)e0.x * 64 + lane]);
        float v1 = b2f(X[(long)e1.x * 64 + lane]);
        float v2 = b2f(X[(long)e2.x * 64 + lane]);
        float v3 = b2f(X[(long)e3.x * 64 + lane]);
        acc += v0 * __int_as_float(e0.y) + v1 * __int_as_float(e1.y)
             + v2 * __int_as_float(e2.y) + v3 * __int_as_float(e3.y);
    }
    for (; j < j1; j++) {
        int2 e = eb[j];
        acc += b2f(X[(long)e.x * 64 + lane]) * __int_as_float(e.y);
    }
    out[(long)wid * 64 + lane] = f2b(acc);
}

__global__ __launch_bounds__(256)
void mol_agg128(const u16* __restrict__ G, const float* __restrict__ dinv,
                const int* __restrict__ off, const int2* __restrict__ eb,
                int NM, u16* __restrict__ out)
{
    int wid  = (int)(((long)blockIdx.x * 256 + threadIdx.x) >> 6);
    int lane = threadIdx.x & 63;
    if (wid >= NM) return;
    float dv = dinv[wid], dv2 = dv * dv;
    u32 u = *(const u32*)(G + (long)wid * 128 + 2 * lane);
    float a0 = b2f((u16)(u & 0xFFFF)) * dv2;
    float a1 = b2f((u16)(u >> 16)) * dv2;
    int j = off[wid], j1 = off[wid + 1];
    for (; j + 3 < j1; j += 4) {
        int2 e0 = eb[j], e1 = eb[j + 1], e2 = eb[j + 2], e3 = eb[j + 3];
        u32 v0 = *(const u32*)(G + (long)e0.x * 128 + 2 * lane);
        u32 v1 = *(const u32*)(G + (long)e1.x * 128 + 2 * lane);
        u32 v2 = *(const u32*)(G + (long)e2.x * 128 + 2 * lane);
        u32 v3 = *(const u32*)(G + (long)e3.x * 128 + 2 * lane);
        float n0 = __int_as_float(e0.y), n1 = __int_as_float(e1.y);
        float n2 = __int_as_float(e2.y), n3 = __int_as_float(e3.y);
        a0 += b2f((u16)(v0 & 0xFFFF)) * n0 + b2f((u16)(v1 & 0xFFFF)) * n1
            + b2f((u16)(v2 & 0xFFFF)) * n2 + b2f((u16)(v3 & 0xFFFF)) * n3;
        a1 += b2f((u16)(v0 >> 16)) * n0 + b2f((u16)(v1 >> 16)) * n1
            + b2f((u16)(v2 >> 16)) * n2 + b2f((u16)(v3 >> 16)) * n3;
    }
    for (; j < j1; j++) {
        int2 e = eb[j];
        u32 v = *(const u32*)(G + (long)e.x * 128 + 2 * lane);
        float n = __int_as_float(e.y);
        a0 += b2f((u16)(v & 0xFFFF)) * n;
        a1 += b2f((u16)(v >> 16)) * n;
    }
    u32 o = (u32)f2b(a0) | ((u32)f2b(a1) << 16);
    *(u32*)(out + (long)wid * 128 + 2 * lane) = o;
}

// RGCN pre-aggregation v2: one wave per (node, relation) segment.
// Segments binned by key dst*8+et; mean norm = 1/max(len,1). Register-only
// accumulation (4 f32/lane covers 256 cols). eb[j] = src node index.
__global__ __launch_bounds__(256)
void kg_preagg2(const u16* __restrict__ xin, const int* __restrict__ off2,
                const int* __restrict__ eb, int NSEG, u16* __restrict__ aggx)
{
    int seg  = (int)(((long)blockIdx.x * 256 + threadIdx.x) >> 6);
    int lane = threadIdx.x & 63;
    if (seg >= NSEG) return;
    int node = seg >> 3, r = seg & 7;
    const int c4 = 4 * lane;
    int j0 = off2[seg], j1 = off2[seg + 1];
    float a0 = 0.f, a1 = 0.f, a2 = 0.f, a3 = 0.f;
    int j = j0;
    for (; j + 3 < j1; j += 4) {
        int s0 = eb[j], s1 = eb[j + 1], s2 = eb[j + 2], s3 = eb[j + 3];
        ushort4 v0 = *(const ushort4*)(xin + (long)s0 * 256 + c4);
        ushort4 v1 = *(const ushort4*)(xin + (long)s1 * 256 + c4);
        ushort4 v2 = *(const ushort4*)(xin + (long)s2 * 256 + c4);
        ushort4 v3 = *(const ushort4*)(xin + (long)s3 * 256 + c4);
        a0 += b2f(v0.x) + b2f(v1.x) + b2f(v2.x) + b2f(v3.x);
        a1 += b2f(v0.y) + b2f(v1.y) + b2f(v2.y) + b2f(v3.y);
        a2 += b2f(v0.z) + b2f(v1.z) + b2f(v2.z) + b2f(v3.z);
        a3 += b2f(v0.w) + b2f(v1.w) + b2f(v2.w) + b2f(v3.w);
    }
    for (; j < j1; j++) {
        ushort4 v = *(const ushort4*)(xin + (long)eb[j] * 256 + c4);
        a0 += b2f(v.x); a1 += b2f(v.y); a2 += b2f(v.z); a3 += b2f(v.w);
    }
    float nrm = 1.0f / fmaxf((float)(j1 - j0), 1.0f);
    ushort4 o;
    o.x = f2b(a0 * nrm); o.y = f2b(a1 * nrm);
    o.z = f2b(a2 * nrm); o.w = f2b(a3 * nrm);
    *(ushort4*)(aggx + (long)node * 2304 + 256 + (r << 8) + c4) = o;
}

// copy xin rows into AGGX cols 0:255
__global__ void xcopy_aggx(const u16* __restrict__ xin, u16* __restrict__ aggx, long n4)
{
    long i = (long)blockIdx.x * blockDim.x + threadIdx.x;
    long st = (long)gridDim.x * blockDim.x;
    for (; i < n4; i += st) {
        long node = i >> 6;
        int c4 = (int)(i & 63) * 4;
        *(ushort4*)(aggx + node * 2304 + c4) = *(const ushort4*)(xin + node * 256 + c4);
    }
}

// mean-pool bf16 chunk [NM,64] with fused BN+ReLU
__global__ __launch_bounds__(256)
void pool_b16(const u16* __restrict__ g, const int* __restrict__ off,
              const int* __restrict__ bins, int ND,
              const float* __restrict__ s1, const float* __restrict__ s2,
              float* __restrict__ gout, int c0)
{
    int wid  = (int)(((long)blockIdx.x * 256 + threadIdx.x) >> 6);
    int lane = threadIdx.x & 63;
    if (wid >= ND) return;
    float m = s1[lane], r = s2[lane];
    int j0 = off[wid], j1 = off[wid + 1];
    float acc = 0.f;
    for (int j = j0; j < j1; j++)
        acc += fmaxf((b2f(g[(long)bins[j] * 64 + lane]) - m) * r, 0.f);
    gout[(long)wid * 256 + c0 + lane] = acc / fmaxf((float)(j1 - j0), 1.0f);
}

// ---------------- attention fusion ------------------------------------------
__global__ void attention_fuse(const float* __restrict__ go, const float* __restrict__ fpv,
                               const float* __restrict__ W1, const float* __restrict__ B1,
                               const float* __restrict__ W2,
                               float* __restrict__ emb, float* __restrict__ beta_out)
{
    int d = blockIdx.x;
    int t = threadIdx.x;
    __shared__ float z[2][256];
    __shared__ float red[128];
    for (int c = t; c < 256; c += 128) {
        z[0][c] = go[(long)d * 256 + c];
        z[1][c] = fpv[(long)d * 256 + c];
    }
    __syncthreads();
    float s[2];
    for (int v = 0; v < 2; v++) {
        float acc = B1[t];
        for (int k = 0; k < 256; k++) acc += z[v][k] * W1[k * 128 + t];
        red[t] = tanhf(acc) * W2[t];
        __syncthreads();
        for (int off = 64; off > 0; off >>= 1) {
            if (t < off) red[t] += red[t + off];
            __syncthreads();
        }
        s[v] = red[0];
        __syncthreads();
    }
    float m = fmaxf(s[0], s[1]);
    float e0 = expf(s[0] - m), e1 = expf(s[1] - m);
    float inv = 1.0f / (e0 + e1);
    float b0 = e0 * inv, b1 = e1 * inv;
    for (int c = t; c < 256; c += 128)
        emb[(long)d * 256 + c] = b0 * z[0][c] + b1 * z[1][c];
    if (t == 0) {
        beta_out[d * 2 + 0] = b0;
        beta_out[d * 2 + 1] = b1;
    }
}

// ---------------- final linear + log_softmax, fused BN on x4 ----------------
__global__ void logits_out_bn(const float* __restrict__ x4,
                              const float* __restrict__ s1, const float* __restrict__ s2,
                              const float* __restrict__ w, const float* __restrict__ b,
                              float* __restrict__ out, int NKG)
{
    int i = blockIdx.x * blockDim.x + threadIdx.x;
    if (i >= NKG) return;
    float a0 = b[0], a1 = b[1];
    for (int k = 0; k < 64; k++) {
        float v = fmaxf((x4[(long)i * 64 + k] - s1[k]) * s2[k], 0.f);
        a0 += v * w[k * 2 + 0];
        a1 += v * w[k * 2 + 1];
    }
    float m = fmaxf(a0, a1);
    float lse = m + logf(expf(a0 - m) + expf(a1 - m));
    out[i * 2 + 0] = a0 - lse;
    out[i * 2 + 1] = a1 - lse;
}

// ============================================================================
extern "C" void kernel_launch(void* const* d_in, const int* in_sizes, int n_in,
                              void* d_out, int out_size, void* d_ws, size_t ws_size,
                              hipStream_t stream)
{
    (void)in_sizes; (void)n_in; (void)out_size; (void)ws_size;
    const int ND = 4096, NM = 131072, NKG = 9510, NGENE = 5414;
    const long EM = 524288, EK = 524288;
    const int NSEG = 8 * NKG;   // 76080 (node, relation) segments

    const void* fp_data = d_in[0];
    const void* mol_x   = d_in[1];
    const int*  mol_batch = (const int*)d_in[2];
    const int*  mol_ei  = (const int*)d_in[3];
    const int*  kg_ei   = (const int*)d_in[4];
    const int*  kg_et   = (const int*)d_in[5];

    const int* mol_src = mol_ei;
    const int* mol_dst = mol_ei + EM;
    const int* kg_src  = kg_ei;
    const int* kg_dst  = kg_ei + EK;

    float* out_ls   = (float*)d_out;          // [9510,2] fp32
    float* out_beta = (float*)d_out + 19020;  // [4096,2,1] fp32

    // ---- workspace carve ----
    char* wp = (char*)d_ws;
    auto carve = [&](size_t bytes) { char* p = wp; wp += (bytes + 255) & ~(size_t)255; return p; };
    float* stats = (float*)carve(4096);
    int*   flag  = (int*)carve(256);
    float* dinv  = (float*)carve((size_t)NM * 4);
    float* enM   = (float*)carve((size_t)EM * 4);
    float* part1 = (float*)carve((size_t)NBLK_STATS * 512 * 4);
    float* part2 = (float*)carve((size_t)NBLK_STATS * 512 * 4);
    int*   sbt   = (int*)carve(256);
    int*   sbo   = (int*)carve(256);
    float* Wpool = (float*)carve((size_t)1630000 * 4);     // fp32 weights
    u16*   WpoolB= (u16*)carve((size_t)1630000 * 2);       // bf16 weights
    u16*   WpoolT= (u16*)carve((size_t)1600000 * 2);       // bf16 transposed gemm weights
    float* fpb   = (float*)carve((size_t)ND * 256 * 4);
    float* gout  = (float*)carve((size_t)ND * 256 * 4);
    int*   key2  = (int*)carve((size_t)EK * 4);            // kg seg keys; reused as ebK2
    int*   koff2 = (int*)carve((size_t)(NSEG + 1) * 4);
    // zero-span
    char*  z0    = wp;
    int* kdeg2 = (int*)carve((size_t)NSEG * 4);
    int* kcur2 = (int*)carve((size_t)NSEG * 4);
    int* mdeg = (int*)carve((size_t)NM * 4);
    int* mcur = (int*)carve((size_t)NM * 4);
    int* pdeg = (int*)carve((size_t)ND * 4);
    int* pcur = (int*)carve((size_t)ND * 4);
    char*  z1    = wp;
    int* moff = (int*)carve((size_t)(NM + 1) * 4);
    int* mbins= (int*)carve((size_t)EM * 4);
    int* kbins= (int*)carve((size_t)EK * 4);
    int* poff = (int*)carve((size_t)(ND + 1) * 4);
    int* pbins= (int*)carve((size_t)NM * 4);
    char*  REG1  = carve((size_t)NM * 128 * 2);            // 33.6 MB
    char*  REG2  = carve((size_t)NM * 128 * 2);            // 33.6 MB  (contiguous with HB)
    u16*   HB    = (u16*)carve((size_t)NM * 64 * 2);       // 16.8 MB

    // phase views
    float* fp1 = (float*)REG1;                 // fp: [4096,512] f32
    u16*   XB  = (u16*)REG1;                   // mol pre: [NM,64] bf16 converted input
    u16*   G1  = (u16*)REG1;                   // mol: [NM,128] bf16
    // rgcn chain in REG1:
    float* xkg = (float*)REG1;                 // [NKG,256] f32 (emb+gene)
    float* x2  = xkg + (size_t)NKG * 256;      // [NKG,256] f32
    float* x3  = x2  + (size_t)NKG * 256;      // [NKG,128] f32
    float* x4  = x3  + (size_t)NKG * 128;      // [NKG,64]  f32
    u16*   xb  = (u16*)(x4 + (size_t)NKG * 64);// [NKG,256] bf16 (after x4, fits REG1)
    u16*   x2b = (u16*)REG1;                   // [NKG,256] bf16 (overlaps xkg: dead then)
    u16*   Xfb = (u16*)REG2;                   // fp: [4096,1024] bf16
    u16*   G1A = (u16*)REG2;                   // mol: [NM,128] bf16 aggregated
    u16*   AGGX= (u16*)REG2;                   // rgcn: [NKG,2304] bf16 (43.8 MB, REG2+HB)
    u16*   fp1b = HB;                          // fp: [4096,512] bf16
    u16*   Xagg = HB;                          // mol L1: [NM,64] bf16
    // flattened CSR edge tables (aliased; lifetimes verified)
    int2* ebM  = (int2*)gout;                  // mol edges; gout written only after dead
    int*  ebK2 = key2;                         // kg src table; key2 dead after bin_by

    // ---- dtype detect + weight conversion (fp32 + bf16 pools) ----
    zero_int<<<1, 1, 0, stream>>>(flag);
    detect_f32<<<1024, 256, 0, stream>>>((const u16*)fp_data, (long)ND * 1024, flag);
    ConvTab tab;
    // NOTE: rg_root before rg_w so [root; W_0..W_7] is contiguous = [2304, N] GEMM B
    const int widx[14] = {6, 8, 10, 12, 14, 15, 16, 19, 18, 22, 21, 24, 26, 27};
    const int wn[14]   = {1024*512, 512*256, 64*128, 128*256, 256*128, 128, 128,
                          256*256, 8*256*256, 256*128, 8*256*128, 128*64, 64*2, 2};
    float* wf[14]; u16* wb[14];
    {
        size_t o = 0;
        for (int i = 0; i < 14; i++) {
            tab.src[i]  = d_in[widx[i]];
            tab.dst[i]  = Wpool + o;
            tab.dstB[i] = WpoolB + o;
            tab.n[i]    = wn[i];
            wf[i] = Wpool + o; wb[i] = WpoolB + o;
            o += (size_t)wn[i];
        }
    }
    conv_all<<<dim3(32, 14), 256, 0, stream>>>(tab, flag);
    float *att_w1c = wf[4], *att_b1c = wf[5], *att_w2c = wf[6];
    float *lin1_wc = wf[11], *lin2_wc = wf[12], *lin2_bc = wf[13];

    // ---- transposed bf16 weights for gemm_bt (BT[n*K+k] = B[k*N+n]) ----
    u16* T_fpw1  = WpoolT;                        // [512,1024]
    u16* T_fpw2  = T_fpw1 + (size_t)512 * 1024;   // [256,512]
    u16* T_gcnw1 = T_fpw2 + (size_t)256 * 512;    // [128,64]
    u16* T_gcnw2 = T_gcnw1 + (size_t)128 * 64;    // [256,128]
    u16* T_w1    = T_gcnw2 + (size_t)256 * 128;   // [256,2304]
    u16* T_w2    = T_w1 + (size_t)256 * 2304;     // [128,2304]
    transpose_b16<<<dim3(32, 16), 256, 0, stream>>>(wb[0], T_fpw1, 1024, 512);
    transpose_b16<<<dim3(16, 8),  256, 0, stream>>>(wb[1], T_fpw2, 512, 256);
    transpose_b16<<<dim3(2, 4),   256, 0, stream>>>(wb[2], T_gcnw1, 64, 128);
    transpose_b16<<<dim3(4, 8),   256, 0, stream>>>(wb[3], T_gcnw2, 128, 256);
    transpose_b16<<<dim3(72, 8),  256, 0, stream>>>(wb[7], T_w1, 2304, 256);
    transpose_b16<<<dim3(72, 4),  256, 0, stream>>>(wb[9], T_w2, 2304, 128);

    // ---- CSR builds ----
    filli<<<512, 256, 0, stream>>>((int*)z0, (long)(z1 - z0) / 4, 0);
    auto scan = [&](const int* deg, int* off, int n) {
        int nb = divup(n, 4096);
        scan_bsum<<<nb, 1024, 0, stream>>>(deg, n, sbt);
        scan_tiny<<<1, 64, 0, stream>>>(sbt, nb, sbo);
        scan_final<<<nb, 1024, 0, stream>>>(deg, n, sbo, nb, off);
    };
    hist_int<<<2048, 256, 0, stream>>>(mol_dst, EM, mdeg);
    scan(mdeg, moff, NM);
    bin_by<<<2048, 256, 0, stream>>>(mol_dst, EM, moff, mcur, mbins);
    dinv_from_deg<<<512, 256, 0, stream>>>(mdeg, dinv, NM);
    mol_enorm<<<1024, 256, 0, stream>>>(mol_src, mol_dst, dinv, EM, enM);
    flatten_mol<<<2048, 256, 0, stream>>>(mbins, mol_src, enM, EM, ebM);

    // KG: segment CSR over (dst, relation); mean norm from segment length
    kg_key2<<<2048, 256, 0, stream>>>(kg_dst, kg_et, EK, key2);
    hist_int<<<2048, 256, 0, stream>>>(key2, EK, kdeg2);
    scan(kdeg2, koff2, NSEG);
    bin_by<<<2048, 256, 0, stream>>>(key2, EK, koff2, kcur2, kbins);
    flatten_kg_src<<<2048, 256, 0, stream>>>(kbins, kg_src, EK, ebK2);  // key2 dead

    hist_int<<<512, 256, 0, stream>>>(mol_batch, NM, pdeg);
    scan(pdeg, poff, ND);
    bin_by<<<512, 256, 0, stream>>>(mol_batch, NM, poff, pcur, pbins);

    // ---- BN helpers (v2) ----
    auto bn_stats = [&](const float* X, int M, int N) {
        colstats_f32_v2<<<NBLK_STATS, 256, 0, stream>>>(X, M, N, part1, part2);
        colstats_reduce_v2<<<N / 64, 256, 0, stream>>>(part1, part2, NBLK_STATS, N,
                                                       1.0f / M, stats, stats + 512);
    };
    auto bn_stats_b16 = [&](const u16* X, int M, int ld, int c0, int NC) {
        colstats_b16_v2<<<NBLK_STATS, 256, 0, stream>>>(X, M, ld, c0, NC, part1, part2);
        colstats_reduce_v2<<<NC / 64, 256, 0, stream>>>(part1, part2, NBLK_STATS, NC,
                                                        1.0f / M, stats, stats + 512);
    };

    // ---------- fingerprint MLP branch (MFMA) ----------
    conv_dual_b16<<<2048, 256, 0, stream>>>(fp_data, Xfb, (long)ND * 1024, flag);
    gemm_bt<float, 2><<<dim3(64, 4), 256, 0, stream>>>(
        Xfb, 1024, T_fpw1, 1024, fp1, 512, ND, 512, 1024);
    bn_stats(fp1, ND, 512);
    bn_apply_dual<<<2048, 256, 0, stream>>>(fp1, fp1b, (long)ND * 512, 511,
                                            stats, stats + 512);
    gemm_bt<float, 1><<<dim3(64, 4), 256, 0, stream>>>(
        fp1b, 512, T_fpw2, 512, fpb, 256, ND, 256, 512);
    bn_stats(fpb, ND, 256);
    bn_apply<<<2048, 256, 0, stream>>>(fpb, (long)ND * 256, 255, stats, stats + 512);

    // ---------- mol GCN layer 1: bf16-convert, aggregate-then-GEMM ----------
    conv_molx<<<2048, 256, 0, stream>>>((const float*)mol_x, XB, (long)NM * 16, flag);
    mol_agg_in<<<32768, 256, 0, stream>>>(mol_x, XB, flag, dinv, moff, ebM, NM, Xagg);
    gemm_bt<u16, 2><<<dim3(2048, 1), 256, 0, stream>>>(
        Xagg, 64, T_gcnw1, 64, G1, 128, NM, 128, 64);   // G1 overwrites XB (dead)
    bn_stats_b16(G1, NM, 128, 0, 128);
    bn_apply_b16_v2<<<8192, 256, 0, stream>>>((u32*)G1, (long)NM * 64, 63,
                                              stats, stats + 512);

    // ---------- mol GCN layer 2: aggregate-then-GEMM + BN + pool ------------
    mol_agg128<<<32768, 256, 0, stream>>>(G1, dinv, moff, ebM, NM, G1A);
    // ebM (gout) is dead past this point; pool_b16 below may overwrite gout
    for (int c0 = 0; c0 < 256; c0 += 64) {
        gemm_bt<u16, 1><<<dim3(2048, 1), 256, 0, stream>>>(
            G1A, 128, T_gcnw2 + (size_t)c0 * 128, 128, HB, 64, NM, 64, 128);
        bn_stats_b16(HB, NM, 64, 0, 64);
        pool_b16<<<1024, 256, 0, stream>>>(HB, poff, pbins, ND,
                                           stats, stats + 512, gout, c0);
    }

    // ---------- attention fusion ----------
    attention_fuse<<<ND, 128, 0, stream>>>(gout, fpb, att_w1c, att_b1c, att_w2c,
                                           xkg, out_beta);
    conv_in<<<512, 256, 0, stream>>>(d_in[17], xkg + (long)ND * 256,
                                     (long)NGENE * 256, flag);
    conv_f32_b16<<<1024, 256, 0, stream>>>(xkg, xb, (long)NKG * 256);

    // ---------- RGCN layer 1 (256 -> 256): preagg2 + single K=2304 GEMM -----
    xcopy_aggx<<<1024, 256, 0, stream>>>(xb, AGGX, (long)NKG * 64);
    kg_preagg2<<<divup((long)NSEG * 64, 256), 256, 0, stream>>>(
        xb, koff2, ebK2, NSEG, AGGX);
    gemm_bt<float, 4><<<dim3(divup(NKG, 64), 1), 256, 0, stream>>>(
        AGGX, 2304, T_w1, 2304, x2, 256, NKG, 256, 2304);
    bn_stats(x2, NKG, 256);
    bn_apply_dual<<<2048, 256, 0, stream>>>(x2, x2b, (long)NKG * 256, 255,
                                            stats, stats + 512);

    // ---------- RGCN layer 2 (256 -> 128): preagg2 + single K=2304 GEMM -----
    xcopy_aggx<<<1024, 256, 0, stream>>>(x2b, AGGX, (long)NKG * 64);
    kg_preagg2<<<divup((long)NSEG * 64, 256), 256, 0, stream>>>(
        x2b, koff2, ebK2, NSEG, AGGX);
    gemm_bt<float, 2><<<dim3(divup(NKG, 64), 1), 256, 0, stream>>>(
        AGGX, 2304, T_w2, 2304, x3, 128, NKG, 128, 2304);
    bn_stats(x3, NKG, 128);
    bn_apply<<<2048, 256, 0, stream>>>(x3, (long)NKG * 128, 127, stats, stats + 512);

    // ---------- classifier head ----------
    gemm64<<<dim3(divup(NKG, 64), 1, 1), 256, 0, stream>>>(
        x3, 128, lin1_wc, 64, x4, 64, NKG, 64, 128);
    bn_stats(x4, NKG, 64);
    logits_out_bn<<<divup(NKG, 256), 256, 0, stream>>>(x4, stats, stats + 512,
                                                       lin2_wc, lin2_bc, out_ls, NKG);
}

// Round 7
// 1227.082 us; speedup vs baseline: 1.1666x; 1.0188x over previous
//
#include <hip/hip_runtime.h>
#include <hip/hip_bf16.h>
#include <cstdint>

typedef __hip_bfloat16 bf16;
typedef unsigned short u16;
typedef unsigned int u32;
typedef __attribute__((ext_vector_type(8))) short short8;
typedef __attribute__((ext_vector_type(4))) float f32x4;

__device__ __forceinline__ float tofloat(float x){ return x; }
__device__ __forceinline__ float tofloat(bf16 x){ return __bfloat162float(x); }
__device__ __forceinline__ float b2f(u16 a){ return __uint_as_float(((unsigned)a) << 16); }
__device__ __forceinline__ u16 f2b(float f){           // round-to-nearest-even
    unsigned u = __float_as_uint(f);
    return (u16)((u + 0x7FFFu + ((u >> 16) & 1u)) >> 16);
}
__device__ __forceinline__ void storec(float* p, float v){ *p = v; }
__device__ __forceinline__ void storec(u16* p, float v){ *p = f2b(v); }

static inline int divup(long a, long b){ return (int)((a + b - 1) / b); }

#define NBLK_STATS 256

// ---------------- input dtype detection -------------------------------------
__global__ void zero_int(int* p){ *p = 0; }

__global__ void detect_f32(const u16* __restrict__ h, long n, int* flag)
{
    long i = (long)blockIdx.x * blockDim.x + threadIdx.x;
    long st = (long)gridDim.x * blockDim.x;
    int c = 0;
    for (; i < n; i += st)
        if (((h[i] >> 7) & 0xFF) == 0xFF) c++;
    if (c) atomicAdd(flag, c);
}

// convert all weights: fp32 pool + bf16 pool in one launch
struct ConvTab { const void* src[14]; float* dst[14]; u16* dstB[14]; int n[14]; };

__global__ void conv_all(ConvTab t, const int* __restrict__ flagp)
{
    bool f32 = (*flagp != 0);
    int seg = blockIdx.y;
    const void* s = t.src[seg];
    float* d = t.dst[seg];
    u16*   dB = t.dstB[seg];
    int n = t.n[seg];
    long i = (long)blockIdx.x * blockDim.x + threadIdx.x;
    long st = (long)gridDim.x * blockDim.x;
    for (; i < n; i += st) {
        float v = f32 ? ((const float*)s)[i] : tofloat(((const bf16*)s)[i]);
        d[i] = v; dB[i] = f2b(v);
    }
}

__global__ void conv_in(const void* __restrict__ src, float* __restrict__ dst,
                        long n, const int* __restrict__ flagp)
{
    bool f32 = (*flagp != 0);
    long i = (long)blockIdx.x * blockDim.x + threadIdx.x;
    long st = (long)gridDim.x * blockDim.x;
    for (; i < n; i += st)
        dst[i] = f32 ? ((const float*)src)[i] : tofloat(((const bf16*)src)[i]);
}

__global__ void conv_dual_b16(const void* __restrict__ src, u16* __restrict__ dst,
                              long n, const int* __restrict__ flagp)
{
    bool f32 = (*flagp != 0);
    long i = (long)blockIdx.x * blockDim.x + threadIdx.x;
    long st = (long)gridDim.x * blockDim.x;
    for (; i < n; i += st)
        dst[i] = f32 ? f2b(((const float*)src)[i]) : ((const u16*)src)[i];
}

__global__ void conv_f32_b16(const float* __restrict__ src, u16* __restrict__ dst, long n)
{
    long i = (long)blockIdx.x * blockDim.x + threadIdx.x;
    long st = (long)gridDim.x * blockDim.x;
    for (; i < n; i += st) dst[i] = f2b(src[i]);
}

// convert mol_x fp32 -> bf16 copy (only when input is fp32); vectorized x4
__global__ void conv_molx(const float* __restrict__ src, u16* __restrict__ dst,
                          long n4, const int* __restrict__ flagp)
{
    if (*flagp == 0) return;   // input already bf16; agg reads original
    long i = (long)blockIdx.x * blockDim.x + threadIdx.x;
    long st = (long)gridDim.x * blockDim.x;
    for (; i < n4; i += st) {
        float4 v = ((const float4*)src)[i];
        ushort4 o;
        o.x = f2b(v.x); o.y = f2b(v.y); o.z = f2b(v.z); o.w = f2b(v.w);
        ((ushort4*)dst)[i] = o;
    }
}

// bf16 transpose: dst[n*K + k] = src[k*N + n]
__global__ __launch_bounds__(256)
void transpose_b16(const u16* __restrict__ src, u16* __restrict__ dst, int K, int N)
{
    __shared__ u16 t[32][33];
    int k0 = blockIdx.x * 32, n0 = blockIdx.y * 32;
    int x = threadIdx.x & 31, y = threadIdx.x >> 5;   // y in 0..7
    for (int yy = y; yy < 32; yy += 8) {
        int k = k0 + yy, n = n0 + x;
        t[yy][x] = (k < K && n < N) ? src[(long)k * N + n] : (u16)0;
    }
    __syncthreads();
    for (int yy = y; yy < 32; yy += 8) {
        int n = n0 + yy, k = k0 + x;
        if (n < N && k < K) dst[(long)n * K + k] = t[x][yy];
    }
}

// ---------------- CSR edge flattening ---------------------------------------
// ebM[j] = {src, bits(en)}
__global__ void flatten_mol(const int* __restrict__ bins, const int* __restrict__ src,
                            const float* __restrict__ en, long E, int2* __restrict__ out)
{
    long i = (long)blockIdx.x * blockDim.x + threadIdx.x;
    long st = (long)gridDim.x * blockDim.x;
    for (; i < E; i += st) {
        int e = bins[i];
        out[i] = make_int2(src[e], __float_as_int(en[e]));
    }
}

// KG segment key: dst*8 + et  (segments = (node, relation) pairs)
__global__ void kg_key2(const int* __restrict__ dst, const int* __restrict__ et,
                        long E, int* __restrict__ key)
{
    long i = (long)blockIdx.x * blockDim.x + threadIdx.x;
    long st = (long)gridDim.x * blockDim.x;
    for (; i < E; i += st) key[i] = dst[i] * 8 + et[i];
}

// flatten KG edges to src index only (mean norm comes from segment length)
__global__ void flatten_kg_src(const int* __restrict__ bins, const int* __restrict__ src,
                               long E, int* __restrict__ out)
{
    long i = (long)blockIdx.x * blockDim.x + threadIdx.x;
    long st = (long)gridDim.x * blockDim.x;
    for (; i < E; i += st) out[i] = src[bins[i]];
}

// ---------------- MFMA GEMM (B pre-transposed): C = A @ B, bf16, fp32 acc ---
// A [M,K] lda; BT [N,K] ldbt. Tile 64 x (NBLK*64). Register-prefetch pipeline:
// next k-step's global loads issue right after the first barrier, hiding HBM
// latency under the MFMA cluster (critical when blocks/CU ~= 1).
template<typename TC, int NBLK>
__global__ __launch_bounds__(256)
void gemm_bt(const u16* __restrict__ A, int lda,
             const u16* __restrict__ BT, int ldbt,
             TC* __restrict__ C, int ldc,
             int M, int N, int K)
{
    __shared__ __align__(16) u16 As[64][40];          // [m][k]
    __shared__ __align__(16) u16 Bs[NBLK * 64][40];   // [n][k]
    const int tid = threadIdx.x;
    const int lane = tid & 63, wave = tid >> 6;
    const int l15 = lane & 15, quad = lane >> 4;
    const int wm = (wave & 1) * 32, wn = (wave >> 1) * 32;
    const int row0 = blockIdx.x * 64, col0 = blockIdx.y * (NBLK * 64);
    const int arow = tid >> 2, ak = (tid & 3) * 8;
    const int aok = row0 + arow < M;

    f32x4 acc[NBLK][2][2];
#pragma unroll
    for (int t = 0; t < NBLK; t++)
#pragma unroll
        for (int i = 0; i < 2; i++)
#pragma unroll
            for (int j = 0; j < 2; j++)
#pragma unroll
                for (int r = 0; r < 4; r++) acc[t][i][j][r] = 0.f;

    const u16* pa = A + (long)(row0 + arow) * lda + ak;
    const u16* pb[NBLK];
#pragma unroll
    for (int t = 0; t < NBLK; t++)
        pb[t] = BT + (long)(col0 + t * 64 + arow) * ldbt + ak;

    ushort4 ra0 = {0,0,0,0}, ra1 = {0,0,0,0};
    ushort4 rb0[NBLK], rb1[NBLK];
    // prologue: load k=0
    if (aok) { ra0 = *(const ushort4*)pa; ra1 = *(const ushort4*)(pa + 4); }
#pragma unroll
    for (int t = 0; t < NBLK; t++) {
        rb0[t] = *(const ushort4*)pb[t];
        rb1[t] = *(const ushort4*)(pb[t] + 4);
    }

    for (int k0 = 0; k0 < K; k0 += 32) {
        *(ushort4*)&As[arow][ak]     = ra0;
        *(ushort4*)&As[arow][ak + 4] = ra1;
#pragma unroll
        for (int t = 0; t < NBLK; t++) {
            *(ushort4*)&Bs[t * 64 + arow][ak]     = rb0[t];
            *(ushort4*)&Bs[t * 64 + arow][ak + 4] = rb1[t];
        }
        __syncthreads();
        if (k0 + 32 < K) {   // issue next-step loads; retire under MFMAs
            if (aok) {
                ra0 = *(const ushort4*)(pa + k0 + 32);
                ra1 = *(const ushort4*)(pa + k0 + 36);
            }
#pragma unroll
            for (int t = 0; t < NBLK; t++) {
                rb0[t] = *(const ushort4*)(pb[t] + k0 + 32);
                rb1[t] = *(const ushort4*)(pb[t] + k0 + 36);
            }
        }
        short8 a0 = *(const short8*)&As[wm + l15][quad * 8];
        short8 a1 = *(const short8*)&As[wm + 16 + l15][quad * 8];
#pragma unroll
        for (int t = 0; t < NBLK; t++) {
            short8 b0 = *(const short8*)&Bs[t * 64 + wn + l15][quad * 8];
            short8 b1 = *(const short8*)&Bs[t * 64 + wn + 16 + l15][quad * 8];
            acc[t][0][0] = __builtin_amdgcn_mfma_f32_16x16x32_bf16(a0, b0, acc[t][0][0], 0, 0, 0);
            acc[t][0][1] = __builtin_amdgcn_mfma_f32_16x16x32_bf16(a0, b1, acc[t][0][1], 0, 0, 0);
            acc[t][1][0] = __builtin_amdgcn_mfma_f32_16x16x32_bf16(a1, b0, acc[t][1][0], 0, 0, 0);
            acc[t][1][1] = __builtin_amdgcn_mfma_f32_16x16x32_bf16(a1, b1, acc[t][1][1], 0, 0, 0);
        }
        __syncthreads();
    }
#pragma unroll
    for (int t = 0; t < NBLK; t++)
#pragma unroll
        for (int i = 0; i < 2; i++)
#pragma unroll
            for (int j = 0; j < 2; j++)
#pragma unroll
                for (int r = 0; r < 4; r++) {
                    int row = row0 + wm + i * 16 + quad * 4 + r;
                    int col = col0 + t * 64 + wn + j * 16 + l15;
                    if (row < M) storec(&C[(long)row * ldc + col], acc[t][i][j][r]);
                }
}

// ---------------- vector GEMM (fp32, small) ---------------------------------
__global__ __launch_bounds__(256)
void gemm64(const float* __restrict__ A, int lda,
            const float* __restrict__ B, int ldb,
            float* __restrict__ C, int ldc,
            int M, int N, int K)
{
    __shared__ float As[16][68];
    __shared__ float Bs[16][68];
    const int tid = threadIdx.x;
    const int row0 = blockIdx.x * 64, col0 = blockIdx.y * 64;
    float acc[4][4];
#pragma unroll
    for (int i = 0; i < 4; i++)
#pragma unroll
        for (int j = 0; j < 4; j++) acc[i][j] = 0.f;
    const int ar = tid >> 2, ak = (tid & 3) * 4;
    const int bk = tid >> 4, bc = (tid & 15) * 4;
    const int ty4 = (tid >> 4) * 4, tx4 = (tid & 15) * 4;
    for (int k0 = 0; k0 < K; k0 += 16) {
        {
            int row = row0 + ar;
            float4 v = make_float4(0.f, 0.f, 0.f, 0.f);
            if (row < M) v = *(const float4*)(A + (long)row * lda + k0 + ak);
            As[ak + 0][ar] = v.x; As[ak + 1][ar] = v.y;
            As[ak + 2][ar] = v.z; As[ak + 3][ar] = v.w;
        }
        {
            int c = col0 + bc;
            float4 v = make_float4(0.f, 0.f, 0.f, 0.f);
            if (c < N) v = *(const float4*)(B + (long)(k0 + bk) * ldb + c);
            *(float4*)&Bs[bk][bc] = v;
        }
        __syncthreads();
#pragma unroll
        for (int k = 0; k < 16; k++) {
            float4 a = *(const float4*)&As[k][ty4];
            float4 b = *(const float4*)&Bs[k][tx4];
            acc[0][0] += a.x * b.x; acc[0][1] += a.x * b.y; acc[0][2] += a.x * b.z; acc[0][3] += a.x * b.w;
            acc[1][0] += a.y * b.x; acc[1][1] += a.y * b.y; acc[1][2] += a.y * b.z; acc[1][3] += a.y * b.w;
            acc[2][0] += a.z * b.x; acc[2][1] += a.z * b.y; acc[2][2] += a.z * b.z; acc[2][3] += a.z * b.w;
            acc[3][0] += a.w * b.x; acc[3][1] += a.w * b.y; acc[3][2] += a.w * b.z; acc[3][3] += a.w * b.w;
        }
        __syncthreads();
    }
    int c = col0 + tx4;
#pragma unroll
    for (int i = 0; i < 4; i++) {
        int r = row0 + ty4 + i;
        if (r < M && c < N)
            *(float4*)&C[(long)r * ldc + c] =
                make_float4(acc[i][0], acc[i][1], acc[i][2], acc[i][3]);
    }
}

// ---------------- utility / CSR build ---------------------------------------
__global__ void filli(int* p, long n, int v)
{
    long i = (long)blockIdx.x * blockDim.x + threadIdx.x;
    long st = (long)gridDim.x * blockDim.x;
    for (; i < n; i += st) p[i] = v;
}

__global__ void hist_int(const int* __restrict__ key, long n, int* __restrict__ h)
{
    long i = (long)blockIdx.x * blockDim.x + threadIdx.x;
    long st = (long)gridDim.x * blockDim.x;
    for (; i < n; i += st) atomicAdd(&h[key[i]], 1);
}

__global__ __launch_bounds__(1024)
void scan_bsum(const int* __restrict__ in, int n, int* __restrict__ btot)
{
    __shared__ int sh[1024];
    int tid = threadIdx.x;
    int i0 = blockIdx.x * 4096 + tid * 4;
    int s = 0;
#pragma unroll
    for (int t = 0; t < 4; t++) { int idx = i0 + t; s += (idx < n) ? in[idx] : 0; }
    sh[tid] = s;
    __syncthreads();
    for (int off = 512; off > 0; off >>= 1) {
        if (tid < off) sh[tid] += sh[tid + off];
        __syncthreads();
    }
    if (tid == 0) btot[blockIdx.x] = sh[0];
}

__global__ void scan_tiny(const int* __restrict__ btot, int nb, int* __restrict__ boff)
{
    if (threadIdx.x == 0) {
        int c = 0;
        for (int b = 0; b < nb; b++) { boff[b] = c; c += btot[b]; }
        boff[nb] = c;
    }
}

__global__ __launch_bounds__(1024)
void scan_final(const int* __restrict__ in, int n, const int* __restrict__ boff,
                int nb, int* __restrict__ out)
{
    __shared__ int buf[1024];
    int tid = threadIdx.x;
    int i0 = blockIdx.x * 4096 + tid * 4;
    int v[4]; int s = 0;
#pragma unroll
    for (int t = 0; t < 4; t++) {
        int idx = i0 + t;
        v[t] = (idx < n) ? in[idx] : 0;
        s += v[t];
    }
    buf[tid] = s;
    __syncthreads();
    for (int off = 1; off < 1024; off <<= 1) {
        int t = (tid >= off) ? buf[tid - off] : 0;
        __syncthreads();
        buf[tid] += t;
        __syncthreads();
    }
    int excl = buf[tid] - s + boff[blockIdx.x];
#pragma unroll
    for (int t = 0; t < 4; t++) {
        int idx = i0 + t;
        if (idx < n) out[idx] = excl;
        excl += v[t];
    }
    if (blockIdx.x == 0 && tid == 0) out[n] = boff[nb];
}

__global__ void bin_by(const int* __restrict__ key, long n,
                       const int* __restrict__ off, int* __restrict__ cursor,
                       int* __restrict__ bins)
{
    long i = (long)blockIdx.x * blockDim.x + threadIdx.x;
    long st = (long)gridDim.x * blockDim.x;
    for (; i < n; i += st) {
        int k = key[i];
        int pos = off[k] + atomicAdd(&cursor[k], 1);
        bins[pos] = (int)i;
    }
}

__global__ void dinv_from_deg(const int* __restrict__ deg, float* __restrict__ dinv, long n)
{
    long i = (long)blockIdx.x * blockDim.x + threadIdx.x;
    long st = (long)gridDim.x * blockDim.x;
    for (; i < n; i += st) dinv[i] = rsqrtf((float)(deg[i] + 1));
}

__global__ void mol_enorm(const int* __restrict__ src, const int* __restrict__ dst,
                          const float* __restrict__ dinv, long E, float* __restrict__ en)
{
    long i = (long)blockIdx.x * blockDim.x + threadIdx.x;
    long st = (long)gridDim.x * blockDim.x;
    for (; i < E; i += st) en[i] = dinv[src[i]] * dinv[dst[i]];
}

// ---------------- batch-norm stats (v2: vectorized, NBLK_STATS blocks) ------
__global__ __launch_bounds__(256)
void colstats_b16_v2(const u16* __restrict__ X, int M, int ld, int c0, int NC,
                     float* __restrict__ p1, float* __restrict__ p2)
{
    __shared__ float sh1[1024], sh2[1024];
    int tid = threadIdx.x;
    int ncg = NC >> 2;                 // col groups of 4
    int cg  = tid & (ncg - 1);
    int rg  = tid / ncg;
    int nrg = 256 / ncg;
    float s0=0,s1=0,s2=0,s3=0, q0=0,q1=0,q2=0,q3=0;
    const u16* base = X + c0 + 4 * cg;
    for (long row = (long)blockIdx.x * nrg + rg; row < M; row += (long)gridDim.x * nrg) {
        ushort4 v = *(const ushort4*)(base + row * (long)ld);
        float f0 = b2f(v.x), f1 = b2f(v.y), f2 = b2f(v.z), f3 = b2f(v.w);
        s0 += f0; q0 += f0 * f0; s1 += f1; q1 += f1 * f1;
        s2 += f2; q2 += f2 * f2; s3 += f3; q3 += f3 * f3;
    }
    float4* S1 = (float4*)sh1; float4* S2 = (float4*)sh2;
    S1[tid] = make_float4(s0, s1, s2, s3);
    S2[tid] = make_float4(q0, q1, q2, q3);
    __syncthreads();
    for (int off = nrg >> 1; off > 0; off >>= 1) {
        if (rg < off) {
            float4 a = S1[tid], b = S1[tid + off * ncg];
            S1[tid] = make_float4(a.x + b.x, a.y + b.y, a.z + b.z, a.w + b.w);
            float4 c = S2[tid], d = S2[tid + off * ncg];
            S2[tid] = make_float4(c.x + d.x, c.y + d.y, c.z + d.z, c.w + d.w);
        }
        __syncthreads();
    }
    if (rg == 0) {
        *(float4*)&p1[(long)blockIdx.x * NC + 4 * cg] = S1[tid];
        *(float4*)&p2[(long)blockIdx.x * NC + 4 * cg] = S2[tid];
    }
}

__global__ __launch_bounds__(256)
void colstats_f32_v2(const float* __restrict__ X, int M, int N,
                     float* __restrict__ p1, float* __restrict__ p2)
{
    __shared__ float sh1[1024], sh2[1024];
    int tid = threadIdx.x;
    int ncg = N >> 2;
    int cg  = tid & (ncg - 1);
    int rg  = tid / ncg;
    int nrg = 256 / ncg;
    float s0=0,s1=0,s2=0,s3=0, q0=0,q1=0,q2=0,q3=0;
    const float* base = X + 4 * cg;
    for (long row = (long)blockIdx.x * nrg + rg; row < M; row += (long)gridDim.x * nrg) {
        float4 v = *(const float4*)(base + row * (long)N);
        s0 += v.x; q0 += v.x * v.x; s1 += v.y; q1 += v.y * v.y;
        s2 += v.z; q2 += v.z * v.z; s3 += v.w; q3 += v.w * v.w;
    }
    float4* S1 = (float4*)sh1; float4* S2 = (float4*)sh2;
    S1[tid] = make_float4(s0, s1, s2, s3);
    S2[tid] = make_float4(q0, q1, q2, q3);
    __syncthreads();
    for (int off = nrg >> 1; off > 0; off >>= 1) {
        if (rg < off) {
            float4 a = S1[tid], b = S1[tid + off * ncg];
            S1[tid] = make_float4(a.x + b.x, a.y + b.y, a.z + b.z, a.w + b.w);
            float4 c = S2[tid], d = S2[tid + off * ncg];
            S2[tid] = make_float4(c.x + d.x, c.y + d.y, c.z + d.z, c.w + d.w);
        }
        __syncthreads();
    }
    if (rg == 0) {
        *(float4*)&p1[(long)blockIdx.x * N + 4 * cg] = S1[tid];
        *(float4*)&p2[(long)blockIdx.x * N + 4 * cg] = S2[tid];
    }
}

__global__ void colstats_reduce_v2(const float* __restrict__ p1, const float* __restrict__ p2,
                                   int nblk, int N, float invM,
                                   float* __restrict__ s1o, float* __restrict__ s2o)
{
    __shared__ float sh1[256], sh2[256];
    int tid = threadIdx.x;
    int col = blockIdx.x * 64 + (tid & 63);
    int seg = tid >> 6;
    float a = 0.f, c = 0.f;
    for (int b = seg; b < nblk; b += 4) {
        a += p1[(long)b * N + col];
        c += p2[(long)b * N + col];
    }
    sh1[tid] = a; sh2[tid] = c;
    __syncthreads();
    if (seg == 0) {
        a = sh1[tid] + sh1[tid + 64] + sh1[tid + 128] + sh1[tid + 192];
        c = sh2[tid] + sh2[tid + 64] + sh2[tid + 128] + sh2[tid + 192];
        float mean = a * invM;
        float var  = fmaxf(c * invM - mean * mean, 0.f);
        s1o[col] = mean;
        s2o[col] = rsqrtf(var + 1e-5f);
    }
}

__global__ void bn_apply(float* X, long total, int mask,
                         const float* __restrict__ s1, const float* __restrict__ s2)
{
    long i = (long)blockIdx.x * blockDim.x + threadIdx.x;
    long st = (long)gridDim.x * blockDim.x;
    for (; i < total; i += st) {
        int j = (int)(i & mask);
        X[i] = fmaxf((X[i] - s1[j]) * s2[j], 0.f);
    }
}

// BN+ReLU, fp32 in place AND bf16 copy
__global__ void bn_apply_dual(float* __restrict__ X, u16* __restrict__ Xb, long total,
                              int mask, const float* __restrict__ s1,
                              const float* __restrict__ s2)
{
    long i = (long)blockIdx.x * blockDim.x + threadIdx.x;
    long st = (long)gridDim.x * blockDim.x;
    for (; i < total; i += st) {
        int j = (int)(i & mask);
        float y = fmaxf((X[i] - s1[j]) * s2[j], 0.f);
        X[i] = y;
        Xb[i] = f2b(y);
    }
}

// BN+ReLU in place on bf16 contiguous [M, NC]; u32 words (2 cols each)
__global__ void bn_apply_b16_v2(u32* __restrict__ X, long n2, int maskHalf,
                                const float* __restrict__ s1, const float* __restrict__ s2)
{
    long i = (long)blockIdx.x * blockDim.x + threadIdx.x;
    long st = (long)gridDim.x * blockDim.x;
    for (; i < n2; i += st) {
        u32 v = X[i];
        int f = (int)(i & maskHalf) * 2;
        float y0 = fmaxf((b2f((u16)(v & 0xFFFF)) - s1[f])     * s2[f],     0.f);
        float y1 = fmaxf((b2f((u16)(v >> 16))    - s1[f + 1]) * s2[f + 1], 0.f);
        X[i] = (u32)f2b(y0) | ((u32)f2b(y1) << 16);
    }
}

// ---------------- CSR aggregation (no atomics) ------------------------------
__global__ __launch_bounds__(256)
void mol_agg_in(const void* __restrict__ Xraw, const u16* __restrict__ Xcvt,
                const int* __restrict__ flagp, const float* __restrict__ dinv,
                const int* __restrict__ off, const int2* __restrict__ eb,
                int NM, u16* __restrict__ out)
{
    const u16* X = (*flagp != 0) ? Xcvt : (const u16*)Xraw;
    int wid  = (int)(((long)blockIdx.x * 256 + threadIdx.x) >> 6);
    int lane = threadIdx.x & 63;
    if (wid >= NM) return;
    float dv = dinv[wid];
    float acc = b2f(X[(long)wid * 64 + lane]) * dv * dv;
    int j = off[wid], j1 = off[wid + 1];
    for (; j + 3 < j1; j += 4) {
        int2 e0 = eb[j], e1 = eb[j + 1], e2 = eb[j + 2], e3 = eb[j + 3];
        float v0 = b2f(X[(long)e0.x * 64 + lane]);
        float v1 = b2f(X[(long)e1.x * 64 + lane]);
        float v2 = b2f(X[(long)e2.x * 64 + lane]);
        float v3 = b2f(X[(long)e3.x * 64 + lane]);
        acc += v0 * __int_as_float(e0.y) + v1 * __int_as_float(e1.y)
             + v2 * __int_as_float(e2.y) + v3 * __int_as_float(e3.y);
    }
    for (; j < j1; j++) {
        int2 e = eb[j];
        acc += b2f(X[(long)e.x * 64 + lane]) * __int_as_float(e.y);
    }
    out[(long)wid * 64 + lane] = f2b(acc);
}

__global__ __launch_bounds__(256)
void mol_agg128(const u16* __restrict__ G, const float* __restrict__ dinv,
                const int* __restrict__ off, const int2* __restrict__ eb,
                int NM, u16* __restrict__ out)
{
    int wid  = (int)(((long)blockIdx.x * 256 + threadIdx.x) >> 6);
    int lane = threadIdx.x & 63;
    if (wid >= NM) return;
    float dv = dinv[wid], dv2 = dv * dv;
    u32 u = *(const u32*)(G + (long)wid * 128 + 2 * lane);
    float a0 = b2f((u16)(u & 0xFFFF)) * dv2;
    float a1 = b2f((u16)(u >> 16)) * dv2;
    int j = off[wid], j1 = off[wid + 1];
    for (; j + 3 < j1; j += 4) {
        int2 e0 = eb[j], e1 = eb[j + 1], e2 = eb[j + 2], e3 = eb[j + 3];
        u32 v0 = *(const u32*)(G + (long)e0.x * 128 + 2 * lane);
        u32 v1 = *(const u32*)(G + (long)e1.x * 128 + 2 * lane);
        u32 v2 = *(const u32*)(G + (long)e2.x * 128 + 2 * lane);
        u32 v3 = *(const u32*)(G + (long)e3.x * 128 + 2 * lane);
        float n0 = __int_as_float(e0.y), n1 = __int_as_float(e1.y);
        float n2 = __int_as_float(e2.y), n3 = __int_as_float(e3.y);
        a0 += b2f((u16)(v0 & 0xFFFF)) * n0 + b2f((u16)(v1 & 0xFFFF)) * n1
            + b2f((u16)(v2 & 0xFFFF)) * n2 + b2f((u16)(v3 & 0xFFFF)) * n3;
        a1 += b2f((u16)(v0 >> 16)) * n0 + b2f((u16)(v1 >> 16)) * n1
            + b2f((u16)(v2 >> 16)) * n2 + b2f((u16)(v3 >> 16)) * n3;
    }
    for (; j < j1; j++) {
        int2 e = eb[j];
        u32 v = *(const u32*)(G + (long)e.x * 128 + 2 * lane);
        float n = __int_as_float(e.y);
        a0 += b2f((u16)(v & 0xFFFF)) * n;
        a1 += b2f((u16)(v >> 16)) * n;
    }
    u32 o = (u32)f2b(a0) | ((u32)f2b(a1) << 16);
    *(u32*)(out + (long)wid * 128 + 2 * lane) = o;
}

// RGCN pre-aggregation v2: one wave per (node, relation) segment.
// Segments binned by key dst*8+et; mean norm = 1/max(len,1). Register-only
// accumulation (4 f32/lane covers 256 cols). eb[j] = src node index.
__global__ __launch_bounds__(256)
void kg_preagg2(const u16* __restrict__ xin, const int* __restrict__ off2,
                const int* __restrict__ eb, int NSEG, u16* __restrict__ aggx)
{
    int seg  = (int)(((long)blockIdx.x * 256 + threadIdx.x) >> 6);
    int lane = threadIdx.x & 63;
    if (seg >= NSEG) return;
    int node = seg >> 3, r = seg & 7;
    const int c4 = 4 * lane;
    int j0 = off2[seg], j1 = off2[seg + 1];
    float a0 = 0.f, a1 = 0.f, a2 = 0.f, a3 = 0.f;
    int j = j0;
    for (; j + 3 < j1; j += 4) {
        int s0 = eb[j], s1 = eb[j + 1], s2 = eb[j + 2], s3 = eb[j + 3];
        ushort4 v0 = *(const ushort4*)(xin + (long)s0 * 256 + c4);
        ushort4 v1 = *(const ushort4*)(xin + (long)s1 * 256 + c4);
        ushort4 v2 = *(const ushort4*)(xin + (long)s2 * 256 + c4);
        ushort4 v3 = *(const ushort4*)(xin + (long)s3 * 256 + c4);
        a0 += b2f(v0.x) + b2f(v1.x) + b2f(v2.x) + b2f(v3.x);
        a1 += b2f(v0.y) + b2f(v1.y) + b2f(v2.y) + b2f(v3.y);
        a2 += b2f(v0.z) + b2f(v1.z) + b2f(v2.z) + b2f(v3.z);
        a3 += b2f(v0.w) + b2f(v1.w) + b2f(v2.w) + b2f(v3.w);
    }
    for (; j < j1; j++) {
        ushort4 v = *(const ushort4*)(xin + (long)eb[j] * 256 + c4);
        a0 += b2f(v.x); a1 += b2f(v.y); a2 += b2f(v.z); a3 += b2f(v.w);
    }
    float nrm = 1.0f / fmaxf((float)(j1 - j0), 1.0f);
    ushort4 o;
    o.x = f2b(a0 * nrm); o.y = f2b(a1 * nrm);
    o.z = f2b(a2 * nrm); o.w = f2b(a3 * nrm);
    *(ushort4*)(aggx + (long)node * 2304 + 256 + (r << 8) + c4) = o;
}

// copy xin rows into AGGX cols 0:255
__global__ void xcopy_aggx(const u16* __restrict__ xin, u16* __restrict__ aggx, long n4)
{
    long i = (long)blockIdx.x * blockDim.x + threadIdx.x;
    long st = (long)gridDim.x * blockDim.x;
    for (; i < n4; i += st) {
        long node = i >> 6;
        int c4 = (int)(i & 63) * 4;
        *(ushort4*)(aggx + node * 2304 + c4) = *(const ushort4*)(xin + node * 256 + c4);
    }
}

// mean-pool bf16 chunk [NM,64] with fused BN+ReLU
__global__ __launch_bounds__(256)
void pool_b16(const u16* __restrict__ g, const int* __restrict__ off,
              const int* __restrict__ bins, int ND,
              const float* __restrict__ s1, const float* __restrict__ s2,
              float* __restrict__ gout, int c0)
{
    int wid  = (int)(((long)blockIdx.x * 256 + threadIdx.x) >> 6);
    int lane = threadIdx.x & 63;
    if (wid >= ND) return;
    float m = s1[lane], r = s2[lane];
    int j0 = off[wid], j1 = off[wid + 1];
    float acc = 0.f;
    for (int j = j0; j < j1; j++)
        acc += fmaxf((b2f(g[(long)bins[j] * 64 + lane]) - m) * r, 0.f);
    gout[(long)wid * 256 + c0 + lane] = acc / fmaxf((float)(j1 - j0), 1.0f);
}

// ---------------- attention fusion ------------------------------------------
__global__ void attention_fuse(const float* __restrict__ go, const float* __restrict__ fpv,
                               const float* __restrict__ W1, const float* __restrict__ B1,
                               const float* __restrict__ W2,
                               float* __restrict__ emb, float* __restrict__ beta_out)
{
    int d = blockIdx.x;
    int t = threadIdx.x;
    __shared__ float z[2][256];
    __shared__ float red[128];
    for (int c = t; c < 256; c += 128) {
        z[0][c] = go[(long)d * 256 + c];
        z[1][c] = fpv[(long)d * 256 + c];
    }
    __syncthreads();
    float s[2];
    for (int v = 0; v < 2; v++) {
        float acc = B1[t];
        for (int k = 0; k < 256; k++) acc += z[v][k] * W1[k * 128 + t];
        red[t] = tanhf(acc) * W2[t];
        __syncthreads();
        for (int off = 64; off > 0; off >>= 1) {
            if (t < off) red[t] += red[t + off];
            __syncthreads();
        }
        s[v] = red[0];
        __syncthreads();
    }
    float m = fmaxf(s[0], s[1]);
    float e0 = expf(s[0] - m), e1 = expf(s[1] - m);
    float inv = 1.0f / (e0 + e1);
    float b0 = e0 * inv, b1 = e1 * inv;
    for (int c = t; c < 256; c += 128)
        emb[(long)d * 256 + c] = b0 * z[0][c] + b1 * z[1][c];
    if (t == 0) {
        beta_out[d * 2 + 0] = b0;
        beta_out[d * 2 + 1] = b1;
    }
}

// ---------------- final linear + log_softmax, fused BN on x4 ----------------
__global__ void logits_out_bn(const float* __restrict__ x4,
                              const float* __restrict__ s1, const float* __restrict__ s2,
                              const float* __restrict__ w, const float* __restrict__ b,
                              float* __restrict__ out, int NKG)
{
    int i = blockIdx.x * blockDim.x + threadIdx.x;
    if (i >= NKG) return;
    float a0 = b[0], a1 = b[1];
    for (int k = 0; k < 64; k++) {
        float v = fmaxf((x4[(long)i * 64 + k] - s1[k]) * s2[k], 0.f);
        a0 += v * w[k * 2 + 0];
        a1 += v * w[k * 2 + 1];
    }
    float m = fmaxf(a0, a1);
    float lse = m + logf(expf(a0 - m) + expf(a1 - m));
    out[i * 2 + 0] = a0 - lse;
    out[i * 2 + 1] = a1 - lse;
}

// ============================================================================
extern "C" void kernel_launch(void* const* d_in, const int* in_sizes, int n_in,
                              void* d_out, int out_size, void* d_ws, size_t ws_size,
                              hipStream_t stream)
{
    (void)in_sizes; (void)n_in; (void)out_size; (void)ws_size;
    const int ND = 4096, NM = 131072, NKG = 9510, NGENE = 5414;
    const long EM = 524288, EK = 524288;
    const int NSEG = 8 * NKG;   // 76080 (node, relation) segments

    const void* fp_data = d_in[0];
    const void* mol_x   = d_in[1];
    const int*  mol_batch = (const int*)d_in[2];
    const int*  mol_ei  = (const int*)d_in[3];
    const int*  kg_ei   = (const int*)d_in[4];
    const int*  kg_et   = (const int*)d_in[5];

    const int* mol_src = mol_ei;
    const int* mol_dst = mol_ei + EM;
    const int* kg_src  = kg_ei;
    const int* kg_dst  = kg_ei + EK;

    float* out_ls   = (float*)d_out;          // [9510,2] fp32
    float* out_beta = (float*)d_out + 19020;  // [4096,2,1] fp32

    // ---- workspace carve ----
    char* wp = (char*)d_ws;
    auto carve = [&](size_t bytes) { char* p = wp; wp += (bytes + 255) & ~(size_t)255; return p; };
    float* stats = (float*)carve(4096);
    int*   flag  = (int*)carve(256);
    float* dinv  = (float*)carve((size_t)NM * 4);
    float* enM   = (float*)carve((size_t)EM * 4);
    float* part1 = (float*)carve((size_t)NBLK_STATS * 512 * 4);
    float* part2 = (float*)carve((size_t)NBLK_STATS * 512 * 4);
    int*   sbt   = (int*)carve(256);
    int*   sbo   = (int*)carve(256);
    float* Wpool = (float*)carve((size_t)1630000 * 4);     // fp32 weights
    u16*   WpoolB= (u16*)carve((size_t)1630000 * 2);       // bf16 weights
    u16*   WpoolT= (u16*)carve((size_t)1600000 * 2);       // bf16 transposed gemm weights
    float* fpb   = (float*)carve((size_t)ND * 256 * 4);
    float* gout  = (float*)carve((size_t)ND * 256 * 4);
    int*   key2  = (int*)carve((size_t)EK * 4);            // kg seg keys; reused as ebK2
    int*   koff2 = (int*)carve((size_t)(NSEG + 1) * 4);
    // zero-span
    char*  z0    = wp;
    int* kdeg2 = (int*)carve((size_t)NSEG * 4);
    int* kcur2 = (int*)carve((size_t)NSEG * 4);
    int* mdeg = (int*)carve((size_t)NM * 4);
    int* mcur = (int*)carve((size_t)NM * 4);
    int* pdeg = (int*)carve((size_t)ND * 4);
    int* pcur = (int*)carve((size_t)ND * 4);
    char*  z1    = wp;
    int* moff = (int*)carve((size_t)(NM + 1) * 4);
    int* mbins= (int*)carve((size_t)EM * 4);
    int* kbins= (int*)carve((size_t)EK * 4);
    int* poff = (int*)carve((size_t)(ND + 1) * 4);
    int* pbins= (int*)carve((size_t)NM * 4);
    char*  REG1  = carve((size_t)NM * 128 * 2);            // 33.6 MB
    char*  REG2  = carve((size_t)NM * 128 * 2);            // 33.6 MB  (contiguous with HB)
    u16*   HB    = (u16*)carve((size_t)NM * 64 * 2);       // 16.8 MB

    // phase views
    float* fp1 = (float*)REG1;                 // fp: [4096,512] f32
    u16*   XB  = (u16*)REG1;                   // mol pre: [NM,64] bf16 converted input
    u16*   G1  = (u16*)REG1;                   // mol: [NM,128] bf16
    // rgcn chain in REG1:
    float* xkg = (float*)REG1;                 // [NKG,256] f32 (emb+gene)
    float* x2  = xkg + (size_t)NKG * 256;      // [NKG,256] f32
    float* x3  = x2  + (size_t)NKG * 256;      // [NKG,128] f32
    float* x4  = x3  + (size_t)NKG * 128;      // [NKG,64]  f32
    u16*   xb  = (u16*)(x4 + (size_t)NKG * 64);// [NKG,256] bf16 (after x4, fits REG1)
    u16*   x2b = (u16*)REG1;                   // [NKG,256] bf16 (overlaps xkg: dead then)
    u16*   Xfb = (u16*)REG2;                   // fp: [4096,1024] bf16
    u16*   G1A = (u16*)REG2;                   // mol: [NM,128] bf16 aggregated
    u16*   AGGX= (u16*)REG2;                   // rgcn: [NKG,2304] bf16 (43.8 MB, REG2+HB)
    u16*   fp1b = HB;                          // fp: [4096,512] bf16
    u16*   Xagg = HB;                          // mol L1: [NM,64] bf16
    // flattened CSR edge tables (aliased; lifetimes verified)
    int2* ebM  = (int2*)gout;                  // mol edges; gout written only after dead
    int*  ebK2 = key2;                         // kg src table; key2 dead after bin_by

    // ---- dtype detect + weight conversion (fp32 + bf16 pools) ----
    zero_int<<<1, 1, 0, stream>>>(flag);
    detect_f32<<<1024, 256, 0, stream>>>((const u16*)fp_data, (long)ND * 1024, flag);
    ConvTab tab;
    // NOTE: rg_root before rg_w so [root; W_0..W_7] is contiguous = [2304, N] GEMM B
    const int widx[14] = {6, 8, 10, 12, 14, 15, 16, 19, 18, 22, 21, 24, 26, 27};
    const int wn[14]   = {1024*512, 512*256, 64*128, 128*256, 256*128, 128, 128,
                          256*256, 8*256*256, 256*128, 8*256*128, 128*64, 64*2, 2};
    float* wf[14]; u16* wb[14];
    {
        size_t o = 0;
        for (int i = 0; i < 14; i++) {
            tab.src[i]  = d_in[widx[i]];
            tab.dst[i]  = Wpool + o;
            tab.dstB[i] = WpoolB + o;
            tab.n[i]    = wn[i];
            wf[i] = Wpool + o; wb[i] = WpoolB + o;
            o += (size_t)wn[i];
        }
    }
    conv_all<<<dim3(32, 14), 256, 0, stream>>>(tab, flag);
    float *att_w1c = wf[4], *att_b1c = wf[5], *att_w2c = wf[6];
    float *lin1_wc = wf[11], *lin2_wc = wf[12], *lin2_bc = wf[13];

    // ---- transposed bf16 weights for gemm_bt (BT[n*K+k] = B[k*N+n]) ----
    u16* T_fpw1  = WpoolT;                        // [512,1024]
    u16* T_fpw2  = T_fpw1 + (size_t)512 * 1024;   // [256,512]
    u16* T_gcnw1 = T_fpw2 + (size_t)256 * 512;    // [128,64]
    u16* T_gcnw2 = T_gcnw1 + (size_t)128 * 64;    // [256,128]
    u16* T_w1    = T_gcnw2 + (size_t)256 * 128;   // [256,2304]
    u16* T_w2    = T_w1 + (size_t)256 * 2304;     // [128,2304]
    transpose_b16<<<dim3(32, 16), 256, 0, stream>>>(wb[0], T_fpw1, 1024, 512);
    transpose_b16<<<dim3(16, 8),  256, 0, stream>>>(wb[1], T_fpw2, 512, 256);
    transpose_b16<<<dim3(2, 4),   256, 0, stream>>>(wb[2], T_gcnw1, 64, 128);
    transpose_b16<<<dim3(4, 8),   256, 0, stream>>>(wb[3], T_gcnw2, 128, 256);
    transpose_b16<<<dim3(72, 8),  256, 0, stream>>>(wb[7], T_w1, 2304, 256);
    transpose_b16<<<dim3(72, 4),  256, 0, stream>>>(wb[9], T_w2, 2304, 128);

    // ---- CSR builds ----
    filli<<<512, 256, 0, stream>>>((int*)z0, (long)(z1 - z0) / 4, 0);
    auto scan = [&](const int* deg, int* off, int n) {
        int nb = divup(n, 4096);
        scan_bsum<<<nb, 1024, 0, stream>>>(deg, n, sbt);
        scan_tiny<<<1, 64, 0, stream>>>(sbt, nb, sbo);
        scan_final<<<nb, 1024, 0, stream>>>(deg, n, sbo, nb, off);
    };
    hist_int<<<2048, 256, 0, stream>>>(mol_dst, EM, mdeg);
    scan(mdeg, moff, NM);
    bin_by<<<2048, 256, 0, stream>>>(mol_dst, EM, moff, mcur, mbins);
    dinv_from_deg<<<512, 256, 0, stream>>>(mdeg, dinv, NM);
    mol_enorm<<<1024, 256, 0, stream>>>(mol_src, mol_dst, dinv, EM, enM);
    flatten_mol<<<2048, 256, 0, stream>>>(mbins, mol_src, enM, EM, ebM);

    // KG: segment CSR over (dst, relation); mean norm from segment length
    kg_key2<<<2048, 256, 0, stream>>>(kg_dst, kg_et, EK, key2);
    hist_int<<<2048, 256, 0, stream>>>(key2, EK, kdeg2);
    scan(kdeg2, koff2, NSEG);
    bin_by<<<2048, 256, 0, stream>>>(key2, EK, koff2, kcur2, kbins);
    flatten_kg_src<<<2048, 256, 0, stream>>>(kbins, kg_src, EK, ebK2);  // key2 dead

    hist_int<<<512, 256, 0, stream>>>(mol_batch, NM, pdeg);
    scan(pdeg, poff, ND);
    bin_by<<<512, 256, 0, stream>>>(mol_batch, NM, poff, pcur, pbins);

    // ---- BN helpers (v2) ----
    auto bn_stats = [&](const float* X, int M, int N) {
        colstats_f32_v2<<<NBLK_STATS, 256, 0, stream>>>(X, M, N, part1, part2);
        colstats_reduce_v2<<<N / 64, 256, 0, stream>>>(part1, part2, NBLK_STATS, N,
                                                       1.0f / M, stats, stats + 512);
    };
    auto bn_stats_b16 = [&](const u16* X, int M, int ld, int c0, int NC) {
        colstats_b16_v2<<<NBLK_STATS, 256, 0, stream>>>(X, M, ld, c0, NC, part1, part2);
        colstats_reduce_v2<<<NC / 64, 256, 0, stream>>>(part1, part2, NBLK_STATS, NC,
                                                        1.0f / M, stats, stats + 512);
    };

    // ---------- fingerprint MLP branch (MFMA) ----------
    conv_dual_b16<<<2048, 256, 0, stream>>>(fp_data, Xfb, (long)ND * 1024, flag);
    gemm_bt<float, 2><<<dim3(64, 4), 256, 0, stream>>>(
        Xfb, 1024, T_fpw1, 1024, fp1, 512, ND, 512, 1024);
    bn_stats(fp1, ND, 512);
    bn_apply_dual<<<2048, 256, 0, stream>>>(fp1, fp1b, (long)ND * 512, 511,
                                            stats, stats + 512);
    gemm_bt<float, 1><<<dim3(64, 4), 256, 0, stream>>>(
        fp1b, 512, T_fpw2, 512, fpb, 256, ND, 256, 512);
    bn_stats(fpb, ND, 256);
    bn_apply<<<2048, 256, 0, stream>>>(fpb, (long)ND * 256, 255, stats, stats + 512);

    // ---------- mol GCN layer 1: bf16-convert, aggregate-then-GEMM ----------
    conv_molx<<<2048, 256, 0, stream>>>((const float*)mol_x, XB, (long)NM * 16, flag);
    mol_agg_in<<<32768, 256, 0, stream>>>(mol_x, XB, flag, dinv, moff, ebM, NM, Xagg);
    gemm_bt<u16, 2><<<dim3(2048, 1), 256, 0, stream>>>(
        Xagg, 64, T_gcnw1, 64, G1, 128, NM, 128, 64);   // G1 overwrites XB (dead)
    bn_stats_b16(G1, NM, 128, 0, 128);
    bn_apply_b16_v2<<<8192, 256, 0, stream>>>((u32*)G1, (long)NM * 64, 63,
                                              stats, stats + 512);

    // ---------- mol GCN layer 2: aggregate-then-GEMM + BN + pool ------------
    mol_agg128<<<32768, 256, 0, stream>>>(G1, dinv, moff, ebM, NM, G1A);
    // ebM (gout) is dead past this point; pool_b16 below may overwrite gout
    for (int c0 = 0; c0 < 256; c0 += 64) {
        gemm_bt<u16, 1><<<dim3(2048, 1), 256, 0, stream>>>(
            G1A, 128, T_gcnw2 + (size_t)c0 * 128, 128, HB, 64, NM, 64, 128);
        bn_stats_b16(HB, NM, 64, 0, 64);
        pool_b16<<<1024, 256, 0, stream>>>(HB, poff, pbins, ND,
                                           stats, stats + 512, gout, c0);
    }

    // ---------- attention fusion ----------
    attention_fuse<<<ND, 128, 0, stream>>>(gout, fpb, att_w1c, att_b1c, att_w2c,
                                           xkg, out_beta);
    conv_in<<<512, 256, 0, stream>>>(d_in[17], xkg + (long)ND * 256,
                                     (long)NGENE * 256, flag);
    conv_f32_b16<<<1024, 256, 0, stream>>>(xkg, xb, (long)NKG * 256);

    // ---------- RGCN layer 1 (256 -> 256): preagg2 + single K=2304 GEMM -----
    xcopy_aggx<<<1024, 256, 0, stream>>>(xb, AGGX, (long)NKG * 64);
    kg_preagg2<<<divup((long)NSEG * 64, 256), 256, 0, stream>>>(
        xb, koff2, ebK2, NSEG, AGGX);
    gemm_bt<float, 2><<<dim3(divup(NKG, 64), 2), 256, 0, stream>>>(
        AGGX, 2304, T_w1, 2304, x2, 256, NKG, 256, 2304);
    bn_stats(x2, NKG, 256);
    bn_apply_dual<<<2048, 256, 0, stream>>>(x2, x2b, (long)NKG * 256, 255,
                                            stats, stats + 512);

    // ---------- RGCN layer 2 (256 -> 128): preagg2 + single K=2304 GEMM -----
    xcopy_aggx<<<1024, 256, 0, stream>>>(x2b, AGGX, (long)NKG * 64);
    kg_preagg2<<<divup((long)NSEG * 64, 256), 256, 0, stream>>>(
        x2b, koff2, ebK2, NSEG, AGGX);
    gemm_bt<float, 1><<<dim3(divup(NKG, 64), 2), 256, 0, stream>>>(
        AGGX, 2304, T_w2, 2304, x3, 128, NKG, 128, 2304);
    bn_stats(x3, NKG, 128);
    bn_apply<<<2048, 256, 0, stream>>>(x3, (long)NKG * 128, 127, stats, stats + 512);

    // ---------- classifier head ----------
    gemm64<<<dim3(divup(NKG, 64), 1, 1), 256, 0, stream>>>(
        x3, 128, lin1_wc, 64, x4, 64, NKG, 64, 128);
    bn_stats(x4, NKG, 64);
    logits_out_bn<<<divup(NKG, 256), 256, 0, stream>>>(x4, stats, stats + 512,
                                                       lin2_wc, lin2_bc, out_ls, NKG);
}

// Round 8
// 1160.001 us; speedup vs baseline: 1.2341x; 1.0578x over previous
//
#include <hip/hip_runtime.h>
#include <hip/hip_bf16.h>
#include <cstdint>

typedef __hip_bfloat16 bf16;
typedef unsigned short u16;
typedef unsigned int u32;
typedef __attribute__((ext_vector_type(8))) short short8;
typedef __attribute__((ext_vector_type(4))) float f32x4;

__device__ __forceinline__ float tofloat(float x){ return x; }
__device__ __forceinline__ float tofloat(bf16 x){ return __bfloat162float(x); }
__device__ __forceinline__ float b2f(u16 a){ return __uint_as_float(((unsigned)a) << 16); }
__device__ __forceinline__ u16 f2b(float f){           // round-to-nearest-even
    unsigned u = __float_as_uint(f);
    return (u16)((u + 0x7FFFu + ((u >> 16) & 1u)) >> 16);
}
__device__ __forceinline__ void storec(float* p, float v){ *p = v; }
__device__ __forceinline__ void storec(u16* p, float v){ *p = f2b(v); }

static inline int divup(long a, long b){ return (int)((a + b - 1) / b); }

#define NBLK_STATS 256

// ---------------- input dtype detection -------------------------------------
__global__ void zero_int(int* p){ *p = 0; }

__global__ void detect_f32(const u16* __restrict__ h, long n, int* flag)
{
    long i = (long)blockIdx.x * blockDim.x + threadIdx.x;
    long st = (long)gridDim.x * blockDim.x;
    int c = 0;
    for (; i < n; i += st)
        if (((h[i] >> 7) & 0xFF) == 0xFF) c++;
    if (c) atomicAdd(flag, c);
}

// convert all weights: fp32 pool + bf16 pool in one launch
struct ConvTab { const void* src[14]; float* dst[14]; u16* dstB[14]; int n[14]; };

__global__ void conv_all(ConvTab t, const int* __restrict__ flagp)
{
    bool f32 = (*flagp != 0);
    int seg = blockIdx.y;
    const void* s = t.src[seg];
    float* d = t.dst[seg];
    u16*   dB = t.dstB[seg];
    int n = t.n[seg];
    long i = (long)blockIdx.x * blockDim.x + threadIdx.x;
    long st = (long)gridDim.x * blockDim.x;
    for (; i < n; i += st) {
        float v = f32 ? ((const float*)s)[i] : tofloat(((const bf16*)s)[i]);
        d[i] = v; dB[i] = f2b(v);
    }
}

__global__ void conv_in(const void* __restrict__ src, float* __restrict__ dst,
                        long n, const int* __restrict__ flagp)
{
    bool f32 = (*flagp != 0);
    long i = (long)blockIdx.x * blockDim.x + threadIdx.x;
    long st = (long)gridDim.x * blockDim.x;
    for (; i < n; i += st)
        dst[i] = f32 ? ((const float*)src)[i] : tofloat(((const bf16*)src)[i]);
}

__global__ void conv_dual_b16(const void* __restrict__ src, u16* __restrict__ dst,
                              long n, const int* __restrict__ flagp)
{
    bool f32 = (*flagp != 0);
    long i = (long)blockIdx.x * blockDim.x + threadIdx.x;
    long st = (long)gridDim.x * blockDim.x;
    for (; i < n; i += st)
        dst[i] = f32 ? f2b(((const float*)src)[i]) : ((const u16*)src)[i];
}

__global__ void conv_f32_b16(const float* __restrict__ src, u16* __restrict__ dst, long n)
{
    long i = (long)blockIdx.x * blockDim.x + threadIdx.x;
    long st = (long)gridDim.x * blockDim.x;
    for (; i < n; i += st) dst[i] = f2b(src[i]);
}

// convert mol_x fp32 -> bf16 copy (only when input is fp32); vectorized x4
__global__ void conv_molx(const float* __restrict__ src, u16* __restrict__ dst,
                          long n4, const int* __restrict__ flagp)
{
    if (*flagp == 0) return;   // input already bf16; agg reads original
    long i = (long)blockIdx.x * blockDim.x + threadIdx.x;
    long st = (long)gridDim.x * blockDim.x;
    for (; i < n4; i += st) {
        float4 v = ((const float4*)src)[i];
        ushort4 o;
        o.x = f2b(v.x); o.y = f2b(v.y); o.z = f2b(v.z); o.w = f2b(v.w);
        ((ushort4*)dst)[i] = o;
    }
}

// bf16 transpose: dst[n*K + k] = src[k*N + n]
__global__ __launch_bounds__(256)
void transpose_b16(const u16* __restrict__ src, u16* __restrict__ dst, int K, int N)
{
    __shared__ u16 t[32][33];
    int k0 = blockIdx.x * 32, n0 = blockIdx.y * 32;
    int x = threadIdx.x & 31, y = threadIdx.x >> 5;   // y in 0..7
    for (int yy = y; yy < 32; yy += 8) {
        int k = k0 + yy, n = n0 + x;
        t[yy][x] = (k < K && n < N) ? src[(long)k * N + n] : (u16)0;
    }
    __syncthreads();
    for (int yy = y; yy < 32; yy += 8) {
        int n = n0 + yy, k = k0 + x;
        if (n < N && k < K) dst[(long)n * K + k] = t[x][yy];
    }
}

// ---------------- CSR edge flattening ---------------------------------------
// ebM[j] = {src, bits(en)}
__global__ void flatten_mol(const int* __restrict__ bins, const int* __restrict__ src,
                            const float* __restrict__ en, long E, int2* __restrict__ out)
{
    long i = (long)blockIdx.x * blockDim.x + threadIdx.x;
    long st = (long)gridDim.x * blockDim.x;
    for (; i < E; i += st) {
        int e = bins[i];
        out[i] = make_int2(src[e], __float_as_int(en[e]));
    }
}

// KG segment key: dst*8 + et  (segments = (node, relation) pairs)
__global__ void kg_key2(const int* __restrict__ dst, const int* __restrict__ et,
                        long E, int* __restrict__ key)
{
    long i = (long)blockIdx.x * blockDim.x + threadIdx.x;
    long st = (long)gridDim.x * blockDim.x;
    for (; i < E; i += st) key[i] = dst[i] * 8 + et[i];
}

// flatten KG edges to src index only (mean norm comes from segment length)
__global__ void flatten_kg_src(const int* __restrict__ bins, const int* __restrict__ src,
                               long E, int* __restrict__ out)
{
    long i = (long)blockIdx.x * blockDim.x + threadIdx.x;
    long st = (long)gridDim.x * blockDim.x;
    for (; i < E; i += st) out[i] = src[bins[i]];
}

// ---------------- MFMA GEMM (B pre-transposed): C = A @ B, bf16, fp32 acc ---
// A [M,K] lda; BT [N,K] ldbt. Tile 64 x (NBLK*64). Register-prefetch pipeline.
template<typename TC, int NBLK>
__global__ __launch_bounds__(256)
void gemm_bt(const u16* __restrict__ A, int lda,
             const u16* __restrict__ BT, int ldbt,
             TC* __restrict__ C, int ldc,
             int M, int N, int K)
{
    __shared__ __align__(16) u16 As[64][40];          // [m][k]
    __shared__ __align__(16) u16 Bs[NBLK * 64][40];   // [n][k]
    const int tid = threadIdx.x;
    const int lane = tid & 63, wave = tid >> 6;
    const int l15 = lane & 15, quad = lane >> 4;
    const int wm = (wave & 1) * 32, wn = (wave >> 1) * 32;
    const int row0 = blockIdx.x * 64, col0 = blockIdx.y * (NBLK * 64);
    const int arow = tid >> 2, ak = (tid & 3) * 8;
    const int aok = row0 + arow < M;

    f32x4 acc[NBLK][2][2];
#pragma unroll
    for (int t = 0; t < NBLK; t++)
#pragma unroll
        for (int i = 0; i < 2; i++)
#pragma unroll
            for (int j = 0; j < 2; j++)
#pragma unroll
                for (int r = 0; r < 4; r++) acc[t][i][j][r] = 0.f;

    const u16* pa = A + (long)(row0 + arow) * lda + ak;
    const u16* pb[NBLK];
#pragma unroll
    for (int t = 0; t < NBLK; t++)
        pb[t] = BT + (long)(col0 + t * 64 + arow) * ldbt + ak;

    ushort4 ra0 = {0,0,0,0}, ra1 = {0,0,0,0};
    ushort4 rb0[NBLK], rb1[NBLK];
    if (aok) { ra0 = *(const ushort4*)pa; ra1 = *(const ushort4*)(pa + 4); }
#pragma unroll
    for (int t = 0; t < NBLK; t++) {
        rb0[t] = *(const ushort4*)pb[t];
        rb1[t] = *(const ushort4*)(pb[t] + 4);
    }

    for (int k0 = 0; k0 < K; k0 += 32) {
        *(ushort4*)&As[arow][ak]     = ra0;
        *(ushort4*)&As[arow][ak + 4] = ra1;
#pragma unroll
        for (int t = 0; t < NBLK; t++) {
            *(ushort4*)&Bs[t * 64 + arow][ak]     = rb0[t];
            *(ushort4*)&Bs[t * 64 + arow][ak + 4] = rb1[t];
        }
        __syncthreads();
        if (k0 + 32 < K) {   // issue next-step loads; retire under MFMAs
            if (aok) {
                ra0 = *(const ushort4*)(pa + k0 + 32);
                ra1 = *(const ushort4*)(pa + k0 + 36);
            }
#pragma unroll
            for (int t = 0; t < NBLK; t++) {
                rb0[t] = *(const ushort4*)(pb[t] + k0 + 32);
                rb1[t] = *(const ushort4*)(pb[t] + k0 + 36);
            }
        }
        short8 a0 = *(const short8*)&As[wm + l15][quad * 8];
        short8 a1 = *(const short8*)&As[wm + 16 + l15][quad * 8];
#pragma unroll
        for (int t = 0; t < NBLK; t++) {
            short8 b0 = *(const short8*)&Bs[t * 64 + wn + l15][quad * 8];
            short8 b1 = *(const short8*)&Bs[t * 64 + wn + 16 + l15][quad * 8];
            acc[t][0][0] = __builtin_amdgcn_mfma_f32_16x16x32_bf16(a0, b0, acc[t][0][0], 0, 0, 0);
            acc[t][0][1] = __builtin_amdgcn_mfma_f32_16x16x32_bf16(a0, b1, acc[t][0][1], 0, 0, 0);
            acc[t][1][0] = __builtin_amdgcn_mfma_f32_16x16x32_bf16(a1, b0, acc[t][1][0], 0, 0, 0);
            acc[t][1][1] = __builtin_amdgcn_mfma_f32_16x16x32_bf16(a1, b1, acc[t][1][1], 0, 0, 0);
        }
        __syncthreads();
    }
#pragma unroll
    for (int t = 0; t < NBLK; t++)
#pragma unroll
        for (int i = 0; i < 2; i++)
#pragma unroll
            for (int j = 0; j < 2; j++)
#pragma unroll
                for (int r = 0; r < 4; r++) {
                    int row = row0 + wm + i * 16 + quad * 4 + r;
                    int col = col0 + t * 64 + wn + j * 16 + l15;
                    if (row < M) storec(&C[(long)row * ldc + col], acc[t][i][j][r]);
                }
}

// ---------------- vector GEMM (fp32, small) ---------------------------------
__global__ __launch_bounds__(256)
void gemm64(const float* __restrict__ A, int lda,
            const float* __restrict__ B, int ldb,
            float* __restrict__ C, int ldc,
            int M, int N, int K)
{
    __shared__ float As[16][68];
    __shared__ float Bs[16][68];
    const int tid = threadIdx.x;
    const int row0 = blockIdx.x * 64, col0 = blockIdx.y * 64;
    float acc[4][4];
#pragma unroll
    for (int i = 0; i < 4; i++)
#pragma unroll
        for (int j = 0; j < 4; j++) acc[i][j] = 0.f;
    const int ar = tid >> 2, ak = (tid & 3) * 4;
    const int bk = tid >> 4, bc = (tid & 15) * 4;
    const int ty4 = (tid >> 4) * 4, tx4 = (tid & 15) * 4;
    for (int k0 = 0; k0 < K; k0 += 16) {
        {
            int row = row0 + ar;
            float4 v = make_float4(0.f, 0.f, 0.f, 0.f);
            if (row < M) v = *(const float4*)(A + (long)row * lda + k0 + ak);
            As[ak + 0][ar] = v.x; As[ak + 1][ar] = v.y;
            As[ak + 2][ar] = v.z; As[ak + 3][ar] = v.w;
        }
        {
            int c = col0 + bc;
            float4 v = make_float4(0.f, 0.f, 0.f, 0.f);
            if (c < N) v = *(const float4*)(B + (long)(k0 + bk) * ldb + c);
            *(float4*)&Bs[bk][bc] = v;
        }
        __syncthreads();
#pragma unroll
        for (int k = 0; k < 16; k++) {
            float4 a = *(const float4*)&As[k][ty4];
            float4 b = *(const float4*)&Bs[k][tx4];
            acc[0][0] += a.x * b.x; acc[0][1] += a.x * b.y; acc[0][2] += a.x * b.z; acc[0][3] += a.x * b.w;
            acc[1][0] += a.y * b.x; acc[1][1] += a.y * b.y; acc[1][2] += a.y * b.z; acc[1][3] += a.y * b.w;
            acc[2][0] += a.z * b.x; acc[2][1] += a.z * b.y; acc[2][2] += a.z * b.z; acc[2][3] += a.z * b.w;
            acc[3][0] += a.w * b.x; acc[3][1] += a.w * b.y; acc[3][2] += a.w * b.z; acc[3][3] += a.w * b.w;
        }
        __syncthreads();
    }
    int c = col0 + tx4;
#pragma unroll
    for (int i = 0; i < 4; i++) {
        int r = row0 + ty4 + i;
        if (r < M && c < N)
            *(float4*)&C[(long)r * ldc + c] =
                make_float4(acc[i][0], acc[i][1], acc[i][2], acc[i][3]);
    }
}

// ---------------- utility / CSR build ---------------------------------------
__global__ void filli(int* p, long n, int v)
{
    long i = (long)blockIdx.x * blockDim.x + threadIdx.x;
    long st = (long)gridDim.x * blockDim.x;
    for (; i < n; i += st) p[i] = v;
}

__global__ void hist_int(const int* __restrict__ key, long n, int* __restrict__ h)
{
    long i = (long)blockIdx.x * blockDim.x + threadIdx.x;
    long st = (long)gridDim.x * blockDim.x;
    for (; i < n; i += st) atomicAdd(&h[key[i]], 1);
}

__global__ __launch_bounds__(1024)
void scan_bsum(const int* __restrict__ in, int n, int* __restrict__ btot)
{
    __shared__ int sh[1024];
    int tid = threadIdx.x;
    int i0 = blockIdx.x * 4096 + tid * 4;
    int s = 0;
#pragma unroll
    for (int t = 0; t < 4; t++) { int idx = i0 + t; s += (idx < n) ? in[idx] : 0; }
    sh[tid] = s;
    __syncthreads();
    for (int off = 512; off > 0; off >>= 1) {
        if (tid < off) sh[tid] += sh[tid + off];
        __syncthreads();
    }
    if (tid == 0) btot[blockIdx.x] = sh[0];
}

__global__ void scan_tiny(const int* __restrict__ btot, int nb, int* __restrict__ boff)
{
    if (threadIdx.x == 0) {
        int c = 0;
        for (int b = 0; b < nb; b++) { boff[b] = c; c += btot[b]; }
        boff[nb] = c;
    }
}

__global__ __launch_bounds__(1024)
void scan_final(const int* __restrict__ in, int n, const int* __restrict__ boff,
                int nb, int* __restrict__ out)
{
    __shared__ int buf[1024];
    int tid = threadIdx.x;
    int i0 = blockIdx.x * 4096 + tid * 4;
    int v[4]; int s = 0;
#pragma unroll
    for (int t = 0; t < 4; t++) {
        int idx = i0 + t;
        v[t] = (idx < n) ? in[idx] : 0;
        s += v[t];
    }
    buf[tid] = s;
    __syncthreads();
    for (int off = 1; off < 1024; off <<= 1) {
        int t = (tid >= off) ? buf[tid - off] : 0;
        __syncthreads();
        buf[tid] += t;
        __syncthreads();
    }
    int excl = buf[tid] - s + boff[blockIdx.x];
#pragma unroll
    for (int t = 0; t < 4; t++) {
        int idx = i0 + t;
        if (idx < n) out[idx] = excl;
        excl += v[t];
    }
    if (blockIdx.x == 0 && tid == 0) out[n] = boff[nb];
}

__global__ void bin_by(const int* __restrict__ key, long n,
                       const int* __restrict__ off, int* __restrict__ cursor,
                       int* __restrict__ bins)
{
    long i = (long)blockIdx.x * blockDim.x + threadIdx.x;
    long st = (long)gridDim.x * blockDim.x;
    for (; i < n; i += st) {
        int k = key[i];
        int pos = off[k] + atomicAdd(&cursor[k], 1);
        bins[pos] = (int)i;
    }
}

__global__ void dinv_from_deg(const int* __restrict__ deg, float* __restrict__ dinv, long n)
{
    long i = (long)blockIdx.x * blockDim.x + threadIdx.x;
    long st = (long)gridDim.x * blockDim.x;
    for (; i < n; i += st) dinv[i] = rsqrtf((float)(deg[i] + 1));
}

__global__ void mol_enorm(const int* __restrict__ src, const int* __restrict__ dst,
                          const float* __restrict__ dinv, long E, float* __restrict__ en)
{
    long i = (long)blockIdx.x * blockDim.x + threadIdx.x;
    long st = (long)gridDim.x * blockDim.x;
    for (; i < E; i += st) en[i] = dinv[src[i]] * dinv[dst[i]];
}

// ---------------- batch-norm stats (v2: vectorized, NBLK_STATS blocks) ------
__global__ __launch_bounds__(256)
void colstats_b16_v2(const u16* __restrict__ X, int M, int ld, int c0, int NC,
                     float* __restrict__ p1, float* __restrict__ p2)
{
    __shared__ float sh1[1024], sh2[1024];
    int tid = threadIdx.x;
    int ncg = NC >> 2;                 // col groups of 4
    int cg  = tid & (ncg - 1);
    int rg  = tid / ncg;
    int nrg = 256 / ncg;
    float s0=0,s1=0,s2=0,s3=0, q0=0,q1=0,q2=0,q3=0;
    const u16* base = X + c0 + 4 * cg;
    for (long row = (long)blockIdx.x * nrg + rg; row < M; row += (long)gridDim.x * nrg) {
        ushort4 v = *(const ushort4*)(base + row * (long)ld);
        float f0 = b2f(v.x), f1 = b2f(v.y), f2 = b2f(v.z), f3 = b2f(v.w);
        s0 += f0; q0 += f0 * f0; s1 += f1; q1 += f1 * f1;
        s2 += f2; q2 += f2 * f2; s3 += f3; q3 += f3 * f3;
    }
    float4* S1 = (float4*)sh1; float4* S2 = (float4*)sh2;
    S1[tid] = make_float4(s0, s1, s2, s3);
    S2[tid] = make_float4(q0, q1, q2, q3);
    __syncthreads();
    for (int off = nrg >> 1; off > 0; off >>= 1) {
        if (rg < off) {
            float4 a = S1[tid], b = S1[tid + off * ncg];
            S1[tid] = make_float4(a.x + b.x, a.y + b.y, a.z + b.z, a.w + b.w);
            float4 c = S2[tid], d = S2[tid + off * ncg];
            S2[tid] = make_float4(c.x + d.x, c.y + d.y, c.z + d.z, c.w + d.w);
        }
        __syncthreads();
    }
    if (rg == 0) {
        *(float4*)&p1[(long)blockIdx.x * NC + 4 * cg] = S1[tid];
        *(float4*)&p2[(long)blockIdx.x * NC + 4 * cg] = S2[tid];
    }
}

__global__ __launch_bounds__(256)
void colstats_f32_v2(const float* __restrict__ X, int M, int N,
                     float* __restrict__ p1, float* __restrict__ p2)
{
    __shared__ float sh1[1024], sh2[1024];
    int tid = threadIdx.x;
    int ncg = N >> 2;
    int cg  = tid & (ncg - 1);
    int rg  = tid / ncg;
    int nrg = 256 / ncg;
    float s0=0,s1=0,s2=0,s3=0, q0=0,q1=0,q2=0,q3=0;
    const float* base = X + 4 * cg;
    for (long row = (long)blockIdx.x * nrg + rg; row < M; row += (long)gridDim.x * nrg) {
        float4 v = *(const float4*)(base + row * (long)N);
        s0 += v.x; q0 += v.x * v.x; s1 += v.y; q1 += v.y * v.y;
        s2 += v.z; q2 += v.z * v.z; s3 += v.w; q3 += v.w * v.w;
    }
    float4* S1 = (float4*)sh1; float4* S2 = (float4*)sh2;
    S1[tid] = make_float4(s0, s1, s2, s3);
    S2[tid] = make_float4(q0, q1, q2, q3);
    __syncthreads();
    for (int off = nrg >> 1; off > 0; off >>= 1) {
        if (rg < off) {
            float4 a = S1[tid], b = S1[tid + off * ncg];
            S1[tid] = make_float4(a.x + b.x, a.y + b.y, a.z + b.z, a.w + b.w);
            float4 c = S2[tid], d = S2[tid + off * ncg];
            S2[tid] = make_float4(c.x + d.x, c.y + d.y, c.z + d.z, c.w + d.w);
        }
        __syncthreads();
    }
    if (rg == 0) {
        *(float4*)&p1[(long)blockIdx.x * N + 4 * cg] = S1[tid];
        *(float4*)&p2[(long)blockIdx.x * N + 4 * cg] = S2[tid];
    }
}

__global__ void colstats_reduce_v2(const float* __restrict__ p1, const float* __restrict__ p2,
                                   int nblk, int N, float invM,
                                   float* __restrict__ s1o, float* __restrict__ s2o)
{
    __shared__ float sh1[256], sh2[256];
    int tid = threadIdx.x;
    int col = blockIdx.x * 64 + (tid & 63);
    int seg = tid >> 6;
    float a = 0.f, c = 0.f;
    for (int b = seg; b < nblk; b += 4) {
        a += p1[(long)b * N + col];
        c += p2[(long)b * N + col];
    }
    sh1[tid] = a; sh2[tid] = c;
    __syncthreads();
    if (seg == 0) {
        a = sh1[tid] + sh1[tid + 64] + sh1[tid + 128] + sh1[tid + 192];
        c = sh2[tid] + sh2[tid + 64] + sh2[tid + 128] + sh2[tid + 192];
        float mean = a * invM;
        float var  = fmaxf(c * invM - mean * mean, 0.f);
        s1o[col] = mean;
        s2o[col] = rsqrtf(var + 1e-5f);
    }
}

__global__ void bn_apply(float* X, long total, int mask,
                         const float* __restrict__ s1, const float* __restrict__ s2)
{
    long i = (long)blockIdx.x * blockDim.x + threadIdx.x;
    long st = (long)gridDim.x * blockDim.x;
    for (; i < total; i += st) {
        int j = (int)(i & mask);
        X[i] = fmaxf((X[i] - s1[j]) * s2[j], 0.f);
    }
}

// BN+ReLU, fp32 in place AND bf16 copy
__global__ void bn_apply_dual(float* __restrict__ X, u16* __restrict__ Xb, long total,
                              int mask, const float* __restrict__ s1,
                              const float* __restrict__ s2)
{
    long i = (long)blockIdx.x * blockDim.x + threadIdx.x;
    long st = (long)gridDim.x * blockDim.x;
    for (; i < total; i += st) {
        int j = (int)(i & mask);
        float y = fmaxf((X[i] - s1[j]) * s2[j], 0.f);
        X[i] = y;
        Xb[i] = f2b(y);
    }
}

// ---------------- CSR aggregation (no atomics) ------------------------------
__global__ __launch_bounds__(256)
void mol_agg_in(const void* __restrict__ Xraw, const u16* __restrict__ Xcvt,
                const int* __restrict__ flagp, const float* __restrict__ dinv,
                const int* __restrict__ off, const int2* __restrict__ eb,
                int NM, u16* __restrict__ out)
{
    const u16* X = (*flagp != 0) ? Xcvt : (const u16*)Xraw;
    int wid  = (int)(((long)blockIdx.x * 256 + threadIdx.x) >> 6);
    int lane = threadIdx.x & 63;
    if (wid >= NM) return;
    float dv = dinv[wid];
    float acc = b2f(X[(long)wid * 64 + lane]) * dv * dv;
    int j = off[wid], j1 = off[wid + 1];
    for (; j + 3 < j1; j += 4) {
        int2 e0 = eb[j], e1 = eb[j + 1], e2 = eb[j + 2], e3 = eb[j + 3];
        float v0 = b2f(X[(long)e0.x * 64 + lane]);
        float v1 = b2f(X[(long)e1.x * 64 + lane]);
        float v2 = b2f(X[(long)e2.x * 64 + lane]);
        float v3 = b2f(X[(long)e3.x * 64 + lane]);
        acc += v0 * __int_as_float(e0.y) + v1 * __int_as_float(e1.y)
             + v2 * __int_as_float(e2.y) + v3 * __int_as_float(e3.y);
    }
    for (; j < j1; j++) {
        int2 e = eb[j];
        acc += b2f(X[(long)e.x * 64 + lane]) * __int_as_float(e.y);
    }
    out[(long)wid * 64 + lane] = f2b(acc);
}

// mol layer-2 aggregation with FUSED BN+ReLU on gathered G1 values.
// G raw [NM,128] bf16; s1/s2 = column mean / rsqrt(var) (128 cols).
// y = relu((g - m) * r) applied in fp32 to self and every gathered row.
__global__ __launch_bounds__(256)
void mol_agg128_bn(const u16* __restrict__ G, const float* __restrict__ dinv,
                   const int* __restrict__ off, const int2* __restrict__ eb,
                   int NM, const float* __restrict__ s1, const float* __restrict__ s2,
                   u16* __restrict__ out)
{
    int wid  = (int)(((long)blockIdx.x * 256 + threadIdx.x) >> 6);
    int lane = threadIdx.x & 63;
    if (wid >= NM) return;
    const float m0 = s1[2 * lane],     r0 = s2[2 * lane];
    const float m1 = s1[2 * lane + 1], r1 = s2[2 * lane + 1];
    float dv = dinv[wid], dv2 = dv * dv;
    u32 u = *(const u32*)(G + (long)wid * 128 + 2 * lane);
    float a0 = fmaxf((b2f((u16)(u & 0xFFFF)) - m0) * r0, 0.f) * dv2;
    float a1 = fmaxf((b2f((u16)(u >> 16))    - m1) * r1, 0.f) * dv2;
    int j = off[wid], j1 = off[wid + 1];
    for (; j + 3 < j1; j += 4) {
        int2 e0 = eb[j], e1 = eb[j + 1], e2 = eb[j + 2], e3 = eb[j + 3];
        u32 v0 = *(const u32*)(G + (long)e0.x * 128 + 2 * lane);
        u32 v1 = *(const u32*)(G + (long)e1.x * 128 + 2 * lane);
        u32 v2 = *(const u32*)(G + (long)e2.x * 128 + 2 * lane);
        u32 v3 = *(const u32*)(G + (long)e3.x * 128 + 2 * lane);
        float n0 = __int_as_float(e0.y), n1 = __int_as_float(e1.y);
        float n2 = __int_as_float(e2.y), n3 = __int_as_float(e3.y);
        a0 += fmaxf((b2f((u16)(v0 & 0xFFFF)) - m0) * r0, 0.f) * n0
            + fmaxf((b2f((u16)(v1 & 0xFFFF)) - m0) * r0, 0.f) * n1
            + fmaxf((b2f((u16)(v2 & 0xFFFF)) - m0) * r0, 0.f) * n2
            + fmaxf((b2f((u16)(v3 & 0xFFFF)) - m0) * r0, 0.f) * n3;
        a1 += fmaxf((b2f((u16)(v0 >> 16)) - m1) * r1, 0.f) * n0
            + fmaxf((b2f((u16)(v1 >> 16)) - m1) * r1, 0.f) * n1
            + fmaxf((b2f((u16)(v2 >> 16)) - m1) * r1, 0.f) * n2
            + fmaxf((b2f((u16)(v3 >> 16)) - m1) * r1, 0.f) * n3;
    }
    for (; j < j1; j++) {
        int2 e = eb[j];
        u32 v = *(const u32*)(G + (long)e.x * 128 + 2 * lane);
        float n = __int_as_float(e.y);
        a0 += fmaxf((b2f((u16)(v & 0xFFFF)) - m0) * r0, 0.f) * n;
        a1 += fmaxf((b2f((u16)(v >> 16))    - m1) * r1, 0.f) * n;
    }
    u32 o = (u32)f2b(a0) | ((u32)f2b(a1) << 16);
    *(u32*)(out + (long)wid * 128 + 2 * lane) = o;
}

// RGCN pre-aggregation v2: one wave per (node, relation) segment.
__global__ __launch_bounds__(256)
void kg_preagg2(const u16* __restrict__ xin, const int* __restrict__ off2,
                const int* __restrict__ eb, int NSEG, u16* __restrict__ aggx)
{
    int seg  = (int)(((long)blockIdx.x * 256 + threadIdx.x) >> 6);
    int lane = threadIdx.x & 63;
    if (seg >= NSEG) return;
    int node = seg >> 3, r = seg & 7;
    const int c4 = 4 * lane;
    int j0 = off2[seg], j1 = off2[seg + 1];
    float a0 = 0.f, a1 = 0.f, a2 = 0.f, a3 = 0.f;
    int j = j0;
    for (; j + 3 < j1; j += 4) {
        int s0 = eb[j], s1 = eb[j + 1], s2 = eb[j + 2], s3 = eb[j + 3];
        ushort4 v0 = *(const ushort4*)(xin + (long)s0 * 256 + c4);
        ushort4 v1 = *(const ushort4*)(xin + (long)s1 * 256 + c4);
        ushort4 v2 = *(const ushort4*)(xin + (long)s2 * 256 + c4);
        ushort4 v3 = *(const ushort4*)(xin + (long)s3 * 256 + c4);
        a0 += b2f(v0.x) + b2f(v1.x) + b2f(v2.x) + b2f(v3.x);
        a1 += b2f(v0.y) + b2f(v1.y) + b2f(v2.y) + b2f(v3.y);
        a2 += b2f(v0.z) + b2f(v1.z) + b2f(v2.z) + b2f(v3.z);
        a3 += b2f(v0.w) + b2f(v1.w) + b2f(v2.w) + b2f(v3.w);
    }
    for (; j < j1; j++) {
        ushort4 v = *(const ushort4*)(xin + (long)eb[j] * 256 + c4);
        a0 += b2f(v.x); a1 += b2f(v.y); a2 += b2f(v.z); a3 += b2f(v.w);
    }
    float nrm = 1.0f / fmaxf((float)(j1 - j0), 1.0f);
    ushort4 o;
    o.x = f2b(a0 * nrm); o.y = f2b(a1 * nrm);
    o.z = f2b(a2 * nrm); o.w = f2b(a3 * nrm);
    *(ushort4*)(aggx + (long)node * 2304 + 256 + (r << 8) + c4) = o;
}

// copy xin rows into AGGX cols 0:255
__global__ void xcopy_aggx(const u16* __restrict__ xin, u16* __restrict__ aggx, long n4)
{
    long i = (long)blockIdx.x * blockDim.x + threadIdx.x;
    long st = (long)gridDim.x * blockDim.x;
    for (; i < n4; i += st) {
        long node = i >> 6;
        int c4 = (int)(i & 63) * 4;
        *(ushort4*)(aggx + node * 2304 + c4) = *(const ushort4*)(xin + node * 256 + c4);
    }
}

// mean-pool bf16 chunk [NM, ld] cols [cc, cc+64) with fused BN+ReLU
__global__ __launch_bounds__(256)
void pool_b16(const u16* __restrict__ g, int ld, int cc,
              const int* __restrict__ off, const int* __restrict__ bins, int ND,
              const float* __restrict__ s1, const float* __restrict__ s2,
              float* __restrict__ gout, int c0out)
{
    int wid  = (int)(((long)blockIdx.x * 256 + threadIdx.x) >> 6);
    int lane = threadIdx.x & 63;
    if (wid >= ND) return;
    float m = s1[cc + lane], r = s2[cc + lane];
    int j0 = off[wid], j1 = off[wid + 1];
    float acc = 0.f;
    for (int j = j0; j < j1; j++)
        acc += fmaxf((b2f(g[(long)bins[j] * ld + cc + lane]) - m) * r, 0.f);
    gout[(long)wid * 256 + c0out + lane] = acc / fmaxf((float)(j1 - j0), 1.0f);
}

// ---------------- attention fusion ------------------------------------------
__global__ void attention_fuse(const float* __restrict__ go, const float* __restrict__ fpv,
                               const float* __restrict__ W1, const float* __restrict__ B1,
                               const float* __restrict__ W2,
                               float* __restrict__ emb, float* __restrict__ beta_out)
{
    int d = blockIdx.x;
    int t = threadIdx.x;
    __shared__ float z[2][256];
    __shared__ float red[128];
    for (int c = t; c < 256; c += 128) {
        z[0][c] = go[(long)d * 256 + c];
        z[1][c] = fpv[(long)d * 256 + c];
    }
    __syncthreads();
    float s[2];
    for (int v = 0; v < 2; v++) {
        float acc = B1[t];
        for (int k = 0; k < 256; k++) acc += z[v][k] * W1[k * 128 + t];
        red[t] = tanhf(acc) * W2[t];
        __syncthreads();
        for (int off = 64; off > 0; off >>= 1) {
            if (t < off) red[t] += red[t + off];
            __syncthreads();
        }
        s[v] = red[0];
        __syncthreads();
    }
    float m = fmaxf(s[0], s[1]);
    float e0 = expf(s[0] - m), e1 = expf(s[1] - m);
    float inv = 1.0f / (e0 + e1);
    float b0 = e0 * inv, b1 = e1 * inv;
    for (int c = t; c < 256; c += 128)
        emb[(long)d * 256 + c] = b0 * z[0][c] + b1 * z[1][c];
    if (t == 0) {
        beta_out[d * 2 + 0] = b0;
        beta_out[d * 2 + 1] = b1;
    }
}

// ---------------- final linear + log_softmax, fused BN on x4 ----------------
__global__ void logits_out_bn(const float* __restrict__ x4,
                              const float* __restrict__ s1, const float* __restrict__ s2,
                              const float* __restrict__ w, const float* __restrict__ b,
                              float* __restrict__ out, int NKG)
{
    int i = blockIdx.x * blockDim.x + threadIdx.x;
    if (i >= NKG) return;
    float a0 = b[0], a1 = b[1];
    for (int k = 0; k < 64; k++) {
        float v = fmaxf((x4[(long)i * 64 + k] - s1[k]) * s2[k], 0.f);
        a0 += v * w[k * 2 + 0];
        a1 += v * w[k * 2 + 1];
    }
    float m = fmaxf(a0, a1);
    float lse = m + logf(expf(a0 - m) + expf(a1 - m));
    out[i * 2 + 0] = a0 - lse;
    out[i * 2 + 1] = a1 - lse;
}

// ============================================================================
extern "C" void kernel_launch(void* const* d_in, const int* in_sizes, int n_in,
                              void* d_out, int out_size, void* d_ws, size_t ws_size,
                              hipStream_t stream)
{
    (void)in_sizes; (void)n_in; (void)out_size; (void)ws_size;
    const int ND = 4096, NM = 131072, NKG = 9510, NGENE = 5414;
    const long EM = 524288, EK = 524288;
    const int NSEG = 8 * NKG;   // 76080 (node, relation) segments

    const void* fp_data = d_in[0];
    const void* mol_x   = d_in[1];
    const int*  mol_batch = (const int*)d_in[2];
    const int*  mol_ei  = (const int*)d_in[3];
    const int*  kg_ei   = (const int*)d_in[4];
    const int*  kg_et   = (const int*)d_in[5];

    const int* mol_src = mol_ei;
    const int* mol_dst = mol_ei + EM;
    const int* kg_src  = kg_ei;
    const int* kg_dst  = kg_ei + EK;

    float* out_ls   = (float*)d_out;          // [9510,2] fp32
    float* out_beta = (float*)d_out + 19020;  // [4096,2,1] fp32

    // ---- workspace carve ----
    char* wp = (char*)d_ws;
    auto carve = [&](size_t bytes) { char* p = wp; wp += (bytes + 255) & ~(size_t)255; return p; };
    float* stats = (float*)carve(4096);
    int*   flag  = (int*)carve(256);
    float* dinv  = (float*)carve((size_t)NM * 4);
    float* enM   = (float*)carve((size_t)EM * 4);
    float* part1 = (float*)carve((size_t)NBLK_STATS * 512 * 4);
    float* part2 = (float*)carve((size_t)NBLK_STATS * 512 * 4);
    int*   sbt   = (int*)carve(256);
    int*   sbo   = (int*)carve(256);
    float* Wpool = (float*)carve((size_t)1630000 * 4);     // fp32 weights
    u16*   WpoolB= (u16*)carve((size_t)1630000 * 2);       // bf16 weights
    u16*   WpoolT= (u16*)carve((size_t)1600000 * 2);       // bf16 transposed gemm weights
    float* fpb   = (float*)carve((size_t)ND * 256 * 4);
    float* gout  = (float*)carve((size_t)ND * 256 * 4);
    int*   key2  = (int*)carve((size_t)EK * 4);            // kg seg keys; reused as ebK2
    int*   koff2 = (int*)carve((size_t)(NSEG + 1) * 4);
    // zero-span
    char*  z0    = wp;
    int* kdeg2 = (int*)carve((size_t)NSEG * 4);
    int* kcur2 = (int*)carve((size_t)NSEG * 4);
    int* mdeg = (int*)carve((size_t)NM * 4);
    int* mcur = (int*)carve((size_t)NM * 4);
    int* pdeg = (int*)carve((size_t)ND * 4);
    int* pcur = (int*)carve((size_t)ND * 4);
    char*  z1    = wp;
    int* moff = (int*)carve((size_t)(NM + 1) * 4);
    int* mbins= (int*)carve((size_t)EM * 4);
    int* kbins= (int*)carve((size_t)EK * 4);
    int* poff = (int*)carve((size_t)(ND + 1) * 4);
    int* pbins= (int*)carve((size_t)NM * 4);
    char*  REG1  = carve((size_t)NM * 128 * 2);            // 33.6 MB
    char*  REG2  = carve((size_t)NM * 128 * 2);            // 33.6 MB  (contiguous with HB)
    u16*   HB    = (u16*)carve((size_t)NM * 64 * 2);       // 16.8 MB

    // phase views
    float* fp1 = (float*)REG1;                 // fp: [4096,512] f32
    u16*   XB  = (u16*)REG1;                   // mol pre: [NM,64] bf16 converted input
    u16*   G1  = (u16*)REG1;                   // mol: [NM,128] bf16 (raw gemm out)
    u16*   H2  = (u16*)REG1;                   // mol L2: [NM,128] bf16 half-output (G1 dead)
    // rgcn chain in REG1:
    float* xkg = (float*)REG1;                 // [NKG,256] f32 (emb+gene)
    float* x2  = xkg + (size_t)NKG * 256;      // [NKG,256] f32
    float* x3  = x2  + (size_t)NKG * 256;      // [NKG,128] f32
    float* x4  = x3  + (size_t)NKG * 128;      // [NKG,64]  f32
    u16*   xb  = (u16*)(x4 + (size_t)NKG * 64);// [NKG,256] bf16 (after x4, fits REG1)
    u16*   x2b = (u16*)REG1;                   // [NKG,256] bf16 (overlaps xkg: dead then)
    u16*   Xfb = (u16*)REG2;                   // fp: [4096,1024] bf16
    u16*   G1A = (u16*)REG2;                   // mol: [NM,128] bf16 aggregated
    u16*   AGGX= (u16*)REG2;                   // rgcn: [NKG,2304] bf16 (43.8 MB, REG2+HB)
    u16*   fp1b = HB;                          // fp: [4096,512] bf16
    u16*   Xagg = HB;                          // mol L1: [NM,64] bf16
    // flattened CSR edge tables (aliased; lifetimes verified)
    int2* ebM  = (int2*)gout;                  // mol edges; gout written only after dead
    int*  ebK2 = key2;                         // kg src table; key2 dead after bin_by

    // ---- dtype detect + weight conversion (fp32 + bf16 pools) ----
    zero_int<<<1, 1, 0, stream>>>(flag);
    detect_f32<<<1024, 256, 0, stream>>>((const u16*)fp_data, (long)ND * 1024, flag);
    ConvTab tab;
    // NOTE: rg_root before rg_w so [root; W_0..W_7] is contiguous = [2304, N] GEMM B
    const int widx[14] = {6, 8, 10, 12, 14, 15, 16, 19, 18, 22, 21, 24, 26, 27};
    const int wn[14]   = {1024*512, 512*256, 64*128, 128*256, 256*128, 128, 128,
                          256*256, 8*256*256, 256*128, 8*256*128, 128*64, 64*2, 2};
    float* wf[14]; u16* wb[14];
    {
        size_t o = 0;
        for (int i = 0; i < 14; i++) {
            tab.src[i]  = d_in[widx[i]];
            tab.dst[i]  = Wpool + o;
            tab.dstB[i] = WpoolB + o;
            tab.n[i]    = wn[i];
            wf[i] = Wpool + o; wb[i] = WpoolB + o;
            o += (size_t)wn[i];
        }
    }
    conv_all<<<dim3(32, 14), 256, 0, stream>>>(tab, flag);
    float *att_w1c = wf[4], *att_b1c = wf[5], *att_w2c = wf[6];
    float *lin1_wc = wf[11], *lin2_wc = wf[12], *lin2_bc = wf[13];

    // ---- transposed bf16 weights for gemm_bt (BT[n*K+k] = B[k*N+n]) ----
    u16* T_fpw1  = WpoolT;                        // [512,1024]
    u16* T_fpw2  = T_fpw1 + (size_t)512 * 1024;   // [256,512]
    u16* T_gcnw1 = T_fpw2 + (size_t)256 * 512;    // [128,64]
    u16* T_gcnw2 = T_gcnw1 + (size_t)128 * 64;    // [256,128]
    u16* T_w1    = T_gcnw2 + (size_t)256 * 128;   // [256,2304]
    u16* T_w2    = T_w1 + (size_t)256 * 2304;     // [128,2304]
    transpose_b16<<<dim3(32, 16), 256, 0, stream>>>(wb[0], T_fpw1, 1024, 512);
    transpose_b16<<<dim3(16, 8),  256, 0, stream>>>(wb[1], T_fpw2, 512, 256);
    transpose_b16<<<dim3(2, 4),   256, 0, stream>>>(wb[2], T_gcnw1, 64, 128);
    transpose_b16<<<dim3(4, 8),   256, 0, stream>>>(wb[3], T_gcnw2, 128, 256);
    transpose_b16<<<dim3(72, 8),  256, 0, stream>>>(wb[7], T_w1, 2304, 256);
    transpose_b16<<<dim3(72, 4),  256, 0, stream>>>(wb[9], T_w2, 2304, 128);

    // ---- CSR builds ----
    filli<<<512, 256, 0, stream>>>((int*)z0, (long)(z1 - z0) / 4, 0);
    auto scan = [&](const int* deg, int* off, int n) {
        int nb = divup(n, 4096);
        scan_bsum<<<nb, 1024, 0, stream>>>(deg, n, sbt);
        scan_tiny<<<1, 64, 0, stream>>>(sbt, nb, sbo);
        scan_final<<<nb, 1024, 0, stream>>>(deg, n, sbo, nb, off);
    };
    hist_int<<<2048, 256, 0, stream>>>(mol_dst, EM, mdeg);
    scan(mdeg, moff, NM);
    bin_by<<<2048, 256, 0, stream>>>(mol_dst, EM, moff, mcur, mbins);
    dinv_from_deg<<<512, 256, 0, stream>>>(mdeg, dinv, NM);
    mol_enorm<<<1024, 256, 0, stream>>>(mol_src, mol_dst, dinv, EM, enM);
    flatten_mol<<<2048, 256, 0, stream>>>(mbins, mol_src, enM, EM, ebM);

    // KG: segment CSR over (dst, relation); mean norm from segment length
    kg_key2<<<2048, 256, 0, stream>>>(kg_dst, kg_et, EK, key2);
    hist_int<<<2048, 256, 0, stream>>>(key2, EK, kdeg2);
    scan(kdeg2, koff2, NSEG);
    bin_by<<<2048, 256, 0, stream>>>(key2, EK, koff2, kcur2, kbins);
    flatten_kg_src<<<2048, 256, 0, stream>>>(kbins, kg_src, EK, ebK2);  // key2 dead

    hist_int<<<512, 256, 0, stream>>>(mol_batch, NM, pdeg);
    scan(pdeg, poff, ND);
    bin_by<<<512, 256, 0, stream>>>(mol_batch, NM, poff, pcur, pbins);

    // ---- BN helpers (v2) ----
    auto bn_stats = [&](const float* X, int M, int N) {
        colstats_f32_v2<<<NBLK_STATS, 256, 0, stream>>>(X, M, N, part1, part2);
        colstats_reduce_v2<<<N / 64, 256, 0, stream>>>(part1, part2, NBLK_STATS, N,
                                                       1.0f / M, stats, stats + 512);
    };
    auto bn_stats_b16 = [&](const u16* X, int M, int ld, int c0, int NC) {
        colstats_b16_v2<<<NBLK_STATS, 256, 0, stream>>>(X, M, ld, c0, NC, part1, part2);
        colstats_reduce_v2<<<NC / 64, 256, 0, stream>>>(part1, part2, NBLK_STATS, NC,
                                                        1.0f / M, stats, stats + 512);
    };

    // ---------- fingerprint MLP branch (MFMA) ----------
    conv_dual_b16<<<2048, 256, 0, stream>>>(fp_data, Xfb, (long)ND * 1024, flag);
    gemm_bt<float, 2><<<dim3(64, 4), 256, 0, stream>>>(
        Xfb, 1024, T_fpw1, 1024, fp1, 512, ND, 512, 1024);
    bn_stats(fp1, ND, 512);
    bn_apply_dual<<<2048, 256, 0, stream>>>(fp1, fp1b, (long)ND * 512, 511,
                                            stats, stats + 512);
    gemm_bt<float, 1><<<dim3(64, 4), 256, 0, stream>>>(
        fp1b, 512, T_fpw2, 512, fpb, 256, ND, 256, 512);
    bn_stats(fpb, ND, 256);
    bn_apply<<<2048, 256, 0, stream>>>(fpb, (long)ND * 256, 255, stats, stats + 512);

    // ---------- mol GCN layer 1: bf16-convert, aggregate-then-GEMM ----------
    conv_molx<<<2048, 256, 0, stream>>>((const float*)mol_x, XB, (long)NM * 16, flag);
    mol_agg_in<<<32768, 256, 0, stream>>>(mol_x, XB, flag, dinv, moff, ebM, NM, Xagg);
    gemm_bt<u16, 2><<<dim3(2048, 1), 256, 0, stream>>>(
        Xagg, 64, T_gcnw1, 64, G1, 128, NM, 128, 64);   // G1 overwrites XB (dead)
    bn_stats_b16(G1, NM, 128, 0, 128);
    // BN+ReLU is fused into mol_agg128_bn below (G1 has no other consumer)

    // ---------- mol GCN layer 2: fused-BN aggregate, 2-half GEMM + pool -----
    mol_agg128_bn<<<32768, 256, 0, stream>>>(G1, dinv, moff, ebM, NM,
                                             stats, stats + 512, G1A);
    // ebM (gout) dead past this point; G1 (REG1) dead -> H2 reuses it
    for (int h = 0; h < 2; h++) {
        gemm_bt<u16, 2><<<dim3(2048, 1), 256, 0, stream>>>(
            G1A, 128, T_gcnw2 + (size_t)h * 128 * 128, 128, H2, 128, NM, 128, 128);
        bn_stats_b16(H2, NM, 128, 0, 128);
        pool_b16<<<1024, 256, 0, stream>>>(H2, 128, 0, poff, pbins, ND,
                                           stats, stats + 512, gout, h * 128);
        pool_b16<<<1024, 256, 0, stream>>>(H2, 128, 64, poff, pbins, ND,
                                           stats, stats + 512, gout, h * 128 + 64);
    }

    // ---------- attention fusion ----------
    attention_fuse<<<ND, 128, 0, stream>>>(gout, fpb, att_w1c, att_b1c, att_w2c,
                                           xkg, out_beta);
    conv_in<<<512, 256, 0, stream>>>(d_in[17], xkg + (long)ND * 256,
                                     (long)NGENE * 256, flag);
    conv_f32_b16<<<1024, 256, 0, stream>>>(xkg, xb, (long)NKG * 256);

    // ---------- RGCN layer 1 (256 -> 256): preagg2 + single K=2304 GEMM -----
    xcopy_aggx<<<1024, 256, 0, stream>>>(xb, AGGX, (long)NKG * 64);
    kg_preagg2<<<divup((long)NSEG * 64, 256), 256, 0, stream>>>(
        xb, koff2, ebK2, NSEG, AGGX);
    gemm_bt<float, 2><<<dim3(divup(NKG, 64), 2), 256, 0, stream>>>(
        AGGX, 2304, T_w1, 2304, x2, 256, NKG, 256, 2304);
    bn_stats(x2, NKG, 256);
    bn_apply_dual<<<2048, 256, 0, stream>>>(x2, x2b, (long)NKG * 256, 255,
                                            stats, stats + 512);

    // ---------- RGCN layer 2 (256 -> 128): preagg2 + single K=2304 GEMM -----
    xcopy_aggx<<<1024, 256, 0, stream>>>(x2b, AGGX, (long)NKG * 64);
    kg_preagg2<<<divup((long)NSEG * 64, 256), 256, 0, stream>>>(
        x2b, koff2, ebK2, NSEG, AGGX);
    gemm_bt<float, 1><<<dim3(divup(NKG, 64), 2), 256, 0, stream>>>(
        AGGX, 2304, T_w2, 2304, x3, 128, NKG, 128, 2304);
    bn_stats(x3, NKG, 128);
    bn_apply<<<2048, 256, 0, stream>>>(x3, (long)NKG * 128, 127, stats, stats + 512);

    // ---------- classifier head ----------
    gemm64<<<dim3(divup(NKG, 64), 1, 1), 256, 0, stream>>>(
        x3, 128, lin1_wc, 64, x4, 64, NKG, 64, 128);
    bn_stats(x4, NKG, 64);
    logits_out_bn<<<divup(NKG, 256), 256, 0, stream>>>(x4, stats, stats + 512,
                                                       lin2_wc, lin2_bc, out_ls, NKG);
}

// Round 9
// 1086.490 us; speedup vs baseline: 1.3176x; 1.0677x over previous
//
#include <hip/hip_runtime.h>
#include <hip/hip_bf16.h>
#include <cstdint>

typedef __hip_bfloat16 bf16;
typedef unsigned short u16;
typedef unsigned int u32;
typedef __attribute__((ext_vector_type(8))) short short8;
typedef __attribute__((ext_vector_type(4))) float f32x4;

__device__ __forceinline__ float tofloat(float x){ return x; }
__device__ __forceinline__ float tofloat(bf16 x){ return __bfloat162float(x); }
__device__ __forceinline__ float b2f(u16 a){ return __uint_as_float(((unsigned)a) << 16); }
__device__ __forceinline__ u16 f2b(float f){           // round-to-nearest-even
    unsigned u = __float_as_uint(f);
    return (u16)((u + 0x7FFFu + ((u >> 16) & 1u)) >> 16);
}

static inline int divup(long a, long b){ return (int)((a + b - 1) / b); }

#define NBLK_STATS 256

// ---------------- input dtype detection -------------------------------------
__global__ void zero_int(int* p){ *p = 0; }

__global__ void detect_f32(const u16* __restrict__ h, long n, int* flag)
{
    long i = (long)blockIdx.x * blockDim.x + threadIdx.x;
    long st = (long)gridDim.x * blockDim.x;
    int c = 0;
    for (; i < n; i += st)
        if (((h[i] >> 7) & 0xFF) == 0xFF) c++;
    if (c) atomicAdd(flag, c);
}

// convert all weights: fp32 pool + bf16 pool in one launch
struct ConvTab { const void* src[14]; float* dst[14]; u16* dstB[14]; int n[14]; };

__global__ void conv_all(ConvTab t, const int* __restrict__ flagp)
{
    bool f32 = (*flagp != 0);
    int seg = blockIdx.y;
    const void* s = t.src[seg];
    float* d = t.dst[seg];
    u16*   dB = t.dstB[seg];
    int n = t.n[seg];
    long i = (long)blockIdx.x * blockDim.x + threadIdx.x;
    long st = (long)gridDim.x * blockDim.x;
    for (; i < n; i += st) {
        float v = f32 ? ((const float*)s)[i] : tofloat(((const bf16*)s)[i]);
        d[i] = v; dB[i] = f2b(v);
    }
}

__global__ void conv_in(const void* __restrict__ src, float* __restrict__ dst,
                        long n, const int* __restrict__ flagp)
{
    bool f32 = (*flagp != 0);
    long i = (long)blockIdx.x * blockDim.x + threadIdx.x;
    long st = (long)gridDim.x * blockDim.x;
    for (; i < n; i += st)
        dst[i] = f32 ? ((const float*)src)[i] : tofloat(((const bf16*)src)[i]);
}

__global__ void conv_dual_b16(const void* __restrict__ src, u16* __restrict__ dst,
                              long n, const int* __restrict__ flagp)
{
    bool f32 = (*flagp != 0);
    long i = (long)blockIdx.x * blockDim.x + threadIdx.x;
    long st = (long)gridDim.x * blockDim.x;
    for (; i < n; i += st)
        dst[i] = f32 ? f2b(((const float*)src)[i]) : ((const u16*)src)[i];
}

__global__ void conv_f32_b16(const float* __restrict__ src, u16* __restrict__ dst, long n)
{
    long i = (long)blockIdx.x * blockDim.x + threadIdx.x;
    long st = (long)gridDim.x * blockDim.x;
    for (; i < n; i += st) dst[i] = f2b(src[i]);
}

// convert mol_x fp32 -> bf16 copy (only when input is fp32); vectorized x4
__global__ void conv_molx(const float* __restrict__ src, u16* __restrict__ dst,
                          long n4, const int* __restrict__ flagp)
{
    if (*flagp == 0) return;   // input already bf16; agg reads original
    long i = (long)blockIdx.x * blockDim.x + threadIdx.x;
    long st = (long)gridDim.x * blockDim.x;
    for (; i < n4; i += st) {
        float4 v = ((const float4*)src)[i];
        ushort4 o;
        o.x = f2b(v.x); o.y = f2b(v.y); o.z = f2b(v.z); o.w = f2b(v.w);
        ((ushort4*)dst)[i] = o;
    }
}

// bf16 transpose: dst[n*K + k] = src[k*N + n]
__global__ __launch_bounds__(256)
void transpose_b16(const u16* __restrict__ src, u16* __restrict__ dst, int K, int N)
{
    __shared__ u16 t[32][33];
    int k0 = blockIdx.x * 32, n0 = blockIdx.y * 32;
    int x = threadIdx.x & 31, y = threadIdx.x >> 5;   // y in 0..7
    for (int yy = y; yy < 32; yy += 8) {
        int k = k0 + yy, n = n0 + x;
        t[yy][x] = (k < K && n < N) ? src[(long)k * N + n] : (u16)0;
    }
    __syncthreads();
    for (int yy = y; yy < 32; yy += 8) {
        int n = n0 + yy, k = k0 + x;
        if (n < N && k < K) dst[(long)n * K + k] = t[x][yy];
    }
}

// ---------------- CSR edge flattening ---------------------------------------
// ebM[j] = {src, bits(en)}
__global__ void flatten_mol(const int* __restrict__ bins, const int* __restrict__ src,
                            const float* __restrict__ en, long E, int2* __restrict__ out)
{
    long i = (long)blockIdx.x * blockDim.x + threadIdx.x;
    long st = (long)gridDim.x * blockDim.x;
    for (; i < E; i += st) {
        int e = bins[i];
        out[i] = make_int2(src[e], __float_as_int(en[e]));
    }
}

// KG segment key: dst*8 + et  (segments = (node, relation) pairs)
__global__ void kg_key2(const int* __restrict__ dst, const int* __restrict__ et,
                        long E, int* __restrict__ key)
{
    long i = (long)blockIdx.x * blockDim.x + threadIdx.x;
    long st = (long)gridDim.x * blockDim.x;
    for (; i < E; i += st) key[i] = dst[i] * 8 + et[i];
}

// flatten KG edges to src index only (mean norm comes from segment length)
__global__ void flatten_kg_src(const int* __restrict__ bins, const int* __restrict__ src,
                               long E, int* __restrict__ out)
{
    long i = (long)blockIdx.x * blockDim.x + threadIdx.x;
    long st = (long)gridDim.x * blockDim.x;
    for (; i < E; i += st) out[i] = src[bins[i]];
}

// ---------------- MFMA GEMM (B pre-transposed): C = A @ B, bf16, fp32 acc ---
// A [M,K] lda; BT [N,K] ldbt. Tile 64 x (NBLK*64). Register-prefetch pipeline.
// STATS: fuse per-column sum/sumsq of the STORED values into the epilogue,
// writing per-block partials SP1/SP2[blockIdx.x * Ntot + col] (bitwise-identical
// to a separate pass reading the stored output). OOB rows contribute 0.
template<typename TC, int NBLK, bool STATS>
__global__ __launch_bounds__(256)
void gemm_bt(const u16* __restrict__ A, int lda,
             const u16* __restrict__ BT, int ldbt,
             TC* __restrict__ C, int ldc,
             int M, int N, int K,
             float* __restrict__ SP1, float* __restrict__ SP2, int Ntot)
{
    __shared__ __align__(16) u16 As[64][40];          // [m][k]
    __shared__ __align__(16) u16 Bs[NBLK * 64][40];   // [n][k]
    __shared__ float st1[NBLK * 64], st2[NBLK * 64];
    const int tid = threadIdx.x;
    const int lane = tid & 63, wave = tid >> 6;
    const int l15 = lane & 15, quad = lane >> 4;
    const int wm = (wave & 1) * 32, wn = (wave >> 1) * 32;
    const int row0 = blockIdx.x * 64, col0 = blockIdx.y * (NBLK * 64);
    const int arow = tid >> 2, ak = (tid & 3) * 8;
    const int aok = row0 + arow < M;

    if (STATS && tid < NBLK * 64) { st1[tid] = 0.f; st2[tid] = 0.f; }

    f32x4 acc[NBLK][2][2];
#pragma unroll
    for (int t = 0; t < NBLK; t++)
#pragma unroll
        for (int i = 0; i < 2; i++)
#pragma unroll
            for (int j = 0; j < 2; j++)
#pragma unroll
                for (int r = 0; r < 4; r++) acc[t][i][j][r] = 0.f;

    const u16* pa = A + (long)(row0 + arow) * lda + ak;
    const u16* pb[NBLK];
#pragma unroll
    for (int t = 0; t < NBLK; t++)
        pb[t] = BT + (long)(col0 + t * 64 + arow) * ldbt + ak;

    ushort4 ra0 = {0,0,0,0}, ra1 = {0,0,0,0};
    ushort4 rb0[NBLK], rb1[NBLK];
    if (aok) { ra0 = *(const ushort4*)pa; ra1 = *(const ushort4*)(pa + 4); }
#pragma unroll
    for (int t = 0; t < NBLK; t++) {
        rb0[t] = *(const ushort4*)pb[t];
        rb1[t] = *(const ushort4*)(pb[t] + 4);
    }

    for (int k0 = 0; k0 < K; k0 += 32) {
        *(ushort4*)&As[arow][ak]     = ra0;
        *(ushort4*)&As[arow][ak + 4] = ra1;
#pragma unroll
        for (int t = 0; t < NBLK; t++) {
            *(ushort4*)&Bs[t * 64 + arow][ak]     = rb0[t];
            *(ushort4*)&Bs[t * 64 + arow][ak + 4] = rb1[t];
        }
        __syncthreads();
        if (k0 + 32 < K) {   // issue next-step loads; retire under MFMAs
            if (aok) {
                ra0 = *(const ushort4*)(pa + k0 + 32);
                ra1 = *(const ushort4*)(pa + k0 + 36);
            }
#pragma unroll
            for (int t = 0; t < NBLK; t++) {
                rb0[t] = *(const ushort4*)(pb[t] + k0 + 32);
                rb1[t] = *(const ushort4*)(pb[t] + k0 + 36);
            }
        }
        short8 a0 = *(const short8*)&As[wm + l15][quad * 8];
        short8 a1 = *(const short8*)&As[wm + 16 + l15][quad * 8];
#pragma unroll
        for (int t = 0; t < NBLK; t++) {
            short8 b0 = *(const short8*)&Bs[t * 64 + wn + l15][quad * 8];
            short8 b1 = *(const short8*)&Bs[t * 64 + wn + 16 + l15][quad * 8];
            acc[t][0][0] = __builtin_amdgcn_mfma_f32_16x16x32_bf16(a0, b0, acc[t][0][0], 0, 0, 0);
            acc[t][0][1] = __builtin_amdgcn_mfma_f32_16x16x32_bf16(a0, b1, acc[t][0][1], 0, 0, 0);
            acc[t][1][0] = __builtin_amdgcn_mfma_f32_16x16x32_bf16(a1, b0, acc[t][1][0], 0, 0, 0);
            acc[t][1][1] = __builtin_amdgcn_mfma_f32_16x16x32_bf16(a1, b1, acc[t][1][1], 0, 0, 0);
        }
        __syncthreads();
    }
#pragma unroll
    for (int t = 0; t < NBLK; t++)
#pragma unroll
        for (int j = 0; j < 2; j++) {
            float s = 0.f, q = 0.f;
#pragma unroll
            for (int i = 0; i < 2; i++)
#pragma unroll
                for (int r = 0; r < 4; r++) {
                    int row = row0 + wm + i * 16 + quad * 4 + r;
                    int col = col0 + t * 64 + wn + j * 16 + l15;
                    float v = acc[t][i][j][r];
                    float y;
                    if constexpr (sizeof(TC) == 2) {
                        u16 h = f2b(v);
                        if (row < M) ((u16*)C)[(long)row * ldc + col] = h;
                        y = b2f(h);
                    } else {
                        if (row < M) ((float*)C)[(long)row * ldc + col] = v;
                        y = v;
                    }
                    if (STATS) { s += y; q += y * y; }
                }
            if (STATS) {
                s += __shfl_xor(s, 16); s += __shfl_xor(s, 32);
                q += __shfl_xor(q, 16); q += __shfl_xor(q, 32);
                if (quad == 0) {
                    atomicAdd(&st1[t * 64 + wn + j * 16 + l15], s);
                    atomicAdd(&st2[t * 64 + wn + j * 16 + l15], q);
                }
            }
        }
    if (STATS) {
        __syncthreads();
        if (tid < NBLK * 64) {
            long off = (long)blockIdx.x * Ntot + (long)blockIdx.y * (NBLK * 64) + tid;
            SP1[off] = st1[tid];
            SP2[off] = st2[tid];
        }
    }
}

// ---------------- vector GEMM (fp32, small) ---------------------------------
__global__ __launch_bounds__(256)
void gemm64(const float* __restrict__ A, int lda,
            const float* __restrict__ B, int ldb,
            float* __restrict__ C, int ldc,
            int M, int N, int K)
{
    __shared__ float As[16][68];
    __shared__ float Bs[16][68];
    const int tid = threadIdx.x;
    const int row0 = blockIdx.x * 64, col0 = blockIdx.y * 64;
    float acc[4][4];
#pragma unroll
    for (int i = 0; i < 4; i++)
#pragma unroll
        for (int j = 0; j < 4; j++) acc[i][j] = 0.f;
    const int ar = tid >> 2, ak = (tid & 3) * 4;
    const int bk = tid >> 4, bc = (tid & 15) * 4;
    const int ty4 = (tid >> 4) * 4, tx4 = (tid & 15) * 4;
    for (int k0 = 0; k0 < K; k0 += 16) {
        {
            int row = row0 + ar;
            float4 v = make_float4(0.f, 0.f, 0.f, 0.f);
            if (row < M) v = *(const float4*)(A + (long)row * lda + k0 + ak);
            As[ak + 0][ar] = v.x; As[ak + 1][ar] = v.y;
            As[ak + 2][ar] = v.z; As[ak + 3][ar] = v.w;
        }
        {
            int c = col0 + bc;
            float4 v = make_float4(0.f, 0.f, 0.f, 0.f);
            if (c < N) v = *(const float4*)(B + (long)(k0 + bk) * ldb + c);
            *(float4*)&Bs[bk][bc] = v;
        }
        __syncthreads();
#pragma unroll
        for (int k = 0; k < 16; k++) {
            float4 a = *(const float4*)&As[k][ty4];
            float4 b = *(const float4*)&Bs[k][tx4];
            acc[0][0] += a.x * b.x; acc[0][1] += a.x * b.y; acc[0][2] += a.x * b.z; acc[0][3] += a.x * b.w;
            acc[1][0] += a.y * b.x; acc[1][1] += a.y * b.y; acc[1][2] += a.y * b.z; acc[1][3] += a.y * b.w;
            acc[2][0] += a.z * b.x; acc[2][1] += a.z * b.y; acc[2][2] += a.z * b.z; acc[2][3] += a.z * b.w;
            acc[3][0] += a.w * b.x; acc[3][1] += a.w * b.y; acc[3][2] += a.w * b.z; acc[3][3] += a.w * b.w;
        }
        __syncthreads();
    }
    int c = col0 + tx4;
#pragma unroll
    for (int i = 0; i < 4; i++) {
        int r = row0 + ty4 + i;
        if (r < M && c < N)
            *(float4*)&C[(long)r * ldc + c] =
                make_float4(acc[i][0], acc[i][1], acc[i][2], acc[i][3]);
    }
}

// ---------------- utility / CSR build ---------------------------------------
__global__ void filli(int* p, long n, int v)
{
    long i = (long)blockIdx.x * blockDim.x + threadIdx.x;
    long st = (long)gridDim.x * blockDim.x;
    for (; i < n; i += st) p[i] = v;
}

__global__ void hist_int(const int* __restrict__ key, long n, int* __restrict__ h)
{
    long i = (long)blockIdx.x * blockDim.x + threadIdx.x;
    long st = (long)gridDim.x * blockDim.x;
    for (; i < n; i += st) atomicAdd(&h[key[i]], 1);
}

__global__ __launch_bounds__(1024)
void scan_bsum(const int* __restrict__ in, int n, int* __restrict__ btot)
{
    __shared__ int sh[1024];
    int tid = threadIdx.x;
    int i0 = blockIdx.x * 4096 + tid * 4;
    int s = 0;
#pragma unroll
    for (int t = 0; t < 4; t++) { int idx = i0 + t; s += (idx < n) ? in[idx] : 0; }
    sh[tid] = s;
    __syncthreads();
    for (int off = 512; off > 0; off >>= 1) {
        if (tid < off) sh[tid] += sh[tid + off];
        __syncthreads();
    }
    if (tid == 0) btot[blockIdx.x] = sh[0];
}

__global__ void scan_tiny(const int* __restrict__ btot, int nb, int* __restrict__ boff)
{
    if (threadIdx.x == 0) {
        int c = 0;
        for (int b = 0; b < nb; b++) { boff[b] = c; c += btot[b]; }
        boff[nb] = c;
    }
}

__global__ __launch_bounds__(1024)
void scan_final(const int* __restrict__ in, int n, const int* __restrict__ boff,
                int nb, int* __restrict__ out)
{
    __shared__ int buf[1024];
    int tid = threadIdx.x;
    int i0 = blockIdx.x * 4096 + tid * 4;
    int v[4]; int s = 0;
#pragma unroll
    for (int t = 0; t < 4; t++) {
        int idx = i0 + t;
        v[t] = (idx < n) ? in[idx] : 0;
        s += v[t];
    }
    buf[tid] = s;
    __syncthreads();
    for (int off = 1; off < 1024; off <<= 1) {
        int t = (tid >= off) ? buf[tid - off] : 0;
        __syncthreads();
        buf[tid] += t;
        __syncthreads();
    }
    int excl = buf[tid] - s + boff[blockIdx.x];
#pragma unroll
    for (int t = 0; t < 4; t++) {
        int idx = i0 + t;
        if (idx < n) out[idx] = excl;
        excl += v[t];
    }
    if (blockIdx.x == 0 && tid == 0) out[n] = boff[nb];
}

__global__ void bin_by(const int* __restrict__ key, long n,
                       const int* __restrict__ off, int* __restrict__ cursor,
                       int* __restrict__ bins)
{
    long i = (long)blockIdx.x * blockDim.x + threadIdx.x;
    long st = (long)gridDim.x * blockDim.x;
    for (; i < n; i += st) {
        int k = key[i];
        int pos = off[k] + atomicAdd(&cursor[k], 1);
        bins[pos] = (int)i;
    }
}

__global__ void dinv_from_deg(const int* __restrict__ deg, float* __restrict__ dinv, long n)
{
    long i = (long)blockIdx.x * blockDim.x + threadIdx.x;
    long st = (long)gridDim.x * blockDim.x;
    for (; i < n; i += st) dinv[i] = rsqrtf((float)(deg[i] + 1));
}

__global__ void mol_enorm(const int* __restrict__ src, const int* __restrict__ dst,
                          const float* __restrict__ dinv, long E, float* __restrict__ en)
{
    long i = (long)blockIdx.x * blockDim.x + threadIdx.x;
    long st = (long)gridDim.x * blockDim.x;
    for (; i < E; i += st) en[i] = dinv[src[i]] * dinv[dst[i]];
}

// ---------------- batch-norm stats ------------------------------------------
// fp32 matrix [M, N] -> partials (for gemm64 output only)
__global__ __launch_bounds__(256)
void colstats_f32_v2(const float* __restrict__ X, int M, int N,
                     float* __restrict__ p1, float* __restrict__ p2)
{
    __shared__ float sh1[1024], sh2[1024];
    int tid = threadIdx.x;
    int ncg = N >> 2;
    int cg  = tid & (ncg - 1);
    int rg  = tid / ncg;
    int nrg = 256 / ncg;
    float s0=0,s1=0,s2=0,s3=0, q0=0,q1=0,q2=0,q3=0;
    const float* base = X + 4 * cg;
    for (long row = (long)blockIdx.x * nrg + rg; row < M; row += (long)gridDim.x * nrg) {
        float4 v = *(const float4*)(base + row * (long)N);
        s0 += v.x; q0 += v.x * v.x; s1 += v.y; q1 += v.y * v.y;
        s2 += v.z; q2 += v.z * v.z; s3 += v.w; q3 += v.w * v.w;
    }
    float4* S1 = (float4*)sh1; float4* S2 = (float4*)sh2;
    S1[tid] = make_float4(s0, s1, s2, s3);
    S2[tid] = make_float4(q0, q1, q2, q3);
    __syncthreads();
    for (int off = nrg >> 1; off > 0; off >>= 1) {
        if (rg < off) {
            float4 a = S1[tid], b = S1[tid + off * ncg];
            S1[tid] = make_float4(a.x + b.x, a.y + b.y, a.z + b.z, a.w + b.w);
            float4 c = S2[tid], d = S2[tid + off * ncg];
            S2[tid] = make_float4(c.x + d.x, c.y + d.y, c.z + d.z, c.w + d.w);
        }
        __syncthreads();
    }
    if (rg == 0) {
        *(float4*)&p1[(long)blockIdx.x * N + 4 * cg] = S1[tid];
        *(float4*)&p2[(long)blockIdx.x * N + 4 * cg] = S2[tid];
    }
}

// reduce partials (nblk up to 2048): grid N/64 blocks x 1024 thr (16 segments)
__global__ __launch_bounds__(1024)
void colstats_reduce_v3(const float* __restrict__ p1, const float* __restrict__ p2,
                        int nblk, int N, float invM,
                        float* __restrict__ s1o, float* __restrict__ s2o)
{
    __shared__ float sh1[1024], sh2[1024];
    int tid = threadIdx.x;
    int col = blockIdx.x * 64 + (tid & 63);
    int seg = tid >> 6;                       // 0..15
    float a = 0.f, c = 0.f;
    for (int b = seg; b < nblk; b += 16) {
        a += p1[(long)b * N + col];
        c += p2[(long)b * N + col];
    }
    sh1[tid] = a; sh2[tid] = c;
    __syncthreads();
    for (int off = 8; off > 0; off >>= 1) {
        if (seg < off) {
            sh1[tid] += sh1[tid + off * 64];
            sh2[tid] += sh2[tid + off * 64];
        }
        __syncthreads();
    }
    if (seg == 0) {
        float mean = sh1[tid] * invM;
        float var  = fmaxf(sh2[tid] * invM - mean * mean, 0.f);
        s1o[col] = mean;
        s2o[col] = rsqrtf(var + 1e-5f);
    }
}

__global__ void bn_apply(float* X, long total, int mask,
                         const float* __restrict__ s1, const float* __restrict__ s2)
{
    long i = (long)blockIdx.x * blockDim.x + threadIdx.x;
    long st = (long)gridDim.x * blockDim.x;
    for (; i < total; i += st) {
        int j = (int)(i & mask);
        X[i] = fmaxf((X[i] - s1[j]) * s2[j], 0.f);
    }
}

// BN+ReLU, fp32 in place AND bf16 copy
__global__ void bn_apply_dual(float* __restrict__ X, u16* __restrict__ Xb, long total,
                              int mask, const float* __restrict__ s1,
                              const float* __restrict__ s2)
{
    long i = (long)blockIdx.x * blockDim.x + threadIdx.x;
    long st = (long)gridDim.x * blockDim.x;
    for (; i < total; i += st) {
        int j = (int)(i & mask);
        float y = fmaxf((X[i] - s1[j]) * s2[j], 0.f);
        X[i] = y;
        Xb[i] = f2b(y);
    }
}

// ---------------- CSR aggregation (no atomics) ------------------------------
__global__ __launch_bounds__(256)
void mol_agg_in(const void* __restrict__ Xraw, const u16* __restrict__ Xcvt,
                const int* __restrict__ flagp, const float* __restrict__ dinv,
                const int* __restrict__ off, const int2* __restrict__ eb,
                int NM, u16* __restrict__ out)
{
    const u16* X = (*flagp != 0) ? Xcvt : (const u16*)Xraw;
    int wid  = (int)(((long)blockIdx.x * 256 + threadIdx.x) >> 6);
    int lane = threadIdx.x & 63;
    if (wid >= NM) return;
    float dv = dinv[wid];
    float acc = b2f(X[(long)wid * 64 + lane]) * dv * dv;
    int j = off[wid], j1 = off[wid + 1];
    for (; j + 3 < j1; j += 4) {
        int2 e0 = eb[j], e1 = eb[j + 1], e2 = eb[j + 2], e3 = eb[j + 3];
        float v0 = b2f(X[(long)e0.x * 64 + lane]);
        float v1 = b2f(X[(long)e1.x * 64 + lane]);
        float v2 = b2f(X[(long)e2.x * 64 + lane]);
        float v3 = b2f(X[(long)e3.x * 64 + lane]);
        acc += v0 * __int_as_float(e0.y) + v1 * __int_as_float(e1.y)
             + v2 * __int_as_float(e2.y) + v3 * __int_as_float(e3.y);
    }
    for (; j < j1; j++) {
        int2 e = eb[j];
        acc += b2f(X[(long)e.x * 64 + lane]) * __int_as_float(e.y);
    }
    out[(long)wid * 64 + lane] = f2b(acc);
}

// mol layer-2 aggregation with FUSED BN+ReLU on gathered G1 values.
__global__ __launch_bounds__(256)
void mol_agg128_bn(const u16* __restrict__ G, const float* __restrict__ dinv,
                   const int* __restrict__ off, const int2* __restrict__ eb,
                   int NM, const float* __restrict__ s1, const float* __restrict__ s2,
                   u16* __restrict__ out)
{
    int wid  = (int)(((long)blockIdx.x * 256 + threadIdx.x) >> 6);
    int lane = threadIdx.x & 63;
    if (wid >= NM) return;
    const float m0 = s1[2 * lane],     r0 = s2[2 * lane];
    const float m1 = s1[2 * lane + 1], r1 = s2[2 * lane + 1];
    float dv = dinv[wid], dv2 = dv * dv;
    u32 u = *(const u32*)(G + (long)wid * 128 + 2 * lane);
    float a0 = fmaxf((b2f((u16)(u & 0xFFFF)) - m0) * r0, 0.f) * dv2;
    float a1 = fmaxf((b2f((u16)(u >> 16))    - m1) * r1, 0.f) * dv2;
    int j = off[wid], j1 = off[wid + 1];
    for (; j + 3 < j1; j += 4) {
        int2 e0 = eb[j], e1 = eb[j + 1], e2 = eb[j + 2], e3 = eb[j + 3];
        u32 v0 = *(const u32*)(G + (long)e0.x * 128 + 2 * lane);
        u32 v1 = *(const u32*)(G + (long)e1.x * 128 + 2 * lane);
        u32 v2 = *(const u32*)(G + (long)e2.x * 128 + 2 * lane);
        u32 v3 = *(const u32*)(G + (long)e3.x * 128 + 2 * lane);
        float n0 = __int_as_float(e0.y), n1 = __int_as_float(e1.y);
        float n2 = __int_as_float(e2.y), n3 = __int_as_float(e3.y);
        a0 += fmaxf((b2f((u16)(v0 & 0xFFFF)) - m0) * r0, 0.f) * n0
            + fmaxf((b2f((u16)(v1 & 0xFFFF)) - m0) * r0, 0.f) * n1
            + fmaxf((b2f((u16)(v2 & 0xFFFF)) - m0) * r0, 0.f) * n2
            + fmaxf((b2f((u16)(v3 & 0xFFFF)) - m0) * r0, 0.f) * n3;
        a1 += fmaxf((b2f((u16)(v0 >> 16)) - m1) * r1, 0.f) * n0
            + fmaxf((b2f((u16)(v1 >> 16)) - m1) * r1, 0.f) * n1
            + fmaxf((b2f((u16)(v2 >> 16)) - m1) * r1, 0.f) * n2
            + fmaxf((b2f((u16)(v3 >> 16)) - m1) * r1, 0.f) * n3;
    }
    for (; j < j1; j++) {
        int2 e = eb[j];
        u32 v = *(const u32*)(G + (long)e.x * 128 + 2 * lane);
        float n = __int_as_float(e.y);
        a0 += fmaxf((b2f((u16)(v & 0xFFFF)) - m0) * r0, 0.f) * n;
        a1 += fmaxf((b2f((u16)(v >> 16))    - m1) * r1, 0.f) * n;
    }
    u32 o = (u32)f2b(a0) | ((u32)f2b(a1) << 16);
    *(u32*)(out + (long)wid * 128 + 2 * lane) = o;
}

// RGCN pre-aggregation v2: one wave per (node, relation) segment.
__global__ __launch_bounds__(256)
void kg_preagg2(const u16* __restrict__ xin, const int* __restrict__ off2,
                const int* __restrict__ eb, int NSEG, u16* __restrict__ aggx)
{
    int seg  = (int)(((long)blockIdx.x * 256 + threadIdx.x) >> 6);
    int lane = threadIdx.x & 63;
    if (seg >= NSEG) return;
    int node = seg >> 3, r = seg & 7;
    const int c4 = 4 * lane;
    int j0 = off2[seg], j1 = off2[seg + 1];
    float a0 = 0.f, a1 = 0.f, a2 = 0.f, a3 = 0.f;
    int j = j0;
    for (; j + 3 < j1; j += 4) {
        int s0 = eb[j], s1 = eb[j + 1], s2 = eb[j + 2], s3 = eb[j + 3];
        ushort4 v0 = *(const ushort4*)(xin + (long)s0 * 256 + c4);
        ushort4 v1 = *(const ushort4*)(xin + (long)s1 * 256 + c4);
        ushort4 v2 = *(const ushort4*)(xin + (long)s2 * 256 + c4);
        ushort4 v3 = *(const ushort4*)(xin + (long)s3 * 256 + c4);
        a0 += b2f(v0.x) + b2f(v1.x) + b2f(v2.x) + b2f(v3.x);
        a1 += b2f(v0.y) + b2f(v1.y) + b2f(v2.y) + b2f(v3.y);
        a2 += b2f(v0.z) + b2f(v1.z) + b2f(v2.z) + b2f(v3.z);
        a3 += b2f(v0.w) + b2f(v1.w) + b2f(v2.w) + b2f(v3.w);
    }
    for (; j < j1; j++) {
        ushort4 v = *(const ushort4*)(xin + (long)eb[j] * 256 + c4);
        a0 += b2f(v.x); a1 += b2f(v.y); a2 += b2f(v.z); a3 += b2f(v.w);
    }
    float nrm = 1.0f / fmaxf((float)(j1 - j0), 1.0f);
    ushort4 o;
    o.x = f2b(a0 * nrm); o.y = f2b(a1 * nrm);
    o.z = f2b(a2 * nrm); o.w = f2b(a3 * nrm);
    *(ushort4*)(aggx + (long)node * 2304 + 256 + (r << 8) + c4) = o;
}

// copy xin rows into AGGX cols 0:255
__global__ void xcopy_aggx(const u16* __restrict__ xin, u16* __restrict__ aggx, long n4)
{
    long i = (long)blockIdx.x * blockDim.x + threadIdx.x;
    long st = (long)gridDim.x * blockDim.x;
    for (; i < n4; i += st) {
        long node = i >> 6;
        int c4 = (int)(i & 63) * 4;
        *(ushort4*)(aggx + node * 2304 + c4) = *(const ushort4*)(xin + node * 256 + c4);
    }
}

// mean-pool bf16 chunk [NM, ld] cols [cc, cc+64) with fused BN+ReLU
__global__ __launch_bounds__(256)
void pool_b16(const u16* __restrict__ g, int ld, int cc,
              const int* __restrict__ off, const int* __restrict__ bins, int ND,
              const float* __restrict__ s1, const float* __restrict__ s2,
              float* __restrict__ gout, int c0out)
{
    int wid  = (int)(((long)blockIdx.x * 256 + threadIdx.x) >> 6);
    int lane = threadIdx.x & 63;
    if (wid >= ND) return;
    float m = s1[cc + lane], r = s2[cc + lane];
    int j0 = off[wid], j1 = off[wid + 1];
    float acc = 0.f;
    for (int j = j0; j < j1; j++)
        acc += fmaxf((b2f(g[(long)bins[j] * ld + cc + lane]) - m) * r, 0.f);
    gout[(long)wid * 256 + c0out + lane] = acc / fmaxf((float)(j1 - j0), 1.0f);
}

// ---------------- attention fusion ------------------------------------------
__global__ void attention_fuse(const float* __restrict__ go, const float* __restrict__ fpv,
                               const float* __restrict__ W1, const float* __restrict__ B1,
                               const float* __restrict__ W2,
                               float* __restrict__ emb, float* __restrict__ beta_out)
{
    int d = blockIdx.x;
    int t = threadIdx.x;
    __shared__ float z[2][256];
    __shared__ float red[128];
    for (int c = t; c < 256; c += 128) {
        z[0][c] = go[(long)d * 256 + c];
        z[1][c] = fpv[(long)d * 256 + c];
    }
    __syncthreads();
    float s[2];
    for (int v = 0; v < 2; v++) {
        float acc = B1[t];
        for (int k = 0; k < 256; k++) acc += z[v][k] * W1[k * 128 + t];
        red[t] = tanhf(acc) * W2[t];
        __syncthreads();
        for (int off = 64; off > 0; off >>= 1) {
            if (t < off) red[t] += red[t + off];
            __syncthreads();
        }
        s[v] = red[0];
        __syncthreads();
    }
    float m = fmaxf(s[0], s[1]);
    float e0 = expf(s[0] - m), e1 = expf(s[1] - m);
    float inv = 1.0f / (e0 + e1);
    float b0 = e0 * inv, b1 = e1 * inv;
    for (int c = t; c < 256; c += 128)
        emb[(long)d * 256 + c] = b0 * z[0][c] + b1 * z[1][c];
    if (t == 0) {
        beta_out[d * 2 + 0] = b0;
        beta_out[d * 2 + 1] = b1;
    }
}

// ---------------- final linear + log_softmax, fused BN on x4 ----------------
__global__ void logits_out_bn(const float* __restrict__ x4,
                              const float* __restrict__ s1, const float* __restrict__ s2,
                              const float* __restrict__ w, const float* __restrict__ b,
                              float* __restrict__ out, int NKG)
{
    int i = blockIdx.x * blockDim.x + threadIdx.x;
    if (i >= NKG) return;
    float a0 = b[0], a1 = b[1];
    for (int k = 0; k < 64; k++) {
        float v = fmaxf((x4[(long)i * 64 + k] - s1[k]) * s2[k], 0.f);
        a0 += v * w[k * 2 + 0];
        a1 += v * w[k * 2 + 1];
    }
    float m = fmaxf(a0, a1);
    float lse = m + logf(expf(a0 - m) + expf(a1 - m));
    out[i * 2 + 0] = a0 - lse;
    out[i * 2 + 1] = a1 - lse;
}

// ============================================================================
extern "C" void kernel_launch(void* const* d_in, const int* in_sizes, int n_in,
                              void* d_out, int out_size, void* d_ws, size_t ws_size,
                              hipStream_t stream)
{
    (void)in_sizes; (void)n_in; (void)out_size; (void)ws_size;
    const int ND = 4096, NM = 131072, NKG = 9510, NGENE = 5414;
    const long EM = 524288, EK = 524288;
    const int NSEG = 8 * NKG;   // 76080 (node, relation) segments

    const void* fp_data = d_in[0];
    const void* mol_x   = d_in[1];
    const int*  mol_batch = (const int*)d_in[2];
    const int*  mol_ei  = (const int*)d_in[3];
    const int*  kg_ei   = (const int*)d_in[4];
    const int*  kg_et   = (const int*)d_in[5];

    const int* mol_src = mol_ei;
    const int* mol_dst = mol_ei + EM;
    const int* kg_src  = kg_ei;
    const int* kg_dst  = kg_ei + EK;

    float* out_ls   = (float*)d_out;          // [9510,2] fp32
    float* out_beta = (float*)d_out + 19020;  // [4096,2,1] fp32

    // ---- workspace carve ----
    char* wp = (char*)d_ws;
    auto carve = [&](size_t bytes) { char* p = wp; wp += (bytes + 255) & ~(size_t)255; return p; };
    float* stats = (float*)carve(4096);
    int*   flag  = (int*)carve(256);
    float* dinv  = (float*)carve((size_t)NM * 4);
    float* enM   = (float*)carve((size_t)EM * 4);
    float* part1 = (float*)carve((size_t)2048 * 128 * 4);   // 1 MB (gemm stats partials)
    float* part2 = (float*)carve((size_t)2048 * 128 * 4);
    int*   sbt   = (int*)carve(256);
    int*   sbo   = (int*)carve(256);
    float* Wpool = (float*)carve((size_t)1630000 * 4);     // fp32 weights
    u16*   WpoolB= (u16*)carve((size_t)1630000 * 2);       // bf16 weights
    u16*   WpoolT= (u16*)carve((size_t)1600000 * 2);       // bf16 transposed gemm weights
    float* fpb   = (float*)carve((size_t)ND * 256 * 4);
    float* gout  = (float*)carve((size_t)ND * 256 * 4);
    int*   key2  = (int*)carve((size_t)EK * 4);            // kg seg keys; reused as ebK2
    int*   koff2 = (int*)carve((size_t)(NSEG + 1) * 4);
    // zero-span
    char*  z0    = wp;
    int* kdeg2 = (int*)carve((size_t)NSEG * 4);
    int* kcur2 = (int*)carve((size_t)NSEG * 4);
    int* mdeg = (int*)carve((size_t)NM * 4);
    int* mcur = (int*)carve((size_t)NM * 4);
    int* pdeg = (int*)carve((size_t)ND * 4);
    int* pcur = (int*)carve((size_t)ND * 4);
    char*  z1    = wp;
    int* moff = (int*)carve((size_t)(NM + 1) * 4);
    int* mbins= (int*)carve((size_t)EM * 4);
    int* kbins= (int*)carve((size_t)EK * 4);
    int* poff = (int*)carve((size_t)(ND + 1) * 4);
    int* pbins= (int*)carve((size_t)NM * 4);
    char*  REG1  = carve((size_t)NM * 128 * 2);            // 33.6 MB
    char*  REG2  = carve((size_t)NM * 128 * 2);            // 33.6 MB  (contiguous with HB)
    u16*   HB    = (u16*)carve((size_t)NM * 64 * 2);       // 16.8 MB

    // phase views
    float* fp1 = (float*)REG1;                 // fp: [4096,512] f32
    u16*   XB  = (u16*)REG1;                   // mol pre: [NM,64] bf16 converted input
    u16*   G1  = (u16*)REG1;                   // mol: [NM,128] bf16 (raw gemm out)
    u16*   H2  = (u16*)REG1;                   // mol L2: [NM,128] bf16 half-output (G1 dead)
    // rgcn chain in REG1:
    float* xkg = (float*)REG1;                 // [NKG,256] f32 (emb+gene)
    float* x2  = xkg + (size_t)NKG * 256;      // [NKG,256] f32
    float* x3  = x2  + (size_t)NKG * 256;      // [NKG,128] f32
    float* x4  = x3  + (size_t)NKG * 128;      // [NKG,64]  f32
    u16*   xb  = (u16*)(x4 + (size_t)NKG * 64);// [NKG,256] bf16 (after x4, fits REG1)
    u16*   x2b = (u16*)REG1;                   // [NKG,256] bf16 (overlaps xkg: dead then)
    u16*   Xfb = (u16*)REG2;                   // fp: [4096,1024] bf16
    u16*   G1A = (u16*)REG2;                   // mol: [NM,128] bf16 aggregated
    u16*   AGGX= (u16*)REG2;                   // rgcn: [NKG,2304] bf16 (43.8 MB, REG2+HB)
    u16*   fp1b = HB;                          // fp: [4096,512] bf16
    u16*   Xagg = HB;                          // mol L1: [NM,64] bf16
    // flattened CSR edge tables (aliased; lifetimes verified)
    int2* ebM  = (int2*)gout;                  // mol edges; gout written only after dead
    int*  ebK2 = key2;                         // kg src table; key2 dead after bin_by

    // ---- dtype detect + weight conversion (fp32 + bf16 pools) ----
    zero_int<<<1, 1, 0, stream>>>(flag);
    detect_f32<<<1024, 256, 0, stream>>>((const u16*)fp_data, (long)ND * 1024, flag);
    ConvTab tab;
    // NOTE: rg_root before rg_w so [root; W_0..W_7] is contiguous = [2304, N] GEMM B
    const int widx[14] = {6, 8, 10, 12, 14, 15, 16, 19, 18, 22, 21, 24, 26, 27};
    const int wn[14]   = {1024*512, 512*256, 64*128, 128*256, 256*128, 128, 128,
                          256*256, 8*256*256, 256*128, 8*256*128, 128*64, 64*2, 2};
    float* wf[14]; u16* wb[14];
    {
        size_t o = 0;
        for (int i = 0; i < 14; i++) {
            tab.src[i]  = d_in[widx[i]];
            tab.dst[i]  = Wpool + o;
            tab.dstB[i] = WpoolB + o;
            tab.n[i]    = wn[i];
            wf[i] = Wpool + o; wb[i] = WpoolB + o;
            o += (size_t)wn[i];
        }
    }
    conv_all<<<dim3(32, 14), 256, 0, stream>>>(tab, flag);
    float *att_w1c = wf[4], *att_b1c = wf[5], *att_w2c = wf[6];
    float *lin1_wc = wf[11], *lin2_wc = wf[12], *lin2_bc = wf[13];

    // ---- transposed bf16 weights for gemm_bt (BT[n*K+k] = B[k*N+n]) ----
    u16* T_fpw1  = WpoolT;                        // [512,1024]
    u16* T_fpw2  = T_fpw1 + (size_t)512 * 1024;   // [256,512]
    u16* T_gcnw1 = T_fpw2 + (size_t)256 * 512;    // [128,64]
    u16* T_gcnw2 = T_gcnw1 + (size_t)128 * 64;    // [256,128]
    u16* T_w1    = T_gcnw2 + (size_t)256 * 128;   // [256,2304]
    u16* T_w2    = T_w1 + (size_t)256 * 2304;     // [128,2304]
    transpose_b16<<<dim3(32, 16), 256, 0, stream>>>(wb[0], T_fpw1, 1024, 512);
    transpose_b16<<<dim3(16, 8),  256, 0, stream>>>(wb[1], T_fpw2, 512, 256);
    transpose_b16<<<dim3(2, 4),   256, 0, stream>>>(wb[2], T_gcnw1, 64, 128);
    transpose_b16<<<dim3(4, 8),   256, 0, stream>>>(wb[3], T_gcnw2, 128, 256);
    transpose_b16<<<dim3(72, 8),  256, 0, stream>>>(wb[7], T_w1, 2304, 256);
    transpose_b16<<<dim3(72, 4),  256, 0, stream>>>(wb[9], T_w2, 2304, 128);

    // ---- CSR builds ----
    filli<<<512, 256, 0, stream>>>((int*)z0, (long)(z1 - z0) / 4, 0);
    auto scan = [&](const int* deg, int* off, int n) {
        int nb = divup(n, 4096);
        scan_bsum<<<nb, 1024, 0, stream>>>(deg, n, sbt);
        scan_tiny<<<1, 64, 0, stream>>>(sbt, nb, sbo);
        scan_final<<<nb, 1024, 0, stream>>>(deg, n, sbo, nb, off);
    };
    hist_int<<<2048, 256, 0, stream>>>(mol_dst, EM, mdeg);
    scan(mdeg, moff, NM);
    bin_by<<<2048, 256, 0, stream>>>(mol_dst, EM, moff, mcur, mbins);
    dinv_from_deg<<<512, 256, 0, stream>>>(mdeg, dinv, NM);
    mol_enorm<<<1024, 256, 0, stream>>>(mol_src, mol_dst, dinv, EM, enM);
    flatten_mol<<<2048, 256, 0, stream>>>(mbins, mol_src, enM, EM, ebM);

    // KG: segment CSR over (dst, relation); mean norm from segment length
    kg_key2<<<2048, 256, 0, stream>>>(kg_dst, kg_et, EK, key2);
    hist_int<<<2048, 256, 0, stream>>>(key2, EK, kdeg2);
    scan(kdeg2, koff2, NSEG);
    bin_by<<<2048, 256, 0, stream>>>(key2, EK, koff2, kcur2, kbins);
    flatten_kg_src<<<2048, 256, 0, stream>>>(kbins, kg_src, EK, ebK2);  // key2 dead

    hist_int<<<512, 256, 0, stream>>>(mol_batch, NM, pdeg);
    scan(pdeg, poff, ND);
    bin_by<<<512, 256, 0, stream>>>(mol_batch, NM, poff, pcur, pbins);

    // stats finalize helper: partials (nblk rows x N cols) -> mean + rsqrt(var)
    auto reduceN = [&](int nblk, int N, float invM) {
        colstats_reduce_v3<<<N / 64, 1024, 0, stream>>>(part1, part2, nblk, N,
                                                        invM, stats, stats + 512);
    };

    // ---------- fingerprint MLP branch (MFMA, stats fused) ----------
    conv_dual_b16<<<2048, 256, 0, stream>>>(fp_data, Xfb, (long)ND * 1024, flag);
    gemm_bt<float, 2, true><<<dim3(64, 4), 256, 0, stream>>>(
        Xfb, 1024, T_fpw1, 1024, fp1, 512, ND, 512, 1024, part1, part2, 512);
    reduceN(64, 512, 1.0f / ND);
    bn_apply_dual<<<2048, 256, 0, stream>>>(fp1, fp1b, (long)ND * 512, 511,
                                            stats, stats + 512);
    gemm_bt<float, 1, true><<<dim3(64, 4), 256, 0, stream>>>(
        fp1b, 512, T_fpw2, 512, fpb, 256, ND, 256, 512, part1, part2, 256);
    reduceN(64, 256, 1.0f / ND);
    bn_apply<<<2048, 256, 0, stream>>>(fpb, (long)ND * 256, 255, stats, stats + 512);

    // ---------- mol GCN layer 1: bf16-convert, aggregate-then-GEMM ----------
    conv_molx<<<2048, 256, 0, stream>>>((const float*)mol_x, XB, (long)NM * 16, flag);
    mol_agg_in<<<32768, 256, 0, stream>>>(mol_x, XB, flag, dinv, moff, ebM, NM, Xagg);
    gemm_bt<u16, 2, true><<<dim3(2048, 1), 256, 0, stream>>>(
        Xagg, 64, T_gcnw1, 64, G1, 128, NM, 128, 64, part1, part2, 128);
    reduceN(2048, 128, 1.0f / NM);
    // BN+ReLU fused into mol_agg128_bn below (G1 has no other consumer)

    // ---------- mol GCN layer 2: fused-BN aggregate, 2-half GEMM + pool -----
    mol_agg128_bn<<<32768, 256, 0, stream>>>(G1, dinv, moff, ebM, NM,
                                             stats, stats + 512, G1A);
    // ebM (gout) dead past this point; G1 (REG1) dead -> H2 reuses it
    for (int h = 0; h < 2; h++) {
        gemm_bt<u16, 2, true><<<dim3(2048, 1), 256, 0, stream>>>(
            G1A, 128, T_gcnw2 + (size_t)h * 128 * 128, 128, H2, 128, NM, 128, 128,
            part1, part2, 128);
        reduceN(2048, 128, 1.0f / NM);
        pool_b16<<<1024, 256, 0, stream>>>(H2, 128, 0, poff, pbins, ND,
                                           stats, stats + 512, gout, h * 128);
        pool_b16<<<1024, 256, 0, stream>>>(H2, 128, 64, poff, pbins, ND,
                                           stats, stats + 512, gout, h * 128 + 64);
    }

    // ---------- attention fusion ----------
    attention_fuse<<<ND, 128, 0, stream>>>(gout, fpb, att_w1c, att_b1c, att_w2c,
                                           xkg, out_beta);
    conv_in<<<512, 256, 0, stream>>>(d_in[17], xkg + (long)ND * 256,
                                     (long)NGENE * 256, flag);
    conv_f32_b16<<<1024, 256, 0, stream>>>(xkg, xb, (long)NKG * 256);

    // ---------- RGCN layer 1 (256 -> 256): preagg2 + single K=2304 GEMM -----
    xcopy_aggx<<<1024, 256, 0, stream>>>(xb, AGGX, (long)NKG * 64);
    kg_preagg2<<<divup((long)NSEG * 64, 256), 256, 0, stream>>>(
        xb, koff2, ebK2, NSEG, AGGX);
    gemm_bt<float, 2, true><<<dim3(divup(NKG, 64), 2), 256, 0, stream>>>(
        AGGX, 2304, T_w1, 2304, x2, 256, NKG, 256, 2304, part1, part2, 256);
    reduceN(divup(NKG, 64), 256, 1.0f / NKG);
    bn_apply_dual<<<2048, 256, 0, stream>>>(x2, x2b, (long)NKG * 256, 255,
                                            stats, stats + 512);

    // ---------- RGCN layer 2 (256 -> 128): preagg2 + single K=2304 GEMM -----
    xcopy_aggx<<<1024, 256, 0, stream>>>(x2b, AGGX, (long)NKG * 64);
    kg_preagg2<<<divup((long)NSEG * 64, 256), 256, 0, stream>>>(
        x2b, koff2, ebK2, NSEG, AGGX);
    gemm_bt<float, 1, true><<<dim3(divup(NKG, 64), 2), 256, 0, stream>>>(
        AGGX, 2304, T_w2, 2304, x3, 128, NKG, 128, 2304, part1, part2, 128);
    reduceN(divup(NKG, 64), 128, 1.0f / NKG);
    bn_apply<<<2048, 256, 0, stream>>>(x3, (long)NKG * 128, 127, stats, stats + 512);

    // ---------- classifier head ----------
    gemm64<<<dim3(divup(NKG, 64), 1, 1), 256, 0, stream>>>(
        x3, 128, lin1_wc, 64, x4, 64, NKG, 64, 128);
    colstats_f32_v2<<<NBLK_STATS, 256, 0, stream>>>(x4, NKG, 64, part1, part2);
    reduceN(NBLK_STATS, 64, 1.0f / NKG);
    logits_out_bn<<<divup(NKG, 256), 256, 0, stream>>>(x4, stats, stats + 512,
                                                       lin2_wc, lin2_bc, out_ls, NKG);
}

// Round 10
// 1028.029 us; speedup vs baseline: 1.3925x; 1.0569x over previous
//
#include <hip/hip_runtime.h>
#include <hip/hip_bf16.h>
#include <cstdint>

typedef __hip_bfloat16 bf16;
typedef unsigned short u16;
typedef unsigned int u32;
typedef __attribute__((ext_vector_type(8))) short short8;
typedef __attribute__((ext_vector_type(4))) float f32x4;

__device__ __forceinline__ float tofloat(float x){ return x; }
__device__ __forceinline__ float tofloat(bf16 x){ return __bfloat162float(x); }
__device__ __forceinline__ float b2f(u16 a){ return __uint_as_float(((unsigned)a) << 16); }
__device__ __forceinline__ u16 f2b(float f){           // round-to-nearest-even
    unsigned u = __float_as_uint(f);
    return (u16)((u + 0x7FFFu + ((u >> 16) & 1u)) >> 16);
}

static inline int divup(long a, long b){ return (int)((a + b - 1) / b); }

#define NBLK_STATS 256

// ---------------- input dtype detection -------------------------------------
__global__ void zero_int(int* p){ *p = 0; }

__global__ void detect_f32(const u16* __restrict__ h, long n, int* flag)
{
    long i = (long)blockIdx.x * blockDim.x + threadIdx.x;
    long st = (long)gridDim.x * blockDim.x;
    int c = 0;
    for (; i < n; i += st)
        if (((h[i] >> 7) & 0xFF) == 0xFF) c++;
    if (c) atomicAdd(flag, c);
}

// convert all weights: fp32 pool + bf16 pool in one launch
struct ConvTab { const void* src[14]; float* dst[14]; u16* dstB[14]; int n[14]; };

__global__ void conv_all(ConvTab t, const int* __restrict__ flagp)
{
    bool f32 = (*flagp != 0);
    int seg = blockIdx.y;
    const void* s = t.src[seg];
    float* d = t.dst[seg];
    u16*   dB = t.dstB[seg];
    int n = t.n[seg];
    long i = (long)blockIdx.x * blockDim.x + threadIdx.x;
    long st = (long)gridDim.x * blockDim.x;
    for (; i < n; i += st) {
        float v = f32 ? ((const float*)s)[i] : tofloat(((const bf16*)s)[i]);
        d[i] = v; dB[i] = f2b(v);
    }
}

__global__ void conv_in(const void* __restrict__ src, float* __restrict__ dst,
                        long n, const int* __restrict__ flagp)
{
    bool f32 = (*flagp != 0);
    long i = (long)blockIdx.x * blockDim.x + threadIdx.x;
    long st = (long)gridDim.x * blockDim.x;
    for (; i < n; i += st)
        dst[i] = f32 ? ((const float*)src)[i] : tofloat(((const bf16*)src)[i]);
}

__global__ void conv_dual_b16(const void* __restrict__ src, u16* __restrict__ dst,
                              long n, const int* __restrict__ flagp)
{
    bool f32 = (*flagp != 0);
    long i = (long)blockIdx.x * blockDim.x + threadIdx.x;
    long st = (long)gridDim.x * blockDim.x;
    for (; i < n; i += st)
        dst[i] = f32 ? f2b(((const float*)src)[i]) : ((const u16*)src)[i];
}

__global__ void conv_f32_b16(const float* __restrict__ src, u16* __restrict__ dst, long n)
{
    long i = (long)blockIdx.x * blockDim.x + threadIdx.x;
    long st = (long)gridDim.x * blockDim.x;
    for (; i < n; i += st) dst[i] = f2b(src[i]);
}

// convert mol_x fp32 -> bf16 copy (only when input is fp32); vectorized x4
__global__ void conv_molx(const float* __restrict__ src, u16* __restrict__ dst,
                          long n4, const int* __restrict__ flagp)
{
    if (*flagp == 0) return;   // input already bf16; agg reads original
    long i = (long)blockIdx.x * blockDim.x + threadIdx.x;
    long st = (long)gridDim.x * blockDim.x;
    for (; i < n4; i += st) {
        float4 v = ((const float4*)src)[i];
        ushort4 o;
        o.x = f2b(v.x); o.y = f2b(v.y); o.z = f2b(v.z); o.w = f2b(v.w);
        ((ushort4*)dst)[i] = o;
    }
}

// bf16 transpose: dst[n*K + k] = src[k*N + n]
__global__ __launch_bounds__(256)
void transpose_b16(const u16* __restrict__ src, u16* __restrict__ dst, int K, int N)
{
    __shared__ u16 t[32][33];
    int k0 = blockIdx.x * 32, n0 = blockIdx.y * 32;
    int x = threadIdx.x & 31, y = threadIdx.x >> 5;   // y in 0..7
    for (int yy = y; yy < 32; yy += 8) {
        int k = k0 + yy, n = n0 + x;
        t[yy][x] = (k < K && n < N) ? src[(long)k * N + n] : (u16)0;
    }
    __syncthreads();
    for (int yy = y; yy < 32; yy += 8) {
        int n = n0 + yy, k = k0 + x;
        if (n < N && k < K) dst[(long)n * K + k] = t[x][yy];
    }
}

// ---------------- CSR edge flattening ---------------------------------------
// ebM[j] = {src, bits(en)}
__global__ void flatten_mol(const int* __restrict__ bins, const int* __restrict__ src,
                            const float* __restrict__ en, long E, int2* __restrict__ out)
{
    long i = (long)blockIdx.x * blockDim.x + threadIdx.x;
    long st = (long)gridDim.x * blockDim.x;
    for (; i < E; i += st) {
        int e = bins[i];
        out[i] = make_int2(src[e], __float_as_int(en[e]));
    }
}

// KG segment key: dst*8 + et  (segments = (node, relation) pairs)
__global__ void kg_key2(const int* __restrict__ dst, const int* __restrict__ et,
                        long E, int* __restrict__ key)
{
    long i = (long)blockIdx.x * blockDim.x + threadIdx.x;
    long st = (long)gridDim.x * blockDim.x;
    for (; i < E; i += st) key[i] = dst[i] * 8 + et[i];
}

// flatten KG edges to src index only (mean norm comes from segment length)
__global__ void flatten_kg_src(const int* __restrict__ bins, const int* __restrict__ src,
                               long E, int* __restrict__ out)
{
    long i = (long)blockIdx.x * blockDim.x + threadIdx.x;
    long st = (long)gridDim.x * blockDim.x;
    for (; i < E; i += st) out[i] = src[bins[i]];
}

// ---------------- MFMA GEMM (B pre-transposed): C = A @ B, bf16, fp32 acc ---
// A [M,K] lda; BT [N,K] ldbt. Tile 64 x (NBLK*64). Register-prefetch pipeline.
// STATS: fuse per-column sum/sumsq of the STORED values into the epilogue.
template<typename TC, int NBLK, bool STATS>
__global__ __launch_bounds__(256)
void gemm_bt(const u16* __restrict__ A, int lda,
             const u16* __restrict__ BT, int ldbt,
             TC* __restrict__ C, int ldc,
             int M, int N, int K,
             float* __restrict__ SP1, float* __restrict__ SP2, int Ntot)
{
    __shared__ __align__(16) u16 As[64][40];          // [m][k]
    __shared__ __align__(16) u16 Bs[NBLK * 64][40];   // [n][k]
    __shared__ float st1[NBLK * 64], st2[NBLK * 64];
    const int tid = threadIdx.x;
    const int lane = tid & 63, wave = tid >> 6;
    const int l15 = lane & 15, quad = lane >> 4;
    const int wm = (wave & 1) * 32, wn = (wave >> 1) * 32;
    const int row0 = blockIdx.x * 64, col0 = blockIdx.y * (NBLK * 64);
    const int arow = tid >> 2, ak = (tid & 3) * 8;
    const int aok = row0 + arow < M;

    if (STATS && tid < NBLK * 64) { st1[tid] = 0.f; st2[tid] = 0.f; }

    f32x4 acc[NBLK][2][2];
#pragma unroll
    for (int t = 0; t < NBLK; t++)
#pragma unroll
        for (int i = 0; i < 2; i++)
#pragma unroll
            for (int j = 0; j < 2; j++)
#pragma unroll
                for (int r = 0; r < 4; r++) acc[t][i][j][r] = 0.f;

    const u16* pa = A + (long)(row0 + arow) * lda + ak;
    const u16* pb[NBLK];
#pragma unroll
    for (int t = 0; t < NBLK; t++)
        pb[t] = BT + (long)(col0 + t * 64 + arow) * ldbt + ak;

    ushort4 ra0 = {0,0,0,0}, ra1 = {0,0,0,0};
    ushort4 rb0[NBLK], rb1[NBLK];
    if (aok) { ra0 = *(const ushort4*)pa; ra1 = *(const ushort4*)(pa + 4); }
#pragma unroll
    for (int t = 0; t < NBLK; t++) {
        rb0[t] = *(const ushort4*)pb[t];
        rb1[t] = *(const ushort4*)(pb[t] + 4);
    }

    for (int k0 = 0; k0 < K; k0 += 32) {
        *(ushort4*)&As[arow][ak]     = ra0;
        *(ushort4*)&As[arow][ak + 4] = ra1;
#pragma unroll
        for (int t = 0; t < NBLK; t++) {
            *(ushort4*)&Bs[t * 64 + arow][ak]     = rb0[t];
            *(ushort4*)&Bs[t * 64 + arow][ak + 4] = rb1[t];
        }
        __syncthreads();
        if (k0 + 32 < K) {   // issue next-step loads; retire under MFMAs
            if (aok) {
                ra0 = *(const ushort4*)(pa + k0 + 32);
                ra1 = *(const ushort4*)(pa + k0 + 36);
            }
#pragma unroll
            for (int t = 0; t < NBLK; t++) {
                rb0[t] = *(const ushort4*)(pb[t] + k0 + 32);
                rb1[t] = *(const ushort4*)(pb[t] + k0 + 36);
            }
        }
        short8 a0 = *(const short8*)&As[wm + l15][quad * 8];
        short8 a1 = *(const short8*)&As[wm + 16 + l15][quad * 8];
#pragma unroll
        for (int t = 0; t < NBLK; t++) {
            short8 b0 = *(const short8*)&Bs[t * 64 + wn + l15][quad * 8];
            short8 b1 = *(const short8*)&Bs[t * 64 + wn + 16 + l15][quad * 8];
            acc[t][0][0] = __builtin_amdgcn_mfma_f32_16x16x32_bf16(a0, b0, acc[t][0][0], 0, 0, 0);
            acc[t][0][1] = __builtin_amdgcn_mfma_f32_16x16x32_bf16(a0, b1, acc[t][0][1], 0, 0, 0);
            acc[t][1][0] = __builtin_amdgcn_mfma_f32_16x16x32_bf16(a1, b0, acc[t][1][0], 0, 0, 0);
            acc[t][1][1] = __builtin_amdgcn_mfma_f32_16x16x32_bf16(a1, b1, acc[t][1][1], 0, 0, 0);
        }
        __syncthreads();
    }
#pragma unroll
    for (int t = 0; t < NBLK; t++)
#pragma unroll
        for (int j = 0; j < 2; j++) {
            float s = 0.f, q = 0.f;
#pragma unroll
            for (int i = 0; i < 2; i++)
#pragma unroll
                for (int r = 0; r < 4; r++) {
                    int row = row0 + wm + i * 16 + quad * 4 + r;
                    int col = col0 + t * 64 + wn + j * 16 + l15;
                    float v = acc[t][i][j][r];
                    float y;
                    if constexpr (sizeof(TC) == 2) {
                        u16 h = f2b(v);
                        if (row < M) ((u16*)C)[(long)row * ldc + col] = h;
                        y = b2f(h);
                    } else {
                        if (row < M) ((float*)C)[(long)row * ldc + col] = v;
                        y = v;
                    }
                    if (STATS) { s += y; q += y * y; }
                }
            if (STATS) {
                s += __shfl_xor(s, 16); s += __shfl_xor(s, 32);
                q += __shfl_xor(q, 16); q += __shfl_xor(q, 32);
                if (quad == 0) {
                    atomicAdd(&st1[t * 64 + wn + j * 16 + l15], s);
                    atomicAdd(&st2[t * 64 + wn + j * 16 + l15], q);
                }
            }
        }
    if (STATS) {
        __syncthreads();
        if (tid < NBLK * 64) {
            long off = (long)blockIdx.x * Ntot + (long)blockIdx.y * (NBLK * 64) + tid;
            SP1[off] = st1[tid];
            SP2[off] = st2[tid];
        }
    }
}

// ---------------- vector GEMM (fp32, small) ---------------------------------
__global__ __launch_bounds__(256)
void gemm64(const float* __restrict__ A, int lda,
            const float* __restrict__ B, int ldb,
            float* __restrict__ C, int ldc,
            int M, int N, int K)
{
    __shared__ float As[16][68];
    __shared__ float Bs[16][68];
    const int tid = threadIdx.x;
    const int row0 = blockIdx.x * 64, col0 = blockIdx.y * 64;
    float acc[4][4];
#pragma unroll
    for (int i = 0; i < 4; i++)
#pragma unroll
        for (int j = 0; j < 4; j++) acc[i][j] = 0.f;
    const int ar = tid >> 2, ak = (tid & 3) * 4;
    const int bk = tid >> 4, bc = (tid & 15) * 4;
    const int ty4 = (tid >> 4) * 4, tx4 = (tid & 15) * 4;
    for (int k0 = 0; k0 < K; k0 += 16) {
        {
            int row = row0 + ar;
            float4 v = make_float4(0.f, 0.f, 0.f, 0.f);
            if (row < M) v = *(const float4*)(A + (long)row * lda + k0 + ak);
            As[ak + 0][ar] = v.x; As[ak + 1][ar] = v.y;
            As[ak + 2][ar] = v.z; As[ak + 3][ar] = v.w;
        }
        {
            int c = col0 + bc;
            float4 v = make_float4(0.f, 0.f, 0.f, 0.f);
            if (c < N) v = *(const float4*)(B + (long)(k0 + bk) * ldb + c);
            *(float4*)&Bs[bk][bc] = v;
        }
        __syncthreads();
#pragma unroll
        for (int k = 0; k < 16; k++) {
            float4 a = *(const float4*)&As[k][ty4];
            float4 b = *(const float4*)&Bs[k][tx4];
            acc[0][0] += a.x * b.x; acc[0][1] += a.x * b.y; acc[0][2] += a.x * b.z; acc[0][3] += a.x * b.w;
            acc[1][0] += a.y * b.x; acc[1][1] += a.y * b.y; acc[1][2] += a.y * b.z; acc[1][3] += a.y * b.w;
            acc[2][0] += a.z * b.x; acc[2][1] += a.z * b.y; acc[2][2] += a.z * b.z; acc[2][3] += a.z * b.w;
            acc[3][0] += a.w * b.x; acc[3][1] += a.w * b.y; acc[3][2] += a.w * b.z; acc[3][3] += a.w * b.w;
        }
        __syncthreads();
    }
    int c = col0 + tx4;
#pragma unroll
    for (int i = 0; i < 4; i++) {
        int r = row0 + ty4 + i;
        if (r < M && c < N)
            *(float4*)&C[(long)r * ldc + c] =
                make_float4(acc[i][0], acc[i][1], acc[i][2], acc[i][3]);
    }
}

// ---------------- utility / CSR build ---------------------------------------
__global__ void filli(int* p, long n, int v)
{
    long i = (long)blockIdx.x * blockDim.x + threadIdx.x;
    long st = (long)gridDim.x * blockDim.x;
    for (; i < n; i += st) p[i] = v;
}

__global__ void hist_int(const int* __restrict__ key, long n, int* __restrict__ h)
{
    long i = (long)blockIdx.x * blockDim.x + threadIdx.x;
    long st = (long)gridDim.x * blockDim.x;
    for (; i < n; i += st) atomicAdd(&h[key[i]], 1);
}

__global__ __launch_bounds__(1024)
void scan_bsum(const int* __restrict__ in, int n, int* __restrict__ btot)
{
    __shared__ int sh[1024];
    int tid = threadIdx.x;
    int i0 = blockIdx.x * 4096 + tid * 4;
    int s = 0;
#pragma unroll
    for (int t = 0; t < 4; t++) { int idx = i0 + t; s += (idx < n) ? in[idx] : 0; }
    sh[tid] = s;
    __syncthreads();
    for (int off = 512; off > 0; off >>= 1) {
        if (tid < off) sh[tid] += sh[tid + off];
        __syncthreads();
    }
    if (tid == 0) btot[blockIdx.x] = sh[0];
}

__global__ void scan_tiny(const int* __restrict__ btot, int nb, int* __restrict__ boff)
{
    if (threadIdx.x == 0) {
        int c = 0;
        for (int b = 0; b < nb; b++) { boff[b] = c; c += btot[b]; }
        boff[nb] = c;
    }
}

__global__ __launch_bounds__(1024)
void scan_final(const int* __restrict__ in, int n, const int* __restrict__ boff,
                int nb, int* __restrict__ out)
{
    __shared__ int buf[1024];
    int tid = threadIdx.x;
    int i0 = blockIdx.x * 4096 + tid * 4;
    int v[4]; int s = 0;
#pragma unroll
    for (int t = 0; t < 4; t++) {
        int idx = i0 + t;
        v[t] = (idx < n) ? in[idx] : 0;
        s += v[t];
    }
    buf[tid] = s;
    __syncthreads();
    for (int off = 1; off < 1024; off <<= 1) {
        int t = (tid >= off) ? buf[tid - off] : 0;
        __syncthreads();
        buf[tid] += t;
        __syncthreads();
    }
    int excl = buf[tid] - s + boff[blockIdx.x];
#pragma unroll
    for (int t = 0; t < 4; t++) {
        int idx = i0 + t;
        if (idx < n) out[idx] = excl;
        excl += v[t];
    }
    if (blockIdx.x == 0 && tid == 0) out[n] = boff[nb];
}

__global__ void bin_by(const int* __restrict__ key, long n,
                       const int* __restrict__ off, int* __restrict__ cursor,
                       int* __restrict__ bins)
{
    long i = (long)blockIdx.x * blockDim.x + threadIdx.x;
    long st = (long)gridDim.x * blockDim.x;
    for (; i < n; i += st) {
        int k = key[i];
        int pos = off[k] + atomicAdd(&cursor[k], 1);
        bins[pos] = (int)i;
    }
}

__global__ void dinv_from_deg(const int* __restrict__ deg, float* __restrict__ dinv, long n)
{
    long i = (long)blockIdx.x * blockDim.x + threadIdx.x;
    long st = (long)gridDim.x * blockDim.x;
    for (; i < n; i += st) dinv[i] = rsqrtf((float)(deg[i] + 1));
}

__global__ void mol_enorm(const int* __restrict__ src, const int* __restrict__ dst,
                          const float* __restrict__ dinv, long E, float* __restrict__ en)
{
    long i = (long)blockIdx.x * blockDim.x + threadIdx.x;
    long st = (long)gridDim.x * blockDim.x;
    for (; i < E; i += st) en[i] = dinv[src[i]] * dinv[dst[i]];
}

// ---------------- batch-norm stats ------------------------------------------
// fp32 matrix [M, N] -> partials (for gemm64 output only)
__global__ __launch_bounds__(256)
void colstats_f32_v2(const float* __restrict__ X, int M, int N,
                     float* __restrict__ p1, float* __restrict__ p2)
{
    __shared__ float sh1[1024], sh2[1024];
    int tid = threadIdx.x;
    int ncg = N >> 2;
    int cg  = tid & (ncg - 1);
    int rg  = tid / ncg;
    int nrg = 256 / ncg;
    float s0=0,s1=0,s2=0,s3=0, q0=0,q1=0,q2=0,q3=0;
    const float* base = X + 4 * cg;
    for (long row = (long)blockIdx.x * nrg + rg; row < M; row += (long)gridDim.x * nrg) {
        float4 v = *(const float4*)(base + row * (long)N);
        s0 += v.x; q0 += v.x * v.x; s1 += v.y; q1 += v.y * v.y;
        s2 += v.z; q2 += v.z * v.z; s3 += v.w; q3 += v.w * v.w;
    }
    float4* S1 = (float4*)sh1; float4* S2 = (float4*)sh2;
    S1[tid] = make_float4(s0, s1, s2, s3);
    S2[tid] = make_float4(q0, q1, q2, q3);
    __syncthreads();
    for (int off = nrg >> 1; off > 0; off >>= 1) {
        if (rg < off) {
            float4 a = S1[tid], b = S1[tid + off * ncg];
            S1[tid] = make_float4(a.x + b.x, a.y + b.y, a.z + b.z, a.w + b.w);
            float4 c = S2[tid], d = S2[tid + off * ncg];
            S2[tid] = make_float4(c.x + d.x, c.y + d.y, c.z + d.z, c.w + d.w);
        }
        __syncthreads();
    }
    if (rg == 0) {
        *(float4*)&p1[(long)blockIdx.x * N + 4 * cg] = S1[tid];
        *(float4*)&p2[(long)blockIdx.x * N + 4 * cg] = S2[tid];
    }
}

// reduce partials (nblk up to 2048): grid N/64 blocks x 1024 thr (16 segments)
__global__ __launch_bounds__(1024)
void colstats_reduce_v3(const float* __restrict__ p1, const float* __restrict__ p2,
                        int nblk, int N, float invM,
                        float* __restrict__ s1o, float* __restrict__ s2o)
{
    __shared__ float sh1[1024], sh2[1024];
    int tid = threadIdx.x;
    int col = blockIdx.x * 64 + (tid & 63);
    int seg = tid >> 6;                       // 0..15
    float a = 0.f, c = 0.f;
    for (int b = seg; b < nblk; b += 16) {
        a += p1[(long)b * N + col];
        c += p2[(long)b * N + col];
    }
    sh1[tid] = a; sh2[tid] = c;
    __syncthreads();
    for (int off = 8; off > 0; off >>= 1) {
        if (seg < off) {
            sh1[tid] += sh1[tid + off * 64];
            sh2[tid] += sh2[tid + off * 64];
        }
        __syncthreads();
    }
    if (seg == 0) {
        float mean = sh1[tid] * invM;
        float var  = fmaxf(sh2[tid] * invM - mean * mean, 0.f);
        s1o[col] = mean;
        s2o[col] = rsqrtf(var + 1e-5f);
    }
}

__global__ void bn_apply(float* X, long total, int mask,
                         const float* __restrict__ s1, const float* __restrict__ s2)
{
    long i = (long)blockIdx.x * blockDim.x + threadIdx.x;
    long st = (long)gridDim.x * blockDim.x;
    for (; i < total; i += st) {
        int j = (int)(i & mask);
        X[i] = fmaxf((X[i] - s1[j]) * s2[j], 0.f);
    }
}

// BN+ReLU in place on bf16 contiguous [M, NC]; u32 words (2 cols each)
__global__ void bn_apply_b16v(u32* __restrict__ X, long n2, int maskHalf,
                              const float* __restrict__ s1, const float* __restrict__ s2)
{
    long i = (long)blockIdx.x * blockDim.x + threadIdx.x;
    long st = (long)gridDim.x * blockDim.x;
    for (; i < n2; i += st) {
        u32 v = X[i];
        int f = (int)(i & maskHalf) * 2;
        float y0 = fmaxf((b2f((u16)(v & 0xFFFF)) - s1[f])     * s2[f],     0.f);
        float y1 = fmaxf((b2f((u16)(v >> 16))    - s1[f + 1]) * s2[f + 1], 0.f);
        X[i] = (u32)f2b(y0) | ((u32)f2b(y1) << 16);
    }
}

// ---------------- CSR aggregation (no atomics) ------------------------------
__global__ __launch_bounds__(256)
void mol_agg_in(const void* __restrict__ Xraw, const u16* __restrict__ Xcvt,
                const int* __restrict__ flagp, const float* __restrict__ dinv,
                const int* __restrict__ off, const int2* __restrict__ eb,
                int NM, u16* __restrict__ out)
{
    const u16* X = (*flagp != 0) ? Xcvt : (const u16*)Xraw;
    int wid  = (int)(((long)blockIdx.x * 256 + threadIdx.x) >> 6);
    int lane = threadIdx.x & 63;
    if (wid >= NM) return;
    float dv = dinv[wid];
    float acc = b2f(X[(long)wid * 64 + lane]) * dv * dv;
    int j = off[wid], j1 = off[wid + 1];
    for (; j + 3 < j1; j += 4) {
        int2 e0 = eb[j], e1 = eb[j + 1], e2 = eb[j + 2], e3 = eb[j + 3];
        float v0 = b2f(X[(long)e0.x * 64 + lane]);
        float v1 = b2f(X[(long)e1.x * 64 + lane]);
        float v2 = b2f(X[(long)e2.x * 64 + lane]);
        float v3 = b2f(X[(long)e3.x * 64 + lane]);
        acc += v0 * __int_as_float(e0.y) + v1 * __int_as_float(e1.y)
             + v2 * __int_as_float(e2.y) + v3 * __int_as_float(e3.y);
    }
    for (; j < j1; j++) {
        int2 e = eb[j];
        acc += b2f(X[(long)e.x * 64 + lane]) * __int_as_float(e.y);
    }
    out[(long)wid * 64 + lane] = f2b(acc);
}

// mol layer-2 aggregation with FUSED BN+ReLU on gathered G1 values.
__global__ __launch_bounds__(256)
void mol_agg128_bn(const u16* __restrict__ G, const float* __restrict__ dinv,
                   const int* __restrict__ off, const int2* __restrict__ eb,
                   int NM, const float* __restrict__ s1, const float* __restrict__ s2,
                   u16* __restrict__ out)
{
    int wid  = (int)(((long)blockIdx.x * 256 + threadIdx.x) >> 6);
    int lane = threadIdx.x & 63;
    if (wid >= NM) return;
    const float m0 = s1[2 * lane],     r0 = s2[2 * lane];
    const float m1 = s1[2 * lane + 1], r1 = s2[2 * lane + 1];
    float dv = dinv[wid], dv2 = dv * dv;
    u32 u = *(const u32*)(G + (long)wid * 128 + 2 * lane);
    float a0 = fmaxf((b2f((u16)(u & 0xFFFF)) - m0) * r0, 0.f) * dv2;
    float a1 = fmaxf((b2f((u16)(u >> 16))    - m1) * r1, 0.f) * dv2;
    int j = off[wid], j1 = off[wid + 1];
    for (; j + 3 < j1; j += 4) {
        int2 e0 = eb[j], e1 = eb[j + 1], e2 = eb[j + 2], e3 = eb[j + 3];
        u32 v0 = *(const u32*)(G + (long)e0.x * 128 + 2 * lane);
        u32 v1 = *(const u32*)(G + (long)e1.x * 128 + 2 * lane);
        u32 v2 = *(const u32*)(G + (long)e2.x * 128 + 2 * lane);
        u32 v3 = *(const u32*)(G + (long)e3.x * 128 + 2 * lane);
        float n0 = __int_as_float(e0.y), n1 = __int_as_float(e1.y);
        float n2 = __int_as_float(e2.y), n3 = __int_as_float(e3.y);
        a0 += fmaxf((b2f((u16)(v0 & 0xFFFF)) - m0) * r0, 0.f) * n0
            + fmaxf((b2f((u16)(v1 & 0xFFFF)) - m0) * r0, 0.f) * n1
            + fmaxf((b2f((u16)(v2 & 0xFFFF)) - m0) * r0, 0.f) * n2
            + fmaxf((b2f((u16)(v3 & 0xFFFF)) - m0) * r0, 0.f) * n3;
        a1 += fmaxf((b2f((u16)(v0 >> 16)) - m1) * r1, 0.f) * n0
            + fmaxf((b2f((u16)(v1 >> 16)) - m1) * r1, 0.f) * n1
            + fmaxf((b2f((u16)(v2 >> 16)) - m1) * r1, 0.f) * n2
            + fmaxf((b2f((u16)(v3 >> 16)) - m1) * r1, 0.f) * n3;
    }
    for (; j < j1; j++) {
        int2 e = eb[j];
        u32 v = *(const u32*)(G + (long)e.x * 128 + 2 * lane);
        float n = __int_as_float(e.y);
        a0 += fmaxf((b2f((u16)(v & 0xFFFF)) - m0) * r0, 0.f) * n;
        a1 += fmaxf((b2f((u16)(v >> 16))    - m1) * r1, 0.f) * n;
    }
    u32 o = (u32)f2b(a0) | ((u32)f2b(a1) << 16);
    *(u32*)(out + (long)wid * 128 + 2 * lane) = o;
}

// RGCN pre-aggregation v2: one wave per (node, relation) segment.
__global__ __launch_bounds__(256)
void kg_preagg2(const u16* __restrict__ xin, const int* __restrict__ off2,
                const int* __restrict__ eb, int NSEG, u16* __restrict__ aggx)
{
    int seg  = (int)(((long)blockIdx.x * 256 + threadIdx.x) >> 6);
    int lane = threadIdx.x & 63;
    if (seg >= NSEG) return;
    int node = seg >> 3, r = seg & 7;
    const int c4 = 4 * lane;
    int j0 = off2[seg], j1 = off2[seg + 1];
    float a0 = 0.f, a1 = 0.f, a2 = 0.f, a3 = 0.f;
    int j = j0;
    for (; j + 3 < j1; j += 4) {
        int s0 = eb[j], s1 = eb[j + 1], s2 = eb[j + 2], s3 = eb[j + 3];
        ushort4 v0 = *(const ushort4*)(xin + (long)s0 * 256 + c4);
        ushort4 v1 = *(const ushort4*)(xin + (long)s1 * 256 + c4);
        ushort4 v2 = *(const ushort4*)(xin + (long)s2 * 256 + c4);
        ushort4 v3 = *(const ushort4*)(xin + (long)s3 * 256 + c4);
        a0 += b2f(v0.x) + b2f(v1.x) + b2f(v2.x) + b2f(v3.x);
        a1 += b2f(v0.y) + b2f(v1.y) + b2f(v2.y) + b2f(v3.y);
        a2 += b2f(v0.z) + b2f(v1.z) + b2f(v2.z) + b2f(v3.z);
        a3 += b2f(v0.w) + b2f(v1.w) + b2f(v2.w) + b2f(v3.w);
    }
    for (; j < j1; j++) {
        ushort4 v = *(const ushort4*)(xin + (long)eb[j] * 256 + c4);
        a0 += b2f(v.x); a1 += b2f(v.y); a2 += b2f(v.z); a3 += b2f(v.w);
    }
    float nrm = 1.0f / fmaxf((float)(j1 - j0), 1.0f);
    ushort4 o;
    o.x = f2b(a0 * nrm); o.y = f2b(a1 * nrm);
    o.z = f2b(a2 * nrm); o.w = f2b(a3 * nrm);
    *(ushort4*)(aggx + (long)node * 2304 + 256 + (r << 8) + c4) = o;
}

// copy xin rows into AGGX cols 0:255
__global__ void xcopy_aggx(const u16* __restrict__ xin, u16* __restrict__ aggx, long n4)
{
    long i = (long)blockIdx.x * blockDim.x + threadIdx.x;
    long st = (long)gridDim.x * blockDim.x;
    for (; i < n4; i += st) {
        long node = i >> 6;
        int c4 = (int)(i & 63) * 4;
        *(ushort4*)(aggx + node * 2304 + c4) = *(const ushort4*)(xin + node * 256 + c4);
    }
}

// mean-pool bf16 [NM,128] (all 128 cols via u32/lane) with fused BN+ReLU
__global__ __launch_bounds__(256)
void pool128(const u16* __restrict__ g, const int* __restrict__ off,
             const int* __restrict__ bins, int ND,
             const float* __restrict__ s1, const float* __restrict__ s2,
             float* __restrict__ gout, int c0out)
{
    int wid  = (int)(((long)blockIdx.x * 256 + threadIdx.x) >> 6);
    int lane = threadIdx.x & 63;
    if (wid >= ND) return;
    const float m0 = s1[2 * lane],     r0 = s2[2 * lane];
    const float m1 = s1[2 * lane + 1], r1 = s2[2 * lane + 1];
    int j0 = off[wid], j1 = off[wid + 1];
    float a0 = 0.f, a1 = 0.f;
    for (int j = j0; j < j1; j++) {
        u32 v = *(const u32*)(g + (long)bins[j] * 128 + 2 * lane);
        a0 += fmaxf((b2f((u16)(v & 0xFFFF)) - m0) * r0, 0.f);
        a1 += fmaxf((b2f((u16)(v >> 16))    - m1) * r1, 0.f);
    }
    float inv = 1.0f / fmaxf((float)(j1 - j0), 1.0f);
    *(float2*)(gout + (long)wid * 256 + c0out + 2 * lane) =
        make_float2(a0 * inv, a1 * inv);
}

// ---------------- attention fusion (BN of fp view fused) --------------------
__global__ void attention_fuse(const float* __restrict__ go, const float* __restrict__ fpv,
                               const float* __restrict__ fs1, const float* __restrict__ fs2,
                               const float* __restrict__ W1, const float* __restrict__ B1,
                               const float* __restrict__ W2,
                               float* __restrict__ emb, float* __restrict__ beta_out)
{
    int d = blockIdx.x;
    int t = threadIdx.x;
    __shared__ float z[2][256];
    __shared__ float red[128];
    for (int c = t; c < 256; c += 128) {
        z[0][c] = go[(long)d * 256 + c];
        z[1][c] = fmaxf((fpv[(long)d * 256 + c] - fs1[c]) * fs2[c], 0.f);
    }
    __syncthreads();
    float s[2];
    for (int v = 0; v < 2; v++) {
        float acc = B1[t];
        for (int k = 0; k < 256; k++) acc += z[v][k] * W1[k * 128 + t];
        red[t] = tanhf(acc) * W2[t];
        __syncthreads();
        for (int off = 64; off > 0; off >>= 1) {
            if (t < off) red[t] += red[t + off];
            __syncthreads();
        }
        s[v] = red[0];
        __syncthreads();
    }
    float m = fmaxf(s[0], s[1]);
    float e0 = expf(s[0] - m), e1 = expf(s[1] - m);
    float inv = 1.0f / (e0 + e1);
    float b0 = e0 * inv, b1 = e1 * inv;
    for (int c = t; c < 256; c += 128)
        emb[(long)d * 256 + c] = b0 * z[0][c] + b1 * z[1][c];
    if (t == 0) {
        beta_out[d * 2 + 0] = b0;
        beta_out[d * 2 + 1] = b1;
    }
}

// ---------------- final linear + log_softmax, fused BN on x4 ----------------
__global__ void logits_out_bn(const float* __restrict__ x4,
                              const float* __restrict__ s1, const float* __restrict__ s2,
                              const float* __restrict__ w, const float* __restrict__ b,
                              float* __restrict__ out, int NKG)
{
    int i = blockIdx.x * blockDim.x + threadIdx.x;
    if (i >= NKG) return;
    float a0 = b[0], a1 = b[1];
    for (int k = 0; k < 64; k++) {
        float v = fmaxf((x4[(long)i * 64 + k] - s1[k]) * s2[k], 0.f);
        a0 += v * w[k * 2 + 0];
        a1 += v * w[k * 2 + 1];
    }
    float m = fmaxf(a0, a1);
    float lse = m + logf(expf(a0 - m) + expf(a1 - m));
    out[i * 2 + 0] = a0 - lse;
    out[i * 2 + 1] = a1 - lse;
}

// ============================================================================
extern "C" void kernel_launch(void* const* d_in, const int* in_sizes, int n_in,
                              void* d_out, int out_size, void* d_ws, size_t ws_size,
                              hipStream_t stream)
{
    (void)in_sizes; (void)n_in; (void)out_size; (void)ws_size;
    const int ND = 4096, NM = 131072, NKG = 9510, NGENE = 5414;
    const long EM = 524288, EK = 524288;
    const int NSEG = 8 * NKG;   // 76080 (node, relation) segments

    const void* fp_data = d_in[0];
    const void* mol_x   = d_in[1];
    const int*  mol_batch = (const int*)d_in[2];
    const int*  mol_ei  = (const int*)d_in[3];
    const int*  kg_ei   = (const int*)d_in[4];
    const int*  kg_et   = (const int*)d_in[5];

    const int* mol_src = mol_ei;
    const int* mol_dst = mol_ei + EM;
    const int* kg_src  = kg_ei;
    const int* kg_dst  = kg_ei + EK;

    float* out_ls   = (float*)d_out;          // [9510,2] fp32
    float* out_beta = (float*)d_out + 19020;  // [4096,2,1] fp32

    // ---- workspace carve ----
    char* wp = (char*)d_ws;
    auto carve = [&](size_t bytes) { char* p = wp; wp += (bytes + 255) & ~(size_t)255; return p; };
    float* stats   = (float*)carve(4096);
    float* statsFP = (float*)carve(4096);     // fpb stats (must survive mol phase)
    int*   flag  = (int*)carve(256);
    float* dinv  = (float*)carve((size_t)NM * 4);
    float* enM   = (float*)carve((size_t)EM * 4);
    float* part1 = (float*)carve((size_t)2048 * 128 * 4);   // 1 MB (gemm stats partials)
    float* part2 = (float*)carve((size_t)2048 * 128 * 4);
    int*   sbt   = (int*)carve(256);
    int*   sbo   = (int*)carve(256);
    float* Wpool = (float*)carve((size_t)1630000 * 4);     // fp32 weights
    u16*   WpoolB= (u16*)carve((size_t)1630000 * 2);       // bf16 weights
    u16*   WpoolT= (u16*)carve((size_t)1600000 * 2);       // bf16 transposed gemm weights
    float* fpb   = (float*)carve((size_t)ND * 256 * 4);
    float* gout  = (float*)carve((size_t)ND * 256 * 4);
    int*   key2  = (int*)carve((size_t)EK * 4);            // kg seg keys; reused as ebK2
    int*   koff2 = (int*)carve((size_t)(NSEG + 1) * 4);
    // zero-span
    char*  z0    = wp;
    int* kdeg2 = (int*)carve((size_t)NSEG * 4);
    int* kcur2 = (int*)carve((size_t)NSEG * 4);
    int* mdeg = (int*)carve((size_t)NM * 4);
    int* mcur = (int*)carve((size_t)NM * 4);
    int* pdeg = (int*)carve((size_t)ND * 4);
    int* pcur = (int*)carve((size_t)ND * 4);
    char*  z1    = wp;
    int* moff = (int*)carve((size_t)(NM + 1) * 4);
    int* mbins= (int*)carve((size_t)EM * 4);
    int* kbins= (int*)carve((size_t)EK * 4);
    int* poff = (int*)carve((size_t)(ND + 1) * 4);
    int* pbins= (int*)carve((size_t)NM * 4);
    char*  REG1  = carve((size_t)NM * 128 * 2);            // 33.6 MB
    char*  REG2  = carve((size_t)NM * 128 * 2);            // 33.6 MB  (contiguous with HB)
    u16*   HB    = (u16*)carve((size_t)NM * 64 * 2);       // 16.8 MB

    // phase views
    u16*   XB  = (u16*)REG1;                   // mol pre: [NM,64] bf16 converted input
    u16*   G1  = (u16*)REG1;                   // mol: [NM,128] bf16 (raw gemm out)
    u16*   H2  = (u16*)REG1;                   // mol L2: [NM,128] bf16 half-output (G1 dead)
    // rgcn chain in REG1:
    float* xkg = (float*)REG1;                 // [NKG,256] f32 (emb+gene)
    u16*   x2b = (u16*)REG1;                   // [NKG,256] bf16 (overlaps xkg: dead then)
    float* x3  = (float*)REG1 + (size_t)NKG * 512;  // [NKG,128] f32 (same slot as before)
    float* x4  = x3 + (size_t)NKG * 128;       // [NKG,64]  f32
    u16*   xb  = (u16*)(x4 + (size_t)NKG * 64);// [NKG,256] bf16 (fits REG1)
    u16*   Xfb = (u16*)REG2;                   // fp: [4096,1024] bf16
    u16*   G1A = (u16*)REG2;                   // mol: [NM,128] bf16 aggregated
    u16*   AGGX= (u16*)REG2;                   // rgcn: [NKG,2304] bf16 (43.8 MB, REG2+HB)
    u16*   fp1b = HB;                          // fp: [4096,512] bf16 (gemm1 direct out)
    u16*   Xagg = HB;                          // mol L1: [NM,64] bf16
    // flattened CSR edge tables (aliased; lifetimes verified)
    int2* ebM  = (int2*)gout;                  // mol edges; gout written only after dead
    int*  ebK2 = key2;                         // kg src table; key2 dead after bin_by

    // ---- dtype detect + weight conversion (fp32 + bf16 pools) ----
    zero_int<<<1, 1, 0, stream>>>(flag);
    detect_f32<<<1024, 256, 0, stream>>>((const u16*)fp_data, (long)ND * 1024, flag);
    ConvTab tab;
    // NOTE: rg_root before rg_w so [root; W_0..W_7] is contiguous = [2304, N] GEMM B
    const int widx[14] = {6, 8, 10, 12, 14, 15, 16, 19, 18, 22, 21, 24, 26, 27};
    const int wn[14]   = {1024*512, 512*256, 64*128, 128*256, 256*128, 128, 128,
                          256*256, 8*256*256, 256*128, 8*256*128, 128*64, 64*2, 2};
    float* wf[14]; u16* wb[14];
    {
        size_t o = 0;
        for (int i = 0; i < 14; i++) {
            tab.src[i]  = d_in[widx[i]];
            tab.dst[i]  = Wpool + o;
            tab.dstB[i] = WpoolB + o;
            tab.n[i]    = wn[i];
            wf[i] = Wpool + o; wb[i] = WpoolB + o;
            o += (size_t)wn[i];
        }
    }
    conv_all<<<dim3(32, 14), 256, 0, stream>>>(tab, flag);
    float *att_w1c = wf[4], *att_b1c = wf[5], *att_w2c = wf[6];
    float *lin1_wc = wf[11], *lin2_wc = wf[12], *lin2_bc = wf[13];

    // ---- transposed bf16 weights for gemm_bt (BT[n*K+k] = B[k*N+n]) ----
    u16* T_fpw1  = WpoolT;                        // [512,1024]
    u16* T_fpw2  = T_fpw1 + (size_t)512 * 1024;   // [256,512]
    u16* T_gcnw1 = T_fpw2 + (size_t)256 * 512;    // [128,64]
    u16* T_gcnw2 = T_gcnw1 + (size_t)128 * 64;    // [256,128]
    u16* T_w1    = T_gcnw2 + (size_t)256 * 128;   // [256,2304]
    u16* T_w2    = T_w1 + (size_t)256 * 2304;     // [128,2304]
    transpose_b16<<<dim3(32, 16), 256, 0, stream>>>(wb[0], T_fpw1, 1024, 512);
    transpose_b16<<<dim3(16, 8),  256, 0, stream>>>(wb[1], T_fpw2, 512, 256);
    transpose_b16<<<dim3(2, 4),   256, 0, stream>>>(wb[2], T_gcnw1, 64, 128);
    transpose_b16<<<dim3(4, 8),   256, 0, stream>>>(wb[3], T_gcnw2, 128, 256);
    transpose_b16<<<dim3(72, 8),  256, 0, stream>>>(wb[7], T_w1, 2304, 256);
    transpose_b16<<<dim3(72, 4),  256, 0, stream>>>(wb[9], T_w2, 2304, 128);

    // ---- CSR builds ----
    filli<<<512, 256, 0, stream>>>((int*)z0, (long)(z1 - z0) / 4, 0);
    auto scan = [&](const int* deg, int* off, int n) {
        int nb = divup(n, 4096);
        scan_bsum<<<nb, 1024, 0, stream>>>(deg, n, sbt);
        scan_tiny<<<1, 64, 0, stream>>>(sbt, nb, sbo);
        scan_final<<<nb, 1024, 0, stream>>>(deg, n, sbo, nb, off);
    };
    hist_int<<<2048, 256, 0, stream>>>(mol_dst, EM, mdeg);
    scan(mdeg, moff, NM);
    bin_by<<<2048, 256, 0, stream>>>(mol_dst, EM, moff, mcur, mbins);
    dinv_from_deg<<<512, 256, 0, stream>>>(mdeg, dinv, NM);
    mol_enorm<<<1024, 256, 0, stream>>>(mol_src, mol_dst, dinv, EM, enM);
    flatten_mol<<<2048, 256, 0, stream>>>(mbins, mol_src, enM, EM, ebM);

    // KG: segment CSR over (dst, relation); mean norm from segment length
    kg_key2<<<2048, 256, 0, stream>>>(kg_dst, kg_et, EK, key2);
    hist_int<<<2048, 256, 0, stream>>>(key2, EK, kdeg2);
    scan(kdeg2, koff2, NSEG);
    bin_by<<<2048, 256, 0, stream>>>(key2, EK, koff2, kcur2, kbins);
    flatten_kg_src<<<2048, 256, 0, stream>>>(kbins, kg_src, EK, ebK2);  // key2 dead

    hist_int<<<512, 256, 0, stream>>>(mol_batch, NM, pdeg);
    scan(pdeg, poff, ND);
    bin_by<<<512, 256, 0, stream>>>(mol_batch, NM, poff, pcur, pbins);

    // stats finalize helper: partials (nblk rows x N cols) -> mean + rsqrt(var)
    auto reduceNto = [&](int nblk, int N, float invM, float* s1o, float* s2o) {
        colstats_reduce_v3<<<N / 64, 1024, 0, stream>>>(part1, part2, nblk, N,
                                                        invM, s1o, s2o);
    };

    // ---------- fingerprint MLP branch (MFMA, stats fused, bf16 chain) ------
    conv_dual_b16<<<2048, 256, 0, stream>>>(fp_data, Xfb, (long)ND * 1024, flag);
    gemm_bt<u16, 2, true><<<dim3(64, 4), 256, 0, stream>>>(
        Xfb, 1024, T_fpw1, 1024, fp1b, 512, ND, 512, 1024, part1, part2, 512);
    reduceNto(64, 512, 1.0f / ND, stats, stats + 512);
    bn_apply_b16v<<<2048, 256, 0, stream>>>((u32*)fp1b, (long)ND * 256, 255,
                                            stats, stats + 512);
    gemm_bt<float, 1, true><<<dim3(64, 4), 256, 0, stream>>>(
        fp1b, 512, T_fpw2, 512, fpb, 256, ND, 256, 512, part1, part2, 256);
    reduceNto(64, 256, 1.0f / ND, statsFP, statsFP + 512);
    // fpb BN+ReLU is fused into attention_fuse (statsFP survives mol phase)

    // ---------- mol GCN layer 1: bf16-convert, aggregate-then-GEMM ----------
    conv_molx<<<2048, 256, 0, stream>>>((const float*)mol_x, XB, (long)NM * 16, flag);
    mol_agg_in<<<32768, 256, 0, stream>>>(mol_x, XB, flag, dinv, moff, ebM, NM, Xagg);
    gemm_bt<u16, 2, true><<<dim3(2048, 1), 256, 0, stream>>>(
        Xagg, 64, T_gcnw1, 64, G1, 128, NM, 128, 64, part1, part2, 128);
    reduceNto(2048, 128, 1.0f / NM, stats, stats + 512);
    // BN+ReLU fused into mol_agg128_bn below (G1 has no other consumer)

    // ---------- mol GCN layer 2: fused-BN aggregate, 2-half GEMM + pool -----
    mol_agg128_bn<<<32768, 256, 0, stream>>>(G1, dinv, moff, ebM, NM,
                                             stats, stats + 512, G1A);
    // ebM (gout) dead past this point; G1 (REG1) dead -> H2 reuses it
    for (int h = 0; h < 2; h++) {
        gemm_bt<u16, 2, true><<<dim3(2048, 1), 256, 0, stream>>>(
            G1A, 128, T_gcnw2 + (size_t)h * 128 * 128, 128, H2, 128, NM, 128, 128,
            part1, part2, 128);
        reduceNto(2048, 128, 1.0f / NM, stats, stats + 512);
        pool128<<<1024, 256, 0, stream>>>(H2, poff, pbins, ND,
                                          stats, stats + 512, gout, h * 128);
    }

    // ---------- attention fusion (fpb BN fused) ----------
    attention_fuse<<<ND, 128, 0, stream>>>(gout, fpb, statsFP, statsFP + 512,
                                           att_w1c, att_b1c, att_w2c,
                                           xkg, out_beta);
    conv_in<<<512, 256, 0, stream>>>(d_in[17], xkg + (long)ND * 256,
                                     (long)NGENE * 256, flag);
    conv_f32_b16<<<1024, 256, 0, stream>>>(xkg, xb, (long)NKG * 256);

    // ---------- RGCN layer 1 (256 -> 256): preagg2 + K=2304 GEMM, bf16 out --
    xcopy_aggx<<<1024, 256, 0, stream>>>(xb, AGGX, (long)NKG * 64);
    kg_preagg2<<<divup((long)NSEG * 64, 256), 256, 0, stream>>>(
        xb, koff2, ebK2, NSEG, AGGX);
    gemm_bt<u16, 2, true><<<dim3(divup(NKG, 64), 2), 256, 0, stream>>>(
        AGGX, 2304, T_w1, 2304, x2b, 256, NKG, 256, 2304, part1, part2, 256);
    reduceNto(divup(NKG, 64), 256, 1.0f / NKG, stats, stats + 512);
    bn_apply_b16v<<<1024, 256, 0, stream>>>((u32*)x2b, (long)NKG * 128, 127,
                                            stats, stats + 512);

    // ---------- RGCN layer 2 (256 -> 128): preagg2 + K=2304 GEMM ------------
    xcopy_aggx<<<1024, 256, 0, stream>>>(x2b, AGGX, (long)NKG * 64);
    kg_preagg2<<<divup((long)NSEG * 64, 256), 256, 0, stream>>>(
        x2b, koff2, ebK2, NSEG, AGGX);
    gemm_bt<float, 1, true><<<dim3(divup(NKG, 64), 2), 256, 0, stream>>>(
        AGGX, 2304, T_w2, 2304, x3, 128, NKG, 128, 2304, part1, part2, 128);
    reduceNto(divup(NKG, 64), 128, 1.0f / NKG, stats, stats + 512);
    bn_apply<<<2048, 256, 0, stream>>>(x3, (long)NKG * 128, 127, stats, stats + 512);

    // ---------- classifier head ----------
    gemm64<<<dim3(divup(NKG, 64), 1, 1), 256, 0, stream>>>(
        x3, 128, lin1_wc, 64, x4, 64, NKG, 64, 128);
    colstats_f32_v2<<<NBLK_STATS, 256, 0, stream>>>(x4, NKG, 64, part1, part2);
    reduceNto(NBLK_STATS, 64, 1.0f / NKG, stats, stats + 512);
    logits_out_bn<<<divup(NKG, 256), 256, 0, stream>>>(x4, stats, stats + 512,
                                                       lin2_wc, lin2_bc, out_ls, NKG);
}

// Round 11
// 986.609 us; speedup vs baseline: 1.4510x; 1.0420x over previous
//
#include <hip/hip_runtime.h>
#include <hip/hip_bf16.h>
#include <cstdint>

typedef __hip_bfloat16 bf16;
typedef unsigned short u16;
typedef unsigned int u32;
typedef __attribute__((ext_vector_type(8))) short short8;
typedef __attribute__((ext_vector_type(4))) float f32x4;

__device__ __forceinline__ float tofloat(float x){ return x; }
__device__ __forceinline__ float tofloat(bf16 x){ return __bfloat162float(x); }
__device__ __forceinline__ float b2f(u16 a){ return __uint_as_float(((unsigned)a) << 16); }
__device__ __forceinline__ u16 f2b(float f){           // round-to-nearest-even
    unsigned u = __float_as_uint(f);
    return (u16)((u + 0x7FFFu + ((u >> 16) & 1u)) >> 16);
}

static inline int divup(long a, long b){ return (int)((a + b - 1) / b); }

#define NBLK_STATS 256

// ---------------- input dtype detection -------------------------------------
__global__ void zero_int(int* p){ *p = 0; }

__global__ void detect_f32(const u16* __restrict__ h, long n, int* flag)
{
    long i = (long)blockIdx.x * blockDim.x + threadIdx.x;
    long st = (long)gridDim.x * blockDim.x;
    int c = 0;
    for (; i < n; i += st)
        if (((h[i] >> 7) & 0xFF) == 0xFF) c++;
    if (c) atomicAdd(flag, c);
}

// convert all weights: fp32 pool + bf16 pool in one launch
struct ConvTab { const void* src[14]; float* dst[14]; u16* dstB[14]; int n[14]; };

__global__ void conv_all(ConvTab t, const int* __restrict__ flagp)
{
    bool f32 = (*flagp != 0);
    int seg = blockIdx.y;
    const void* s = t.src[seg];
    float* d = t.dst[seg];
    u16*   dB = t.dstB[seg];
    int n = t.n[seg];
    long i = (long)blockIdx.x * blockDim.x + threadIdx.x;
    long st = (long)gridDim.x * blockDim.x;
    for (; i < n; i += st) {
        float v = f32 ? ((const float*)s)[i] : tofloat(((const bf16*)s)[i]);
        d[i] = v; dB[i] = f2b(v);
    }
}

__global__ void conv_dual_b16(const void* __restrict__ src, u16* __restrict__ dst,
                              long n, const int* __restrict__ flagp)
{
    bool f32 = (*flagp != 0);
    long i = (long)blockIdx.x * blockDim.x + threadIdx.x;
    long st = (long)gridDim.x * blockDim.x;
    for (; i < n; i += st)
        dst[i] = f32 ? f2b(((const float*)src)[i]) : ((const u16*)src)[i];
}

// convert mol_x fp32 -> bf16 copy (only when input is fp32); vectorized x4
__global__ void conv_molx(const float* __restrict__ src, u16* __restrict__ dst,
                          long n4, const int* __restrict__ flagp)
{
    if (*flagp == 0) return;   // input already bf16; agg reads original
    long i = (long)blockIdx.x * blockDim.x + threadIdx.x;
    long st = (long)gridDim.x * blockDim.x;
    for (; i < n4; i += st) {
        float4 v = ((const float4*)src)[i];
        ushort4 o;
        o.x = f2b(v.x); o.y = f2b(v.y); o.z = f2b(v.z); o.w = f2b(v.w);
        ((ushort4*)dst)[i] = o;
    }
}

// batched bf16 transpose (6 matrices): dst[n*K + k] = src[k*N + n]
struct TransTab { const u16* src[6]; u16* dst[6]; int K[6]; int N[6]; };

__global__ __launch_bounds__(256)
void transpose6(TransTab t)
{
    int s = blockIdx.z;
    int K = t.K[s], N = t.N[s];
    int k0 = blockIdx.x * 32, n0 = blockIdx.y * 32;
    if (k0 >= K || n0 >= N) return;
    const u16* src = t.src[s];
    u16* dst = t.dst[s];
    __shared__ u16 tl[32][33];
    int x = threadIdx.x & 31, y = threadIdx.x >> 5;   // y in 0..7
    for (int yy = y; yy < 32; yy += 8) {
        int k = k0 + yy, n = n0 + x;
        tl[yy][x] = (k < K && n < N) ? src[(long)k * N + n] : (u16)0;
    }
    __syncthreads();
    for (int yy = y; yy < 32; yy += 8) {
        int n = n0 + yy, k = k0 + x;
        if (n < N && k < K) dst[(long)n * K + k] = tl[x][yy];
    }
}

// ---------------- batched CSR build -----------------------------------------
struct KV3 { const int* key[3]; int* h[3]; long n[3]; };

__global__ void hist3(KV3 t)
{
    int s = blockIdx.y;
    const int* key = t.key[s]; int* h = t.h[s]; long n = t.n[s];
    long i = (long)blockIdx.x * blockDim.x + threadIdx.x;
    long st = (long)gridDim.x * blockDim.x;
    for (; i < n; i += st) atomicAdd(&h[key[i]], 1);
}

struct Scan3 { const int* in[3]; int* out[3]; int* bt[3]; int* bo[3]; int n[3]; };

__global__ __launch_bounds__(1024)
void scan_bsum3(Scan3 t)
{
    int s = blockIdx.y;
    int n = t.n[s];
    int nb = (n + 4095) >> 12;
    if ((int)blockIdx.x >= nb) return;
    const int* in = t.in[s];
    __shared__ int sh[1024];
    int tid = threadIdx.x;
    int i0 = blockIdx.x * 4096 + tid * 4;
    int acc = 0;
#pragma unroll
    for (int k = 0; k < 4; k++) { int idx = i0 + k; acc += (idx < n) ? in[idx] : 0; }
    sh[tid] = acc;
    __syncthreads();
    for (int off = 512; off > 0; off >>= 1) {
        if (tid < off) sh[tid] += sh[tid + off];
        __syncthreads();
    }
    if (tid == 0) t.bt[s][blockIdx.x] = sh[0];
}

__global__ void scan_tiny3(Scan3 t)
{
    int s = blockIdx.x;
    if (threadIdx.x != 0) return;
    int nb = (t.n[s] + 4095) >> 12;
    const int* bt = t.bt[s]; int* bo = t.bo[s];
    int c = 0;
    for (int b = 0; b < nb; b++) { bo[b] = c; c += bt[b]; }
    bo[nb] = c;
}

__global__ __launch_bounds__(1024)
void scan_final3(Scan3 t)
{
    int s = blockIdx.y;
    int n = t.n[s];
    int nb = (n + 4095) >> 12;
    if ((int)blockIdx.x >= nb) return;
    const int* in = t.in[s]; int* out = t.out[s]; const int* bo = t.bo[s];
    __shared__ int buf[1024];
    int tid = threadIdx.x;
    int i0 = blockIdx.x * 4096 + tid * 4;
    int v[4]; int acc = 0;
#pragma unroll
    for (int k = 0; k < 4; k++) {
        int idx = i0 + k;
        v[k] = (idx < n) ? in[idx] : 0;
        acc += v[k];
    }
    buf[tid] = acc;
    __syncthreads();
    for (int off = 1; off < 1024; off <<= 1) {
        int tv = (tid >= off) ? buf[tid - off] : 0;
        __syncthreads();
        buf[tid] += tv;
        __syncthreads();
    }
    int excl = buf[tid] - acc + bo[blockIdx.x];
#pragma unroll
    for (int k = 0; k < 4; k++) {
        int idx = i0 + k;
        if (idx < n) out[idx] = excl;
        excl += v[k];
    }
    if (blockIdx.x == 0 && tid == 0) out[n] = bo[nb];
}

struct Bin3 { const int* key[3]; const int* off[3]; int* cur[3]; int* bins[3]; long n[3]; };

__global__ void bin3(Bin3 t)
{
    int s = blockIdx.y;
    const int* key = t.key[s]; const int* off = t.off[s];
    int* cur = t.cur[s]; int* bins = t.bins[s]; long n = t.n[s];
    long i = (long)blockIdx.x * blockDim.x + threadIdx.x;
    long st = (long)gridDim.x * blockDim.x;
    for (; i < n; i += st) {
        int k = key[i];
        int pos = off[k] + atomicAdd(&cur[k], 1);
        bins[pos] = (int)i;
    }
}

// KG segment key: dst*8 + et  (segments = (node, relation) pairs)
__global__ void kg_key2(const int* __restrict__ dst, const int* __restrict__ et,
                        long E, int* __restrict__ key)
{
    long i = (long)blockIdx.x * blockDim.x + threadIdx.x;
    long st = (long)gridDim.x * blockDim.x;
    for (; i < E; i += st) key[i] = dst[i] * 8 + et[i];
}

// seg 0: ebM[i] = {src, bits(dinv[src]*dinv[dst])}; seg 1: ebK[i] = ksrc[kbins[i]]
__global__ void flatten2(const int* __restrict__ mbins, const int* __restrict__ msrc,
                         const int* __restrict__ mdst, const float* __restrict__ dinv,
                         int2* __restrict__ ebM,
                         const int* __restrict__ kbins, const int* __restrict__ ksrc,
                         int* __restrict__ ebK, long E)
{
    long i = (long)blockIdx.x * blockDim.x + threadIdx.x;
    long st = (long)gridDim.x * blockDim.x;
    if (blockIdx.y == 0) {
        for (; i < E; i += st) {
            int e = mbins[i];
            int sn = msrc[e];
            ebM[i] = make_int2(sn, __float_as_int(dinv[sn] * dinv[mdst[e]]));
        }
    } else {
        for (; i < E; i += st) ebK[i] = ksrc[kbins[i]];
    }
}

__global__ void filli(int* p, long n, int v)
{
    long i = (long)blockIdx.x * blockDim.x + threadIdx.x;
    long st = (long)gridDim.x * blockDim.x;
    for (; i < n; i += st) p[i] = v;
}

__global__ void dinv_from_deg(const int* __restrict__ deg, float* __restrict__ dinv, long n)
{
    long i = (long)blockIdx.x * blockDim.x + threadIdx.x;
    long st = (long)gridDim.x * blockDim.x;
    for (; i < n; i += st) dinv[i] = rsqrtf((float)(deg[i] + 1));
}

// ---------------- MFMA GEMM (B pre-transposed): C = A @ B, bf16, fp32 acc ---
// A [M,K] lda; BT [N,K] ldbt. Tile 64 x (NBLK*64). Register-prefetch pipeline.
// STATS: fuse per-column sum/sumsq of the STORED values into the epilogue.
template<typename TC, int NBLK, bool STATS>
__global__ __launch_bounds__(256)
void gemm_bt(const u16* __restrict__ A, int lda,
             const u16* __restrict__ BT, int ldbt,
             TC* __restrict__ C, int ldc,
             int M, int N, int K,
             float* __restrict__ SP1, float* __restrict__ SP2, int Ntot)
{
    __shared__ __align__(16) u16 As[64][40];          // [m][k]
    __shared__ __align__(16) u16 Bs[NBLK * 64][40];   // [n][k]
    __shared__ float st1[NBLK * 64], st2[NBLK * 64];
    const int tid = threadIdx.x;
    const int lane = tid & 63, wave = tid >> 6;
    const int l15 = lane & 15, quad = lane >> 4;
    const int wm = (wave & 1) * 32, wn = (wave >> 1) * 32;
    const int row0 = blockIdx.x * 64, col0 = blockIdx.y * (NBLK * 64);
    const int arow = tid >> 2, ak = (tid & 3) * 8;
    const int aok = row0 + arow < M;

    if (STATS && tid < NBLK * 64) { st1[tid] = 0.f; st2[tid] = 0.f; }

    f32x4 acc[NBLK][2][2];
#pragma unroll
    for (int t = 0; t < NBLK; t++)
#pragma unroll
        for (int i = 0; i < 2; i++)
#pragma unroll
            for (int j = 0; j < 2; j++)
#pragma unroll
                for (int r = 0; r < 4; r++) acc[t][i][j][r] = 0.f;

    const u16* pa = A + (long)(row0 + arow) * lda + ak;
    const u16* pb[NBLK];
#pragma unroll
    for (int t = 0; t < NBLK; t++)
        pb[t] = BT + (long)(col0 + t * 64 + arow) * ldbt + ak;

    ushort4 ra0 = {0,0,0,0}, ra1 = {0,0,0,0};
    ushort4 rb0[NBLK], rb1[NBLK];
    if (aok) { ra0 = *(const ushort4*)pa; ra1 = *(const ushort4*)(pa + 4); }
#pragma unroll
    for (int t = 0; t < NBLK; t++) {
        rb0[t] = *(const ushort4*)pb[t];
        rb1[t] = *(const ushort4*)(pb[t] + 4);
    }

    for (int k0 = 0; k0 < K; k0 += 32) {
        *(ushort4*)&As[arow][ak]     = ra0;
        *(ushort4*)&As[arow][ak + 4] = ra1;
#pragma unroll
        for (int t = 0; t < NBLK; t++) {
            *(ushort4*)&Bs[t * 64 + arow][ak]     = rb0[t];
            *(ushort4*)&Bs[t * 64 + arow][ak + 4] = rb1[t];
        }
        __syncthreads();
        if (k0 + 32 < K) {   // issue next-step loads; retire under MFMAs
            if (aok) {
                ra0 = *(const ushort4*)(pa + k0 + 32);
                ra1 = *(const ushort4*)(pa + k0 + 36);
            }
#pragma unroll
            for (int t = 0; t < NBLK; t++) {
                rb0[t] = *(const ushort4*)(pb[t] + k0 + 32);
                rb1[t] = *(const ushort4*)(pb[t] + k0 + 36);
            }
        }
        short8 a0 = *(const short8*)&As[wm + l15][quad * 8];
        short8 a1 = *(const short8*)&As[wm + 16 + l15][quad * 8];
#pragma unroll
        for (int t = 0; t < NBLK; t++) {
            short8 b0 = *(const short8*)&Bs[t * 64 + wn + l15][quad * 8];
            short8 b1 = *(const short8*)&Bs[t * 64 + wn + 16 + l15][quad * 8];
            acc[t][0][0] = __builtin_amdgcn_mfma_f32_16x16x32_bf16(a0, b0, acc[t][0][0], 0, 0, 0);
            acc[t][0][1] = __builtin_amdgcn_mfma_f32_16x16x32_bf16(a0, b1, acc[t][0][1], 0, 0, 0);
            acc[t][1][0] = __builtin_amdgcn_mfma_f32_16x16x32_bf16(a1, b0, acc[t][1][0], 0, 0, 0);
            acc[t][1][1] = __builtin_amdgcn_mfma_f32_16x16x32_bf16(a1, b1, acc[t][1][1], 0, 0, 0);
        }
        __syncthreads();
    }
#pragma unroll
    for (int t = 0; t < NBLK; t++)
#pragma unroll
        for (int j = 0; j < 2; j++) {
            float s = 0.f, q = 0.f;
#pragma unroll
            for (int i = 0; i < 2; i++)
#pragma unroll
                for (int r = 0; r < 4; r++) {
                    int row = row0 + wm + i * 16 + quad * 4 + r;
                    int col = col0 + t * 64 + wn + j * 16 + l15;
                    float v = acc[t][i][j][r];
                    float y;
                    if constexpr (sizeof(TC) == 2) {
                        u16 h = f2b(v);
                        if (row < M) ((u16*)C)[(long)row * ldc + col] = h;
                        y = b2f(h);
                    } else {
                        if (row < M) ((float*)C)[(long)row * ldc + col] = v;
                        y = v;
                    }
                    if (STATS) { s += y; q += y * y; }
                }
            if (STATS) {
                s += __shfl_xor(s, 16); s += __shfl_xor(s, 32);
                q += __shfl_xor(q, 16); q += __shfl_xor(q, 32);
                if (quad == 0) {
                    atomicAdd(&st1[t * 64 + wn + j * 16 + l15], s);
                    atomicAdd(&st2[t * 64 + wn + j * 16 + l15], q);
                }
            }
        }
    if (STATS) {
        __syncthreads();
        if (tid < NBLK * 64) {
            long off = (long)blockIdx.x * Ntot + (long)blockIdx.y * (NBLK * 64) + tid;
            SP1[off] = st1[tid];
            SP2[off] = st2[tid];
        }
    }
}

// ---------------- vector GEMM (fp32, small) ---------------------------------
__global__ __launch_bounds__(256)
void gemm64(const float* __restrict__ A, int lda,
            const float* __restrict__ B, int ldb,
            float* __restrict__ C, int ldc,
            int M, int N, int K)
{
    __shared__ float As[16][68];
    __shared__ float Bs[16][68];
    const int tid = threadIdx.x;
    const int row0 = blockIdx.x * 64, col0 = blockIdx.y * 64;
    float acc[4][4];
#pragma unroll
    for (int i = 0; i < 4; i++)
#pragma unroll
        for (int j = 0; j < 4; j++) acc[i][j] = 0.f;
    const int ar = tid >> 2, ak = (tid & 3) * 4;
    const int bk = tid >> 4, bc = (tid & 15) * 4;
    const int ty4 = (tid >> 4) * 4, tx4 = (tid & 15) * 4;
    for (int k0 = 0; k0 < K; k0 += 16) {
        {
            int row = row0 + ar;
            float4 v = make_float4(0.f, 0.f, 0.f, 0.f);
            if (row < M) v = *(const float4*)(A + (long)row * lda + k0 + ak);
            As[ak + 0][ar] = v.x; As[ak + 1][ar] = v.y;
            As[ak + 2][ar] = v.z; As[ak + 3][ar] = v.w;
        }
        {
            int c = col0 + bc;
            float4 v = make_float4(0.f, 0.f, 0.f, 0.f);
            if (c < N) v = *(const float4*)(B + (long)(k0 + bk) * ldb + c);
            *(float4*)&Bs[bk][bc] = v;
        }
        __syncthreads();
#pragma unroll
        for (int k = 0; k < 16; k++) {
            float4 a = *(const float4*)&As[k][ty4];
            float4 b = *(const float4*)&Bs[k][tx4];
            acc[0][0] += a.x * b.x; acc[0][1] += a.x * b.y; acc[0][2] += a.x * b.z; acc[0][3] += a.x * b.w;
            acc[1][0] += a.y * b.x; acc[1][1] += a.y * b.y; acc[1][2] += a.y * b.z; acc[1][3] += a.y * b.w;
            acc[2][0] += a.z * b.x; acc[2][1] += a.z * b.y; acc[2][2] += a.z * b.z; acc[2][3] += a.z * b.w;
            acc[3][0] += a.w * b.x; acc[3][1] += a.w * b.y; acc[3][2] += a.w * b.z; acc[3][3] += a.w * b.w;
        }
        __syncthreads();
    }
    int c = col0 + tx4;
#pragma unroll
    for (int i = 0; i < 4; i++) {
        int r = row0 + ty4 + i;
        if (r < M && c < N)
            *(float4*)&C[(long)r * ldc + c] =
                make_float4(acc[i][0], acc[i][1], acc[i][2], acc[i][3]);
    }
}

// ---------------- batch-norm stats ------------------------------------------
// fp32 matrix [M, N] -> partials (for gemm64 output only)
__global__ __launch_bounds__(256)
void colstats_f32_v2(const float* __restrict__ X, int M, int N,
                     float* __restrict__ p1, float* __restrict__ p2)
{
    __shared__ float sh1[1024], sh2[1024];
    int tid = threadIdx.x;
    int ncg = N >> 2;
    int cg  = tid & (ncg - 1);
    int rg  = tid / ncg;
    int nrg = 256 / ncg;
    float s0=0,s1=0,s2=0,s3=0, q0=0,q1=0,q2=0,q3=0;
    const float* base = X + 4 * cg;
    for (long row = (long)blockIdx.x * nrg + rg; row < M; row += (long)gridDim.x * nrg) {
        float4 v = *(const float4*)(base + row * (long)N);
        s0 += v.x; q0 += v.x * v.x; s1 += v.y; q1 += v.y * v.y;
        s2 += v.z; q2 += v.z * v.z; s3 += v.w; q3 += v.w * v.w;
    }
    float4* S1 = (float4*)sh1; float4* S2 = (float4*)sh2;
    S1[tid] = make_float4(s0, s1, s2, s3);
    S2[tid] = make_float4(q0, q1, q2, q3);
    __syncthreads();
    for (int off = nrg >> 1; off > 0; off >>= 1) {
        if (rg < off) {
            float4 a = S1[tid], b = S1[tid + off * ncg];
            S1[tid] = make_float4(a.x + b.x, a.y + b.y, a.z + b.z, a.w + b.w);
            float4 c = S2[tid], d = S2[tid + off * ncg];
            S2[tid] = make_float4(c.x + d.x, c.y + d.y, c.z + d.z, c.w + d.w);
        }
        __syncthreads();
    }
    if (rg == 0) {
        *(float4*)&p1[(long)blockIdx.x * N + 4 * cg] = S1[tid];
        *(float4*)&p2[(long)blockIdx.x * N + 4 * cg] = S2[tid];
    }
}

// reduce partials (nblk up to 2048): grid N/64 blocks x 1024 thr (16 segments)
__global__ __launch_bounds__(1024)
void colstats_reduce_v3(const float* __restrict__ p1, const float* __restrict__ p2,
                        int nblk, int N, float invM,
                        float* __restrict__ s1o, float* __restrict__ s2o)
{
    __shared__ float sh1[1024], sh2[1024];
    int tid = threadIdx.x;
    int col = blockIdx.x * 64 + (tid & 63);
    int seg = tid >> 6;                       // 0..15
    float a = 0.f, c = 0.f;
    for (int b = seg; b < nblk; b += 16) {
        a += p1[(long)b * N + col];
        c += p2[(long)b * N + col];
    }
    sh1[tid] = a; sh2[tid] = c;
    __syncthreads();
    for (int off = 8; off > 0; off >>= 1) {
        if (seg < off) {
            sh1[tid] += sh1[tid + off * 64];
            sh2[tid] += sh2[tid + off * 64];
        }
        __syncthreads();
    }
    if (seg == 0) {
        float mean = sh1[tid] * invM;
        float var  = fmaxf(sh2[tid] * invM - mean * mean, 0.f);
        s1o[col] = mean;
        s2o[col] = rsqrtf(var + 1e-5f);
    }
}

__global__ void bn_apply(float* X, long total, int mask,
                         const float* __restrict__ s1, const float* __restrict__ s2)
{
    long i = (long)blockIdx.x * blockDim.x + threadIdx.x;
    long st = (long)gridDim.x * blockDim.x;
    for (; i < total; i += st) {
        int j = (int)(i & mask);
        X[i] = fmaxf((X[i] - s1[j]) * s2[j], 0.f);
    }
}

// BN+ReLU in place on bf16 contiguous [M, NC]; u32 words (2 cols each)
__global__ void bn_apply_b16v(u32* __restrict__ X, long n2, int maskHalf,
                              const float* __restrict__ s1, const float* __restrict__ s2)
{
    long i = (long)blockIdx.x * blockDim.x + threadIdx.x;
    long st = (long)gridDim.x * blockDim.x;
    for (; i < n2; i += st) {
        u32 v = X[i];
        int f = (int)(i & maskHalf) * 2;
        float y0 = fmaxf((b2f((u16)(v & 0xFFFF)) - s1[f])     * s2[f],     0.f);
        float y1 = fmaxf((b2f((u16)(v >> 16))    - s1[f + 1]) * s2[f + 1], 0.f);
        X[i] = (u32)f2b(y0) | ((u32)f2b(y1) << 16);
    }
}

// ---------------- CSR aggregation (no atomics) ------------------------------
__global__ __launch_bounds__(256)
void mol_agg_in(const void* __restrict__ Xraw, const u16* __restrict__ Xcvt,
                const int* __restrict__ flagp, const float* __restrict__ dinv,
                const int* __restrict__ off, const int2* __restrict__ eb,
                int NM, u16* __restrict__ out)
{
    const u16* X = (*flagp != 0) ? Xcvt : (const u16*)Xraw;
    int wid  = (int)(((long)blockIdx.x * 256 + threadIdx.x) >> 6);
    int lane = threadIdx.x & 63;
    if (wid >= NM) return;
    float dv = dinv[wid];
    float acc = b2f(X[(long)wid * 64 + lane]) * dv * dv;
    int j = off[wid], j1 = off[wid + 1];
    for (; j + 3 < j1; j += 4) {
        int2 e0 = eb[j], e1 = eb[j + 1], e2 = eb[j + 2], e3 = eb[j + 3];
        float v0 = b2f(X[(long)e0.x * 64 + lane]);
        float v1 = b2f(X[(long)e1.x * 64 + lane]);
        float v2 = b2f(X[(long)e2.x * 64 + lane]);
        float v3 = b2f(X[(long)e3.x * 64 + lane]);
        acc += v0 * __int_as_float(e0.y) + v1 * __int_as_float(e1.y)
             + v2 * __int_as_float(e2.y) + v3 * __int_as_float(e3.y);
    }
    for (; j < j1; j++) {
        int2 e = eb[j];
        acc += b2f(X[(long)e.x * 64 + lane]) * __int_as_float(e.y);
    }
    out[(long)wid * 64 + lane] = f2b(acc);
}

// mol layer-2 aggregation with FUSED BN+ReLU on gathered G1 values.
__global__ __launch_bounds__(256)
void mol_agg128_bn(const u16* __restrict__ G, const float* __restrict__ dinv,
                   const int* __restrict__ off, const int2* __restrict__ eb,
                   int NM, const float* __restrict__ s1, const float* __restrict__ s2,
                   u16* __restrict__ out)
{
    int wid  = (int)(((long)blockIdx.x * 256 + threadIdx.x) >> 6);
    int lane = threadIdx.x & 63;
    if (wid >= NM) return;
    const float m0 = s1[2 * lane],     r0 = s2[2 * lane];
    const float m1 = s1[2 * lane + 1], r1 = s2[2 * lane + 1];
    float dv = dinv[wid], dv2 = dv * dv;
    u32 u = *(const u32*)(G + (long)wid * 128 + 2 * lane);
    float a0 = fmaxf((b2f((u16)(u & 0xFFFF)) - m0) * r0, 0.f) * dv2;
    float a1 = fmaxf((b2f((u16)(u >> 16))    - m1) * r1, 0.f) * dv2;
    int j = off[wid], j1 = off[wid + 1];
    for (; j + 3 < j1; j += 4) {
        int2 e0 = eb[j], e1 = eb[j + 1], e2 = eb[j + 2], e3 = eb[j + 3];
        u32 v0 = *(const u32*)(G + (long)e0.x * 128 + 2 * lane);
        u32 v1 = *(const u32*)(G + (long)e1.x * 128 + 2 * lane);
        u32 v2 = *(const u32*)(G + (long)e2.x * 128 + 2 * lane);
        u32 v3 = *(const u32*)(G + (long)e3.x * 128 + 2 * lane);
        float n0 = __int_as_float(e0.y), n1 = __int_as_float(e1.y);
        float n2 = __int_as_float(e2.y), n3 = __int_as_float(e3.y);
        a0 += fmaxf((b2f((u16)(v0 & 0xFFFF)) - m0) * r0, 0.f) * n0
            + fmaxf((b2f((u16)(v1 & 0xFFFF)) - m0) * r0, 0.f) * n1
            + fmaxf((b2f((u16)(v2 & 0xFFFF)) - m0) * r0, 0.f) * n2
            + fmaxf((b2f((u16)(v3 & 0xFFFF)) - m0) * r0, 0.f) * n3;
        a1 += fmaxf((b2f((u16)(v0 >> 16)) - m1) * r1, 0.f) * n0
            + fmaxf((b2f((u16)(v1 >> 16)) - m1) * r1, 0.f) * n1
            + fmaxf((b2f((u16)(v2 >> 16)) - m1) * r1, 0.f) * n2
            + fmaxf((b2f((u16)(v3 >> 16)) - m1) * r1, 0.f) * n3;
    }
    for (; j < j1; j++) {
        int2 e = eb[j];
        u32 v = *(const u32*)(G + (long)e.x * 128 + 2 * lane);
        float n = __int_as_float(e.y);
        a0 += fmaxf((b2f((u16)(v & 0xFFFF)) - m0) * r0, 0.f) * n;
        a1 += fmaxf((b2f((u16)(v >> 16))    - m1) * r1, 0.f) * n;
    }
    u32 o = (u32)f2b(a0) | ((u32)f2b(a1) << 16);
    *(u32*)(out + (long)wid * 128 + 2 * lane) = o;
}

// RGCN pre-aggregation v2 + fused x-row copy:
// segs [0, NSEG): per-(node, relation) mean into AGGX cols 256+r*256
// segs [NSEG, NSEG+NKG): copy xin row -> AGGX cols 0:255
__global__ __launch_bounds__(256)
void kg_preagg2(const u16* __restrict__ xin, const int* __restrict__ off2,
                const int* __restrict__ eb, int NSEG, int NKG, u16* __restrict__ aggx)
{
    int seg  = (int)(((long)blockIdx.x * 256 + threadIdx.x) >> 6);
    int lane = threadIdx.x & 63;
    const int c4 = 4 * lane;
    if (seg >= NSEG + NKG) return;
    if (seg >= NSEG) {
        int node = seg - NSEG;
        *(ushort4*)(aggx + (long)node * 2304 + c4) =
            *(const ushort4*)(xin + (long)node * 256 + c4);
        return;
    }
    int node = seg >> 3, r = seg & 7;
    int j0 = off2[seg], j1 = off2[seg + 1];
    float a0 = 0.f, a1 = 0.f, a2 = 0.f, a3 = 0.f;
    int j = j0;
    for (; j + 3 < j1; j += 4) {
        int s0 = eb[j], s1 = eb[j + 1], s2 = eb[j + 2], s3 = eb[j + 3];
        ushort4 v0 = *(const ushort4*)(xin + (long)s0 * 256 + c4);
        ushort4 v1 = *(const ushort4*)(xin + (long)s1 * 256 + c4);
        ushort4 v2 = *(const ushort4*)(xin + (long)s2 * 256 + c4);
        ushort4 v3 = *(const ushort4*)(xin + (long)s3 * 256 + c4);
        a0 += b2f(v0.x) + b2f(v1.x) + b2f(v2.x) + b2f(v3.x);
        a1 += b2f(v0.y) + b2f(v1.y) + b2f(v2.y) + b2f(v3.y);
        a2 += b2f(v0.z) + b2f(v1.z) + b2f(v2.z) + b2f(v3.z);
        a3 += b2f(v0.w) + b2f(v1.w) + b2f(v2.w) + b2f(v3.w);
    }
    for (; j < j1; j++) {
        ushort4 v = *(const ushort4*)(xin + (long)eb[j] * 256 + c4);
        a0 += b2f(v.x); a1 += b2f(v.y); a2 += b2f(v.z); a3 += b2f(v.w);
    }
    float nrm = 1.0f / fmaxf((float)(j1 - j0), 1.0f);
    ushort4 o;
    o.x = f2b(a0 * nrm); o.y = f2b(a1 * nrm);
    o.z = f2b(a2 * nrm); o.w = f2b(a3 * nrm);
    *(ushort4*)(aggx + (long)node * 2304 + 256 + (r << 8) + c4) = o;
}

// mean-pool bf16 [NM,128] (all 128 cols via u32/lane) with fused BN+ReLU
__global__ __launch_bounds__(256)
void pool128(const u16* __restrict__ g, const int* __restrict__ off,
             const int* __restrict__ bins, int ND,
             const float* __restrict__ s1, const float* __restrict__ s2,
             float* __restrict__ gout, int c0out)
{
    int wid  = (int)(((long)blockIdx.x * 256 + threadIdx.x) >> 6);
    int lane = threadIdx.x & 63;
    if (wid >= ND) return;
    const float m0 = s1[2 * lane],     r0 = s2[2 * lane];
    const float m1 = s1[2 * lane + 1], r1 = s2[2 * lane + 1];
    int j0 = off[wid], j1 = off[wid + 1];
    float a0 = 0.f, a1 = 0.f;
    for (int j = j0; j < j1; j++) {
        u32 v = *(const u32*)(g + (long)bins[j] * 128 + 2 * lane);
        a0 += fmaxf((b2f((u16)(v & 0xFFFF)) - m0) * r0, 0.f);
        a1 += fmaxf((b2f((u16)(v >> 16))    - m1) * r1, 0.f);
    }
    float inv = 1.0f / fmaxf((float)(j1 - j0), 1.0f);
    *(float2*)(gout + (long)wid * 256 + c0out + 2 * lane) =
        make_float2(a0 * inv, a1 * inv);
}

// ---------------- attention fusion (fp BN fused; bf16 emb out) --------------
__global__ void attention_fuse(const float* __restrict__ go, const float* __restrict__ fpv,
                               const float* __restrict__ fs1, const float* __restrict__ fs2,
                               const float* __restrict__ W1, const float* __restrict__ B1,
                               const float* __restrict__ W2,
                               u16* __restrict__ embb, float* __restrict__ beta_out)
{
    int d = blockIdx.x;
    int t = threadIdx.x;
    __shared__ float z[2][256];
    __shared__ float red[128];
    for (int c = t; c < 256; c += 128) {
        z[0][c] = go[(long)d * 256 + c];
        z[1][c] = fmaxf((fpv[(long)d * 256 + c] - fs1[c]) * fs2[c], 0.f);
    }
    __syncthreads();
    float s[2];
    for (int v = 0; v < 2; v++) {
        float acc = B1[t];
        for (int k = 0; k < 256; k++) acc += z[v][k] * W1[k * 128 + t];
        red[t] = tanhf(acc) * W2[t];
        __syncthreads();
        for (int off = 64; off > 0; off >>= 1) {
            if (t < off) red[t] += red[t + off];
            __syncthreads();
        }
        s[v] = red[0];
        __syncthreads();
    }
    float m = fmaxf(s[0], s[1]);
    float e0 = expf(s[0] - m), e1 = expf(s[1] - m);
    float inv = 1.0f / (e0 + e1);
    float b0 = e0 * inv, b1 = e1 * inv;
    for (int c = t; c < 256; c += 128)
        embb[(long)d * 256 + c] = f2b(b0 * z[0][c] + b1 * z[1][c]);
    if (t == 0) {
        beta_out[d * 2 + 0] = b0;
        beta_out[d * 2 + 1] = b1;
    }
}

// ---------------- final linear + log_softmax, fused BN on x4 ----------------
__global__ void logits_out_bn(const float* __restrict__ x4,
                              const float* __restrict__ s1, const float* __restrict__ s2,
                              const float* __restrict__ w, const float* __restrict__ b,
                              float* __restrict__ out, int NKG)
{
    int i = blockIdx.x * blockDim.x + threadIdx.x;
    if (i >= NKG) return;
    float a0 = b[0], a1 = b[1];
    for (int k = 0; k < 64; k++) {
        float v = fmaxf((x4[(long)i * 64 + k] - s1[k]) * s2[k], 0.f);
        a0 += v * w[k * 2 + 0];
        a1 += v * w[k * 2 + 1];
    }
    float m = fmaxf(a0, a1);
    float lse = m + logf(expf(a0 - m) + expf(a1 - m));
    out[i * 2 + 0] = a0 - lse;
    out[i * 2 + 1] = a1 - lse;
}

// ============================================================================
extern "C" void kernel_launch(void* const* d_in, const int* in_sizes, int n_in,
                              void* d_out, int out_size, void* d_ws, size_t ws_size,
                              hipStream_t stream)
{
    (void)in_sizes; (void)n_in; (void)out_size; (void)ws_size;
    const int ND = 4096, NM = 131072, NKG = 9510, NGENE = 5414;
    const long EM = 524288, EK = 524288;
    const int NSEG = 8 * NKG;   // 76080 (node, relation) segments

    const void* fp_data = d_in[0];
    const void* mol_x   = d_in[1];
    const int*  mol_batch = (const int*)d_in[2];
    const int*  mol_ei  = (const int*)d_in[3];
    const int*  kg_ei   = (const int*)d_in[4];
    const int*  kg_et   = (const int*)d_in[5];

    const int* mol_src = mol_ei;
    const int* mol_dst = mol_ei + EM;
    const int* kg_src  = kg_ei;
    const int* kg_dst  = kg_ei + EK;

    float* out_ls   = (float*)d_out;          // [9510,2] fp32
    float* out_beta = (float*)d_out + 19020;  // [4096,2,1] fp32

    // ---- workspace carve ----
    char* wp = (char*)d_ws;
    auto carve = [&](size_t bytes) { char* p = wp; wp += (bytes + 255) & ~(size_t)255; return p; };
    float* stats   = (float*)carve(4096);
    float* statsFP = (float*)carve(4096);     // fpb stats (must survive mol phase)
    int*   flag  = (int*)carve(256);
    float* dinv  = (float*)carve((size_t)NM * 4);
    float* part1 = (float*)carve((size_t)2048 * 128 * 4);   // 1 MB (gemm stats partials)
    float* part2 = (float*)carve((size_t)2048 * 128 * 4);
    int*   sbt3  = (int*)carve(3 * 64 * 4);
    int*   sbo3  = (int*)carve(3 * 64 * 4);
    float* Wpool = (float*)carve((size_t)1630000 * 4);     // fp32 weights
    u16*   WpoolB= (u16*)carve((size_t)1630000 * 2);       // bf16 weights
    u16*   WpoolT= (u16*)carve((size_t)1600000 * 2);       // bf16 transposed gemm weights
    float* fpb   = (float*)carve((size_t)ND * 256 * 4);
    float* gout  = (float*)carve((size_t)ND * 256 * 4);
    int*   key2  = (int*)carve((size_t)EK * 4);            // kg seg keys; reused as ebK2
    int*   koff2 = (int*)carve((size_t)(NSEG + 1) * 4);
    // zero-span
    char*  z0    = wp;
    int* kdeg2 = (int*)carve((size_t)NSEG * 4);
    int* kcur2 = (int*)carve((size_t)NSEG * 4);
    int* mdeg = (int*)carve((size_t)NM * 4);
    int* mcur = (int*)carve((size_t)NM * 4);
    int* pdeg = (int*)carve((size_t)ND * 4);
    int* pcur = (int*)carve((size_t)ND * 4);
    char*  z1    = wp;
    int* moff = (int*)carve((size_t)(NM + 1) * 4);
    int* mbins= (int*)carve((size_t)EM * 4);
    int* kbins= (int*)carve((size_t)EK * 4);
    int* poff = (int*)carve((size_t)(ND + 1) * 4);
    int* pbins= (int*)carve((size_t)NM * 4);
    char*  REG1  = carve((size_t)NM * 128 * 2);            // 33.6 MB
    char*  REG2  = carve((size_t)NM * 128 * 2);            // 33.6 MB  (contiguous with HB)
    u16*   HB    = (u16*)carve((size_t)NM * 64 * 2);       // 16.8 MB

    // phase views
    u16*   XB  = (u16*)REG1;                   // mol pre: [NM,64] bf16 converted input
    u16*   G1  = (u16*)REG1;                   // mol: [NM,128] bf16 (raw gemm out)
    u16*   H2  = (u16*)REG1;                   // mol L2: [NM,128] bf16 half-output (G1 dead)
    // rgcn chain in REG1:
    u16*   x2b = (u16*)REG1;                   // [NKG,256] bf16
    float* x3  = (float*)REG1 + (size_t)NKG * 512;  // [NKG,128] f32
    float* x4  = x3 + (size_t)NKG * 128;       // [NKG,64]  f32
    u16*   xb  = (u16*)(x4 + (size_t)NKG * 64);// [NKG,256] bf16 (fits REG1)
    u16*   Xfb = (u16*)REG2;                   // fp: [4096,1024] bf16
    u16*   G1A = (u16*)REG2;                   // mol: [NM,128] bf16 aggregated
    u16*   AGGX= (u16*)REG2;                   // rgcn: [NKG,2304] bf16 (43.8 MB, REG2+HB)
    u16*   fp1b = HB;                          // fp: [4096,512] bf16 (gemm1 direct out)
    u16*   Xagg = HB;                          // mol L1: [NM,64] bf16
    // flattened CSR edge tables (aliased; lifetimes verified)
    int2* ebM  = (int2*)gout;                  // mol edges; gout written only after dead
    int*  ebK2 = key2;                         // kg src table; key2 dead after bin3

    // ---- dtype detect + weight conversion (fp32 + bf16 pools) ----
    zero_int<<<1, 1, 0, stream>>>(flag);
    detect_f32<<<1024, 256, 0, stream>>>((const u16*)fp_data, (long)ND * 1024, flag);
    ConvTab tab;
    // NOTE: rg_root before rg_w so [root; W_0..W_7] is contiguous = [2304, N] GEMM B
    const int widx[14] = {6, 8, 10, 12, 14, 15, 16, 19, 18, 22, 21, 24, 26, 27};
    const int wn[14]   = {1024*512, 512*256, 64*128, 128*256, 256*128, 128, 128,
                          256*256, 8*256*256, 256*128, 8*256*128, 128*64, 64*2, 2};
    float* wf[14]; u16* wb[14];
    {
        size_t o = 0;
        for (int i = 0; i < 14; i++) {
            tab.src[i]  = d_in[widx[i]];
            tab.dst[i]  = Wpool + o;
            tab.dstB[i] = WpoolB + o;
            tab.n[i]    = wn[i];
            wf[i] = Wpool + o; wb[i] = WpoolB + o;
            o += (size_t)wn[i];
        }
    }
    conv_all<<<dim3(32, 14), 256, 0, stream>>>(tab, flag);
    float *att_w1c = wf[4], *att_b1c = wf[5], *att_w2c = wf[6];
    float *lin1_wc = wf[11], *lin2_wc = wf[12], *lin2_bc = wf[13];

    // ---- transposed bf16 weights for gemm_bt (one batched launch) ----
    u16* T_fpw1  = WpoolT;                        // [512,1024]
    u16* T_fpw2  = T_fpw1 + (size_t)512 * 1024;   // [256,512]
    u16* T_gcnw1 = T_fpw2 + (size_t)256 * 512;    // [128,64]
    u16* T_gcnw2 = T_gcnw1 + (size_t)128 * 64;    // [256,128]
    u16* T_w1    = T_gcnw2 + (size_t)256 * 128;   // [256,2304]
    u16* T_w2    = T_w1 + (size_t)256 * 2304;     // [128,2304]
    TransTab tt;
    tt.src[0] = wb[0]; tt.dst[0] = T_fpw1;  tt.K[0] = 1024; tt.N[0] = 512;
    tt.src[1] = wb[1]; tt.dst[1] = T_fpw2;  tt.K[1] = 512;  tt.N[1] = 256;
    tt.src[2] = wb[2]; tt.dst[2] = T_gcnw1; tt.K[2] = 64;   tt.N[2] = 128;
    tt.src[3] = wb[3]; tt.dst[3] = T_gcnw2; tt.K[3] = 128;  tt.N[3] = 256;
    tt.src[4] = wb[7]; tt.dst[4] = T_w1;    tt.K[4] = 2304; tt.N[4] = 256;
    tt.src[5] = wb[9]; tt.dst[5] = T_w2;    tt.K[5] = 2304; tt.N[5] = 128;
    transpose6<<<dim3(72, 16, 6), 256, 0, stream>>>(tt);

    // ---- CSR builds (batched) ----
    filli<<<512, 256, 0, stream>>>((int*)z0, (long)(z1 - z0) / 4, 0);
    kg_key2<<<2048, 256, 0, stream>>>(kg_dst, kg_et, EK, key2);
    {
        KV3 hv;
        hv.key[0] = mol_dst;   hv.h[0] = mdeg;  hv.n[0] = EM;
        hv.key[1] = key2;      hv.h[1] = kdeg2; hv.n[1] = EK;
        hv.key[2] = mol_batch; hv.h[2] = pdeg;  hv.n[2] = NM;
        hist3<<<dim3(2048, 3), 256, 0, stream>>>(hv);
    }
    dinv_from_deg<<<512, 256, 0, stream>>>(mdeg, dinv, NM);
    {
        Scan3 sc;
        sc.in[0] = mdeg;  sc.out[0] = moff;  sc.n[0] = NM;
        sc.in[1] = kdeg2; sc.out[1] = koff2; sc.n[1] = NSEG;
        sc.in[2] = pdeg;  sc.out[2] = poff;  sc.n[2] = ND;
        for (int s = 0; s < 3; s++) { sc.bt[s] = sbt3 + s * 64; sc.bo[s] = sbo3 + s * 64; }
        scan_bsum3<<<dim3(32, 3), 1024, 0, stream>>>(sc);
        scan_tiny3<<<3, 64, 0, stream>>>(sc);
        scan_final3<<<dim3(32, 3), 1024, 0, stream>>>(sc);
    }
    {
        Bin3 bv;
        bv.key[0] = mol_dst;   bv.off[0] = moff;  bv.cur[0] = mcur;  bv.bins[0] = mbins; bv.n[0] = EM;
        bv.key[1] = key2;      bv.off[1] = koff2; bv.cur[1] = kcur2; bv.bins[1] = kbins; bv.n[1] = EK;
        bv.key[2] = mol_batch; bv.off[2] = poff;  bv.cur[2] = pcur;  bv.bins[2] = pbins; bv.n[2] = NM;
        bin3<<<dim3(2048, 3), 256, 0, stream>>>(bv);
    }
    flatten2<<<dim3(2048, 2), 256, 0, stream>>>(mbins, mol_src, mol_dst, dinv, ebM,
                                                kbins, kg_src, ebK2, EM);

    // stats finalize helper: partials (nblk rows x N cols) -> mean + rsqrt(var)
    auto reduceNto = [&](int nblk, int N, float invM, float* s1o, float* s2o) {
        colstats_reduce_v3<<<N / 64, 1024, 0, stream>>>(part1, part2, nblk, N,
                                                        invM, s1o, s2o);
    };

    // ---------- fingerprint MLP branch (MFMA, stats fused, bf16 chain) ------
    conv_dual_b16<<<2048, 256, 0, stream>>>(fp_data, Xfb, (long)ND * 1024, flag);
    gemm_bt<u16, 2, true><<<dim3(64, 4), 256, 0, stream>>>(
        Xfb, 1024, T_fpw1, 1024, fp1b, 512, ND, 512, 1024, part1, part2, 512);
    reduceNto(64, 512, 1.0f / ND, stats, stats + 512);
    bn_apply_b16v<<<2048, 256, 0, stream>>>((u32*)fp1b, (long)ND * 256, 255,
                                            stats, stats + 512);
    gemm_bt<float, 1, true><<<dim3(64, 4), 256, 0, stream>>>(
        fp1b, 512, T_fpw2, 512, fpb, 256, ND, 256, 512, part1, part2, 256);
    reduceNto(64, 256, 1.0f / ND, statsFP, statsFP + 512);
    // fpb BN+ReLU is fused into attention_fuse (statsFP survives mol phase)

    // ---------- mol GCN layer 1: bf16-convert, aggregate-then-GEMM ----------
    conv_molx<<<2048, 256, 0, stream>>>((const float*)mol_x, XB, (long)NM * 16, flag);
    mol_agg_in<<<32768, 256, 0, stream>>>(mol_x, XB, flag, dinv, moff, ebM, NM, Xagg);
    gemm_bt<u16, 2, true><<<dim3(2048, 1), 256, 0, stream>>>(
        Xagg, 64, T_gcnw1, 64, G1, 128, NM, 128, 64, part1, part2, 128);
    reduceNto(2048, 128, 1.0f / NM, stats, stats + 512);
    // BN+ReLU fused into mol_agg128_bn below (G1 has no other consumer)

    // ---------- mol GCN layer 2: fused-BN aggregate, 2-half GEMM + pool -----
    mol_agg128_bn<<<32768, 256, 0, stream>>>(G1, dinv, moff, ebM, NM,
                                             stats, stats + 512, G1A);
    // ebM (gout) dead past this point; G1 (REG1) dead -> H2 reuses it
    for (int h = 0; h < 2; h++) {
        gemm_bt<u16, 2, true><<<dim3(2048, 1), 256, 0, stream>>>(
            G1A, 128, T_gcnw2 + (size_t)h * 128 * 128, 128, H2, 128, NM, 128, 128,
            part1, part2, 128);
        reduceNto(2048, 128, 1.0f / NM, stats, stats + 512);
        pool128<<<1024, 256, 0, stream>>>(H2, poff, pbins, ND,
                                          stats, stats + 512, gout, h * 128);
    }

    // ---------- attention fusion (fpb BN fused; bf16 out into xb) ----------
    attention_fuse<<<ND, 128, 0, stream>>>(gout, fpb, statsFP, statsFP + 512,
                                           att_w1c, att_b1c, att_w2c,
                                           xb, out_beta);
    conv_dual_b16<<<512, 256, 0, stream>>>(d_in[17], xb + (long)ND * 256,
                                           (long)NGENE * 256, flag);

    // ---------- RGCN layer 1 (256 -> 256): preagg2(+copy) + K=2304 GEMM -----
    kg_preagg2<<<divup((long)(NSEG + NKG) * 64, 256), 256, 0, stream>>>(
        xb, koff2, ebK2, NSEG, NKG, AGGX);
    gemm_bt<u16, 2, true><<<dim3(divup(NKG, 64), 2), 256, 0, stream>>>(
        AGGX, 2304, T_w1, 2304, x2b, 256, NKG, 256, 2304, part1, part2, 256);
    reduceNto(divup(NKG, 64), 256, 1.0f / NKG, stats, stats + 512);
    bn_apply_b16v<<<1024, 256, 0, stream>>>((u32*)x2b, (long)NKG * 128, 127,
                                            stats, stats + 512);

    // ---------- RGCN layer 2 (256 -> 128): preagg2(+copy) + K=2304 GEMM -----
    kg_preagg2<<<divup((long)(NSEG + NKG) * 64, 256), 256, 0, stream>>>(
        x2b, koff2, ebK2, NSEG, NKG, AGGX);
    gemm_bt<float, 1, true><<<dim3(divup(NKG, 64), 2), 256, 0, stream>>>(
        AGGX, 2304, T_w2, 2304, x3, 128, NKG, 128, 2304, part1, part2, 128);
    reduceNto(divup(NKG, 64), 128, 1.0f / NKG, stats, stats + 512);
    bn_apply<<<2048, 256, 0, stream>>>(x3, (long)NKG * 128, 127, stats, stats + 512);

    // ---------- classifier head ----------
    gemm64<<<dim3(divup(NKG, 64), 1, 1), 256, 0, stream>>>(
        x3, 128, lin1_wc, 64, x4, 64, NKG, 64, 128);
    colstats_f32_v2<<<NBLK_STATS, 256, 0, stream>>>(x4, NKG, 64, part1, part2);
    reduceNto(NBLK_STATS, 64, 1.0f / NKG, stats, stats + 512);
    logits_out_bn<<<divup(NKG, 256), 256, 0, stream>>>(x4, stats, stats + 512,
                                                       lin2_wc, lin2_bc, out_ls, NKG);
}

// Round 12
// 918.209 us; speedup vs baseline: 1.5590x; 1.0745x over previous
//
#include <hip/hip_runtime.h>
#include <hip/hip_bf16.h>
#include <cstdint>

typedef __hip_bfloat16 bf16;
typedef unsigned short u16;
typedef unsigned int u32;
typedef __attribute__((ext_vector_type(8))) short short8;
typedef __attribute__((ext_vector_type(4))) float f32x4;

__device__ __forceinline__ float tofloat(float x){ return x; }
__device__ __forceinline__ float tofloat(bf16 x){ return __bfloat162float(x); }
__device__ __forceinline__ float b2f(u16 a){ return __uint_as_float(((unsigned)a) << 16); }
__device__ __forceinline__ u16 f2b(float f){           // round-to-nearest-even
    unsigned u = __float_as_uint(f);
    return (u16)((u + 0x7FFFu + ((u >> 16) & 1u)) >> 16);
}

static inline int divup(long a, long b){ return (int)((a + b - 1) / b); }

#define NBLK_STATS 256

// ---------------- input dtype detection -------------------------------------
__global__ void zero_int(int* p){ *p = 0; }

__global__ void detect_f32(const u16* __restrict__ h, long n, int* flag)
{
    long i = (long)blockIdx.x * blockDim.x + threadIdx.x;
    long st = (long)gridDim.x * blockDim.x;
    int c = 0;
    for (; i < n; i += st)
        if (((h[i] >> 7) & 0xFF) == 0xFF) c++;
    if (c) atomicAdd(flag, c);
}

// convert all weights: fp32 pool + bf16 pool in one launch
struct ConvTab { const void* src[14]; float* dst[14]; u16* dstB[14]; int n[14]; };

__global__ void conv_all(ConvTab t, const int* __restrict__ flagp)
{
    bool f32 = (*flagp != 0);
    int seg = blockIdx.y;
    const void* s = t.src[seg];
    float* d = t.dst[seg];
    u16*   dB = t.dstB[seg];
    int n = t.n[seg];
    long i = (long)blockIdx.x * blockDim.x + threadIdx.x;
    long st = (long)gridDim.x * blockDim.x;
    for (; i < n; i += st) {
        float v = f32 ? ((const float*)s)[i] : tofloat(((const bf16*)s)[i]);
        d[i] = v; dB[i] = f2b(v);
    }
}

__global__ void conv_dual_b16(const void* __restrict__ src, u16* __restrict__ dst,
                              long n, const int* __restrict__ flagp)
{
    bool f32 = (*flagp != 0);
    long i = (long)blockIdx.x * blockDim.x + threadIdx.x;
    long st = (long)gridDim.x * blockDim.x;
    for (; i < n; i += st)
        dst[i] = f32 ? f2b(((const float*)src)[i]) : ((const u16*)src)[i];
}

// convert mol_x fp32 -> bf16 copy (only when input is fp32); vectorized x4
__global__ void conv_molx(const float* __restrict__ src, u16* __restrict__ dst,
                          long n4, const int* __restrict__ flagp)
{
    if (*flagp == 0) return;   // input already bf16; agg reads original
    long i = (long)blockIdx.x * blockDim.x + threadIdx.x;
    long st = (long)gridDim.x * blockDim.x;
    for (; i < n4; i += st) {
        float4 v = ((const float4*)src)[i];
        ushort4 o;
        o.x = f2b(v.x); o.y = f2b(v.y); o.z = f2b(v.z); o.w = f2b(v.w);
        ((ushort4*)dst)[i] = o;
    }
}

// batched bf16 transpose (6 matrices): dst[n*K + k] = src[k*N + n]
struct TransTab { const u16* src[6]; u16* dst[6]; int K[6]; int N[6]; };

__global__ __launch_bounds__(256)
void transpose6(TransTab t)
{
    int s = blockIdx.z;
    int K = t.K[s], N = t.N[s];
    int k0 = blockIdx.x * 32, n0 = blockIdx.y * 32;
    if (k0 >= K || n0 >= N) return;
    const u16* src = t.src[s];
    u16* dst = t.dst[s];
    __shared__ u16 tl[32][33];
    int x = threadIdx.x & 31, y = threadIdx.x >> 5;   // y in 0..7
    for (int yy = y; yy < 32; yy += 8) {
        int k = k0 + yy, n = n0 + x;
        tl[yy][x] = (k < K && n < N) ? src[(long)k * N + n] : (u16)0;
    }
    __syncthreads();
    for (int yy = y; yy < 32; yy += 8) {
        int n = n0 + yy, k = k0 + x;
        if (n < N && k < K) dst[(long)n * K + k] = tl[x][yy];
    }
}

// ---------------- batched CSR build -----------------------------------------
struct KV2 { const int* key[2]; int* h[2]; long n[2]; };

__global__ void hist2(KV2 t)
{
    int s = blockIdx.y;
    const int* key = t.key[s]; int* h = t.h[s]; long n = t.n[s];
    long i = (long)blockIdx.x * blockDim.x + threadIdx.x;
    long st = (long)gridDim.x * blockDim.x;
    for (; i < n; i += st) atomicAdd(&h[key[i]], 1);
}

struct Scan2 { const int* in[2]; int* out[2]; int* bt[2]; int* bo[2]; int n[2]; };

__global__ __launch_bounds__(1024)
void scan_bsum2(Scan2 t)
{
    int s = blockIdx.y;
    int n = t.n[s];
    int nb = (n + 4095) >> 12;
    if ((int)blockIdx.x >= nb) return;
    const int* in = t.in[s];
    __shared__ int sh[1024];
    int tid = threadIdx.x;
    int i0 = blockIdx.x * 4096 + tid * 4;
    int acc = 0;
#pragma unroll
    for (int k = 0; k < 4; k++) { int idx = i0 + k; acc += (idx < n) ? in[idx] : 0; }
    sh[tid] = acc;
    __syncthreads();
    for (int off = 512; off > 0; off >>= 1) {
        if (tid < off) sh[tid] += sh[tid + off];
        __syncthreads();
    }
    if (tid == 0) t.bt[s][blockIdx.x] = sh[0];
}

__global__ void scan_tiny2(Scan2 t)
{
    int s = blockIdx.x;
    if (threadIdx.x != 0) return;
    int nb = (t.n[s] + 4095) >> 12;
    const int* bt = t.bt[s]; int* bo = t.bo[s];
    int c = 0;
    for (int b = 0; b < nb; b++) { bo[b] = c; c += bt[b]; }
    bo[nb] = c;
}

__global__ __launch_bounds__(1024)
void scan_final2(Scan2 t)
{
    int s = blockIdx.y;
    int n = t.n[s];
    int nb = (n + 4095) >> 12;
    if ((int)blockIdx.x >= nb) return;
    const int* in = t.in[s]; int* out = t.out[s]; const int* bo = t.bo[s];
    __shared__ int buf[1024];
    int tid = threadIdx.x;
    int i0 = blockIdx.x * 4096 + tid * 4;
    int v[4]; int acc = 0;
#pragma unroll
    for (int k = 0; k < 4; k++) {
        int idx = i0 + k;
        v[k] = (idx < n) ? in[idx] : 0;
        acc += v[k];
    }
    buf[tid] = acc;
    __syncthreads();
    for (int off = 1; off < 1024; off <<= 1) {
        int tv = (tid >= off) ? buf[tid - off] : 0;
        __syncthreads();
        buf[tid] += tv;
        __syncthreads();
    }
    int excl = buf[tid] - acc + bo[blockIdx.x];
#pragma unroll
    for (int k = 0; k < 4; k++) {
        int idx = i0 + k;
        if (idx < n) out[idx] = excl;
        excl += v[k];
    }
    if (blockIdx.x == 0 && tid == 0) out[n] = bo[nb];
}

// direct-payload binning (fused flatten):
// seg 0 (mol): pos = moff[dst]+cur++, ebM[pos] = {src, bits(dinv[src]*dinv[dst])}
// seg 1 (kg):  pos = koff2[key2]+cur++, ebK[pos] = src
__global__ void bin_direct(const int* __restrict__ mdst, const int* __restrict__ msrc,
                           const int* __restrict__ moff, int* __restrict__ mcur,
                           const float* __restrict__ dinv, int2* __restrict__ ebM,
                           const int* __restrict__ kkey, const int* __restrict__ ksrc,
                           const int* __restrict__ koff, int* __restrict__ kcur,
                           int* __restrict__ ebK, long E)
{
    long i = (long)blockIdx.x * blockDim.x + threadIdx.x;
    long st = (long)gridDim.x * blockDim.x;
    if (blockIdx.y == 0) {
        for (; i < E; i += st) {
            int d = mdst[i], sn = msrc[i];
            int pos = moff[d] + atomicAdd(&mcur[d], 1);
            ebM[pos] = make_int2(sn, __float_as_int(dinv[sn] * dinv[d]));
        }
    } else {
        for (; i < E; i += st) {
            int k = kkey[i];
            int pos = koff[k] + atomicAdd(&kcur[k], 1);
            ebK[pos] = ksrc[i];
        }
    }
}

// KG segment key: dst*8 + et  (segments = (node, relation) pairs)
__global__ void kg_key2(const int* __restrict__ dst, const int* __restrict__ et,
                        long E, int* __restrict__ key)
{
    long i = (long)blockIdx.x * blockDim.x + threadIdx.x;
    long st = (long)gridDim.x * blockDim.x;
    for (; i < E; i += st) key[i] = dst[i] * 8 + et[i];
}

// poff[d] = lower_bound(batch, d) -- batch is sorted
__global__ void poff_bsearch(const int* __restrict__ batch, int NMn, int NDn,
                             int* __restrict__ poff)
{
    int d = blockIdx.x * blockDim.x + threadIdx.x;
    if (d > NDn) return;
    int lo = 0, hi = NMn;
    while (lo < hi) { int mid = (lo + hi) >> 1; if (batch[mid] < d) lo = mid + 1; else hi = mid; }
    poff[d] = lo;
}

__global__ void filli(int* p, long n, int v)
{
    long i = (long)blockIdx.x * blockDim.x + threadIdx.x;
    long st = (long)gridDim.x * blockDim.x;
    for (; i < n; i += st) p[i] = v;
}

__global__ void dinv_from_deg(const int* __restrict__ deg, float* __restrict__ dinv, long n)
{
    long i = (long)blockIdx.x * blockDim.x + threadIdx.x;
    long st = (long)gridDim.x * blockDim.x;
    for (; i < n; i += st) dinv[i] = rsqrtf((float)(deg[i] + 1));
}

// ---------------- MFMA GEMM (B pre-transposed): C = A @ B, bf16, fp32 acc ---
// A [M,K] lda; BT [N,K] ldbt. Tile 64 x (NBLK*64). Register-prefetch pipeline.
// STATS: fuse per-column sum/sumsq of the STORED values into the epilogue.
template<typename TC, int NBLK, bool STATS>
__global__ __launch_bounds__(256)
void gemm_bt(const u16* __restrict__ A, int lda,
             const u16* __restrict__ BT, int ldbt,
             TC* __restrict__ C, int ldc,
             int M, int N, int K,
             float* __restrict__ SP1, float* __restrict__ SP2, int Ntot)
{
    __shared__ __align__(16) u16 As[64][40];          // [m][k]
    __shared__ __align__(16) u16 Bs[NBLK * 64][40];   // [n][k]
    __shared__ float st1[NBLK * 64], st2[NBLK * 64];
    const int tid = threadIdx.x;
    const int lane = tid & 63, wave = tid >> 6;
    const int l15 = lane & 15, quad = lane >> 4;
    const int wm = (wave & 1) * 32, wn = (wave >> 1) * 32;
    const int row0 = blockIdx.x * 64, col0 = blockIdx.y * (NBLK * 64);
    const int arow = tid >> 2, ak = (tid & 3) * 8;
    const int aok = row0 + arow < M;

    if (STATS && tid < NBLK * 64) { st1[tid] = 0.f; st2[tid] = 0.f; }

    f32x4 acc[NBLK][2][2];
#pragma unroll
    for (int t = 0; t < NBLK; t++)
#pragma unroll
        for (int i = 0; i < 2; i++)
#pragma unroll
            for (int j = 0; j < 2; j++)
#pragma unroll
                for (int r = 0; r < 4; r++) acc[t][i][j][r] = 0.f;

    const u16* pa = A + (long)(row0 + arow) * lda + ak;
    const u16* pb[NBLK];
#pragma unroll
    for (int t = 0; t < NBLK; t++)
        pb[t] = BT + (long)(col0 + t * 64 + arow) * ldbt + ak;

    ushort4 ra0 = {0,0,0,0}, ra1 = {0,0,0,0};
    ushort4 rb0[NBLK], rb1[NBLK];
    if (aok) { ra0 = *(const ushort4*)pa; ra1 = *(const ushort4*)(pa + 4); }
#pragma unroll
    for (int t = 0; t < NBLK; t++) {
        rb0[t] = *(const ushort4*)pb[t];
        rb1[t] = *(const ushort4*)(pb[t] + 4);
    }

    for (int k0 = 0; k0 < K; k0 += 32) {
        *(ushort4*)&As[arow][ak]     = ra0;
        *(ushort4*)&As[arow][ak + 4] = ra1;
#pragma unroll
        for (int t = 0; t < NBLK; t++) {
            *(ushort4*)&Bs[t * 64 + arow][ak]     = rb0[t];
            *(ushort4*)&Bs[t * 64 + arow][ak + 4] = rb1[t];
        }
        __syncthreads();
        if (k0 + 32 < K) {   // issue next-step loads; retire under MFMAs
            if (aok) {
                ra0 = *(const ushort4*)(pa + k0 + 32);
                ra1 = *(const ushort4*)(pa + k0 + 36);
            }
#pragma unroll
            for (int t = 0; t < NBLK; t++) {
                rb0[t] = *(const ushort4*)(pb[t] + k0 + 32);
                rb1[t] = *(const ushort4*)(pb[t] + k0 + 36);
            }
        }
        short8 a0 = *(const short8*)&As[wm + l15][quad * 8];
        short8 a1 = *(const short8*)&As[wm + 16 + l15][quad * 8];
#pragma unroll
        for (int t = 0; t < NBLK; t++) {
            short8 b0 = *(const short8*)&Bs[t * 64 + wn + l15][quad * 8];
            short8 b1 = *(const short8*)&Bs[t * 64 + wn + 16 + l15][quad * 8];
            acc[t][0][0] = __builtin_amdgcn_mfma_f32_16x16x32_bf16(a0, b0, acc[t][0][0], 0, 0, 0);
            acc[t][0][1] = __builtin_amdgcn_mfma_f32_16x16x32_bf16(a0, b1, acc[t][0][1], 0, 0, 0);
            acc[t][1][0] = __builtin_amdgcn_mfma_f32_16x16x32_bf16(a1, b0, acc[t][1][0], 0, 0, 0);
            acc[t][1][1] = __builtin_amdgcn_mfma_f32_16x16x32_bf16(a1, b1, acc[t][1][1], 0, 0, 0);
        }
        __syncthreads();
    }
#pragma unroll
    for (int t = 0; t < NBLK; t++)
#pragma unroll
        for (int j = 0; j < 2; j++) {
            float s = 0.f, q = 0.f;
#pragma unroll
            for (int i = 0; i < 2; i++)
#pragma unroll
                for (int r = 0; r < 4; r++) {
                    int row = row0 + wm + i * 16 + quad * 4 + r;
                    int col = col0 + t * 64 + wn + j * 16 + l15;
                    float v = acc[t][i][j][r];
                    float y;
                    if constexpr (sizeof(TC) == 2) {
                        u16 h = f2b(v);
                        if (row < M) ((u16*)C)[(long)row * ldc + col] = h;
                        y = b2f(h);
                    } else {
                        if (row < M) ((float*)C)[(long)row * ldc + col] = v;
                        y = v;
                    }
                    if (STATS) { s += y; q += y * y; }
                }
            if (STATS) {
                s += __shfl_xor(s, 16); s += __shfl_xor(s, 32);
                q += __shfl_xor(q, 16); q += __shfl_xor(q, 32);
                if (quad == 0) {
                    atomicAdd(&st1[t * 64 + wn + j * 16 + l15], s);
                    atomicAdd(&st2[t * 64 + wn + j * 16 + l15], q);
                }
            }
        }
    if (STATS) {
        __syncthreads();
        if (tid < NBLK * 64) {
            long off = (long)blockIdx.x * Ntot + (long)blockIdx.y * (NBLK * 64) + tid;
            SP1[off] = st1[tid];
            SP2[off] = st2[tid];
        }
    }
}

// ---------------- vector GEMM (fp32, small) ---------------------------------
__global__ __launch_bounds__(256)
void gemm64(const float* __restrict__ A, int lda,
            const float* __restrict__ B, int ldb,
            float* __restrict__ C, int ldc,
            int M, int N, int K)
{
    __shared__ float As[16][68];
    __shared__ float Bs[16][68];
    const int tid = threadIdx.x;
    const int row0 = blockIdx.x * 64, col0 = blockIdx.y * 64;
    float acc[4][4];
#pragma unroll
    for (int i = 0; i < 4; i++)
#pragma unroll
        for (int j = 0; j < 4; j++) acc[i][j] = 0.f;
    const int ar = tid >> 2, ak = (tid & 3) * 4;
    const int bk = tid >> 4, bc = (tid & 15) * 4;
    const int ty4 = (tid >> 4) * 4, tx4 = (tid & 15) * 4;
    for (int k0 = 0; k0 < K; k0 += 16) {
        {
            int row = row0 + ar;
            float4 v = make_float4(0.f, 0.f, 0.f, 0.f);
            if (row < M) v = *(const float4*)(A + (long)row * lda + k0 + ak);
            As[ak + 0][ar] = v.x; As[ak + 1][ar] = v.y;
            As[ak + 2][ar] = v.z; As[ak + 3][ar] = v.w;
        }
        {
            int c = col0 + bc;
            float4 v = make_float4(0.f, 0.f, 0.f, 0.f);
            if (c < N) v = *(const float4*)(B + (long)(k0 + bk) * ldb + c);
            *(float4*)&Bs[bk][bc] = v;
        }
        __syncthreads();
#pragma unroll
        for (int k = 0; k < 16; k++) {
            float4 a = *(const float4*)&As[k][ty4];
            float4 b = *(const float4*)&Bs[k][tx4];
            acc[0][0] += a.x * b.x; acc[0][1] += a.x * b.y; acc[0][2] += a.x * b.z; acc[0][3] += a.x * b.w;
            acc[1][0] += a.y * b.x; acc[1][1] += a.y * b.y; acc[1][2] += a.y * b.z; acc[1][3] += a.y * b.w;
            acc[2][0] += a.z * b.x; acc[2][1] += a.z * b.y; acc[2][2] += a.z * b.z; acc[2][3] += a.z * b.w;
            acc[3][0] += a.w * b.x; acc[3][1] += a.w * b.y; acc[3][2] += a.w * b.z; acc[3][3] += a.w * b.w;
        }
        __syncthreads();
    }
    int c = col0 + tx4;
#pragma unroll
    for (int i = 0; i < 4; i++) {
        int r = row0 + ty4 + i;
        if (r < M && c < N)
            *(float4*)&C[(long)r * ldc + c] =
                make_float4(acc[i][0], acc[i][1], acc[i][2], acc[i][3]);
    }
}

// ---------------- batch-norm stats ------------------------------------------
// fp32 matrix [M, N] -> partials (for gemm64 output only)
__global__ __launch_bounds__(256)
void colstats_f32_v2(const float* __restrict__ X, int M, int N,
                     float* __restrict__ p1, float* __restrict__ p2)
{
    __shared__ float sh1[1024], sh2[1024];
    int tid = threadIdx.x;
    int ncg = N >> 2;
    int cg  = tid & (ncg - 1);
    int rg  = tid / ncg;
    int nrg = 256 / ncg;
    float s0=0,s1=0,s2=0,s3=0, q0=0,q1=0,q2=0,q3=0;
    const float* base = X + 4 * cg;
    for (long row = (long)blockIdx.x * nrg + rg; row < M; row += (long)gridDim.x * nrg) {
        float4 v = *(const float4*)(base + row * (long)N);
        s0 += v.x; q0 += v.x * v.x; s1 += v.y; q1 += v.y * v.y;
        s2 += v.z; q2 += v.z * v.z; s3 += v.w; q3 += v.w * v.w;
    }
    float4* S1 = (float4*)sh1; float4* S2 = (float4*)sh2;
    S1[tid] = make_float4(s0, s1, s2, s3);
    S2[tid] = make_float4(q0, q1, q2, q3);
    __syncthreads();
    for (int off = nrg >> 1; off > 0; off >>= 1) {
        if (rg < off) {
            float4 a = S1[tid], b = S1[tid + off * ncg];
            S1[tid] = make_float4(a.x + b.x, a.y + b.y, a.z + b.z, a.w + b.w);
            float4 c = S2[tid], d = S2[tid + off * ncg];
            S2[tid] = make_float4(c.x + d.x, c.y + d.y, c.z + d.z, c.w + d.w);
        }
        __syncthreads();
    }
    if (rg == 0) {
        *(float4*)&p1[(long)blockIdx.x * N + 4 * cg] = S1[tid];
        *(float4*)&p2[(long)blockIdx.x * N + 4 * cg] = S2[tid];
    }
}

// reduce partials (nblk up to 2048): grid N/64 blocks x 1024 thr (16 segments)
__global__ __launch_bounds__(1024)
void colstats_reduce_v3(const float* __restrict__ p1, const float* __restrict__ p2,
                        int nblk, int N, float invM,
                        float* __restrict__ s1o, float* __restrict__ s2o)
{
    __shared__ float sh1[1024], sh2[1024];
    int tid = threadIdx.x;
    int col = blockIdx.x * 64 + (tid & 63);
    int seg = tid >> 6;                       // 0..15
    float a = 0.f, c = 0.f;
    for (int b = seg; b < nblk; b += 16) {
        a += p1[(long)b * N + col];
        c += p2[(long)b * N + col];
    }
    sh1[tid] = a; sh2[tid] = c;
    __syncthreads();
    for (int off = 8; off > 0; off >>= 1) {
        if (seg < off) {
            sh1[tid] += sh1[tid + off * 64];
            sh2[tid] += sh2[tid + off * 64];
        }
        __syncthreads();
    }
    if (seg == 0) {
        float mean = sh1[tid] * invM;
        float var  = fmaxf(sh2[tid] * invM - mean * mean, 0.f);
        s1o[col] = mean;
        s2o[col] = rsqrtf(var + 1e-5f);
    }
}

__global__ void bn_apply(float* X, long total, int mask,
                         const float* __restrict__ s1, const float* __restrict__ s2)
{
    long i = (long)blockIdx.x * blockDim.x + threadIdx.x;
    long st = (long)gridDim.x * blockDim.x;
    for (; i < total; i += st) {
        int j = (int)(i & mask);
        X[i] = fmaxf((X[i] - s1[j]) * s2[j], 0.f);
    }
}

// BN+ReLU in place on bf16 contiguous [M, NC]; u32 words (2 cols each)
__global__ void bn_apply_b16v(u32* __restrict__ X, long n2, int maskHalf,
                              const float* __restrict__ s1, const float* __restrict__ s2)
{
    long i = (long)blockIdx.x * blockDim.x + threadIdx.x;
    long st = (long)gridDim.x * blockDim.x;
    for (; i < n2; i += st) {
        u32 v = X[i];
        int f = (int)(i & maskHalf) * 2;
        float y0 = fmaxf((b2f((u16)(v & 0xFFFF)) - s1[f])     * s2[f],     0.f);
        float y1 = fmaxf((b2f((u16)(v >> 16))    - s1[f + 1]) * s2[f + 1], 0.f);
        X[i] = (u32)f2b(y0) | ((u32)f2b(y1) << 16);
    }
}

// ---------------- CSR aggregation (no atomics) ------------------------------
__global__ __launch_bounds__(256)
void mol_agg_in(const void* __restrict__ Xraw, const u16* __restrict__ Xcvt,
                const int* __restrict__ flagp, const float* __restrict__ dinv,
                const int* __restrict__ off, const int2* __restrict__ eb,
                int NM, u16* __restrict__ out)
{
    const u16* X = (*flagp != 0) ? Xcvt : (const u16*)Xraw;
    int wid  = (int)(((long)blockIdx.x * 256 + threadIdx.x) >> 6);
    int lane = threadIdx.x & 63;
    if (wid >= NM) return;
    float dv = dinv[wid];
    float acc = b2f(X[(long)wid * 64 + lane]) * dv * dv;
    int j = off[wid], j1 = off[wid + 1];
    for (; j + 3 < j1; j += 4) {
        int2 e0 = eb[j], e1 = eb[j + 1], e2 = eb[j + 2], e3 = eb[j + 3];
        float v0 = b2f(X[(long)e0.x * 64 + lane]);
        float v1 = b2f(X[(long)e1.x * 64 + lane]);
        float v2 = b2f(X[(long)e2.x * 64 + lane]);
        float v3 = b2f(X[(long)e3.x * 64 + lane]);
        acc += v0 * __int_as_float(e0.y) + v1 * __int_as_float(e1.y)
             + v2 * __int_as_float(e2.y) + v3 * __int_as_float(e3.y);
    }
    for (; j < j1; j++) {
        int2 e = eb[j];
        acc += b2f(X[(long)e.x * 64 + lane]) * __int_as_float(e.y);
    }
    out[(long)wid * 64 + lane] = f2b(acc);
}

// mol layer-2 aggregation with FUSED BN+ReLU on gathered G1 values.
__global__ __launch_bounds__(256)
void mol_agg128_bn(const u16* __restrict__ G, const float* __restrict__ dinv,
                   const int* __restrict__ off, const int2* __restrict__ eb,
                   int NM, const float* __restrict__ s1, const float* __restrict__ s2,
                   u16* __restrict__ out)
{
    int wid  = (int)(((long)blockIdx.x * 256 + threadIdx.x) >> 6);
    int lane = threadIdx.x & 63;
    if (wid >= NM) return;
    const float m0 = s1[2 * lane],     r0 = s2[2 * lane];
    const float m1 = s1[2 * lane + 1], r1 = s2[2 * lane + 1];
    float dv = dinv[wid], dv2 = dv * dv;
    u32 u = *(const u32*)(G + (long)wid * 128 + 2 * lane);
    float a0 = fmaxf((b2f((u16)(u & 0xFFFF)) - m0) * r0, 0.f) * dv2;
    float a1 = fmaxf((b2f((u16)(u >> 16))    - m1) * r1, 0.f) * dv2;
    int j = off[wid], j1 = off[wid + 1];
    for (; j + 3 < j1; j += 4) {
        int2 e0 = eb[j], e1 = eb[j + 1], e2 = eb[j + 2], e3 = eb[j + 3];
        u32 v0 = *(const u32*)(G + (long)e0.x * 128 + 2 * lane);
        u32 v1 = *(const u32*)(G + (long)e1.x * 128 + 2 * lane);
        u32 v2 = *(const u32*)(G + (long)e2.x * 128 + 2 * lane);
        u32 v3 = *(const u32*)(G + (long)e3.x * 128 + 2 * lane);
        float n0 = __int_as_float(e0.y), n1 = __int_as_float(e1.y);
        float n2 = __int_as_float(e2.y), n3 = __int_as_float(e3.y);
        a0 += fmaxf((b2f((u16)(v0 & 0xFFFF)) - m0) * r0, 0.f) * n0
            + fmaxf((b2f((u16)(v1 & 0xFFFF)) - m0) * r0, 0.f) * n1
            + fmaxf((b2f((u16)(v2 & 0xFFFF)) - m0) * r0, 0.f) * n2
            + fmaxf((b2f((u16)(v3 & 0xFFFF)) - m0) * r0, 0.f) * n3;
        a1 += fmaxf((b2f((u16)(v0 >> 16)) - m1) * r1, 0.f) * n0
            + fmaxf((b2f((u16)(v1 >> 16)) - m1) * r1, 0.f) * n1
            + fmaxf((b2f((u16)(v2 >> 16)) - m1) * r1, 0.f) * n2
            + fmaxf((b2f((u16)(v3 >> 16)) - m1) * r1, 0.f) * n3;
    }
    for (; j < j1; j++) {
        int2 e = eb[j];
        u32 v = *(const u32*)(G + (long)e.x * 128 + 2 * lane);
        float n = __int_as_float(e.y);
        a0 += fmaxf((b2f((u16)(v & 0xFFFF)) - m0) * r0, 0.f) * n;
        a1 += fmaxf((b2f((u16)(v >> 16))    - m1) * r1, 0.f) * n;
    }
    u32 o = (u32)f2b(a0) | ((u32)f2b(a1) << 16);
    *(u32*)(out + (long)wid * 128 + 2 * lane) = o;
}

// RGCN pre-aggregation v2 + fused x-row copy:
// segs [0, NSEG): per-(node, relation) mean into AGGX cols 256+r*256
// segs [NSEG, NSEG+NKG): copy xin row -> AGGX cols 0:255
__global__ __launch_bounds__(256)
void kg_preagg2(const u16* __restrict__ xin, const int* __restrict__ off2,
                const int* __restrict__ eb, int NSEG, int NKG, u16* __restrict__ aggx)
{
    int seg  = (int)(((long)blockIdx.x * 256 + threadIdx.x) >> 6);
    int lane = threadIdx.x & 63;
    const int c4 = 4 * lane;
    if (seg >= NSEG + NKG) return;
    if (seg >= NSEG) {
        int node = seg - NSEG;
        *(ushort4*)(aggx + (long)node * 2304 + c4) =
            *(const ushort4*)(xin + (long)node * 256 + c4);
        return;
    }
    int node = seg >> 3, r = seg & 7;
    int j0 = off2[seg], j1 = off2[seg + 1];
    float a0 = 0.f, a1 = 0.f, a2 = 0.f, a3 = 0.f;
    int j = j0;
    for (; j + 3 < j1; j += 4) {
        int s0 = eb[j], s1 = eb[j + 1], s2 = eb[j + 2], s3 = eb[j + 3];
        ushort4 v0 = *(const ushort4*)(xin + (long)s0 * 256 + c4);
        ushort4 v1 = *(const ushort4*)(xin + (long)s1 * 256 + c4);
        ushort4 v2 = *(const ushort4*)(xin + (long)s2 * 256 + c4);
        ushort4 v3 = *(const ushort4*)(xin + (long)s3 * 256 + c4);
        a0 += b2f(v0.x) + b2f(v1.x) + b2f(v2.x) + b2f(v3.x);
        a1 += b2f(v0.y) + b2f(v1.y) + b2f(v2.y) + b2f(v3.y);
        a2 += b2f(v0.z) + b2f(v1.z) + b2f(v2.z) + b2f(v3.z);
        a3 += b2f(v0.w) + b2f(v1.w) + b2f(v2.w) + b2f(v3.w);
    }
    for (; j < j1; j++) {
        ushort4 v = *(const ushort4*)(xin + (long)eb[j] * 256 + c4);
        a0 += b2f(v.x); a1 += b2f(v.y); a2 += b2f(v.z); a3 += b2f(v.w);
    }
    float nrm = 1.0f / fmaxf((float)(j1 - j0), 1.0f);
    ushort4 o;
    o.x = f2b(a0 * nrm); o.y = f2b(a1 * nrm);
    o.z = f2b(a2 * nrm); o.w = f2b(a3 * nrm);
    *(ushort4*)(aggx + (long)node * 2304 + 256 + (r << 8) + c4) = o;
}

// mean-pool bf16 [NM,128]; mol_batch sorted -> member rows are CONTIGUOUS
// [off[d], off[d+1]); fused BN+ReLU; u32 loads (2 cols/lane)
__global__ __launch_bounds__(256)
void pool128(const u16* __restrict__ g, const int* __restrict__ off, int ND,
             const float* __restrict__ s1, const float* __restrict__ s2,
             float* __restrict__ gout, int c0out)
{
    int wid  = (int)(((long)blockIdx.x * 256 + threadIdx.x) >> 6);
    int lane = threadIdx.x & 63;
    if (wid >= ND) return;
    const float m0 = s1[2 * lane],     r0 = s2[2 * lane];
    const float m1 = s1[2 * lane + 1], r1 = s2[2 * lane + 1];
    int j0 = off[wid], j1 = off[wid + 1];
    float a0 = 0.f, a1 = 0.f;
    for (int j = j0; j < j1; j++) {
        u32 v = *(const u32*)(g + (long)j * 128 + 2 * lane);
        a0 += fmaxf((b2f((u16)(v & 0xFFFF)) - m0) * r0, 0.f);
        a1 += fmaxf((b2f((u16)(v >> 16))    - m1) * r1, 0.f);
    }
    float inv = 1.0f / fmaxf((float)(j1 - j0), 1.0f);
    *(float2*)(gout + (long)wid * 256 + c0out + 2 * lane) =
        make_float2(a0 * inv, a1 * inv);
}

// ---------------- attention fusion (fp BN fused; bf16 emb out) --------------
__global__ void attention_fuse(const float* __restrict__ go, const float* __restrict__ fpv,
                               const float* __restrict__ fs1, const float* __restrict__ fs2,
                               const float* __restrict__ W1, const float* __restrict__ B1,
                               const float* __restrict__ W2,
                               u16* __restrict__ embb, float* __restrict__ beta_out)
{
    int d = blockIdx.x;
    int t = threadIdx.x;
    __shared__ float z[2][256];
    __shared__ float red[128];
    for (int c = t; c < 256; c += 128) {
        z[0][c] = go[(long)d * 256 + c];
        z[1][c] = fmaxf((fpv[(long)d * 256 + c] - fs1[c]) * fs2[c], 0.f);
    }
    __syncthreads();
    float s[2];
    for (int v = 0; v < 2; v++) {
        float acc = B1[t];
        for (int k = 0; k < 256; k++) acc += z[v][k] * W1[k * 128 + t];
        red[t] = tanhf(acc) * W2[t];
        __syncthreads();
        for (int off = 64; off > 0; off >>= 1) {
            if (t < off) red[t] += red[t + off];
            __syncthreads();
        }
        s[v] = red[0];
        __syncthreads();
    }
    float m = fmaxf(s[0], s[1]);
    float e0 = expf(s[0] - m), e1 = expf(s[1] - m);
    float inv = 1.0f / (e0 + e1);
    float b0 = e0 * inv, b1 = e1 * inv;
    for (int c = t; c < 256; c += 128)
        embb[(long)d * 256 + c] = f2b(b0 * z[0][c] + b1 * z[1][c]);
    if (t == 0) {
        beta_out[d * 2 + 0] = b0;
        beta_out[d * 2 + 1] = b1;
    }
}

// ---------------- final linear + log_softmax, fused BN on x4 ----------------
__global__ void logits_out_bn(const float* __restrict__ x4,
                              const float* __restrict__ s1, const float* __restrict__ s2,
                              const float* __restrict__ w, const float* __restrict__ b,
                              float* __restrict__ out, int NKG)
{
    int i = blockIdx.x * blockDim.x + threadIdx.x;
    if (i >= NKG) return;
    float a0 = b[0], a1 = b[1];
    for (int k = 0; k < 64; k++) {
        float v = fmaxf((x4[(long)i * 64 + k] - s1[k]) * s2[k], 0.f);
        a0 += v * w[k * 2 + 0];
        a1 += v * w[k * 2 + 1];
    }
    float m = fmaxf(a0, a1);
    float lse = m + logf(expf(a0 - m) + expf(a1 - m));
    out[i * 2 + 0] = a0 - lse;
    out[i * 2 + 1] = a1 - lse;
}

// ============================================================================
extern "C" void kernel_launch(void* const* d_in, const int* in_sizes, int n_in,
                              void* d_out, int out_size, void* d_ws, size_t ws_size,
                              hipStream_t stream)
{
    (void)in_sizes; (void)n_in; (void)out_size; (void)ws_size;
    const int ND = 4096, NM = 131072, NKG = 9510, NGENE = 5414;
    const long EM = 524288, EK = 524288;
    const int NSEG = 8 * NKG;   // 76080 (node, relation) segments

    const void* fp_data = d_in[0];
    const void* mol_x   = d_in[1];
    const int*  mol_batch = (const int*)d_in[2];
    const int*  mol_ei  = (const int*)d_in[3];
    const int*  kg_ei   = (const int*)d_in[4];
    const int*  kg_et   = (const int*)d_in[5];

    const int* mol_src = mol_ei;
    const int* mol_dst = mol_ei + EM;
    const int* kg_src  = kg_ei;
    const int* kg_dst  = kg_ei + EK;

    float* out_ls   = (float*)d_out;          // [9510,2] fp32
    float* out_beta = (float*)d_out + 19020;  // [4096,2,1] fp32

    // ---- workspace carve ----
    char* wp = (char*)d_ws;
    auto carve = [&](size_t bytes) { char* p = wp; wp += (bytes + 255) & ~(size_t)255; return p; };
    float* stats   = (float*)carve(4096);
    float* statsFP = (float*)carve(4096);     // fpb stats (must survive mol phase)
    int*   flag  = (int*)carve(256);
    float* dinv  = (float*)carve((size_t)NM * 4);
    float* part1 = (float*)carve((size_t)2048 * 128 * 4);   // 1 MB (gemm stats partials)
    float* part2 = (float*)carve((size_t)2048 * 128 * 4);
    int*   sbt2  = (int*)carve(2 * 64 * 4);
    int*   sbo2  = (int*)carve(2 * 64 * 4);
    float* Wpool = (float*)carve((size_t)1630000 * 4);     // fp32 weights
    u16*   WpoolB= (u16*)carve((size_t)1630000 * 2);       // bf16 weights
    u16*   WpoolT= (u16*)carve((size_t)1600000 * 2);       // bf16 transposed gemm weights
    float* fpb   = (float*)carve((size_t)ND * 256 * 4);
    float* gout  = (float*)carve((size_t)ND * 256 * 4);
    int*   key2  = (int*)carve((size_t)EK * 4);            // kg seg keys
    int*   koff2 = (int*)carve((size_t)(NSEG + 1) * 4);
    int*   ebK2  = (int*)carve((size_t)EK * 4);            // kg src table (direct bin)
    int*   poff  = (int*)carve((size_t)(ND + 1) * 4);
    // zero-span
    char*  z0    = wp;
    int* kdeg2 = (int*)carve((size_t)NSEG * 4);
    int* kcur2 = (int*)carve((size_t)NSEG * 4);
    int* mdeg = (int*)carve((size_t)NM * 4);
    int* mcur = (int*)carve((size_t)NM * 4);
    char*  z1    = wp;
    int* moff = (int*)carve((size_t)(NM + 1) * 4);
    char*  REG1  = carve((size_t)NM * 128 * 2);            // 33.6 MB
    char*  REG2  = carve((size_t)NM * 128 * 2);            // 33.6 MB  (contiguous with HB)
    u16*   HB    = (u16*)carve((size_t)NM * 64 * 2);       // 16.8 MB

    // phase views
    u16*   XB  = (u16*)REG1;                   // mol pre: [NM,64] bf16 converted input
    u16*   G1  = (u16*)REG1;                   // mol: [NM,128] bf16 (raw gemm out)
    u16*   H2  = (u16*)REG1;                   // mol L2: [NM,128] bf16 half-output (G1 dead)
    // rgcn chain in REG1:
    u16*   x2b = (u16*)REG1;                   // [NKG,256] bf16
    float* x3  = (float*)REG1 + (size_t)NKG * 512;  // [NKG,128] f32
    float* x4  = x3 + (size_t)NKG * 128;       // [NKG,64]  f32
    u16*   xb  = (u16*)(x4 + (size_t)NKG * 64);// [NKG,256] bf16 (fits REG1)
    u16*   Xfb = (u16*)REG2;                   // fp: [4096,1024] bf16
    u16*   G1A = (u16*)REG2;                   // mol: [NM,128] bf16 aggregated
    u16*   AGGX= (u16*)REG2;                   // rgcn: [NKG,2304] bf16 (43.8 MB, REG2+HB)
    u16*   fp1b = HB;                          // fp: [4096,512] bf16 (gemm1 direct out)
    u16*   Xagg = HB;                          // mol L1: [NM,64] bf16
    // mol edge payloads live in gout (4 MB = EM*8 exactly); dead before pool
    int2* ebM  = (int2*)gout;

    // ---- dtype detect + weight conversion (fp32 + bf16 pools) ----
    zero_int<<<1, 1, 0, stream>>>(flag);
    detect_f32<<<1024, 256, 0, stream>>>((const u16*)fp_data, (long)ND * 1024, flag);
    ConvTab tab;
    // NOTE: rg_root before rg_w so [root; W_0..W_7] is contiguous = [2304, N] GEMM B
    const int widx[14] = {6, 8, 10, 12, 14, 15, 16, 19, 18, 22, 21, 24, 26, 27};
    const int wn[14]   = {1024*512, 512*256, 64*128, 128*256, 256*128, 128, 128,
                          256*256, 8*256*256, 256*128, 8*256*128, 128*64, 64*2, 2};
    float* wf[14]; u16* wb[14];
    {
        size_t o = 0;
        for (int i = 0; i < 14; i++) {
            tab.src[i]  = d_in[widx[i]];
            tab.dst[i]  = Wpool + o;
            tab.dstB[i] = WpoolB + o;
            tab.n[i]    = wn[i];
            wf[i] = Wpool + o; wb[i] = WpoolB + o;
            o += (size_t)wn[i];
        }
    }
    conv_all<<<dim3(32, 14), 256, 0, stream>>>(tab, flag);
    float *att_w1c = wf[4], *att_b1c = wf[5], *att_w2c = wf[6];
    float *lin1_wc = wf[11], *lin2_wc = wf[12], *lin2_bc = wf[13];

    // ---- transposed bf16 weights for gemm_bt (one batched launch) ----
    u16* T_fpw1  = WpoolT;                        // [512,1024]
    u16* T_fpw2  = T_fpw1 + (size_t)512 * 1024;   // [256,512]
    u16* T_gcnw1 = T_fpw2 + (size_t)256 * 512;    // [128,64]
    u16* T_gcnw2 = T_gcnw1 + (size_t)128 * 64;    // [256,128]
    u16* T_w1    = T_gcnw2 + (size_t)256 * 128;   // [256,2304]
    u16* T_w2    = T_w1 + (size_t)256 * 2304;     // [128,2304]
    TransTab tt;
    tt.src[0] = wb[0]; tt.dst[0] = T_fpw1;  tt.K[0] = 1024; tt.N[0] = 512;
    tt.src[1] = wb[1]; tt.dst[1] = T_fpw2;  tt.K[1] = 512;  tt.N[1] = 256;
    tt.src[2] = wb[2]; tt.dst[2] = T_gcnw1; tt.K[2] = 64;   tt.N[2] = 128;
    tt.src[3] = wb[3]; tt.dst[3] = T_gcnw2; tt.K[3] = 128;  tt.N[3] = 256;
    tt.src[4] = wb[7]; tt.dst[4] = T_w1;    tt.K[4] = 2304; tt.N[4] = 256;
    tt.src[5] = wb[9]; tt.dst[5] = T_w2;    tt.K[5] = 2304; tt.N[5] = 128;
    transpose6<<<dim3(72, 16, 6), 256, 0, stream>>>(tt);

    // ---- CSR builds (batched, direct-payload) ----
    filli<<<512, 256, 0, stream>>>((int*)z0, (long)(z1 - z0) / 4, 0);
    kg_key2<<<2048, 256, 0, stream>>>(kg_dst, kg_et, EK, key2);
    {
        KV2 hv;
        hv.key[0] = mol_dst; hv.h[0] = mdeg;  hv.n[0] = EM;
        hv.key[1] = key2;    hv.h[1] = kdeg2; hv.n[1] = EK;
        hist2<<<dim3(2048, 2), 256, 0, stream>>>(hv);
    }
    dinv_from_deg<<<512, 256, 0, stream>>>(mdeg, dinv, NM);
    poff_bsearch<<<divup(ND + 1, 256), 256, 0, stream>>>(mol_batch, NM, ND, poff);
    {
        Scan2 sc;
        sc.in[0] = mdeg;  sc.out[0] = moff;  sc.n[0] = NM;
        sc.in[1] = kdeg2; sc.out[1] = koff2; sc.n[1] = NSEG;
        for (int s = 0; s < 2; s++) { sc.bt[s] = sbt2 + s * 64; sc.bo[s] = sbo2 + s * 64; }
        scan_bsum2<<<dim3(32, 2), 1024, 0, stream>>>(sc);
        scan_tiny2<<<2, 64, 0, stream>>>(sc);
        scan_final2<<<dim3(32, 2), 1024, 0, stream>>>(sc);
    }
    bin_direct<<<dim3(2048, 2), 256, 0, stream>>>(mol_dst, mol_src, moff, mcur,
                                                  dinv, ebM,
                                                  key2, kg_src, koff2, kcur2,
                                                  ebK2, EM);

    // stats finalize helper: partials (nblk rows x N cols) -> mean + rsqrt(var)
    auto reduceNto = [&](int nblk, int N, float invM, float* s1o, float* s2o) {
        colstats_reduce_v3<<<N / 64, 1024, 0, stream>>>(part1, part2, nblk, N,
                                                        invM, s1o, s2o);
    };

    // ---------- fingerprint MLP branch (MFMA, stats fused, bf16 chain) ------
    conv_dual_b16<<<2048, 256, 0, stream>>>(fp_data, Xfb, (long)ND * 1024, flag);
    gemm_bt<u16, 2, true><<<dim3(64, 4), 256, 0, stream>>>(
        Xfb, 1024, T_fpw1, 1024, fp1b, 512, ND, 512, 1024, part1, part2, 512);
    reduceNto(64, 512, 1.0f / ND, stats, stats + 512);
    bn_apply_b16v<<<2048, 256, 0, stream>>>((u32*)fp1b, (long)ND * 256, 255,
                                            stats, stats + 512);
    gemm_bt<float, 1, true><<<dim3(64, 4), 256, 0, stream>>>(
        fp1b, 512, T_fpw2, 512, fpb, 256, ND, 256, 512, part1, part2, 256);
    reduceNto(64, 256, 1.0f / ND, statsFP, statsFP + 512);
    // fpb BN+ReLU is fused into attention_fuse (statsFP survives mol phase)

    // ---------- mol GCN layer 1: bf16-convert, aggregate-then-GEMM ----------
    conv_molx<<<2048, 256, 0, stream>>>((const float*)mol_x, XB, (long)NM * 16, flag);
    mol_agg_in<<<32768, 256, 0, stream>>>(mol_x, XB, flag, dinv, moff, ebM, NM, Xagg);
    gemm_bt<u16, 2, true><<<dim3(2048, 1), 256, 0, stream>>>(
        Xagg, 64, T_gcnw1, 64, G1, 128, NM, 128, 64, part1, part2, 128);
    reduceNto(2048, 128, 1.0f / NM, stats, stats + 512);
    // BN+ReLU fused into mol_agg128_bn below (G1 has no other consumer)

    // ---------- mol GCN layer 2: fused-BN aggregate, 2-half GEMM + pool -----
    mol_agg128_bn<<<32768, 256, 0, stream>>>(G1, dinv, moff, ebM, NM,
                                             stats, stats + 512, G1A);
    // ebM (gout) dead past this point; G1 (REG1) dead -> H2 reuses it
    for (int h = 0; h < 2; h++) {
        gemm_bt<u16, 2, true><<<dim3(2048, 1), 256, 0, stream>>>(
            G1A, 128, T_gcnw2 + (size_t)h * 128 * 128, 128, H2, 128, NM, 128, 128,
            part1, part2, 128);
        reduceNto(2048, 128, 1.0f / NM, stats, stats + 512);
        pool128<<<1024, 256, 0, stream>>>(H2, poff, ND,
                                          stats, stats + 512, gout, h * 128);
    }

    // ---------- attention fusion (fpb BN fused; bf16 out into xb) ----------
    attention_fuse<<<ND, 128, 0, stream>>>(gout, fpb, statsFP, statsFP + 512,
                                           att_w1c, att_b1c, att_w2c,
                                           xb, out_beta);
    conv_dual_b16<<<512, 256, 0, stream>>>(d_in[17], xb + (long)ND * 256,
                                           (long)NGENE * 256, flag);

    // ---------- RGCN layer 1 (256 -> 256): preagg2(+copy) + K=2304 GEMM -----
    kg_preagg2<<<divup((long)(NSEG + NKG) * 64, 256), 256, 0, stream>>>(
        xb, koff2, ebK2, NSEG, NKG, AGGX);
    gemm_bt<u16, 2, true><<<dim3(divup(NKG, 64), 2), 256, 0, stream>>>(
        AGGX, 2304, T_w1, 2304, x2b, 256, NKG, 256, 2304, part1, part2, 256);
    reduceNto(divup(NKG, 64), 256, 1.0f / NKG, stats, stats + 512);
    bn_apply_b16v<<<1024, 256, 0, stream>>>((u32*)x2b, (long)NKG * 128, 127,
                                            stats, stats + 512);

    // ---------- RGCN layer 2 (256 -> 128): preagg2(+copy) + K=2304 GEMM -----
    kg_preagg2<<<divup((long)(NSEG + NKG) * 64, 256), 256, 0, stream>>>(
        x2b, koff2, ebK2, NSEG, NKG, AGGX);
    gemm_bt<float, 1, true><<<dim3(divup(NKG, 64), 2), 256, 0, stream>>>(
        AGGX, 2304, T_w2, 2304, x3, 128, NKG, 128, 2304, part1, part2, 128);
    reduceNto(divup(NKG, 64), 128, 1.0f / NKG, stats, stats + 512);
    bn_apply<<<2048, 256, 0, stream>>>(x3, (long)NKG * 128, 127, stats, stats + 512);

    // ---------- classifier head ----------
    gemm64<<<dim3(divup(NKG, 64), 1, 1), 256, 0, stream>>>(
        x3, 128, lin1_wc, 64, x4, 64, NKG, 64, 128);
    colstats_f32_v2<<<NBLK_STATS, 256, 0, stream>>>(x4, NKG, 64, part1, part2);
    reduceNto(NBLK_STATS, 64, 1.0f / NKG, stats, stats + 512);
    logits_out_bn<<<divup(NKG, 256), 256, 0, stream>>>(x4, stats, stats + 512,
                                                       lin2_wc, lin2_bc, out_ls, NKG);
}